// Round 1
// baseline (4066.063 us; speedup 1.0000x reference)
//
#include <hip/hip_runtime.h>
#include <hip/hip_bf16.h>
#include <math.h>

typedef __hip_bfloat16 bf16;

constexpr int Bn  = 4;
constexpr int Cn  = 512;
constexpr int Hn  = 128;
constexpr int Wn  = 128;
constexpr int Nn  = Hn * Wn;   // 16384
constexpr int CQn = 64;
constexpr int CIn = 256;

__device__ __forceinline__ float bf2f(bf16 v){ return __bfloat162float(v); }
__device__ __forceinline__ bf16  f2bf(float v){ return __float2bfloat16(v); }

// ============================ stage 0 ============================

// out[b*Nn+n] = sum_c w[b*wstride + c] * x[(b*Cn+c)*Nn + n]
__global__ __launch_bounds__(256) void k_dotc(const float* __restrict__ x,
                                              const float* __restrict__ w,
                                              int wstride,
                                              float* __restrict__ out){
  int t = blockIdx.x * 256 + threadIdx.x;      // over B*Nn
  int b = t >> 14;
  const float* wp = w + (size_t)b * wstride;
  const float* xp = x + (size_t)b * Cn * Nn + (t & (Nn - 1));
  float acc = 0.f;
  #pragma unroll 8
  for (int c = 0; c < Cn; ++c) acc += wp[c] * xp[(size_t)c * Nn];
  out[t] = acc;
}

// out[bc] = scale * sum_n x[bc*Nn+n]
__global__ __launch_bounds__(256) void k_rowmean(const float* __restrict__ x,
                                                 float* __restrict__ out,
                                                 float scale){
  int bc = blockIdx.x;
  const float* xp = x + (size_t)bc * Nn;
  float acc = 0.f;
  for (int n = threadIdx.x; n < Nn; n += 256) acc += xp[n];
  for (int o = 32; o > 0; o >>= 1) acc += __shfl_down(acc, o);
  __shared__ float red[4];
  if ((threadIdx.x & 63) == 0) red[threadIdx.x >> 6] = acc;
  __syncthreads();
  if (threadIdx.x == 0) out[bc] = (red[0] + red[1] + red[2] + red[3]) * scale;
}

// avg[b,ci] = sum_c w_q_left[ci,c]*xbar[b,c];  u[b,c] = sum_ci avg[b,ci]*w_v_left[ci,c]
__global__ __launch_bounds__(256) void k_avg_u(const float* __restrict__ w_q_left,
                                               const float* __restrict__ w_v_left,
                                               const float* __restrict__ xbar,
                                               float* __restrict__ u){
  __shared__ float avg_s[Bn * CIn];
  for (int i = threadIdx.x; i < Bn * CIn; i += 256){
    int b = i >> 8, ci = i & (CIn - 1);
    const float* wp = w_q_left + (size_t)ci * Cn;
    const float* xb = xbar + b * Cn;
    float a = 0.f;
    for (int c = 0; c < Cn; ++c) a += wp[c] * xb[c];
    avg_s[i] = a;
  }
  __syncthreads();
  for (int i = threadIdx.x; i < Bn * Cn; i += 256){
    int b = i >> 9, c = i & (Cn - 1);
    const float* as = avg_s + b * CIn;
    float a = 0.f;
    for (int ci = 0; ci < CIn; ++ci) a += as[ci] * w_v_left[(size_t)ci * Cn + c];
    u[i] = a;
  }
}

// per-b max & sumexp over Nn values
__global__ __launch_bounds__(1024) void k_stats(const float* __restrict__ vv,
                                                float* __restrict__ stats){
  int b = blockIdx.x;
  const float* pp = vv + (size_t)b * Nn;
  int t = threadIdx.x;
  float m = -3.4e38f;
  for (int n = t; n < Nn; n += 1024) m = fmaxf(m, pp[n]);
  for (int o = 32; o > 0; o >>= 1) m = fmaxf(m, __shfl_down(m, o));
  __shared__ float red[16];
  int wid = t >> 6, lid = t & 63;
  if (lid == 0) red[wid] = m;
  __syncthreads();
  if (t == 0){
    float q = red[0];
    for (int i = 1; i < 16; i++) q = fmaxf(q, red[i]);
    red[0] = q;
  }
  __syncthreads();
  m = red[0];
  __syncthreads();
  float s = 0.f;
  for (int n = t; n < Nn; n += 1024) s += expf(pp[n] - m);
  for (int o = 32; o > 0; o >>= 1) s += __shfl_down(s, o);
  if (lid == 0) red[wid] = s;
  __syncthreads();
  if (t == 0){
    float q = 0.f;
    for (int i = 0; i < 16; i++) q += red[i];
    stats[b * 2]     = m;
    stats[b * 2 + 1] = q;
  }
}

// weighted[b,c] = sum_n x[b,c,n]*exp(l[b,n]-m)/den
__global__ __launch_bounds__(256) void k_weighted(const float* __restrict__ x,
                                                  const float* __restrict__ logits,
                                                  const float* __restrict__ stats,
                                                  float* __restrict__ out){
  int bc = blockIdx.x;
  int b = bc >> 9;
  const float* xp = x + (size_t)bc * Nn;
  const float* lp = logits + (size_t)b * Nn;
  float m = stats[b * 2], den = stats[b * 2 + 1];
  float acc = 0.f;
  for (int n = threadIdx.x; n < Nn; n += 256) acc += xp[n] * expf(lp[n] - m);
  for (int o = 32; o > 0; o >>= 1) acc += __shfl_down(acc, o);
  __shared__ float red[4];
  if ((threadIdx.x & 63) == 0) red[threadIdx.x >> 6] = acc;
  __syncthreads();
  if (threadIdx.x == 0) out[bc] = (red[0] + red[1] + red[2] + red[3]) / den;
}

// ctx[b,ci] = sum_c w_v_right[ci,c]*weighted[b,c];
// mch[b,o] = sigmoid(sum_ci w_up[o,ci]*ctx[b,ci] + b_up[o])
__global__ __launch_bounds__(256) void k_mch(const float* __restrict__ w_v_right,
                                             const float* __restrict__ w_up,
                                             const float* __restrict__ b_up,
                                             const float* __restrict__ weighted,
                                             float* __restrict__ mch){
  __shared__ float ctx_s[Bn * CIn];
  for (int i = threadIdx.x; i < Bn * CIn; i += 256){
    int b = i >> 8, ci = i & (CIn - 1);
    const float* wp = w_v_right + (size_t)ci * Cn;
    const float* wg = weighted + b * Cn;
    float a = 0.f;
    for (int c = 0; c < Cn; ++c) a += wp[c] * wg[c];
    ctx_s[i] = a;
  }
  __syncthreads();
  for (int i = threadIdx.x; i < Bn * Cn; i += 256){
    int b = i >> 9, o = i & (Cn - 1);
    const float* cs = ctx_s + b * CIn;
    float a = b_up[o];
    for (int ci = 0; ci < CIn; ++ci) a += w_up[(size_t)o * CIn + ci] * cs[ci];
    mch[i] = 1.f / (1.f + expf(-a));
  }
}

// msp[b,n] = sigmoid(exp(l-m)/den)
__global__ __launch_bounds__(256) void k_msp(const float* __restrict__ lg,
                                             const float* __restrict__ stats,
                                             float* __restrict__ msp){
  int t = blockIdx.x * 256 + threadIdx.x;
  int b = t >> 14;
  float v = expf(lg[t] - stats[b * 2]) / stats[b * 2 + 1];
  msp[t] = 1.f / (1.f + expf(-v));
}

// cc = x * mch[b,c] ; cs = x * msp[b,n]
__global__ __launch_bounds__(256) void k_apply(const float* __restrict__ x,
                                               const float* __restrict__ mch,
                                               const float* __restrict__ msp,
                                               float* __restrict__ cc,
                                               float* __restrict__ cs){
  size_t t = (size_t)blockIdx.x * 256 + threadIdx.x;
  int bc = (int)(t >> 14);
  int b  = bc >> 9;
  int n  = (int)(t & (Nn - 1));
  float xv = x[t];
  cc[t] = xv * mch[bc];
  cs[t] = xv * msp[b * Nn + n];
}

// ============================ cross attention ============================

// q/k projection, 128-n tile, all 64 outputs; bf16 out, std layout [b,o,h,w]
__global__ __launch_bounds__(256) void k_qk(const float* __restrict__ in,
                                            const float* __restrict__ wq,
                                            const float* __restrict__ bq,
                                            const float* __restrict__ wk,
                                            const float* __restrict__ bk,
                                            bf16* __restrict__ q,
                                            bf16* __restrict__ k){
  __shared__ float xs[64 * 128];
  __shared__ float wqs[64 * 64];
  __shared__ float wks[64 * 64];
  int nt = blockIdx.x, b = blockIdx.y;
  int n0 = nt * 128;
  int t = threadIdx.x;
  int og = t >> 5, ng = t & 31;
  float accq[8][4], acck[8][4];
  #pragma unroll
  for (int j = 0; j < 8; j++)
    #pragma unroll
    for (int i = 0; i < 4; i++){ accq[j][i] = 0.f; acck[j][i] = 0.f; }
  for (int c0 = 0; c0 < Cn; c0 += 64){
    for (int i = t; i < 8192; i += 256){
      int cl = i >> 7, nl = i & 127;
      xs[i] = in[((size_t)(b * Cn + c0 + cl)) * Nn + n0 + nl];
    }
    for (int i = t; i < 4096; i += 256){
      int ol = i >> 6, cl = i & 63;
      wqs[i] = wq[(size_t)ol * Cn + c0 + cl];
      wks[i] = wk[(size_t)ol * Cn + c0 + cl];
    }
    __syncthreads();
    for (int c = 0; c < 64; ++c){
      float xv[4];
      #pragma unroll
      for (int i = 0; i < 4; i++) xv[i] = xs[c * 128 + ng + 32 * i];
      #pragma unroll
      for (int j = 0; j < 8; j++){
        float wqv = wqs[(og * 8 + j) * 64 + c];
        float wkv = wks[(og * 8 + j) * 64 + c];
        #pragma unroll
        for (int i = 0; i < 4; i++){
          accq[j][i] += wqv * xv[i];
          acck[j][i] += wkv * xv[i];
        }
      }
    }
    __syncthreads();
  }
  #pragma unroll
  for (int j = 0; j < 8; j++){
    int o = og * 8 + j;
    float bqv = bq[o], bkv = bk[o];
    #pragma unroll
    for (int i = 0; i < 4; i++){
      size_t idx = ((size_t)(b * CQn + o)) * Nn + n0 + ng + 32 * i;
      q[idx] = f2bf(accq[j][i] + bqv);
      k[idx] = f2bf(acck[j][i] + bkv);
    }
  }
}

// v projection: c-tile 128 x n-tile 64
__global__ __launch_bounds__(256) void k_v(const float* __restrict__ in,
                                           const float* __restrict__ wv,
                                           const float* __restrict__ bv,
                                           bf16* __restrict__ v){
  __shared__ float xs[64 * 64];
  __shared__ float wvs[128 * 64];
  int ct = blockIdx.x, nt = blockIdx.y, b = blockIdx.z;
  int cbase = ct * 128, n0 = nt * 64;
  int t = threadIdx.x;
  int og = t >> 4, ng = t & 15;
  float acc[8][4];
  #pragma unroll
  for (int j = 0; j < 8; j++)
    #pragma unroll
    for (int i = 0; i < 4; i++) acc[j][i] = 0.f;
  for (int c0 = 0; c0 < Cn; c0 += 64){
    for (int i = t; i < 4096; i += 256){
      int cl = i >> 6, nl = i & 63;
      xs[i] = in[((size_t)(b * Cn + c0 + cl)) * Nn + n0 + nl];
    }
    for (int i = t; i < 8192; i += 256){
      int ol = i >> 6, cl = i & 63;
      wvs[i] = wv[(size_t)(cbase + ol) * Cn + c0 + cl];
    }
    __syncthreads();
    for (int c = 0; c < 64; ++c){
      float xv[4];
      #pragma unroll
      for (int i = 0; i < 4; i++) xv[i] = xs[c * 64 + ng + 16 * i];
      #pragma unroll
      for (int j = 0; j < 8; j++){
        float wvv = wvs[(og * 8 + j) * 64 + c];
        #pragma unroll
        for (int i = 0; i < 4; i++) acc[j][i] += wvv * xv[i];
      }
    }
    __syncthreads();
  }
  #pragma unroll
  for (int j = 0; j < 8; j++){
    int c = cbase + og * 8 + j;
    float bvv = bv[c];
    #pragma unroll
    for (int i = 0; i < 4; i++)
      v[((size_t)(b * Cn + c)) * Nn + n0 + ng + 16 * i] = f2bf(acc[j][i] + bvv);
  }
}

// [b,c,h,w] -> [b,w,c,h] (bf16), 32x32 tiles
__global__ __launch_bounds__(256) void k_trans(const bf16* __restrict__ in,
                                               bf16* __restrict__ out,
                                               int CH){
  __shared__ bf16 tile[32][33];
  int tl = blockIdx.x, c = blockIdx.y, b = blockIdx.z;
  int th = tl >> 2, tw = tl & 3;
  int h0 = th * 32, w0 = tw * 32;
  int t = threadIdx.x;
  const bf16* ip = in + ((size_t)(b * CH + c)) * Nn;
  #pragma unroll
  for (int kk = 0; kk < 4; ++kk){
    int idx = t + kk * 256;
    int hl = idx >> 5, wl = idx & 31;
    tile[hl][wl] = ip[(h0 + hl) * Wn + w0 + wl];
  }
  __syncthreads();
  #pragma unroll
  for (int kk = 0; kk < 4; ++kk){
    int idx = t + kk * 256;
    int wl = idx >> 5, hl = idx & 31;
    out[((size_t)(b * Wn + w0 + wl) * CH + c) * Hn + h0 + hl] = tile[hl][wl];
  }
}

// e_h[h,g] = sum_c qT[b,w,c,h]*kT[b,w,c,g], diag -> -1e30
__global__ __launch_bounds__(256) void k_eh(const bf16* __restrict__ qT,
                                            const bf16* __restrict__ kT,
                                            float* __restrict__ e){
  __shared__ float smem[16384];
  float* qs = smem;
  float* ks = smem + 8192;
  int w = blockIdx.x, b = blockIdx.y;
  int t = threadIdx.x;
  const bf16* qp = qT + (size_t)(b * Wn + w) * CQn * Hn;
  const bf16* kp = kT + (size_t)(b * Wn + w) * CQn * Hn;
  for (int i = t; i < 8192; i += 256){ qs[i] = bf2f(qp[i]); ks[i] = bf2f(kp[i]); }
  __syncthreads();
  int hg = t >> 3, gg = t & 7;
  float acc[4][16];
  #pragma unroll
  for (int i = 0; i < 4; i++)
    #pragma unroll
    for (int j = 0; j < 16; j++) acc[i][j] = 0.f;
  for (int c = 0; c < CQn; ++c){
    float qv[4], kv[16];
    #pragma unroll
    for (int i = 0; i < 4; i++) qv[i] = qs[c * 128 + hg * 4 + i];
    #pragma unroll
    for (int j = 0; j < 16; j++) kv[j] = ks[c * 128 + gg + 8 * j];
    #pragma unroll
    for (int i = 0; i < 4; i++)
      #pragma unroll
      for (int j = 0; j < 16; j++) acc[i][j] += qv[i] * kv[j];
  }
  __syncthreads();
  #pragma unroll
  for (int i = 0; i < 4; i++)
    #pragma unroll
    for (int j = 0; j < 16; j++)
      smem[(hg * 4 + i) * 128 + gg + 8 * j] = acc[i][j];
  __syncthreads();
  for (int kk = 0; kk < 64; ++kk){
    int idx = t + kk * 256;
    int h = idx >> 7, g = idx & 127;
    float val = (h == g) ? -1e30f : smem[idx];
    e[((size_t)(b * Hn + h) * Wn + w) * 256 + g] = val;
  }
}

// e_w[w,v] = sum_c q[b,c,h,w]*k[b,c,h,v]
__global__ __launch_bounds__(256) void k_ew(const bf16* __restrict__ q,
                                            const bf16* __restrict__ k,
                                            float* __restrict__ e){
  __shared__ float smem[16384];
  float* qs = smem;
  float* ks = smem + 8192;
  int h = blockIdx.x, b = blockIdx.y;
  int t = threadIdx.x;
  for (int i = t; i < 8192; i += 256){
    int c = i >> 7, wl = i & 127;
    size_t base = ((size_t)(b * CQn + c) * Hn + h) * Wn + wl;
    qs[i] = bf2f(q[base]);
    ks[i] = bf2f(k[base]);
  }
  __syncthreads();
  int wg = t >> 3, vg = t & 7;
  float acc[4][16];
  #pragma unroll
  for (int i = 0; i < 4; i++)
    #pragma unroll
    for (int j = 0; j < 16; j++) acc[i][j] = 0.f;
  for (int c = 0; c < CQn; ++c){
    float qv[4], kv[16];
    #pragma unroll
    for (int i = 0; i < 4; i++) qv[i] = qs[c * 128 + wg * 4 + i];
    #pragma unroll
    for (int j = 0; j < 16; j++) kv[j] = ks[c * 128 + vg + 8 * j];
    #pragma unroll
    for (int i = 0; i < 4; i++)
      #pragma unroll
      for (int j = 0; j < 16; j++) acc[i][j] += qv[i] * kv[j];
  }
  __syncthreads();
  #pragma unroll
  for (int i = 0; i < 4; i++)
    #pragma unroll
    for (int j = 0; j < 16; j++)
      smem[(wg * 4 + i) * 128 + vg + 8 * j] = acc[i][j];
  __syncthreads();
  for (int kk = 0; kk < 64; ++kk){
    int idx = t + kk * 256;
    int wr = idx >> 7, vc = idx & 127;
    e[((size_t)(b * Hn + h) * Wn + wr) * 256 + 128 + vc] = smem[idx];
  }
}

// softmax over 256 per row, in place; one wave per row
__global__ __launch_bounds__(256) void k_softmax(float* __restrict__ e){
  int wid = threadIdx.x >> 6, lid = threadIdx.x & 63;
  size_t row = (size_t)blockIdx.x * 4 + wid;
  float* p = e + row * 256;
  float v[4];
  #pragma unroll
  for (int i = 0; i < 4; i++) v[i] = p[lid + 64 * i];
  float m = fmaxf(fmaxf(v[0], v[1]), fmaxf(v[2], v[3]));
  for (int o = 32; o > 0; o >>= 1) m = fmaxf(m, __shfl_xor(m, o));
  float s = 0.f;
  #pragma unroll
  for (int i = 0; i < 4; i++){ v[i] = expf(v[i] - m); s += v[i]; }
  for (int o = 32; o > 0; o >>= 1) s += __shfl_xor(s, o);
  float inv = 1.f / s;
  #pragma unroll
  for (int i = 0; i < 4; i++) p[lid + 64 * i] = v[i] * inv;
}

// out_h: per (b,w): ohT[b,w,c,h] = sum_g att[b,h,w,g]*vT[b,w,c,g]
__global__ __launch_bounds__(256) void k_comb_h(const float* __restrict__ att,
                                                const bf16* __restrict__ vT,
                                                bf16* __restrict__ ohT){
  __shared__ bf16 Ab[128 * 129];
  __shared__ bf16 vsb[8192];
  int w = blockIdx.x, b = blockIdx.y;
  int t = threadIdx.x;
  for (int i = t; i < 16384; i += 256){
    int h = i >> 7, g = i & 127;
    Ab[h * 129 + g] = f2bf(att[((size_t)(b * Hn + h) * Wn + w) * 256 + g]);
  }
  const bf16* vp = vT + (size_t)(b * Wn + w) * Cn * Hn;
  int hg = t & 31, cg = t >> 5;
  for (int c0 = 0; c0 < Cn; c0 += 64){
    __syncthreads();
    for (int i = t; i < 8192; i += 256)
      vsb[i] = vp[(size_t)(c0 + (i >> 7)) * Hn + (i & 127)];
    __syncthreads();
    float acc[4][8];
    #pragma unroll
    for (int i = 0; i < 4; i++)
      #pragma unroll
      for (int j = 0; j < 8; j++) acc[i][j] = 0.f;
    for (int g = 0; g < 128; ++g){
      float av[4];
      #pragma unroll
      for (int i = 0; i < 4; i++) av[i] = bf2f(Ab[(hg + 32 * i) * 129 + g]);
      #pragma unroll
      for (int j = 0; j < 8; j++){
        float vvv = bf2f(vsb[(cg * 8 + j) * 128 + g]);
        #pragma unroll
        for (int i = 0; i < 4; i++) acc[i][j] += av[i] * vvv;
      }
    }
    #pragma unroll
    for (int j = 0; j < 8; j++){
      int c = c0 + cg * 8 + j;
      #pragma unroll
      for (int i = 0; i < 4; i++)
        ohT[((size_t)(b * Wn + w) * Cn + c) * Hn + hg + 32 * i] = f2bf(acc[i][j]);
    }
  }
}

// out_w: per (b,h): ow[b,c,h,w] = sum_v att[b,h,w,128+v]*vstd[b,c,h,v]
__global__ __launch_bounds__(256) void k_comb_w(const float* __restrict__ att,
                                                const bf16* __restrict__ v,
                                                bf16* __restrict__ ow){
  __shared__ bf16 Ab[128 * 129];
  __shared__ bf16 vsb[8192];
  int h = blockIdx.x, b = blockIdx.y;
  int t = threadIdx.x;
  for (int i = t; i < 16384; i += 256){
    int wl = i >> 7, vc = i & 127;
    Ab[wl * 129 + vc] = f2bf(att[((size_t)(b * Hn + h) * Wn + wl) * 256 + 128 + vc]);
  }
  int wg = t & 31, cg = t >> 5;
  for (int c0 = 0; c0 < Cn; c0 += 64){
    __syncthreads();
    for (int i = t; i < 8192; i += 256)
      vsb[i] = v[((size_t)(b * Cn + c0 + (i >> 7)) * Hn + h) * Wn + (i & 127)];
    __syncthreads();
    float acc[4][8];
    #pragma unroll
    for (int i = 0; i < 4; i++)
      #pragma unroll
      for (int j = 0; j < 8; j++) acc[i][j] = 0.f;
    for (int g = 0; g < 128; ++g){
      float av[4];
      #pragma unroll
      for (int i = 0; i < 4; i++) av[i] = bf2f(Ab[(wg + 32 * i) * 129 + g]);
      #pragma unroll
      for (int j = 0; j < 8; j++){
        float vvv = bf2f(vsb[(cg * 8 + j) * 128 + g]);
        #pragma unroll
        for (int i = 0; i < 4; i++) acc[i][j] += av[i] * vvv;
      }
    }
    #pragma unroll
    for (int j = 0; j < 8; j++){
      int c = c0 + cg * 8 + j;
      #pragma unroll
      for (int i = 0; i < 4; i++)
        ow[((size_t)(b * Cn + c)) * Nn + h * Wn + wg + 32 * i] = f2bf(acc[i][j]);
    }
  }
}

// out = gamma*(ohT^T + ow) + in (+ addend)
__global__ __launch_bounds__(256) void k_fuse(const float* __restrict__ in,
                                              const bf16* __restrict__ ohT,
                                              const bf16* __restrict__ ow,
                                              const float* __restrict__ addend,
                                              const float* __restrict__ gamma,
                                              float* __restrict__ out){
  __shared__ float tile[32][33];
  int tl = blockIdx.x, c = blockIdx.y, b = blockIdx.z;
  int th = tl >> 2, tw = tl & 3;
  int h0 = th * 32, w0 = tw * 32;
  int t = threadIdx.x;
  float g = gamma[0];
  #pragma unroll
  for (int kk = 0; kk < 4; ++kk){
    int idx = t + kk * 256;
    int wl = idx >> 5, hl = idx & 31;
    tile[wl][hl] = bf2f(ohT[((size_t)(b * Wn + w0 + wl) * Cn + c) * Hn + h0 + hl]);
  }
  __syncthreads();
  #pragma unroll
  for (int kk = 0; kk < 4; ++kk){
    int idx = t + kk * 256;
    int hl = idx >> 5, wl = idx & 31;
    size_t o = ((size_t)(b * Cn + c)) * Nn + (size_t)(h0 + hl) * Wn + w0 + wl;
    float val = g * (tile[wl][hl] + bf2f(ow[o])) + in[o];
    if (addend) val += addend[o];
    out[o] = val;
  }
}

// ============================ host ============================

static void run_ca(const float* in, const float* wq, const float* bq,
                   const float* wk, const float* bk, const float* wv, const float* bv,
                   const float* gamma, const float* addend, float* out,
                   bf16* q, bf16* k, bf16* qT, bf16* kT, bf16* v, bf16* vT,
                   float* e, bf16* tmp, hipStream_t stream){
  bf16* ohT = tmp;
  bf16* ow  = tmp + (size_t)Bn * Cn * Nn;
  k_qk<<<dim3(Nn / 128, Bn), 256, 0, stream>>>(in, wq, bq, wk, bk, q, k);
  k_trans<<<dim3(16, CQn, Bn), 256, 0, stream>>>(q, qT, CQn);
  k_trans<<<dim3(16, CQn, Bn), 256, 0, stream>>>(k, kT, CQn);
  k_v<<<dim3(4, Nn / 64, Bn), 256, 0, stream>>>(in, wv, bv, v);
  k_trans<<<dim3(16, Cn, Bn), 256, 0, stream>>>(v, vT, Cn);
  k_eh<<<dim3(Wn, Bn), 256, 0, stream>>>(qT, kT, e);
  k_ew<<<dim3(Hn, Bn), 256, 0, stream>>>(q, k, e);
  k_softmax<<<(Bn * Nn) / 4, 256, 0, stream>>>(e);
  k_comb_h<<<dim3(Wn, Bn), 256, 0, stream>>>(e, vT, ohT);
  k_comb_w<<<dim3(Hn, Bn), 256, 0, stream>>>(e, v, ow);
  k_fuse<<<dim3(16, Cn, Bn), 256, 0, stream>>>(in, ohT, ow, addend, gamma, out);
}

extern "C" void kernel_launch(void* const* d_in, const int* in_sizes, int n_in,
                              void* d_out, int out_size, void* d_ws, size_t ws_size,
                              hipStream_t stream){
  (void)in_sizes; (void)n_in; (void)out_size; (void)ws_size;
  const float* x         = (const float*)d_in[0];
  const float* w_q_right = (const float*)d_in[1];
  const float* w_v_right = (const float*)d_in[2];
  const float* w_up      = (const float*)d_in[3];
  const float* b_up      = (const float*)d_in[4];
  const float* w_q_left  = (const float*)d_in[5];
  const float* w_v_left  = (const float*)d_in[6];
  const float* wq        = (const float*)d_in[7];
  const float* bq        = (const float*)d_in[8];
  const float* wk        = (const float*)d_in[9];
  const float* bk        = (const float*)d_in[10];
  const float* wv        = (const float*)d_in[11];
  const float* bv        = (const float*)d_in[12];
  const float* gamma     = (const float*)d_in[13];

  const size_t SZ_MAP = (size_t)Bn * Cn * Nn;     // 33.5M elements
  char* p = (char*)d_ws;
  float* buf0   = (float*)p; p += SZ_MAP * 4;
  float* buf1   = (float*)p; p += SZ_MAP * 4;
  bf16*  vbuf   = (bf16*)p;  p += SZ_MAP * 2;
  bf16*  vT     = (bf16*)p;  p += SZ_MAP * 2;
  bf16*  qbuf   = (bf16*)p;  p += (size_t)Bn * CQn * Nn * 2;
  bf16*  kbuf   = (bf16*)p;  p += (size_t)Bn * CQn * Nn * 2;
  bf16*  qT     = (bf16*)p;  p += (size_t)Bn * CQn * Nn * 2;
  bf16*  kT     = (bf16*)p;  p += (size_t)Bn * CQn * Nn * 2;
  float* ebuf   = (float*)p; p += (size_t)Bn * Nn * 256 * 4;
  float* logits = (float*)p; p += (size_t)Bn * Nn * 4;
  float* ctxlog = (float*)p; p += (size_t)Bn * Nn * 4;
  float* msp    = (float*)p; p += (size_t)Bn * Nn * 4;
  float* xbar   = (float*)p; p += Bn * Cn * 4;
  float* wgt    = (float*)p; p += Bn * Cn * 4;
  float* u      = (float*)p; p += Bn * Cn * 4;
  float* mch    = (float*)p; p += Bn * Cn * 4;
  float* stats_sp = (float*)p; p += 64;
  float* stats_ch = (float*)p; p += 64;

  // ---- stage 0: gating masks ----
  k_dotc<<<Bn * Nn / 256, 256, 0, stream>>>(x, w_q_right, 0, logits);
  k_rowmean<<<Bn * Cn, 256, 0, stream>>>(x, xbar, 1.f / Nn);
  k_avg_u<<<1, 256, 0, stream>>>(w_q_left, w_v_left, xbar, u);
  k_stats<<<Bn, 1024, 0, stream>>>(logits, stats_sp);
  k_weighted<<<Bn * Cn, 256, 0, stream>>>(x, logits, stats_sp, wgt);
  k_mch<<<1, 256, 0, stream>>>(w_v_right, w_up, b_up, wgt, mch);
  k_dotc<<<Bn * Nn / 256, 256, 0, stream>>>(x, u, Cn, ctxlog);
  k_stats<<<Bn, 1024, 0, stream>>>(ctxlog, stats_ch);
  k_msp<<<Bn * Nn / 256, 256, 0, stream>>>(ctxlog, stats_ch, msp);
  k_apply<<<(int)(SZ_MAP / 256), 256, 0, stream>>>(x, mch, msp, buf0, buf1);

  // ---- CA1: cc' = CA(cc), in-place buf0; tmp = d_out ----
  run_ca(buf0, wq, bq, wk, bk, wv, bv, gamma, nullptr, buf0,
         qbuf, kbuf, qT, kT, vbuf, vT, ebuf, (bf16*)d_out, stream);
  // ---- CA2: s = CA(cs) + cc' -> buf0 ----
  run_ca(buf1, wq, bq, wk, bk, wv, bv, gamma, buf0, buf0,
         qbuf, kbuf, qT, kT, vbuf, vT, ebuf, (bf16*)d_out, stream);
  // ---- CA3: out = CA(s) -> d_out; tmp = buf1 ----
  run_ca(buf0, wq, bq, wk, bk, wv, bv, gamma, nullptr, (float*)d_out,
         qbuf, kbuf, qT, kT, vbuf, vT, ebuf, (bf16*)buf1, stream);
}

// Round 2
// 2784.276 us; speedup vs baseline: 1.4604x; 1.4604x over previous
//
#include <hip/hip_runtime.h>
#include <hip/hip_bf16.h>
#include <math.h>

typedef __hip_bfloat16 bf16;
typedef __attribute__((ext_vector_type(8))) short s16x8;
typedef __attribute__((ext_vector_type(4))) float f32x4;

constexpr int Bn  = 4;
constexpr int Cn  = 512;
constexpr int Hn  = 128;
constexpr int Wn  = 128;
constexpr int Nn  = Hn * Wn;   // 16384
constexpr int CQn = 64;
constexpr int CIn = 256;

__device__ __forceinline__ float bf2f(bf16 v){ return __bfloat162float(v); }
__device__ __forceinline__ bf16  f2bf(float v){ return __float2bfloat16(v); }

// async global->LDS, 16B per lane; LDS dest must be wave-uniform base (HW adds lane*16)
__device__ __forceinline__ void gload_lds16(const void* g, void* l){
  __builtin_amdgcn_global_load_lds(
      (const __attribute__((address_space(1))) unsigned int*)g,
      (__attribute__((address_space(3))) unsigned int*)l,
      16, 0, 0);
}

// ============================ stage 0 ============================

// out[b*Nn+n] = sum_c w[b*wstride + c] * x[(b*Cn+c)*Nn + n]
__global__ __launch_bounds__(256) void k_dotc(const float* __restrict__ x,
                                              const float* __restrict__ w,
                                              int wstride,
                                              float* __restrict__ out){
  int t = blockIdx.x * 256 + threadIdx.x;      // over B*Nn
  int b = t >> 14;
  const float* wp = w + (size_t)b * wstride;
  const float* xp = x + (size_t)b * Cn * Nn + (t & (Nn - 1));
  float acc = 0.f;
  #pragma unroll 8
  for (int c = 0; c < Cn; ++c) acc += wp[c] * xp[(size_t)c * Nn];
  out[t] = acc;
}

// out[bc] = scale * sum_n x[bc*Nn+n]
__global__ __launch_bounds__(256) void k_rowmean(const float* __restrict__ x,
                                                 float* __restrict__ out,
                                                 float scale){
  int bc = blockIdx.x;
  const float* xp = x + (size_t)bc * Nn;
  float acc = 0.f;
  for (int n = threadIdx.x; n < Nn; n += 256) acc += xp[n];
  for (int o = 32; o > 0; o >>= 1) acc += __shfl_down(acc, o);
  __shared__ float red[4];
  if ((threadIdx.x & 63) == 0) red[threadIdx.x >> 6] = acc;
  __syncthreads();
  if (threadIdx.x == 0) out[bc] = (red[0] + red[1] + red[2] + red[3]) * scale;
}

// avg[b,ci] = sum_c w_q_left[ci,c]*xbar[b,c];  u[b,c] = sum_ci avg[b,ci]*w_v_left[ci,c]
__global__ __launch_bounds__(256) void k_avg_u(const float* __restrict__ w_q_left,
                                               const float* __restrict__ w_v_left,
                                               const float* __restrict__ xbar,
                                               float* __restrict__ u){
  __shared__ float avg_s[Bn * CIn];
  for (int i = threadIdx.x; i < Bn * CIn; i += 256){
    int b = i >> 8, ci = i & (CIn - 1);
    const float* wp = w_q_left + (size_t)ci * Cn;
    const float* xb = xbar + b * Cn;
    float a = 0.f;
    for (int c = 0; c < Cn; ++c) a += wp[c] * xb[c];
    avg_s[i] = a;
  }
  __syncthreads();
  for (int i = threadIdx.x; i < Bn * Cn; i += 256){
    int b = i >> 9, c = i & (Cn - 1);
    const float* as = avg_s + b * CIn;
    float a = 0.f;
    for (int ci = 0; ci < CIn; ++ci) a += as[ci] * w_v_left[(size_t)ci * Cn + c];
    u[i] = a;
  }
}

// per-b max & sumexp over Nn values
__global__ __launch_bounds__(1024) void k_stats(const float* __restrict__ vv,
                                                float* __restrict__ stats){
  int b = blockIdx.x;
  const float* pp = vv + (size_t)b * Nn;
  int t = threadIdx.x;
  float m = -3.4e38f;
  for (int n = t; n < Nn; n += 1024) m = fmaxf(m, pp[n]);
  for (int o = 32; o > 0; o >>= 1) m = fmaxf(m, __shfl_down(m, o));
  __shared__ float red[16];
  int wid = t >> 6, lid = t & 63;
  if (lid == 0) red[wid] = m;
  __syncthreads();
  if (t == 0){
    float q = red[0];
    for (int i = 1; i < 16; i++) q = fmaxf(q, red[i]);
    red[0] = q;
  }
  __syncthreads();
  m = red[0];
  __syncthreads();
  float s = 0.f;
  for (int n = t; n < Nn; n += 1024) s += expf(pp[n] - m);
  for (int o = 32; o > 0; o >>= 1) s += __shfl_down(s, o);
  if (lid == 0) red[wid] = s;
  __syncthreads();
  if (t == 0){
    float q = 0.f;
    for (int i = 0; i < 16; i++) q += red[i];
    stats[b * 2]     = m;
    stats[b * 2 + 1] = q;
  }
}

// weighted[b,c] = sum_n x[b,c,n]*exp(l[b,n]-m)/den
__global__ __launch_bounds__(256) void k_weighted(const float* __restrict__ x,
                                                  const float* __restrict__ logits,
                                                  const float* __restrict__ stats,
                                                  float* __restrict__ out){
  int bc = blockIdx.x;
  int b = bc >> 9;
  const float* xp = x + (size_t)bc * Nn;
  const float* lp = logits + (size_t)b * Nn;
  float m = stats[b * 2], den = stats[b * 2 + 1];
  float acc = 0.f;
  for (int n = threadIdx.x; n < Nn; n += 256) acc += xp[n] * expf(lp[n] - m);
  for (int o = 32; o > 0; o >>= 1) acc += __shfl_down(acc, o);
  __shared__ float red[4];
  if ((threadIdx.x & 63) == 0) red[threadIdx.x >> 6] = acc;
  __syncthreads();
  if (threadIdx.x == 0) out[bc] = (red[0] + red[1] + red[2] + red[3]) / den;
}

// ctx[b,ci] = sum_c w_v_right[ci,c]*weighted[b,c];
// mch[b,o] = sigmoid(sum_ci w_up[o,ci]*ctx[b,ci] + b_up[o])
__global__ __launch_bounds__(256) void k_mch(const float* __restrict__ w_v_right,
                                             const float* __restrict__ w_up,
                                             const float* __restrict__ b_up,
                                             const float* __restrict__ weighted,
                                             float* __restrict__ mch){
  __shared__ float ctx_s[Bn * CIn];
  for (int i = threadIdx.x; i < Bn * CIn; i += 256){
    int b = i >> 8, ci = i & (CIn - 1);
    const float* wp = w_v_right + (size_t)ci * Cn;
    const float* wg = weighted + b * Cn;
    float a = 0.f;
    for (int c = 0; c < Cn; ++c) a += wp[c] * wg[c];
    ctx_s[i] = a;
  }
  __syncthreads();
  for (int i = threadIdx.x; i < Bn * Cn; i += 256){
    int b = i >> 9, o = i & (Cn - 1);
    const float* cs = ctx_s + b * CIn;
    float a = b_up[o];
    for (int ci = 0; ci < CIn; ++ci) a += w_up[(size_t)o * CIn + ci] * cs[ci];
    mch[i] = 1.f / (1.f + expf(-a));
  }
}

// msp[b,n] = sigmoid(exp(l-m)/den)
__global__ __launch_bounds__(256) void k_msp(const float* __restrict__ lg,
                                             const float* __restrict__ stats,
                                             float* __restrict__ msp){
  int t = blockIdx.x * 256 + threadIdx.x;
  int b = t >> 14;
  float v = expf(lg[t] - stats[b * 2]) / stats[b * 2 + 1];
  msp[t] = 1.f / (1.f + expf(-v));
}

// cc = x * mch[b,c] ; cs = x * msp[b,n]
__global__ __launch_bounds__(256) void k_apply(const float* __restrict__ x,
                                               const float* __restrict__ mch,
                                               const float* __restrict__ msp,
                                               float* __restrict__ cc,
                                               float* __restrict__ cs){
  size_t t = (size_t)blockIdx.x * 256 + threadIdx.x;
  int bc = (int)(t >> 14);
  int b  = bc >> 9;
  int n  = (int)(t & (Nn - 1));
  float xv = x[t];
  cc[t] = xv * mch[bc];
  cs[t] = xv * msp[b * Nn + n];
}

// ============================ conversions ============================

// wv fp32 [c][c'] -> bf16 (same layout)
__global__ __launch_bounds__(256) void k_cvt_w(const float* __restrict__ in,
                                               bf16* __restrict__ out, int n){
  int t = blockIdx.x * 256 + threadIdx.x;
  if (t < n) out[t] = f2bf(in[t]);
}

// in[b][c][n] fp32 -> xT[b][n][c] bf16 (transposed, K-contiguous for MFMA B-operand)
__global__ __launch_bounds__(256) void k_cvt_T(const float* __restrict__ in,
                                               bf16* __restrict__ out){
  __shared__ bf16 tile[32][33];
  int nt = blockIdx.x, ct = blockIdx.y, b = blockIdx.z;
  int n0 = nt * 32, c0 = ct * 32;
  int t = threadIdx.x;
  #pragma unroll
  for (int kk = 0; kk < 4; ++kk){
    int idx = t + kk * 256;
    int cl = idx >> 5, nl = idx & 31;
    tile[cl][nl] = f2bf(in[((size_t)(b * Cn + c0 + cl)) * Nn + n0 + nl]);
  }
  __syncthreads();
  #pragma unroll
  for (int kk = 0; kk < 4; ++kk){
    int idx = t + kk * 256;
    int nl = idx >> 5, cl = idx & 31;
    out[((size_t)(b * Nn + n0 + nl)) * Cn + c0 + cl] = tile[cl][nl];
  }
}

// ============================ cross attention ============================

// q/k projection, 128-n tile, all 64 outputs; bf16 out, std layout [b,o,h,w]
__global__ __launch_bounds__(256) void k_qk(const float* __restrict__ in,
                                            const float* __restrict__ wq,
                                            const float* __restrict__ bq,
                                            const float* __restrict__ wk,
                                            const float* __restrict__ bk,
                                            bf16* __restrict__ q,
                                            bf16* __restrict__ k){
  __shared__ float xs[64 * 128];
  __shared__ float wqs[64 * 64];
  __shared__ float wks[64 * 64];
  int nt = blockIdx.x, b = blockIdx.y;
  int n0 = nt * 128;
  int t = threadIdx.x;
  int og = t >> 5, ng = t & 31;
  float accq[8][4], acck[8][4];
  #pragma unroll
  for (int j = 0; j < 8; j++)
    #pragma unroll
    for (int i = 0; i < 4; i++){ accq[j][i] = 0.f; acck[j][i] = 0.f; }
  for (int c0 = 0; c0 < Cn; c0 += 64){
    for (int i = t; i < 8192; i += 256){
      int cl = i >> 7, nl = i & 127;
      xs[i] = in[((size_t)(b * Cn + c0 + cl)) * Nn + n0 + nl];
    }
    for (int i = t; i < 4096; i += 256){
      int ol = i >> 6, cl = i & 63;
      wqs[i] = wq[(size_t)ol * Cn + c0 + cl];
      wks[i] = wk[(size_t)ol * Cn + c0 + cl];
    }
    __syncthreads();
    for (int c = 0; c < 64; ++c){
      float xv[4];
      #pragma unroll
      for (int i = 0; i < 4; i++) xv[i] = xs[c * 128 + ng + 32 * i];
      #pragma unroll
      for (int j = 0; j < 8; j++){
        float wqv = wqs[(og * 8 + j) * 64 + c];
        float wkv = wks[(og * 8 + j) * 64 + c];
        #pragma unroll
        for (int i = 0; i < 4; i++){
          accq[j][i] += wqv * xv[i];
          acck[j][i] += wkv * xv[i];
        }
      }
    }
    __syncthreads();
  }
  #pragma unroll
  for (int j = 0; j < 8; j++){
    int o = og * 8 + j;
    float bqv = bq[o], bkv = bk[o];
    #pragma unroll
    for (int i = 0; i < 4; i++){
      size_t idx = ((size_t)(b * CQn + o)) * Nn + n0 + ng + 32 * i;
      q[idx] = f2bf(accq[j][i] + bqv);
      k[idx] = f2bf(acck[j][i] + bkv);
    }
  }
}

// V = Wv @ X via MFMA. xT: [b][n][c'] bf16 (K-contig), wvb: [c][c'] bf16.
// 128x128 tile, BK=64, 4 waves each 64x64 (4x4 frags of 16x16x32).
__global__ __launch_bounds__(256) void k_v_mfma(const bf16* __restrict__ xT,
                                                const bf16* __restrict__ wvb,
                                                const float* __restrict__ bv,
                                                bf16* __restrict__ v){
  __shared__ short As[128 * 64];   // [c-row][k] row-major
  __shared__ short Bs[128 * 64];   // [n-row][k] row-major
  __shared__ float bvs[128];
  int nb = blockIdx.x * 128, cb = blockIdx.y * 128, b = blockIdx.z;
  int t = threadIdx.x, lane = t & 63, wid = t >> 6;
  int wm = wid >> 1, wn = wid & 1;
  int l15 = lane & 15, l4 = lane >> 4;
  if (t < 128) bvs[t] = bv[cb + t];
  f32x4 acc[4][4];
  #pragma unroll
  for (int i = 0; i < 4; i++)
    #pragma unroll
    for (int j = 0; j < 4; j++) acc[i][j] = (f32x4){0.f, 0.f, 0.f, 0.f};

  const bf16* wp = wvb + (size_t)cb * Cn;
  const bf16* xp = xT + ((size_t)b * Nn + nb) * Cn;
  int r8 = lane >> 3;            // row-within-1KB-chunk
  int kc = (lane & 7) * 8;       // k element offset of this lane's 16B
  for (int kt = 0; kt < 8; ++kt){
    int k0 = kt * 64;
    #pragma unroll
    for (int j = 0; j < 4; ++j){
      int inst = wid * 4 + j;          // 0..15, each covers 8 rows
      int row = inst * 8 + r8;
      gload_lds16(wp + (size_t)row * Cn + k0 + kc, (char*)As + inst * 1024);
      gload_lds16(xp + (size_t)row * Cn + k0 + kc, (char*)Bs + inst * 1024);
    }
    __syncthreads();
    #pragma unroll
    for (int kk = 0; kk < 64; kk += 32){
      s16x8 a[4], bb[4];
      #pragma unroll
      for (int mi = 0; mi < 4; mi++)
        a[mi] = *(const s16x8*)&As[(wm * 64 + mi * 16 + l15) * 64 + kk + l4 * 8];
      #pragma unroll
      for (int ni = 0; ni < 4; ni++)
        bb[ni] = *(const s16x8*)&Bs[(wn * 64 + ni * 16 + l15) * 64 + kk + l4 * 8];
      #pragma unroll
      for (int mi = 0; mi < 4; mi++)
        #pragma unroll
        for (int ni = 0; ni < 4; ni++)
          acc[mi][ni] = __builtin_amdgcn_mfma_f32_16x16x32_bf16(a[mi], bb[ni], acc[mi][ni], 0, 0, 0);
    }
    __syncthreads();
  }
  #pragma unroll
  for (int mi = 0; mi < 4; mi++){
    #pragma unroll
    for (int r = 0; r < 4; r++){
      int cl = wm * 64 + mi * 16 + l4 * 4 + r;
      int c  = cb + cl;
      float bias = bvs[cl];
      #pragma unroll
      for (int ni = 0; ni < 4; ni++){
        int n = nb + wn * 64 + ni * 16 + l15;
        v[((size_t)(b * Cn + c)) * Nn + n] = f2bf(acc[mi][ni][r] + bias);
      }
    }
  }
}

// [b,c,h,w] -> [b,w,c,h] (bf16), 32x32 tiles
__global__ __launch_bounds__(256) void k_trans(const bf16* __restrict__ in,
                                               bf16* __restrict__ out,
                                               int CH){
  __shared__ bf16 tile[32][33];
  int tl = blockIdx.x, c = blockIdx.y, b = blockIdx.z;
  int th = tl >> 2, tw = tl & 3;
  int h0 = th * 32, w0 = tw * 32;
  int t = threadIdx.x;
  const bf16* ip = in + ((size_t)(b * CH + c)) * Nn;
  #pragma unroll
  for (int kk = 0; kk < 4; ++kk){
    int idx = t + kk * 256;
    int hl = idx >> 5, wl = idx & 31;
    tile[hl][wl] = ip[(h0 + hl) * Wn + w0 + wl];
  }
  __syncthreads();
  #pragma unroll
  for (int kk = 0; kk < 4; ++kk){
    int idx = t + kk * 256;
    int wl = idx >> 5, hl = idx & 31;
    out[((size_t)(b * Wn + w0 + wl) * CH + c) * Hn + h0 + hl] = tile[hl][wl];
  }
}

// e_h[h,g] = sum_c qT[b,w,c,h]*kT[b,w,c,g], diag -> -1e30
__global__ __launch_bounds__(256) void k_eh(const bf16* __restrict__ qT,
                                            const bf16* __restrict__ kT,
                                            float* __restrict__ e){
  __shared__ float smem[16384];
  float* qs = smem;
  float* ks = smem + 8192;
  int w = blockIdx.x, b = blockIdx.y;
  int t = threadIdx.x;
  const bf16* qp = qT + (size_t)(b * Wn + w) * CQn * Hn;
  const bf16* kp = kT + (size_t)(b * Wn + w) * CQn * Hn;
  for (int i = t; i < 8192; i += 256){ qs[i] = bf2f(qp[i]); ks[i] = bf2f(kp[i]); }
  __syncthreads();
  int hg = t >> 3, gg = t & 7;
  float acc[4][16];
  #pragma unroll
  for (int i = 0; i < 4; i++)
    #pragma unroll
    for (int j = 0; j < 16; j++) acc[i][j] = 0.f;
  for (int c = 0; c < CQn; ++c){
    float qv[4], kv[16];
    #pragma unroll
    for (int i = 0; i < 4; i++) qv[i] = qs[c * 128 + hg * 4 + i];
    #pragma unroll
    for (int j = 0; j < 16; j++) kv[j] = ks[c * 128 + gg + 8 * j];
    #pragma unroll
    for (int i = 0; i < 4; i++)
      #pragma unroll
      for (int j = 0; j < 16; j++) acc[i][j] += qv[i] * kv[j];
  }
  __syncthreads();
  #pragma unroll
  for (int i = 0; i < 4; i++)
    #pragma unroll
    for (int j = 0; j < 16; j++)
      smem[(hg * 4 + i) * 128 + gg + 8 * j] = acc[i][j];
  __syncthreads();
  for (int kk = 0; kk < 64; ++kk){
    int idx = t + kk * 256;
    int h = idx >> 7, g = idx & 127;
    float val = (h == g) ? -1e30f : smem[idx];
    e[((size_t)(b * Hn + h) * Wn + w) * 256 + g] = val;
  }
}

// e_w[w,v] = sum_c q[b,c,h,w]*k[b,c,h,v]
__global__ __launch_bounds__(256) void k_ew(const bf16* __restrict__ q,
                                            const bf16* __restrict__ k,
                                            float* __restrict__ e){
  __shared__ float smem[16384];
  float* qs = smem;
  float* ks = smem + 8192;
  int h = blockIdx.x, b = blockIdx.y;
  int t = threadIdx.x;
  for (int i = t; i < 8192; i += 256){
    int c = i >> 7, wl = i & 127;
    size_t base = ((size_t)(b * CQn + c) * Hn + h) * Wn + wl;
    qs[i] = bf2f(q[base]);
    ks[i] = bf2f(k[base]);
  }
  __syncthreads();
  int wg = t >> 3, vg = t & 7;
  float acc[4][16];
  #pragma unroll
  for (int i = 0; i < 4; i++)
    #pragma unroll
    for (int j = 0; j < 16; j++) acc[i][j] = 0.f;
  for (int c = 0; c < CQn; ++c){
    float qv[4], kv[16];
    #pragma unroll
    for (int i = 0; i < 4; i++) qv[i] = qs[c * 128 + wg * 4 + i];
    #pragma unroll
    for (int j = 0; j < 16; j++) kv[j] = ks[c * 128 + vg + 8 * j];
    #pragma unroll
    for (int i = 0; i < 4; i++)
      #pragma unroll
      for (int j = 0; j < 16; j++) acc[i][j] += qv[i] * kv[j];
  }
  __syncthreads();
  #pragma unroll
  for (int i = 0; i < 4; i++)
    #pragma unroll
    for (int j = 0; j < 16; j++)
      smem[(wg * 4 + i) * 128 + vg + 8 * j] = acc[i][j];
  __syncthreads();
  for (int kk = 0; kk < 64; ++kk){
    int idx = t + kk * 256;
    int wr = idx >> 7, vc = idx & 127;
    e[((size_t)(b * Hn + h) * Wn + wr) * 256 + 128 + vc] = smem[idx];
  }
}

// softmax over 256 per row, in place; one wave per row
__global__ __launch_bounds__(256) void k_softmax(float* __restrict__ e){
  int wid = threadIdx.x >> 6, lid = threadIdx.x & 63;
  size_t row = (size_t)blockIdx.x * 4 + wid;
  float* p = e + row * 256;
  float v[4];
  #pragma unroll
  for (int i = 0; i < 4; i++) v[i] = p[lid + 64 * i];
  float m = fmaxf(fmaxf(v[0], v[1]), fmaxf(v[2], v[3]));
  for (int o = 32; o > 0; o >>= 1) m = fmaxf(m, __shfl_xor(m, o));
  float s = 0.f;
  #pragma unroll
  for (int i = 0; i < 4; i++){ v[i] = expf(v[i] - m); s += v[i]; }
  for (int o = 32; o > 0; o >>= 1) s += __shfl_xor(s, o);
  float inv = 1.f / s;
  #pragma unroll
  for (int i = 0; i < 4; i++) p[lid + 64 * i] = v[i] * inv;
}

// out_h: per (b,w): ohT[b,w,c,h] = sum_g att[b,h,w,g]*vT[b,w,c,g]
__global__ __launch_bounds__(256) void k_comb_h(const float* __restrict__ att,
                                                const bf16* __restrict__ vT,
                                                bf16* __restrict__ ohT){
  __shared__ bf16 Ab[128 * 129];
  __shared__ bf16 vsb[8192];
  int w = blockIdx.x, b = blockIdx.y;
  int t = threadIdx.x;
  for (int i = t; i < 16384; i += 256){
    int h = i >> 7, g = i & 127;
    Ab[h * 129 + g] = f2bf(att[((size_t)(b * Hn + h) * Wn + w) * 256 + g]);
  }
  const bf16* vp = vT + (size_t)(b * Wn + w) * Cn * Hn;
  int hg = t & 31, cg = t >> 5;
  for (int c0 = 0; c0 < Cn; c0 += 64){
    __syncthreads();
    for (int i = t; i < 8192; i += 256)
      vsb[i] = vp[(size_t)(c0 + (i >> 7)) * Hn + (i & 127)];
    __syncthreads();
    float acc[4][8];
    #pragma unroll
    for (int i = 0; i < 4; i++)
      #pragma unroll
      for (int j = 0; j < 8; j++) acc[i][j] = 0.f;
    for (int g = 0; g < 128; ++g){
      float av[4];
      #pragma unroll
      for (int i = 0; i < 4; i++) av[i] = bf2f(Ab[(hg + 32 * i) * 129 + g]);
      #pragma unroll
      for (int j = 0; j < 8; j++){
        float vvv = bf2f(vsb[(cg * 8 + j) * 128 + g]);
        #pragma unroll
        for (int i = 0; i < 4; i++) acc[i][j] += av[i] * vvv;
      }
    }
    #pragma unroll
    for (int j = 0; j < 8; j++){
      int c = c0 + cg * 8 + j;
      #pragma unroll
      for (int i = 0; i < 4; i++)
        ohT[((size_t)(b * Wn + w) * Cn + c) * Hn + hg + 32 * i] = f2bf(acc[i][j]);
    }
  }
}

// out_w: per (b,h): ow[b,c,h,w] = sum_v att[b,h,w,128+v]*vstd[b,c,h,v]
__global__ __launch_bounds__(256) void k_comb_w(const float* __restrict__ att,
                                                const bf16* __restrict__ v,
                                                bf16* __restrict__ ow){
  __shared__ bf16 Ab[128 * 129];
  __shared__ bf16 vsb[8192];
  int h = blockIdx.x, b = blockIdx.y;
  int t = threadIdx.x;
  for (int i = t; i < 16384; i += 256){
    int wl = i >> 7, vc = i & 127;
    Ab[wl * 129 + vc] = f2bf(att[((size_t)(b * Hn + h) * Wn + wl) * 256 + 128 + vc]);
  }
  int wg = t & 31, cg = t >> 5;
  for (int c0 = 0; c0 < Cn; c0 += 64){
    __syncthreads();
    for (int i = t; i < 8192; i += 256)
      vsb[i] = v[((size_t)(b * Cn + c0 + (i >> 7)) * Hn + h) * Wn + (i & 127)];
    __syncthreads();
    float acc[4][8];
    #pragma unroll
    for (int i = 0; i < 4; i++)
      #pragma unroll
      for (int j = 0; j < 8; j++) acc[i][j] = 0.f;
    for (int g = 0; g < 128; ++g){
      float av[4];
      #pragma unroll
      for (int i = 0; i < 4; i++) av[i] = bf2f(Ab[(wg + 32 * i) * 129 + g]);
      #pragma unroll
      for (int j = 0; j < 8; j++){
        float vvv = bf2f(vsb[(cg * 8 + j) * 128 + g]);
        #pragma unroll
        for (int i = 0; i < 4; i++) acc[i][j] += av[i] * vvv;
      }
    }
    #pragma unroll
    for (int j = 0; j < 8; j++){
      int c = c0 + cg * 8 + j;
      #pragma unroll
      for (int i = 0; i < 4; i++)
        ow[((size_t)(b * Cn + c)) * Nn + h * Wn + wg + 32 * i] = f2bf(acc[i][j]);
    }
  }
}

// out = gamma*(ohT^T + ow) + in (+ addend)
__global__ __launch_bounds__(256) void k_fuse(const float* __restrict__ in,
                                              const bf16* __restrict__ ohT,
                                              const bf16* __restrict__ ow,
                                              const float* __restrict__ addend,
                                              const float* __restrict__ gamma,
                                              float* __restrict__ out){
  __shared__ float tile[32][33];
  int tl = blockIdx.x, c = blockIdx.y, b = blockIdx.z;
  int th = tl >> 2, tw = tl & 3;
  int h0 = th * 32, w0 = tw * 32;
  int t = threadIdx.x;
  float g = gamma[0];
  #pragma unroll
  for (int kk = 0; kk < 4; ++kk){
    int idx = t + kk * 256;
    int wl = idx >> 5, hl = idx & 31;
    tile[wl][hl] = bf2f(ohT[((size_t)(b * Wn + w0 + wl) * Cn + c) * Hn + h0 + hl]);
  }
  __syncthreads();
  #pragma unroll
  for (int kk = 0; kk < 4; ++kk){
    int idx = t + kk * 256;
    int hl = idx >> 5, wl = idx & 31;
    size_t o = ((size_t)(b * Cn + c)) * Nn + (size_t)(h0 + hl) * Wn + w0 + wl;
    float val = g * (tile[wl][hl] + bf2f(ow[o])) + in[o];
    if (addend) val += addend[o];
    out[o] = val;
  }
}

// ============================ host ============================

static void run_ca(const float* in, const float* wq, const float* bq,
                   const float* wk, const float* bk, const bf16* wvb, const float* bv,
                   const float* gamma, const float* addend, float* out,
                   bf16* q, bf16* k, bf16* qT, bf16* kT, bf16* v, bf16* vT,
                   float* e, bf16* xT, bf16* tmp, hipStream_t stream){
  bf16* ohT = tmp;
  bf16* ow  = tmp + (size_t)Bn * Cn * Nn;
  k_cvt_T<<<dim3(Nn / 32, Cn / 32, Bn), 256, 0, stream>>>(in, xT);
  k_qk<<<dim3(Nn / 128, Bn), 256, 0, stream>>>(in, wq, bq, wk, bk, q, k);
  k_trans<<<dim3(16, CQn, Bn), 256, 0, stream>>>(q, qT, CQn);
  k_trans<<<dim3(16, CQn, Bn), 256, 0, stream>>>(k, kT, CQn);
  k_v_mfma<<<dim3(Nn / 128, Cn / 128, Bn), 256, 0, stream>>>(xT, wvb, bv, v);
  k_trans<<<dim3(16, Cn, Bn), 256, 0, stream>>>(v, vT, Cn);
  k_eh<<<dim3(Wn, Bn), 256, 0, stream>>>(qT, kT, e);   // e aliases xT; k_v is done by now
  k_ew<<<dim3(Hn, Bn), 256, 0, stream>>>(q, k, e);
  k_softmax<<<(Bn * Nn) / 4, 256, 0, stream>>>(e);
  k_comb_h<<<dim3(Wn, Bn), 256, 0, stream>>>(e, vT, ohT);
  k_comb_w<<<dim3(Hn, Bn), 256, 0, stream>>>(e, v, ow);
  k_fuse<<<dim3(16, Cn, Bn), 256, 0, stream>>>(in, ohT, ow, addend, gamma, out);
}

extern "C" void kernel_launch(void* const* d_in, const int* in_sizes, int n_in,
                              void* d_out, int out_size, void* d_ws, size_t ws_size,
                              hipStream_t stream){
  (void)in_sizes; (void)n_in; (void)out_size; (void)ws_size;
  const float* x         = (const float*)d_in[0];
  const float* w_q_right = (const float*)d_in[1];
  const float* w_v_right = (const float*)d_in[2];
  const float* w_up      = (const float*)d_in[3];
  const float* b_up      = (const float*)d_in[4];
  const float* w_q_left  = (const float*)d_in[5];
  const float* w_v_left  = (const float*)d_in[6];
  const float* wq        = (const float*)d_in[7];
  const float* bq        = (const float*)d_in[8];
  const float* wk        = (const float*)d_in[9];
  const float* bk        = (const float*)d_in[10];
  const float* wv        = (const float*)d_in[11];
  const float* bv        = (const float*)d_in[12];
  const float* gamma     = (const float*)d_in[13];

  const size_t SZ_MAP = (size_t)Bn * Cn * Nn;     // 33.5M elements
  char* p = (char*)d_ws;
  float* buf0   = (float*)p; p += SZ_MAP * 4;
  float* buf1   = (float*)p; p += SZ_MAP * 4;
  bf16*  vbuf   = (bf16*)p;  p += SZ_MAP * 2;
  bf16*  vT     = (bf16*)p;  p += SZ_MAP * 2;
  bf16*  qbuf   = (bf16*)p;  p += (size_t)Bn * CQn * Nn * 2;
  bf16*  kbuf   = (bf16*)p;  p += (size_t)Bn * CQn * Nn * 2;
  bf16*  qT     = (bf16*)p;  p += (size_t)Bn * CQn * Nn * 2;
  bf16*  kT     = (bf16*)p;  p += (size_t)Bn * CQn * Nn * 2;
  float* ebuf   = (float*)p; p += (size_t)Bn * Nn * 256 * 4;  // 67 MB; doubles as xT (bf16, same size)
  float* logits = (float*)p; p += (size_t)Bn * Nn * 4;
  float* ctxlog = (float*)p; p += (size_t)Bn * Nn * 4;
  float* msp    = (float*)p; p += (size_t)Bn * Nn * 4;
  float* xbar   = (float*)p; p += Bn * Cn * 4;
  float* wgt    = (float*)p; p += Bn * Cn * 4;
  float* u      = (float*)p; p += Bn * Cn * 4;
  float* mch    = (float*)p; p += Bn * Cn * 4;
  float* stats_sp = (float*)p; p += 64;
  float* stats_ch = (float*)p; p += 64;
  bf16*  wvb    = (bf16*)p;  p += (size_t)Cn * Cn * 2;
  bf16*  xTb    = (bf16*)ebuf;   // alias: xT lifetime ends before e is written

  // ---- weight conversion (once) ----
  k_cvt_w<<<(Cn * Cn + 255) / 256, 256, 0, stream>>>(wv, wvb, Cn * Cn);

  // ---- stage 0: gating masks ----
  k_dotc<<<Bn * Nn / 256, 256, 0, stream>>>(x, w_q_right, 0, logits);
  k_rowmean<<<Bn * Cn, 256, 0, stream>>>(x, xbar, 1.f / Nn);
  k_avg_u<<<1, 256, 0, stream>>>(w_q_left, w_v_left, xbar, u);
  k_stats<<<Bn, 1024, 0, stream>>>(logits, stats_sp);
  k_weighted<<<Bn * Cn, 256, 0, stream>>>(x, logits, stats_sp, wgt);
  k_mch<<<1, 256, 0, stream>>>(w_v_right, w_up, b_up, wgt, mch);
  k_dotc<<<Bn * Nn / 256, 256, 0, stream>>>(x, u, Cn, ctxlog);
  k_stats<<<Bn, 1024, 0, stream>>>(ctxlog, stats_ch);
  k_msp<<<Bn * Nn / 256, 256, 0, stream>>>(ctxlog, stats_ch, msp);
  k_apply<<<(int)(SZ_MAP / 256), 256, 0, stream>>>(x, mch, msp, buf0, buf1);

  // ---- CA1: cc' = CA(cc), in-place buf0; tmp = d_out ----
  run_ca(buf0, wq, bq, wk, bk, wvb, bv, gamma, nullptr, buf0,
         qbuf, kbuf, qT, kT, vbuf, vT, ebuf, xTb, (bf16*)d_out, stream);
  // ---- CA2: s = CA(cs) + cc' -> buf0 ----
  run_ca(buf1, wq, bq, wk, bk, wvb, bv, gamma, buf0, buf0,
         qbuf, kbuf, qT, kT, vbuf, vT, ebuf, xTb, (bf16*)d_out, stream);
  // ---- CA3: out = CA(s) -> d_out; tmp = buf1 ----
  run_ca(buf0, wq, bq, wk, bk, wvb, bv, gamma, nullptr, (float*)d_out,
         qbuf, kbuf, qT, kT, vbuf, vT, ebuf, xTb, (bf16*)buf1, stream);
}

// Round 5
// 1887.468 us; speedup vs baseline: 2.1542x; 1.4751x over previous
//
#include <hip/hip_runtime.h>
#include <hip/hip_bf16.h>
#include <math.h>

typedef __hip_bfloat16 bf16;
typedef __attribute__((ext_vector_type(8))) short s16x8;
typedef __attribute__((ext_vector_type(4))) float f32x4;

constexpr int Bn  = 4;
constexpr int Cn  = 512;
constexpr int Hn  = 128;
constexpr int Wn  = 128;
constexpr int Nn  = Hn * Wn;   // 16384
constexpr int CQn = 64;
constexpr int CIn = 256;

__device__ __forceinline__ float bf2f(bf16 v){ return __bfloat162float(v); }
__device__ __forceinline__ bf16  f2bf(float v){ return __float2bfloat16(v); }
__device__ __forceinline__ unsigned pack2bf(float a, float b){
  bf16 x = f2bf(a), y = f2bf(b);
  unsigned short ux = *(unsigned short*)&x, uy = *(unsigned short*)&y;
  return (unsigned)ux | ((unsigned)uy << 16);
}

// async global->LDS, 16B per lane; LDS dest must be wave-uniform base (HW adds lane*16)
__device__ __forceinline__ void gload_lds16(const void* g, void* l){
  __builtin_amdgcn_global_load_lds(
      (const __attribute__((address_space(1))) unsigned int*)g,
      (__attribute__((address_space(3))) unsigned int*)l,
      16, 0, 0);
}

// ============================ stage 0 ============================

// out[b*Nn+n] = sum_c w[b*wstride + c] * x[(b*Cn+c)*Nn + n]
__global__ __launch_bounds__(256) void k_dotc(const float* __restrict__ x,
                                              const float* __restrict__ w,
                                              int wstride,
                                              float* __restrict__ out){
  int t = blockIdx.x * 256 + threadIdx.x;      // over B*Nn
  int b = t >> 14;
  const float* wp = w + (size_t)b * wstride;
  const float* xp = x + (size_t)b * Cn * Nn + (t & (Nn - 1));
  float acc = 0.f;
  #pragma unroll 8
  for (int c = 0; c < Cn; ++c) acc += wp[c] * xp[(size_t)c * Nn];
  out[t] = acc;
}

// out[bc] = scale * sum_n x[bc*Nn+n]
__global__ __launch_bounds__(256) void k_rowmean(const float* __restrict__ x,
                                                 float* __restrict__ out,
                                                 float scale){
  int bc = blockIdx.x;
  const float* xp = x + (size_t)bc * Nn;
  float acc = 0.f;
  for (int n = threadIdx.x; n < Nn; n += 256) acc += xp[n];
  for (int o = 32; o > 0; o >>= 1) acc += __shfl_down(acc, o);
  __shared__ float red[4];
  if ((threadIdx.x & 63) == 0) red[threadIdx.x >> 6] = acc;
  __syncthreads();
  if (threadIdx.x == 0) out[bc] = (red[0] + red[1] + red[2] + red[3]) * scale;
}

// avg[b,ci] = sum_c w_q_left[ci,c]*xbar[b,c];  u[b,c] = sum_ci avg[b,ci]*w_v_left[ci,c]
__global__ __launch_bounds__(256) void k_avg_u(const float* __restrict__ w_q_left,
                                               const float* __restrict__ w_v_left,
                                               const float* __restrict__ xbar,
                                               float* __restrict__ u){
  __shared__ float avg_s[Bn * CIn];
  for (int i = threadIdx.x; i < Bn * CIn; i += 256){
    int b = i >> 8, ci = i & (CIn - 1);
    const float* wp = w_q_left + (size_t)ci * Cn;
    const float* xb = xbar + b * Cn;
    float a = 0.f;
    for (int c = 0; c < Cn; ++c) a += wp[c] * xb[c];
    avg_s[i] = a;
  }
  __syncthreads();
  for (int i = threadIdx.x; i < Bn * Cn; i += 256){
    int b = i >> 9, c = i & (Cn - 1);
    const float* as = avg_s + b * CIn;
    float a = 0.f;
    for (int ci = 0; ci < CIn; ++ci) a += as[ci] * w_v_left[(size_t)ci * Cn + c];
    u[i] = a;
  }
}

// per-b max & sumexp over Nn values
__global__ __launch_bounds__(1024) void k_stats(const float* __restrict__ vv,
                                                float* __restrict__ stats){
  int b = blockIdx.x;
  const float* pp = vv + (size_t)b * Nn;
  int t = threadIdx.x;
  float m = -3.4e38f;
  for (int n = t; n < Nn; n += 1024) m = fmaxf(m, pp[n]);
  for (int o = 32; o > 0; o >>= 1) m = fmaxf(m, __shfl_down(m, o));
  __shared__ float red[16];
  int wid = t >> 6, lid = t & 63;
  if (lid == 0) red[wid] = m;
  __syncthreads();
  if (t == 0){
    float q = red[0];
    for (int i = 1; i < 16; i++) q = fmaxf(q, red[i]);
    red[0] = q;
  }
  __syncthreads();
  m = red[0];
  __syncthreads();
  float s = 0.f;
  for (int n = t; n < Nn; n += 1024) s += expf(pp[n] - m);
  for (int o = 32; o > 0; o >>= 1) s += __shfl_down(s, o);
  if (lid == 0) red[wid] = s;
  __syncthreads();
  if (t == 0){
    float q = 0.f;
    for (int i = 0; i < 16; i++) q += red[i];
    stats[b * 2]     = m;
    stats[b * 2 + 1] = q;
  }
}

// weighted[b,c] = sum_n x[b,c,n]*exp(l[b,n]-m)/den
__global__ __launch_bounds__(256) void k_weighted(const float* __restrict__ x,
                                                  const float* __restrict__ logits,
                                                  const float* __restrict__ stats,
                                                  float* __restrict__ out){
  int bc = blockIdx.x;
  int b = bc >> 9;
  const float* xp = x + (size_t)bc * Nn;
  const float* lp = logits + (size_t)b * Nn;
  float m = stats[b * 2], den = stats[b * 2 + 1];
  float acc = 0.f;
  for (int n = threadIdx.x; n < Nn; n += 256) acc += xp[n] * expf(lp[n] - m);
  for (int o = 32; o > 0; o >>= 1) acc += __shfl_down(acc, o);
  __shared__ float red[4];
  if ((threadIdx.x & 63) == 0) red[threadIdx.x >> 6] = acc;
  __syncthreads();
  if (threadIdx.x == 0) out[bc] = (red[0] + red[1] + red[2] + red[3]) / den;
}

// ctx[b,ci] = sum_c w_v_right[ci,c]*weighted[b,c];
// mch[b,o] = sigmoid(sum_ci w_up[o,ci]*ctx[b,ci] + b_up[o])
__global__ __launch_bounds__(256) void k_mch(const float* __restrict__ w_v_right,
                                             const float* __restrict__ w_up,
                                             const float* __restrict__ b_up,
                                             const float* __restrict__ weighted,
                                             float* __restrict__ mch){
  __shared__ float ctx_s[Bn * CIn];
  for (int i = threadIdx.x; i < Bn * CIn; i += 256){
    int b = i >> 8, ci = i & (CIn - 1);
    const float* wp = w_v_right + (size_t)ci * Cn;
    const float* wg = weighted + b * Cn;
    float a = 0.f;
    for (int c = 0; c < Cn; ++c) a += wp[c] * wg[c];
    ctx_s[i] = a;
  }
  __syncthreads();
  for (int i = threadIdx.x; i < Bn * Cn; i += 256){
    int b = i >> 9, o = i & (Cn - 1);
    const float* cs = ctx_s + b * CIn;
    float a = b_up[o];
    for (int ci = 0; ci < CIn; ++ci) a += w_up[(size_t)o * CIn + ci] * cs[ci];
    mch[i] = 1.f / (1.f + expf(-a));
  }
}

// msp[b,n] = sigmoid(exp(l-m)/den)
__global__ __launch_bounds__(256) void k_msp(const float* __restrict__ lg,
                                             const float* __restrict__ stats,
                                             float* __restrict__ msp){
  int t = blockIdx.x * 256 + threadIdx.x;
  int b = t >> 14;
  float v = expf(lg[t] - stats[b * 2]) / stats[b * 2 + 1];
  msp[t] = 1.f / (1.f + expf(-v));
}

// cc = x * mch[b,c] ; cs = x * msp[b,n]
__global__ __launch_bounds__(256) void k_apply(const float* __restrict__ x,
                                               const float* __restrict__ mch,
                                               const float* __restrict__ msp,
                                               float* __restrict__ cc,
                                               float* __restrict__ cs){
  size_t t = (size_t)blockIdx.x * 256 + threadIdx.x;
  int bc = (int)(t >> 14);
  int b  = bc >> 9;
  int n  = (int)(t & (Nn - 1));
  float xv = x[t];
  cc[t] = xv * mch[bc];
  cs[t] = xv * msp[b * Nn + n];
}

// ============================ conversions ============================

// wv fp32 [c][c'] -> bf16 (same layout)
__global__ __launch_bounds__(256) void k_cvt_w(const float* __restrict__ in,
                                               bf16* __restrict__ out, int n){
  int t = blockIdx.x * 256 + threadIdx.x;
  if (t < n) out[t] = f2bf(in[t]);
}

// wqk hi/lo: rows 0-63 = wq, 64-127 = wk (bf16 split); bqk fp32
__global__ __launch_bounds__(256) void k_prep_wqk(const float* __restrict__ wq,
                                                  const float* __restrict__ wk,
                                                  const float* __restrict__ bq,
                                                  const float* __restrict__ bk,
                                                  bf16* __restrict__ wqk_hi,
                                                  bf16* __restrict__ wqk_lo,
                                                  float* __restrict__ bqk){
  int t = blockIdx.x * 256 + threadIdx.x;   // over 128*512
  int o = t >> 9, c = t & 511;
  float v = (o < 64) ? wq[(size_t)o * Cn + c] : wk[(size_t)(o - 64) * Cn + c];
  bf16 h = f2bf(v);
  wqk_hi[t] = h;
  wqk_lo[t] = f2bf(v - bf2f(h));
  if (t < 128) bqk[t] = (t < 64) ? bq[t] : bk[t - 64];
}

// in[b][c][n] fp32 -> xT_hi/xT_lo [b][n][c] bf16 split (K-contiguous for MFMA)
__global__ __launch_bounds__(256) void k_cvt_T(const float* __restrict__ in,
                                               bf16* __restrict__ out_hi,
                                               bf16* __restrict__ out_lo){
  __shared__ bf16 th_[32][33];
  __shared__ bf16 tl_[32][33];
  int nt = blockIdx.x, ct = blockIdx.y, b = blockIdx.z;
  int n0 = nt * 32, c0 = ct * 32;
  int t = threadIdx.x;
  #pragma unroll
  for (int kk = 0; kk < 4; ++kk){
    int idx = t + kk * 256;
    int cl = idx >> 5, nl = idx & 31;
    float v = in[((size_t)(b * Cn + c0 + cl)) * Nn + n0 + nl];
    bf16 h = f2bf(v);
    th_[cl][nl] = h;
    tl_[cl][nl] = f2bf(v - bf2f(h));
  }
  __syncthreads();
  #pragma unroll
  for (int kk = 0; kk < 4; ++kk){
    int idx = t + kk * 256;
    int nl = idx >> 5, cl = idx & 31;
    size_t o = ((size_t)(b * Nn + n0 + nl)) * Cn + c0 + cl;
    out_hi[o] = th_[cl][nl];
    out_lo[o] = tl_[cl][nl];
  }
}

// ============================ MFMA GEMMs ============================

// V = Wv @ X. xT: [b][n][c'] bf16, wvb: [c][c'] bf16. 128x128 tile, BK=64.
__global__ __launch_bounds__(256) void k_v_mfma(const bf16* __restrict__ xT,
                                                const bf16* __restrict__ wvb,
                                                const float* __restrict__ bv,
                                                bf16* __restrict__ v){
  __shared__ short As[128 * 64];
  __shared__ short Bs[128 * 64];
  __shared__ float bvs[128];
  int nb = blockIdx.x * 128, cb = blockIdx.y * 128, b = blockIdx.z;
  int t = threadIdx.x, lane = t & 63, wid = t >> 6;
  int wm = wid >> 1, wn = wid & 1;
  int l15 = lane & 15, l4 = lane >> 4;
  if (t < 128) bvs[t] = bv[cb + t];
  f32x4 acc[4][4];
  #pragma unroll
  for (int i = 0; i < 4; i++)
    #pragma unroll
    for (int j = 0; j < 4; j++) acc[i][j] = (f32x4){0.f, 0.f, 0.f, 0.f};

  const bf16* wp = wvb + (size_t)cb * Cn;
  const bf16* xp = xT + ((size_t)b * Nn + nb) * Cn;
  int r8 = lane >> 3;
  int kc = (lane & 7) * 8;
  for (int kt = 0; kt < 8; ++kt){
    int k0 = kt * 64;
    #pragma unroll
    for (int j = 0; j < 4; ++j){
      int inst = wid * 4 + j;
      int row = inst * 8 + r8;
      gload_lds16(wp + (size_t)row * Cn + k0 + kc, (char*)As + inst * 1024);
      gload_lds16(xp + (size_t)row * Cn + k0 + kc, (char*)Bs + inst * 1024);
    }
    __syncthreads();
    #pragma unroll
    for (int kk = 0; kk < 64; kk += 32){
      s16x8 a[4], bb[4];
      #pragma unroll
      for (int mi = 0; mi < 4; mi++)
        a[mi] = *(const s16x8*)&As[(wm * 64 + mi * 16 + l15) * 64 + kk + l4 * 8];
      #pragma unroll
      for (int ni = 0; ni < 4; ni++)
        bb[ni] = *(const s16x8*)&Bs[(wn * 64 + ni * 16 + l15) * 64 + kk + l4 * 8];
      #pragma unroll
      for (int mi = 0; mi < 4; mi++)
        #pragma unroll
        for (int ni = 0; ni < 4; ni++)
          acc[mi][ni] = __builtin_amdgcn_mfma_f32_16x16x32_bf16(a[mi], bb[ni], acc[mi][ni], 0, 0, 0);
    }
    __syncthreads();
  }
  #pragma unroll
  for (int mi = 0; mi < 4; mi++){
    #pragma unroll
    for (int r = 0; r < 4; r++){
      int cl = wm * 64 + mi * 16 + l4 * 4 + r;
      int c  = cb + cl;
      float bias = bvs[cl];
      #pragma unroll
      for (int ni = 0; ni < 4; ni++){
        int n = nb + wn * 64 + ni * 16 + l15;
        v[((size_t)(b * Cn + c)) * Nn + n] = f2bf(acc[mi][ni][r] + bias);
      }
    }
  }
}

// Q,K = [Wq;Wk] @ X with split-precision bf16 (x=hi+lo, w=hi+lo; 3 MFMA terms).
__global__ __launch_bounds__(256) void k_qk_mfma(const bf16* __restrict__ xT_hi,
                                                 const bf16* __restrict__ xT_lo,
                                                 const bf16* __restrict__ wqk_hi,
                                                 const bf16* __restrict__ wqk_lo,
                                                 const float* __restrict__ bqk,
                                                 bf16* __restrict__ q,
                                                 bf16* __restrict__ k){
  __shared__ short Ah[128 * 64];
  __shared__ short Al[128 * 64];
  __shared__ short Bh[128 * 64];
  __shared__ short Bl[128 * 64];
  __shared__ float bs[128];
  int nb = blockIdx.x * 128, b = blockIdx.y;
  int t = threadIdx.x, lane = t & 63, wid = t >> 6;
  int wm = wid >> 1, wn = wid & 1;
  int l15 = lane & 15, l4 = lane >> 4;
  if (t < 128) bs[t] = bqk[t];
  f32x4 acc[4][4];
  #pragma unroll
  for (int i = 0; i < 4; i++)
    #pragma unroll
    for (int j = 0; j < 4; j++) acc[i][j] = (f32x4){0.f, 0.f, 0.f, 0.f};

  const bf16* xh = xT_hi + ((size_t)b * Nn + nb) * Cn;
  const bf16* xl = xT_lo + ((size_t)b * Nn + nb) * Cn;
  int r8 = lane >> 3;
  int kc = (lane & 7) * 8;
  for (int kt = 0; kt < 8; ++kt){
    int k0 = kt * 64;
    #pragma unroll
    for (int j = 0; j < 4; ++j){
      int inst = wid * 4 + j;
      int row = inst * 8 + r8;
      size_t off = (size_t)row * Cn + k0 + kc;
      gload_lds16(wqk_hi + off, (char*)Ah + inst * 1024);
      gload_lds16(wqk_lo + off, (char*)Al + inst * 1024);
      gload_lds16(xh + off,     (char*)Bh + inst * 1024);
      gload_lds16(xl + off,     (char*)Bl + inst * 1024);
    }
    __syncthreads();
    #pragma unroll
    for (int kk = 0; kk < 64; kk += 32){
      s16x8 ah[4], al[4], bh[4], bl[4];
      #pragma unroll
      for (int mi = 0; mi < 4; mi++){
        int idx = (wm * 64 + mi * 16 + l15) * 64 + kk + l4 * 8;
        ah[mi] = *(const s16x8*)&Ah[idx];
        al[mi] = *(const s16x8*)&Al[idx];
      }
      #pragma unroll
      for (int ni = 0; ni < 4; ni++){
        int idx = (wn * 64 + ni * 16 + l15) * 64 + kk + l4 * 8;
        bh[ni] = *(const s16x8*)&Bh[idx];
        bl[ni] = *(const s16x8*)&Bl[idx];
      }
      #pragma unroll
      for (int mi = 0; mi < 4; mi++)
        #pragma unroll
        for (int ni = 0; ni < 4; ni++){
          acc[mi][ni] = __builtin_amdgcn_mfma_f32_16x16x32_bf16(ah[mi], bh[ni], acc[mi][ni], 0, 0, 0);
          acc[mi][ni] = __builtin_amdgcn_mfma_f32_16x16x32_bf16(ah[mi], bl[ni], acc[mi][ni], 0, 0, 0);
          acc[mi][ni] = __builtin_amdgcn_mfma_f32_16x16x32_bf16(al[mi], bh[ni], acc[mi][ni], 0, 0, 0);
        }
    }
    __syncthreads();
  }
  #pragma unroll
  for (int mi = 0; mi < 4; mi++){
    #pragma unroll
    for (int r = 0; r < 4; r++){
      int o = wm * 64 + mi * 16 + l4 * 4 + r;
      float bias = bs[o];
      #pragma unroll
      for (int ni = 0; ni < 4; ni++){
        int n = nb + wn * 64 + ni * 16 + l15;
        float val = acc[mi][ni][r] + bias;
        if (o < 64) q[((size_t)(b * CQn + o)) * Nn + n]        = f2bf(val);
        else        k[((size_t)(b * CQn + o - 64)) * Nn + n]   = f2bf(val);
      }
    }
  }
}

// comb_h: per (b,w): ohT[b,w,c,h] = sum_g att[b,h,w,g]*vT[b,w,c,g]
// M=c (128-tile), N=h (128), K=g (128). XOR-swizzled LDS.
__global__ __launch_bounds__(256) void k_comb_h_mfma(const float* __restrict__ att,
                                                     const bf16* __restrict__ vT,
                                                     bf16* __restrict__ ohT){
  __shared__ short As[128 * 128];
  __shared__ short Bs[128 * 128];
  int cb = blockIdx.x * 128, w = blockIdx.y, b = blockIdx.z;
  int t = threadIdx.x, lane = t & 63, wid = t >> 6;
  int wm = wid >> 1, wn = wid & 1;
  int l15 = lane & 15, l4 = lane >> 4;

  // stage V tile (rows c, K-contig), swizzled; 16B (s16x8) chunks
  const bf16* vp = vT + ((size_t)(b * Wn + w) * Cn + cb) * Hn;
  for (int s = t; s < 2048; s += 256){
    int row = s >> 4, seg = s & 15;
    s16x8 d = *(const s16x8*)(vp + (size_t)row * Hn + seg * 8);
    int byte = (row * 256 + seg * 16) ^ ((row & 7) << 4);
    *(s16x8*)((char*)As + byte) = d;
  }
  // stage att tile (rows h), fp32->bf16 pairs, swizzled
  const float* ap = att + (size_t)b * Hn * Wn * 256 + (size_t)w * 256;
  for (int s = t; s < 8192; s += 256){
    int h = s >> 6, g2 = (s & 63) * 2;
    const float* rp = ap + (size_t)h * (Wn * 256);
    unsigned u = pack2bf(rp[g2], rp[g2 + 1]);
    int byte = (h * 256 + g2 * 2) ^ ((h & 7) << 4);
    *(unsigned*)((char*)Bs + byte) = u;
  }
  __syncthreads();

  f32x4 acc[4][4];
  #pragma unroll
  for (int i = 0; i < 4; i++)
    #pragma unroll
    for (int j = 0; j < 4; j++) acc[i][j] = (f32x4){0.f, 0.f, 0.f, 0.f};
  #pragma unroll
  for (int kk = 0; kk < 128; kk += 32){
    s16x8 a[4], bb[4];
    #pragma unroll
    for (int mi = 0; mi < 4; mi++){
      int row = wm * 64 + mi * 16 + l15;
      int byte = (row * 256 + (kk + l4 * 8) * 2) ^ ((row & 7) << 4);
      a[mi] = *(const s16x8*)((char*)As + byte);
    }
    #pragma unroll
    for (int ni = 0; ni < 4; ni++){
      int row = wn * 64 + ni * 16 + l15;
      int byte = (row * 256 + (kk + l4 * 8) * 2) ^ ((row & 7) << 4);
      bb[ni] = *(const s16x8*)((char*)Bs + byte);
    }
    #pragma unroll
    for (int mi = 0; mi < 4; mi++)
      #pragma unroll
      for (int ni = 0; ni < 4; ni++)
        acc[mi][ni] = __builtin_amdgcn_mfma_f32_16x16x32_bf16(a[mi], bb[ni], acc[mi][ni], 0, 0, 0);
  }
  bf16* op = ohT + ((size_t)(b * Wn + w) * Cn + cb) * Hn;
  #pragma unroll
  for (int mi = 0; mi < 4; mi++)
    #pragma unroll
    for (int r = 0; r < 4; r++){
      int cl = wm * 64 + mi * 16 + l4 * 4 + r;
      #pragma unroll
      for (int ni = 0; ni < 4; ni++){
        int h = wn * 64 + ni * 16 + l15;
        op[(size_t)cl * Hn + h] = f2bf(acc[mi][ni][r]);
      }
    }
}

// comb_w: per (b,h): ow[b,c,h,w_] = sum_g att[b,h,w_,128+g]*v[b,c,h,g]
__global__ __launch_bounds__(256) void k_comb_w_mfma(const float* __restrict__ att,
                                                     const bf16* __restrict__ v,
                                                     bf16* __restrict__ ow){
  __shared__ short As[128 * 128];
  __shared__ short Bs[128 * 128];
  int cb = blockIdx.x * 128, h = blockIdx.y, b = blockIdx.z;
  int t = threadIdx.x, lane = t & 63, wid = t >> 6;
  int wm = wid >> 1, wn = wid & 1;
  int l15 = lane & 15, l4 = lane >> 4;

  const bf16* vp = v + (size_t)(b * Cn + cb) * Nn + (size_t)h * Wn;
  for (int s = t; s < 2048; s += 256){
    int row = s >> 4, seg = s & 15;
    s16x8 d = *(const s16x8*)(vp + (size_t)row * Nn + seg * 8);
    int byte = (row * 256 + seg * 16) ^ ((row & 7) << 4);
    *(s16x8*)((char*)As + byte) = d;
  }
  const float* ap = att + ((size_t)(b * Hn + h) * Wn) * 256 + 128;
  for (int s = t; s < 8192; s += 256){
    int wr = s >> 6, g2 = (s & 63) * 2;
    const float* rp = ap + (size_t)wr * 256;
    unsigned u = pack2bf(rp[g2], rp[g2 + 1]);
    int byte = (wr * 256 + g2 * 2) ^ ((wr & 7) << 4);
    *(unsigned*)((char*)Bs + byte) = u;
  }
  __syncthreads();

  f32x4 acc[4][4];
  #pragma unroll
  for (int i = 0; i < 4; i++)
    #pragma unroll
    for (int j = 0; j < 4; j++) acc[i][j] = (f32x4){0.f, 0.f, 0.f, 0.f};
  #pragma unroll
  for (int kk = 0; kk < 128; kk += 32){
    s16x8 a[4], bb[4];
    #pragma unroll
    for (int mi = 0; mi < 4; mi++){
      int row = wm * 64 + mi * 16 + l15;
      int byte = (row * 256 + (kk + l4 * 8) * 2) ^ ((row & 7) << 4);
      a[mi] = *(const s16x8*)((char*)As + byte);
    }
    #pragma unroll
    for (int ni = 0; ni < 4; ni++){
      int row = wn * 64 + ni * 16 + l15;
      int byte = (row * 256 + (kk + l4 * 8) * 2) ^ ((row & 7) << 4);
      bb[ni] = *(const s16x8*)((char*)Bs + byte);
    }
    #pragma unroll
    for (int mi = 0; mi < 4; mi++)
      #pragma unroll
      for (int ni = 0; ni < 4; ni++)
        acc[mi][ni] = __builtin_amdgcn_mfma_f32_16x16x32_bf16(a[mi], bb[ni], acc[mi][ni], 0, 0, 0);
  }
  bf16* op = ow + (size_t)(b * Cn + cb) * Nn + (size_t)h * Wn;
  #pragma unroll
  for (int mi = 0; mi < 4; mi++)
    #pragma unroll
    for (int r = 0; r < 4; r++){
      int cl = wm * 64 + mi * 16 + l4 * 4 + r;
      #pragma unroll
      for (int ni = 0; ni < 4; ni++){
        int wr = wn * 64 + ni * 16 + l15;
        op[(size_t)cl * Nn + wr] = f2bf(acc[mi][ni][r]);
      }
    }
}

// ============================ remaining CA kernels ============================

// [b,c,h,w] -> [b,w,c,h] (bf16), 32x32 tiles
__global__ __launch_bounds__(256) void k_trans(const bf16* __restrict__ in,
                                               bf16* __restrict__ out,
                                               int CH){
  __shared__ bf16 tile[32][33];
  int tl = blockIdx.x, c = blockIdx.y, b = blockIdx.z;
  int th = tl >> 2, tw = tl & 3;
  int h0 = th * 32, w0 = tw * 32;
  int t = threadIdx.x;
  const bf16* ip = in + ((size_t)(b * CH + c)) * Nn;
  #pragma unroll
  for (int kk = 0; kk < 4; ++kk){
    int idx = t + kk * 256;
    int hl = idx >> 5, wl = idx & 31;
    tile[hl][wl] = ip[(h0 + hl) * Wn + w0 + wl];
  }
  __syncthreads();
  #pragma unroll
  for (int kk = 0; kk < 4; ++kk){
    int idx = t + kk * 256;
    int wl = idx >> 5, hl = idx & 31;
    out[((size_t)(b * Wn + w0 + wl) * CH + c) * Hn + h0 + hl] = tile[hl][wl];
  }
}

// e_h[h,g] = sum_c qT[b,w,c,h]*kT[b,w,c,g], diag -> -1e30
__global__ __launch_bounds__(256) void k_eh(const bf16* __restrict__ qT,
                                            const bf16* __restrict__ kT,
                                            float* __restrict__ e){
  __shared__ float smem[16384];
  float* qs = smem;
  float* ks = smem + 8192;
  int w = blockIdx.x, b = blockIdx.y;
  int t = threadIdx.x;
  const bf16* qp = qT + (size_t)(b * Wn + w) * CQn * Hn;
  const bf16* kp = kT + (size_t)(b * Wn + w) * CQn * Hn;
  for (int i = t; i < 8192; i += 256){ qs[i] = bf2f(qp[i]); ks[i] = bf2f(kp[i]); }
  __syncthreads();
  int hg = t >> 3, gg = t & 7;
  float acc[4][16];
  #pragma unroll
  for (int i = 0; i < 4; i++)
    #pragma unroll
    for (int j = 0; j < 16; j++) acc[i][j] = 0.f;
  for (int c = 0; c < CQn; ++c){
    float qv[4], kv[16];
    #pragma unroll
    for (int i = 0; i < 4; i++) qv[i] = qs[c * 128 + hg * 4 + i];
    #pragma unroll
    for (int j = 0; j < 16; j++) kv[j] = ks[c * 128 + gg + 8 * j];
    #pragma unroll
    for (int i = 0; i < 4; i++)
      #pragma unroll
      for (int j = 0; j < 16; j++) acc[i][j] += qv[i] * kv[j];
  }
  __syncthreads();
  #pragma unroll
  for (int i = 0; i < 4; i++)
    #pragma unroll
    for (int j = 0; j < 16; j++)
      smem[(hg * 4 + i) * 128 + gg + 8 * j] = acc[i][j];
  __syncthreads();
  for (int kk = 0; kk < 64; ++kk){
    int idx = t + kk * 256;
    int h = idx >> 7, g = idx & 127;
    float val = (h == g) ? -1e30f : smem[idx];
    e[((size_t)(b * Hn + h) * Wn + w) * 256 + g] = val;
  }
}

// e_w[w,v] = sum_c q[b,c,h,w]*k[b,c,h,v]
__global__ __launch_bounds__(256) void k_ew(const bf16* __restrict__ q,
                                            const bf16* __restrict__ k,
                                            float* __restrict__ e){
  __shared__ float smem[16384];
  float* qs = smem;
  float* ks = smem + 8192;
  int h = blockIdx.x, b = blockIdx.y;
  int t = threadIdx.x;
  for (int i = t; i < 8192; i += 256){
    int c = i >> 7, wl = i & 127;
    size_t base = ((size_t)(b * CQn + c) * Hn + h) * Wn + wl;
    qs[i] = bf2f(q[base]);
    ks[i] = bf2f(k[base]);
  }
  __syncthreads();
  int wg = t >> 3, vg = t & 7;
  float acc[4][16];
  #pragma unroll
  for (int i = 0; i < 4; i++)
    #pragma unroll
    for (int j = 0; j < 16; j++) acc[i][j] = 0.f;
  for (int c = 0; c < CQn; ++c){
    float qv[4], kv[16];
    #pragma unroll
    for (int i = 0; i < 4; i++) qv[i] = qs[c * 128 + wg * 4 + i];
    #pragma unroll
    for (int j = 0; j < 16; j++) kv[j] = ks[c * 128 + vg + 8 * j];
    #pragma unroll
    for (int i = 0; i < 4; i++)
      #pragma unroll
      for (int j = 0; j < 16; j++) acc[i][j] += qv[i] * kv[j];
  }
  __syncthreads();
  #pragma unroll
  for (int i = 0; i < 4; i++)
    #pragma unroll
    for (int j = 0; j < 16; j++)
      smem[(wg * 4 + i) * 128 + vg + 8 * j] = acc[i][j];
  __syncthreads();
  for (int kk = 0; kk < 64; ++kk){
    int idx = t + kk * 256;
    int wr = idx >> 7, vc = idx & 127;
    e[((size_t)(b * Hn + h) * Wn + wr) * 256 + 128 + vc] = smem[idx];
  }
}

// softmax over 256 per row, in place; one wave per row
__global__ __launch_bounds__(256) void k_softmax(float* __restrict__ e){
  int wid = threadIdx.x >> 6, lid = threadIdx.x & 63;
  size_t row = (size_t)blockIdx.x * 4 + wid;
  float* p = e + row * 256;
  float v[4];
  #pragma unroll
  for (int i = 0; i < 4; i++) v[i] = p[lid + 64 * i];
  float m = fmaxf(fmaxf(v[0], v[1]), fmaxf(v[2], v[3]));
  for (int o = 32; o > 0; o >>= 1) m = fmaxf(m, __shfl_xor(m, o));
  float s = 0.f;
  #pragma unroll
  for (int i = 0; i < 4; i++){ v[i] = expf(v[i] - m); s += v[i]; }
  for (int o = 32; o > 0; o >>= 1) s += __shfl_xor(s, o);
  float inv = 1.f / s;
  #pragma unroll
  for (int i = 0; i < 4; i++) p[lid + 64 * i] = v[i] * inv;
}

// out = gamma*(ohT^T + ow) + in (+ addend)
__global__ __launch_bounds__(256) void k_fuse(const float* __restrict__ in,
                                              const bf16* __restrict__ ohT,
                                              const bf16* __restrict__ ow,
                                              const float* __restrict__ addend,
                                              const float* __restrict__ gamma,
                                              float* __restrict__ out){
  __shared__ float tile[32][33];
  int tl = blockIdx.x, c = blockIdx.y, b = blockIdx.z;
  int th = tl >> 2, tw = tl & 3;
  int h0 = th * 32, w0 = tw * 32;
  int t = threadIdx.x;
  float g = gamma[0];
  #pragma unroll
  for (int kk = 0; kk < 4; ++kk){
    int idx = t + kk * 256;
    int wl = idx >> 5, hl = idx & 31;
    tile[wl][hl] = bf2f(ohT[((size_t)(b * Wn + w0 + wl) * Cn + c) * Hn + h0 + hl]);
  }
  __syncthreads();
  #pragma unroll
  for (int kk = 0; kk < 4; ++kk){
    int idx = t + kk * 256;
    int hl = idx >> 5, wl = idx & 31;
    size_t o = ((size_t)(b * Cn + c)) * Nn + (size_t)(h0 + hl) * Wn + w0 + wl;
    float val = g * (tile[wl][hl] + bf2f(ow[o])) + in[o];
    if (addend) val += addend[o];
    out[o] = val;
  }
}

// ============================ host ============================

static void run_ca(const float* in, const bf16* wqk_hi, const bf16* wqk_lo,
                   const float* bqk, const bf16* wvb, const float* bv,
                   const float* gamma, const float* addend, float* out,
                   bf16* q, bf16* k, bf16* qT, bf16* kT, bf16* v, bf16* vT,
                   float* e, bf16* xT_hi, bf16* xT_lo, bf16* tmp, hipStream_t stream){
  bf16* ohT = tmp;
  bf16* ow  = tmp + (size_t)Bn * Cn * Nn;
  k_cvt_T<<<dim3(Nn / 32, Cn / 32, Bn), 256, 0, stream>>>(in, xT_hi, xT_lo);
  k_qk_mfma<<<dim3(Nn / 128, Bn), 256, 0, stream>>>(xT_hi, xT_lo, wqk_hi, wqk_lo, bqk, q, k);
  k_trans<<<dim3(16, CQn, Bn), 256, 0, stream>>>(q, qT, CQn);
  k_trans<<<dim3(16, CQn, Bn), 256, 0, stream>>>(k, kT, CQn);
  k_v_mfma<<<dim3(Nn / 128, Cn / 128, Bn), 256, 0, stream>>>(xT_hi, wvb, bv, v);
  k_trans<<<dim3(16, Cn, Bn), 256, 0, stream>>>(v, vT, Cn);
  k_eh<<<dim3(Wn, Bn), 256, 0, stream>>>(qT, kT, e);   // e aliases xT_hi; all xT readers done
  k_ew<<<dim3(Hn, Bn), 256, 0, stream>>>(q, k, e);
  k_softmax<<<(Bn * Nn) / 4, 256, 0, stream>>>(e);
  k_comb_h_mfma<<<dim3(Cn / 128, Wn, Bn), 256, 0, stream>>>(e, vT, ohT);  // ohT overwrites xT_lo (dead)
  k_comb_w_mfma<<<dim3(Cn / 128, Hn, Bn), 256, 0, stream>>>(e, v, ow);
  k_fuse<<<dim3(16, Cn, Bn), 256, 0, stream>>>(in, ohT, ow, addend, gamma, out);
}

extern "C" void kernel_launch(void* const* d_in, const int* in_sizes, int n_in,
                              void* d_out, int out_size, void* d_ws, size_t ws_size,
                              hipStream_t stream){
  (void)in_sizes; (void)n_in; (void)out_size; (void)ws_size;
  const float* x         = (const float*)d_in[0];
  const float* w_q_right = (const float*)d_in[1];
  const float* w_v_right = (const float*)d_in[2];
  const float* w_up      = (const float*)d_in[3];
  const float* b_up      = (const float*)d_in[4];
  const float* w_q_left  = (const float*)d_in[5];
  const float* w_v_left  = (const float*)d_in[6];
  const float* wq        = (const float*)d_in[7];
  const float* bq        = (const float*)d_in[8];
  const float* wk        = (const float*)d_in[9];
  const float* bk        = (const float*)d_in[10];
  const float* wv        = (const float*)d_in[11];
  const float* bv        = (const float*)d_in[12];
  const float* gamma     = (const float*)d_in[13];

  const size_t SZ_MAP = (size_t)Bn * Cn * Nn;     // 33.5M elements
  char* p = (char*)d_ws;
  float* buf0   = (float*)p; p += SZ_MAP * 4;
  float* buf1   = (float*)p; p += SZ_MAP * 4;
  bf16*  vbuf   = (bf16*)p;  p += SZ_MAP * 2;
  bf16*  vT     = (bf16*)p;  p += SZ_MAP * 2;
  bf16*  qbuf   = (bf16*)p;  p += (size_t)Bn * CQn * Nn * 2;
  bf16*  kbuf   = (bf16*)p;  p += (size_t)Bn * CQn * Nn * 2;
  bf16*  qT     = (bf16*)p;  p += (size_t)Bn * CQn * Nn * 2;
  bf16*  kT     = (bf16*)p;  p += (size_t)Bn * CQn * Nn * 2;
  float* ebuf   = (float*)p; p += (size_t)Bn * Nn * 256 * 4;  // doubles as xT_hi (bf16)
  float* logits = (float*)p; p += (size_t)Bn * Nn * 4;
  float* ctxlog = (float*)p; p += (size_t)Bn * Nn * 4;
  float* msp    = (float*)p; p += (size_t)Bn * Nn * 4;
  float* xbar   = (float*)p; p += Bn * Cn * 4;
  float* wgt    = (float*)p; p += Bn * Cn * 4;
  float* u      = (float*)p; p += Bn * Cn * 4;
  float* mch    = (float*)p; p += Bn * Cn * 4;
  float* stats_sp = (float*)p; p += 64;
  float* stats_ch = (float*)p; p += 64;
  bf16*  wvb    = (bf16*)p;  p += (size_t)Cn * Cn * 2;
  bf16*  wqk_hi = (bf16*)p;  p += (size_t)128 * Cn * 2;
  bf16*  wqk_lo = (bf16*)p;  p += (size_t)128 * Cn * 2;
  float* bqk    = (float*)p; p += 128 * 4;
  bf16*  xT_hi  = (bf16*)ebuf;    // alias: lifetime ends before e is written
  bf16*  xT_lo  = (bf16*)d_out;   // alias: lifetime ends before ohT/fuse writes d_out

  // ---- weight prep (once) ----
  k_cvt_w<<<(Cn * Cn + 255) / 256, 256, 0, stream>>>(wv, wvb, Cn * Cn);
  k_prep_wqk<<<(128 * Cn) / 256, 256, 0, stream>>>(wq, wk, bq, bk, wqk_hi, wqk_lo, bqk);

  // ---- stage 0: gating masks ----
  k_dotc<<<Bn * Nn / 256, 256, 0, stream>>>(x, w_q_right, 0, logits);
  k_rowmean<<<Bn * Cn, 256, 0, stream>>>(x, xbar, 1.f / Nn);
  k_avg_u<<<1, 256, 0, stream>>>(w_q_left, w_v_left, xbar, u);
  k_stats<<<Bn, 1024, 0, stream>>>(logits, stats_sp);
  k_weighted<<<Bn * Cn, 256, 0, stream>>>(x, logits, stats_sp, wgt);
  k_mch<<<1, 256, 0, stream>>>(w_v_right, w_up, b_up, wgt, mch);
  k_dotc<<<Bn * Nn / 256, 256, 0, stream>>>(x, u, Cn, ctxlog);
  k_stats<<<Bn, 1024, 0, stream>>>(ctxlog, stats_ch);
  k_msp<<<Bn * Nn / 256, 256, 0, stream>>>(ctxlog, stats_ch, msp);
  k_apply<<<(int)(SZ_MAP / 256), 256, 0, stream>>>(x, mch, msp, buf0, buf1);

  // ---- CA1: cc' = CA(cc), in-place buf0; tmp = d_out ----
  run_ca(buf0, wqk_hi, wqk_lo, bqk, wvb, bv, gamma, nullptr, buf0,
         qbuf, kbuf, qT, kT, vbuf, vT, ebuf, xT_hi, xT_lo, (bf16*)d_out, stream);
  // ---- CA2: s = CA(cs) + cc' -> buf0 ----
  run_ca(buf1, wqk_hi, wqk_lo, bqk, wvb, bv, gamma, buf0, buf0,
         qbuf, kbuf, qT, kT, vbuf, vT, ebuf, xT_hi, xT_lo, (bf16*)d_out, stream);
  // ---- CA3: out = CA(s) -> d_out; tmp = buf1 ----
  run_ca(buf0, wqk_hi, wqk_lo, bqk, wvb, bv, gamma, nullptr, (float*)d_out,
         qbuf, kbuf, qT, kT, vbuf, vT, ebuf, xT_hi, xT_lo, (bf16*)buf1, stream);
}

// Round 6
// 1631.997 us; speedup vs baseline: 2.4915x; 1.1565x over previous
//
#include <hip/hip_runtime.h>
#include <hip/hip_bf16.h>
#include <math.h>

typedef __hip_bfloat16 bf16;
typedef __attribute__((ext_vector_type(8))) short s16x8;
typedef __attribute__((ext_vector_type(4))) float f32x4;

constexpr int Bn  = 4;
constexpr int Cn  = 512;
constexpr int Hn  = 128;
constexpr int Wn  = 128;
constexpr int Nn  = Hn * Wn;   // 16384
constexpr int CQn = 64;
constexpr int CIn = 256;

__device__ __forceinline__ float bf2f(bf16 v){ return __bfloat162float(v); }
__device__ __forceinline__ bf16  f2bf(float v){ return __float2bfloat16(v); }

// async global->LDS, 16B per lane; LDS dest must be wave-uniform base (HW adds lane*16)
__device__ __forceinline__ void gload_lds16(const void* g, void* l){
  __builtin_amdgcn_global_load_lds(
      (const __attribute__((address_space(1))) unsigned int*)g,
      (__attribute__((address_space(3))) unsigned int*)l,
      16, 0, 0);
}

// ============================ stage 0 ============================

// out[b*Nn+n] = sum_c w[b*wstride + c] * x[(b*Cn+c)*Nn + n]
__global__ __launch_bounds__(256) void k_dotc(const float* __restrict__ x,
                                              const float* __restrict__ w,
                                              int wstride,
                                              float* __restrict__ out){
  int t = blockIdx.x * 256 + threadIdx.x;      // over B*Nn
  int b = t >> 14;
  const float* wp = w + (size_t)b * wstride;
  const float* xp = x + (size_t)b * Cn * Nn + (t & (Nn - 1));
  float acc = 0.f;
  #pragma unroll 8
  for (int c = 0; c < Cn; ++c) acc += wp[c] * xp[(size_t)c * Nn];
  out[t] = acc;
}

// out[bc] = scale * sum_n x[bc*Nn+n]
__global__ __launch_bounds__(256) void k_rowmean(const float* __restrict__ x,
                                                 float* __restrict__ out,
                                                 float scale){
  int bc = blockIdx.x;
  const float* xp = x + (size_t)bc * Nn;
  float acc = 0.f;
  for (int n = threadIdx.x; n < Nn; n += 256) acc += xp[n];
  for (int o = 32; o > 0; o >>= 1) acc += __shfl_down(acc, o);
  __shared__ float red[4];
  if ((threadIdx.x & 63) == 0) red[threadIdx.x >> 6] = acc;
  __syncthreads();
  if (threadIdx.x == 0) out[bc] = (red[0] + red[1] + red[2] + red[3]) * scale;
}

// out[b][i] = sum_j W[i][j]*vec[b][j]; W: CIn x Cn row-major; grid Bn, 256 thr (one per i)
__global__ __launch_bounds__(256) void k_rowdot(const float* __restrict__ W,
                                                const float* __restrict__ vec,
                                                float* __restrict__ out){
  __shared__ float vs[Cn];
  int b = blockIdx.x, t = threadIdx.x;
  for (int j = t; j < Cn; j += 256) vs[j] = vec[b * Cn + j];
  __syncthreads();
  const float4* wp = (const float4*)(W + (size_t)t * Cn);
  float a = 0.f;
  #pragma unroll 4
  for (int j = 0; j < Cn / 4; ++j){
    float4 w4 = wp[j];
    a += w4.x * vs[4*j] + w4.y * vs[4*j+1] + w4.z * vs[4*j+2] + w4.w * vs[4*j+3];
  }
  out[b * CIn + t] = a;
}

// out[b][c] = sum_j W[j][c]*vec[b][j]; W: CIn x Cn; grid (Cn/256, Bn)
__global__ __launch_bounds__(256) void k_coldot(const float* __restrict__ W,
                                                const float* __restrict__ vec,
                                                float* __restrict__ out){
  __shared__ float vs[CIn];
  int b = blockIdx.y, t = threadIdx.x;
  int c = blockIdx.x * 256 + t;
  if (t < CIn) vs[t] = vec[b * CIn + t];
  __syncthreads();
  float a = 0.f;
  #pragma unroll 8
  for (int j = 0; j < CIn; ++j) a += W[(size_t)j * Cn + c] * vs[j];
  out[b * Cn + c] = a;
}

// mch[b][o] = sigmoid(sum_ci w_up[o][ci]*ctx[b][ci] + b_up[o]); grid (Cn/256, Bn)
__global__ __launch_bounds__(256) void k_mch2(const float* __restrict__ w_up,
                                              const float* __restrict__ b_up,
                                              const float* __restrict__ ctx,
                                              float* __restrict__ mch){
  __shared__ float cs[CIn];
  int b = blockIdx.y, t = threadIdx.x;
  int o = blockIdx.x * 256 + t;
  if (t < CIn) cs[t] = ctx[b * CIn + t];
  __syncthreads();
  const float4* wp = (const float4*)(w_up + (size_t)o * CIn);
  float a = b_up[o];
  #pragma unroll 4
  for (int j = 0; j < CIn / 4; ++j){
    float4 w4 = wp[j];
    a += w4.x * cs[4*j] + w4.y * cs[4*j+1] + w4.z * cs[4*j+2] + w4.w * cs[4*j+3];
  }
  mch[b * Cn + o] = 1.f / (1.f + expf(-a));
}

// per-b max & sumexp over Nn values
__global__ __launch_bounds__(1024) void k_stats(const float* __restrict__ vv,
                                                float* __restrict__ stats){
  int b = blockIdx.x;
  const float* pp = vv + (size_t)b * Nn;
  int t = threadIdx.x;
  float m = -3.4e38f;
  for (int n = t; n < Nn; n += 1024) m = fmaxf(m, pp[n]);
  for (int o = 32; o > 0; o >>= 1) m = fmaxf(m, __shfl_down(m, o));
  __shared__ float red[16];
  int wid = t >> 6, lid = t & 63;
  if (lid == 0) red[wid] = m;
  __syncthreads();
  if (t == 0){
    float q = red[0];
    for (int i = 1; i < 16; i++) q = fmaxf(q, red[i]);
    red[0] = q;
  }
  __syncthreads();
  m = red[0];
  __syncthreads();
  float s = 0.f;
  for (int n = t; n < Nn; n += 1024) s += expf(pp[n] - m);
  for (int o = 32; o > 0; o >>= 1) s += __shfl_down(s, o);
  if (lid == 0) red[wid] = s;
  __syncthreads();
  if (t == 0){
    float q = 0.f;
    for (int i = 0; i < 16; i++) q += red[i];
    stats[b * 2]     = m;
    stats[b * 2 + 1] = q;
  }
}

// weighted[b,c] = sum_n x[b,c,n]*exp(l[b,n]-m)/den
__global__ __launch_bounds__(256) void k_weighted(const float* __restrict__ x,
                                                  const float* __restrict__ logits,
                                                  const float* __restrict__ stats,
                                                  float* __restrict__ out){
  int bc = blockIdx.x;
  int b = bc >> 9;
  const float* xp = x + (size_t)bc * Nn;
  const float* lp = logits + (size_t)b * Nn;
  float m = stats[b * 2], den = stats[b * 2 + 1];
  float acc = 0.f;
  for (int n = threadIdx.x; n < Nn; n += 256) acc += xp[n] * expf(lp[n] - m);
  for (int o = 32; o > 0; o >>= 1) acc += __shfl_down(acc, o);
  __shared__ float red[4];
  if ((threadIdx.x & 63) == 0) red[threadIdx.x >> 6] = acc;
  __syncthreads();
  if (threadIdx.x == 0) out[bc] = (red[0] + red[1] + red[2] + red[3]) / den;
}

// msp[b,n] = sigmoid(exp(l-m)/den)
__global__ __launch_bounds__(256) void k_msp(const float* __restrict__ lg,
                                             const float* __restrict__ stats,
                                             float* __restrict__ msp){
  int t = blockIdx.x * 256 + threadIdx.x;
  int b = t >> 14;
  float v = expf(lg[t] - stats[b * 2]) / stats[b * 2 + 1];
  msp[t] = 1.f / (1.f + expf(-v));
}

// cc = x * mch[b,c] ; cs = x * msp[b,n]
__global__ __launch_bounds__(256) void k_apply(const float* __restrict__ x,
                                               const float* __restrict__ mch,
                                               const float* __restrict__ msp,
                                               float* __restrict__ cc,
                                               float* __restrict__ cs){
  size_t t = (size_t)blockIdx.x * 256 + threadIdx.x;
  int bc = (int)(t >> 14);
  int b  = bc >> 9;
  int n  = (int)(t & (Nn - 1));
  float xv = x[t];
  cc[t] = xv * mch[bc];
  cs[t] = xv * msp[b * Nn + n];
}

// ============================ conversions ============================

// wv fp32 [c][c'] -> bf16 (same layout)
__global__ __launch_bounds__(256) void k_cvt_w(const float* __restrict__ in,
                                               bf16* __restrict__ out, int n){
  int t = blockIdx.x * 256 + threadIdx.x;
  if (t < n) out[t] = f2bf(in[t]);
}

// wqk hi/lo: rows 0-63 = wq, 64-127 = wk (bf16 split); bqk fp32
__global__ __launch_bounds__(256) void k_prep_wqk(const float* __restrict__ wq,
                                                  const float* __restrict__ wk,
                                                  const float* __restrict__ bq,
                                                  const float* __restrict__ bk,
                                                  bf16* __restrict__ wqk_hi,
                                                  bf16* __restrict__ wqk_lo,
                                                  float* __restrict__ bqk){
  int t = blockIdx.x * 256 + threadIdx.x;   // over 128*512
  int o = t >> 9, c = t & 511;
  float v = (o < 64) ? wq[(size_t)o * Cn + c] : wk[(size_t)(o - 64) * Cn + c];
  bf16 h = f2bf(v);
  wqk_hi[t] = h;
  wqk_lo[t] = f2bf(v - bf2f(h));
  if (t < 128) bqk[t] = (t < 64) ? bq[t] : bk[t - 64];
}

// in[b][c][n] fp32 -> xT_hi/xT_lo [b][n][c] bf16 split (K-contiguous for MFMA)
__global__ __launch_bounds__(256) void k_cvt_T(const float* __restrict__ in,
                                               bf16* __restrict__ out_hi,
                                               bf16* __restrict__ out_lo){
  __shared__ bf16 th_[32][33];
  __shared__ bf16 tl_[32][33];
  int nt = blockIdx.x, ct = blockIdx.y, b = blockIdx.z;
  int n0 = nt * 32, c0 = ct * 32;
  int t = threadIdx.x;
  #pragma unroll
  for (int kk = 0; kk < 4; ++kk){
    int idx = t + kk * 256;
    int cl = idx >> 5, nl = idx & 31;
    float v = in[((size_t)(b * Cn + c0 + cl)) * Nn + n0 + nl];
    bf16 h = f2bf(v);
    th_[cl][nl] = h;
    tl_[cl][nl] = f2bf(v - bf2f(h));
  }
  __syncthreads();
  #pragma unroll
  for (int kk = 0; kk < 4; ++kk){
    int idx = t + kk * 256;
    int nl = idx >> 5, cl = idx & 31;
    size_t o = ((size_t)(b * Nn + n0 + nl)) * Cn + c0 + cl;
    out_hi[o] = th_[cl][nl];
    out_lo[o] = tl_[cl][nl];
  }
}

// ============================ MFMA GEMMs ============================

// V = Wv @ X. xT: [b][n][c'] bf16, wvb: [c][c'] bf16. 128x128 tile, BK=64.
__global__ __launch_bounds__(256) void k_v_mfma(const bf16* __restrict__ xT,
                                                const bf16* __restrict__ wvb,
                                                const float* __restrict__ bv,
                                                bf16* __restrict__ v){
  __shared__ short As[128 * 64];
  __shared__ short Bs[128 * 64];
  __shared__ float bvs[128];
  int nb = blockIdx.x * 128, cb = blockIdx.y * 128, b = blockIdx.z;
  int t = threadIdx.x, lane = t & 63, wid = t >> 6;
  int wm = wid >> 1, wn = wid & 1;
  int l15 = lane & 15, l4 = lane >> 4;
  if (t < 128) bvs[t] = bv[cb + t];
  f32x4 acc[4][4];
  #pragma unroll
  for (int i = 0; i < 4; i++)
    #pragma unroll
    for (int j = 0; j < 4; j++) acc[i][j] = (f32x4){0.f, 0.f, 0.f, 0.f};

  const bf16* wp = wvb + (size_t)cb * Cn;
  const bf16* xp = xT + ((size_t)b * Nn + nb) * Cn;
  int r8 = lane >> 3;
  int kc = (lane & 7) * 8;
  for (int kt = 0; kt < 8; ++kt){
    int k0 = kt * 64;
    #pragma unroll
    for (int j = 0; j < 4; ++j){
      int inst = wid * 4 + j;
      int row = inst * 8 + r8;
      gload_lds16(wp + (size_t)row * Cn + k0 + kc, (char*)As + inst * 1024);
      gload_lds16(xp + (size_t)row * Cn + k0 + kc, (char*)Bs + inst * 1024);
    }
    __syncthreads();
    #pragma unroll
    for (int kk = 0; kk < 64; kk += 32){
      s16x8 a[4], bb[4];
      #pragma unroll
      for (int mi = 0; mi < 4; mi++)
        a[mi] = *(const s16x8*)&As[(wm * 64 + mi * 16 + l15) * 64 + kk + l4 * 8];
      #pragma unroll
      for (int ni = 0; ni < 4; ni++)
        bb[ni] = *(const s16x8*)&Bs[(wn * 64 + ni * 16 + l15) * 64 + kk + l4 * 8];
      #pragma unroll
      for (int mi = 0; mi < 4; mi++)
        #pragma unroll
        for (int ni = 0; ni < 4; ni++)
          acc[mi][ni] = __builtin_amdgcn_mfma_f32_16x16x32_bf16(a[mi], bb[ni], acc[mi][ni], 0, 0, 0);
    }
    __syncthreads();
  }
  #pragma unroll
  for (int mi = 0; mi < 4; mi++){
    #pragma unroll
    for (int r = 0; r < 4; r++){
      int cl = wm * 64 + mi * 16 + l4 * 4 + r;
      int c  = cb + cl;
      float bias = bvs[cl];
      #pragma unroll
      for (int ni = 0; ni < 4; ni++){
        int n = nb + wn * 64 + ni * 16 + l15;
        v[((size_t)(b * Cn + c)) * Nn + n] = f2bf(acc[mi][ni][r] + bias);
      }
    }
  }
}

// Q,K = [Wq;Wk] @ X with split-precision bf16 (x=hi+lo, w=hi+lo; 3 MFMA terms).
__global__ __launch_bounds__(256) void k_qk_mfma(const bf16* __restrict__ xT_hi,
                                                 const bf16* __restrict__ xT_lo,
                                                 const bf16* __restrict__ wqk_hi,
                                                 const bf16* __restrict__ wqk_lo,
                                                 const float* __restrict__ bqk,
                                                 bf16* __restrict__ q,
                                                 bf16* __restrict__ k){
  __shared__ short Ah[128 * 64];
  __shared__ short Al[128 * 64];
  __shared__ short Bh[128 * 64];
  __shared__ short Bl[128 * 64];
  __shared__ float bs[128];
  int nb = blockIdx.x * 128, b = blockIdx.y;
  int t = threadIdx.x, lane = t & 63, wid = t >> 6;
  int wm = wid >> 1, wn = wid & 1;
  int l15 = lane & 15, l4 = lane >> 4;
  if (t < 128) bs[t] = bqk[t];
  f32x4 acc[4][4];
  #pragma unroll
  for (int i = 0; i < 4; i++)
    #pragma unroll
    for (int j = 0; j < 4; j++) acc[i][j] = (f32x4){0.f, 0.f, 0.f, 0.f};

  const bf16* xh = xT_hi + ((size_t)b * Nn + nb) * Cn;
  const bf16* xl = xT_lo + ((size_t)b * Nn + nb) * Cn;
  int r8 = lane >> 3;
  int kc = (lane & 7) * 8;
  for (int kt = 0; kt < 8; ++kt){
    int k0 = kt * 64;
    #pragma unroll
    for (int j = 0; j < 4; ++j){
      int inst = wid * 4 + j;
      int row = inst * 8 + r8;
      size_t off = (size_t)row * Cn + k0 + kc;
      gload_lds16(wqk_hi + off, (char*)Ah + inst * 1024);
      gload_lds16(wqk_lo + off, (char*)Al + inst * 1024);
      gload_lds16(xh + off,     (char*)Bh + inst * 1024);
      gload_lds16(xl + off,     (char*)Bl + inst * 1024);
    }
    __syncthreads();
    #pragma unroll
    for (int kk = 0; kk < 64; kk += 32){
      s16x8 ah[4], al[4], bh[4], bl[4];
      #pragma unroll
      for (int mi = 0; mi < 4; mi++){
        int idx = (wm * 64 + mi * 16 + l15) * 64 + kk + l4 * 8;
        ah[mi] = *(const s16x8*)&Ah[idx];
        al[mi] = *(const s16x8*)&Al[idx];
      }
      #pragma unroll
      for (int ni = 0; ni < 4; ni++){
        int idx = (wn * 64 + ni * 16 + l15) * 64 + kk + l4 * 8;
        bh[ni] = *(const s16x8*)&Bh[idx];
        bl[ni] = *(const s16x8*)&Bl[idx];
      }
      #pragma unroll
      for (int mi = 0; mi < 4; mi++)
        #pragma unroll
        for (int ni = 0; ni < 4; ni++){
          acc[mi][ni] = __builtin_amdgcn_mfma_f32_16x16x32_bf16(ah[mi], bh[ni], acc[mi][ni], 0, 0, 0);
          acc[mi][ni] = __builtin_amdgcn_mfma_f32_16x16x32_bf16(ah[mi], bl[ni], acc[mi][ni], 0, 0, 0);
          acc[mi][ni] = __builtin_amdgcn_mfma_f32_16x16x32_bf16(al[mi], bh[ni], acc[mi][ni], 0, 0, 0);
        }
    }
    __syncthreads();
  }
  #pragma unroll
  for (int mi = 0; mi < 4; mi++){
    #pragma unroll
    for (int r = 0; r < 4; r++){
      int o = wm * 64 + mi * 16 + l4 * 4 + r;
      float bias = bs[o];
      #pragma unroll
      for (int ni = 0; ni < 4; ni++){
        int n = nb + wn * 64 + ni * 16 + l15;
        float val = acc[mi][ni][r] + bias;
        if (o < 64) q[((size_t)(b * CQn + o)) * Nn + n]        = f2bf(val);
        else        k[((size_t)(b * CQn + o - 64)) * Nn + n]   = f2bf(val);
      }
    }
  }
}

// comb_h: per (b,w): ohT[b,w,c,h] = sum_g att[b,h,w,g]*vT[b,w,c,g]
// M=c (128-tile), N=h (128), K=g (128). XOR-swizzled LDS. att is bf16.
__global__ __launch_bounds__(256) void k_comb_h_mfma(const bf16* __restrict__ att,
                                                     const bf16* __restrict__ vT,
                                                     bf16* __restrict__ ohT){
  __shared__ short As[128 * 128];
  __shared__ short Bs[128 * 128];
  int cb = blockIdx.x * 128, w = blockIdx.y, b = blockIdx.z;
  int t = threadIdx.x, lane = t & 63, wid = t >> 6;
  int wm = wid >> 1, wn = wid & 1;
  int l15 = lane & 15, l4 = lane >> 4;

  // stage V tile (rows c, K-contig), swizzled; 16B (s16x8) chunks
  const bf16* vp = vT + ((size_t)(b * Wn + w) * Cn + cb) * Hn;
  for (int s = t; s < 2048; s += 256){
    int row = s >> 4, seg = s & 15;
    s16x8 d = *(const s16x8*)(vp + (size_t)row * Hn + seg * 8);
    int byte = (row * 256 + seg * 16) ^ ((row & 7) << 4);
    *(s16x8*)((char*)As + byte) = d;
  }
  // stage att tile (rows h, first 128 cols), bf16 direct, swizzled
  const bf16* ap = att + ((size_t)(b * Hn) * Wn + w) * 256;
  for (int s = t; s < 2048; s += 256){
    int row = s >> 4, seg = s & 15;
    s16x8 d = *(const s16x8*)(ap + (size_t)row * (Wn * 256) + seg * 8);
    int byte = (row * 256 + seg * 16) ^ ((row & 7) << 4);
    *(s16x8*)((char*)Bs + byte) = d;
  }
  __syncthreads();

  f32x4 acc[4][4];
  #pragma unroll
  for (int i = 0; i < 4; i++)
    #pragma unroll
    for (int j = 0; j < 4; j++) acc[i][j] = (f32x4){0.f, 0.f, 0.f, 0.f};
  #pragma unroll
  for (int kk = 0; kk < 128; kk += 32){
    s16x8 a[4], bb[4];
    #pragma unroll
    for (int mi = 0; mi < 4; mi++){
      int row = wm * 64 + mi * 16 + l15;
      int byte = (row * 256 + (kk + l4 * 8) * 2) ^ ((row & 7) << 4);
      a[mi] = *(const s16x8*)((char*)As + byte);
    }
    #pragma unroll
    for (int ni = 0; ni < 4; ni++){
      int row = wn * 64 + ni * 16 + l15;
      int byte = (row * 256 + (kk + l4 * 8) * 2) ^ ((row & 7) << 4);
      bb[ni] = *(const s16x8*)((char*)Bs + byte);
    }
    #pragma unroll
    for (int mi = 0; mi < 4; mi++)
      #pragma unroll
      for (int ni = 0; ni < 4; ni++)
        acc[mi][ni] = __builtin_amdgcn_mfma_f32_16x16x32_bf16(a[mi], bb[ni], acc[mi][ni], 0, 0, 0);
  }
  bf16* op = ohT + ((size_t)(b * Wn + w) * Cn + cb) * Hn;
  #pragma unroll
  for (int mi = 0; mi < 4; mi++)
    #pragma unroll
    for (int r = 0; r < 4; r++){
      int cl = wm * 64 + mi * 16 + l4 * 4 + r;
      #pragma unroll
      for (int ni = 0; ni < 4; ni++){
        int h = wn * 64 + ni * 16 + l15;
        op[(size_t)cl * Hn + h] = f2bf(acc[mi][ni][r]);
      }
    }
}

// comb_w: per (b,h): ow[b,c,h,w_] = sum_g att[b,h,w_,128+g]*v[b,c,h,g]; att bf16
__global__ __launch_bounds__(256) void k_comb_w_mfma(const bf16* __restrict__ att,
                                                     const bf16* __restrict__ v,
                                                     bf16* __restrict__ ow){
  __shared__ short As[128 * 128];
  __shared__ short Bs[128 * 128];
  int cb = blockIdx.x * 128, h = blockIdx.y, b = blockIdx.z;
  int t = threadIdx.x, lane = t & 63, wid = t >> 6;
  int wm = wid >> 1, wn = wid & 1;
  int l15 = lane & 15, l4 = lane >> 4;

  const bf16* vp = v + (size_t)(b * Cn + cb) * Nn + (size_t)h * Wn;
  for (int s = t; s < 2048; s += 256){
    int row = s >> 4, seg = s & 15;
    s16x8 d = *(const s16x8*)(vp + (size_t)row * Nn + seg * 8);
    int byte = (row * 256 + seg * 16) ^ ((row & 7) << 4);
    *(s16x8*)((char*)As + byte) = d;
  }
  const bf16* ap = att + ((size_t)(b * Hn + h) * Wn) * 256 + 128;
  for (int s = t; s < 2048; s += 256){
    int row = s >> 4, seg = s & 15;
    s16x8 d = *(const s16x8*)(ap + (size_t)row * 256 + seg * 8);
    int byte = (row * 256 + seg * 16) ^ ((row & 7) << 4);
    *(s16x8*)((char*)Bs + byte) = d;
  }
  __syncthreads();

  f32x4 acc[4][4];
  #pragma unroll
  for (int i = 0; i < 4; i++)
    #pragma unroll
    for (int j = 0; j < 4; j++) acc[i][j] = (f32x4){0.f, 0.f, 0.f, 0.f};
  #pragma unroll
  for (int kk = 0; kk < 128; kk += 32){
    s16x8 a[4], bb[4];
    #pragma unroll
    for (int mi = 0; mi < 4; mi++){
      int row = wm * 64 + mi * 16 + l15;
      int byte = (row * 256 + (kk + l4 * 8) * 2) ^ ((row & 7) << 4);
      a[mi] = *(const s16x8*)((char*)As + byte);
    }
    #pragma unroll
    for (int ni = 0; ni < 4; ni++){
      int row = wn * 64 + ni * 16 + l15;
      int byte = (row * 256 + (kk + l4 * 8) * 2) ^ ((row & 7) << 4);
      bb[ni] = *(const s16x8*)((char*)Bs + byte);
    }
    #pragma unroll
    for (int mi = 0; mi < 4; mi++)
      #pragma unroll
      for (int ni = 0; ni < 4; ni++)
        acc[mi][ni] = __builtin_amdgcn_mfma_f32_16x16x32_bf16(a[mi], bb[ni], acc[mi][ni], 0, 0, 0);
  }
  bf16* op = ow + (size_t)(b * Cn + cb) * Nn + (size_t)h * Wn;
  #pragma unroll
  for (int mi = 0; mi < 4; mi++)
    #pragma unroll
    for (int r = 0; r < 4; r++){
      int cl = wm * 64 + mi * 16 + l4 * 4 + r;
      #pragma unroll
      for (int ni = 0; ni < 4; ni++){
        int wr = wn * 64 + ni * 16 + l15;
        op[(size_t)cl * Nn + wr] = f2bf(acc[mi][ni][r]);
      }
    }
}

// ============================ remaining CA kernels ============================

// [b,c,h,w] -> [b,w,c,h] (bf16), 32x32 tiles
__global__ __launch_bounds__(256) void k_trans(const bf16* __restrict__ in,
                                               bf16* __restrict__ out,
                                               int CH){
  __shared__ bf16 tile[32][33];
  int tl = blockIdx.x, c = blockIdx.y, b = blockIdx.z;
  int th = tl >> 2, tw = tl & 3;
  int h0 = th * 32, w0 = tw * 32;
  int t = threadIdx.x;
  const bf16* ip = in + ((size_t)(b * CH + c)) * Nn;
  #pragma unroll
  for (int kk = 0; kk < 4; ++kk){
    int idx = t + kk * 256;
    int hl = idx >> 5, wl = idx & 31;
    tile[hl][wl] = ip[(h0 + hl) * Wn + w0 + wl];
  }
  __syncthreads();
  #pragma unroll
  for (int kk = 0; kk < 4; ++kk){
    int idx = t + kk * 256;
    int wl = idx >> 5, hl = idx & 31;
    out[((size_t)(b * Wn + w0 + wl) * CH + c) * Hn + h0 + hl] = tile[hl][wl];
  }
}

// e_h[h,g] = sum_c qT[b,w,c,h]*kT[b,w,c,g], diag -> -1e30
__global__ __launch_bounds__(256) void k_eh(const bf16* __restrict__ qT,
                                            const bf16* __restrict__ kT,
                                            float* __restrict__ e){
  __shared__ float smem[16384];
  float* qs = smem;
  float* ks = smem + 8192;
  int w = blockIdx.x, b = blockIdx.y;
  int t = threadIdx.x;
  const bf16* qp = qT + (size_t)(b * Wn + w) * CQn * Hn;
  const bf16* kp = kT + (size_t)(b * Wn + w) * CQn * Hn;
  for (int i = t; i < 8192; i += 256){ qs[i] = bf2f(qp[i]); ks[i] = bf2f(kp[i]); }
  __syncthreads();
  int hg = t >> 3, gg = t & 7;
  float acc[4][16];
  #pragma unroll
  for (int i = 0; i < 4; i++)
    #pragma unroll
    for (int j = 0; j < 16; j++) acc[i][j] = 0.f;
  for (int c = 0; c < CQn; ++c){
    float qv[4], kv[16];
    #pragma unroll
    for (int i = 0; i < 4; i++) qv[i] = qs[c * 128 + hg * 4 + i];
    #pragma unroll
    for (int j = 0; j < 16; j++) kv[j] = ks[c * 128 + gg + 8 * j];
    #pragma unroll
    for (int i = 0; i < 4; i++)
      #pragma unroll
      for (int j = 0; j < 16; j++) acc[i][j] += qv[i] * kv[j];
  }
  __syncthreads();
  #pragma unroll
  for (int i = 0; i < 4; i++)
    #pragma unroll
    for (int j = 0; j < 16; j++)
      smem[(hg * 4 + i) * 128 + gg + 8 * j] = acc[i][j];
  __syncthreads();
  for (int kk = 0; kk < 64; ++kk){
    int idx = t + kk * 256;
    int h = idx >> 7, g = idx & 127;
    float val = (h == g) ? -1e30f : smem[idx];
    e[((size_t)(b * Hn + h) * Wn + w) * 256 + g] = val;
  }
}

// e_w[w,v] = sum_c q[b,c,h,w]*k[b,c,h,v]
__global__ __launch_bounds__(256) void k_ew(const bf16* __restrict__ q,
                                            const bf16* __restrict__ k,
                                            float* __restrict__ e){
  __shared__ float smem[16384];
  float* qs = smem;
  float* ks = smem + 8192;
  int h = blockIdx.x, b = blockIdx.y;
  int t = threadIdx.x;
  for (int i = t; i < 8192; i += 256){
    int c = i >> 7, wl = i & 127;
    size_t base = ((size_t)(b * CQn + c) * Hn + h) * Wn + wl;
    qs[i] = bf2f(q[base]);
    ks[i] = bf2f(k[base]);
  }
  __syncthreads();
  int wg = t >> 3, vg = t & 7;
  float acc[4][16];
  #pragma unroll
  for (int i = 0; i < 4; i++)
    #pragma unroll
    for (int j = 0; j < 16; j++) acc[i][j] = 0.f;
  for (int c = 0; c < CQn; ++c){
    float qv[4], kv[16];
    #pragma unroll
    for (int i = 0; i < 4; i++) qv[i] = qs[c * 128 + wg * 4 + i];
    #pragma unroll
    for (int j = 0; j < 16; j++) kv[j] = ks[c * 128 + vg + 8 * j];
    #pragma unroll
    for (int i = 0; i < 4; i++)
      #pragma unroll
      for (int j = 0; j < 16; j++) acc[i][j] += qv[i] * kv[j];
  }
  __syncthreads();
  #pragma unroll
  for (int i = 0; i < 4; i++)
    #pragma unroll
    for (int j = 0; j < 16; j++)
      smem[(wg * 4 + i) * 128 + vg + 8 * j] = acc[i][j];
  __syncthreads();
  for (int kk = 0; kk < 64; ++kk){
    int idx = t + kk * 256;
    int wr = idx >> 7, vc = idx & 127;
    e[((size_t)(b * Hn + h) * Wn + wr) * 256 + 128 + vc] = smem[idx];
  }
}

// softmax over 256 per row: read fp32 e, write bf16 att; one wave per row
__global__ __launch_bounds__(256) void k_softmax(const float* __restrict__ e,
                                                 bf16* __restrict__ att){
  int wid = threadIdx.x >> 6, lid = threadIdx.x & 63;
  size_t row = (size_t)blockIdx.x * 4 + wid;
  const float* p = e + row * 256;
  float4 v = *(const float4*)(p + lid * 4);
  float m = fmaxf(fmaxf(v.x, v.y), fmaxf(v.z, v.w));
  for (int o = 32; o > 0; o >>= 1) m = fmaxf(m, __shfl_xor(m, o));
  v.x = expf(v.x - m); v.y = expf(v.y - m); v.z = expf(v.z - m); v.w = expf(v.w - m);
  float s = v.x + v.y + v.z + v.w;
  for (int o = 32; o > 0; o >>= 1) s += __shfl_xor(s, o);
  float inv = 1.f / s;
  bf16 b0 = f2bf(v.x * inv), b1 = f2bf(v.y * inv), b2 = f2bf(v.z * inv), b3 = f2bf(v.w * inv);
  ushort4 o4 = { *(unsigned short*)&b0, *(unsigned short*)&b1,
                 *(unsigned short*)&b2, *(unsigned short*)&b3 };
  *(ushort4*)((unsigned short*)att + row * 256 + lid * 4) = o4;
}

// out = gamma*(ohT^T + ow) + in (+ addend)
__global__ __launch_bounds__(256) void k_fuse(const float* __restrict__ in,
                                              const bf16* __restrict__ ohT,
                                              const bf16* __restrict__ ow,
                                              const float* __restrict__ addend,
                                              const float* __restrict__ gamma,
                                              float* __restrict__ out){
  __shared__ float tile[32][33];
  int tl = blockIdx.x, c = blockIdx.y, b = blockIdx.z;
  int th = tl >> 2, tw = tl & 3;
  int h0 = th * 32, w0 = tw * 32;
  int t = threadIdx.x;
  float g = gamma[0];
  #pragma unroll
  for (int kk = 0; kk < 4; ++kk){
    int idx = t + kk * 256;
    int wl = idx >> 5, hl = idx & 31;
    tile[wl][hl] = bf2f(ohT[((size_t)(b * Wn + w0 + wl) * Cn + c) * Hn + h0 + hl]);
  }
  __syncthreads();
  #pragma unroll
  for (int kk = 0; kk < 4; ++kk){
    int idx = t + kk * 256;
    int hl = idx >> 5, wl = idx & 31;
    size_t o = ((size_t)(b * Cn + c)) * Nn + (size_t)(h0 + hl) * Wn + w0 + wl;
    float val = g * (tile[wl][hl] + bf2f(ow[o])) + in[o];
    if (addend) val += addend[o];
    out[o] = val;
  }
}

// ============================ host ============================

static void run_ca(const float* in, const bf16* wqk_hi, const bf16* wqk_lo,
                   const float* bqk, const bf16* wvb, const float* bv,
                   const float* gamma, const float* addend, float* out,
                   bf16* q, bf16* k, bf16* qT, bf16* kT, bf16* v, bf16* vT,
                   float* e, bf16* attb, bf16* xT_hi, bf16* xT_lo, bf16* tmp,
                   hipStream_t stream){
  bf16* ohT = tmp;
  bf16* ow  = tmp + (size_t)Bn * Cn * Nn;
  k_cvt_T<<<dim3(Nn / 32, Cn / 32, Bn), 256, 0, stream>>>(in, xT_hi, xT_lo);
  k_qk_mfma<<<dim3(Nn / 128, Bn), 256, 0, stream>>>(xT_hi, xT_lo, wqk_hi, wqk_lo, bqk, q, k);
  k_trans<<<dim3(16, CQn, Bn), 256, 0, stream>>>(q, qT, CQn);
  k_trans<<<dim3(16, CQn, Bn), 256, 0, stream>>>(k, kT, CQn);
  k_v_mfma<<<dim3(Nn / 128, Cn / 128, Bn), 256, 0, stream>>>(xT_hi, wvb, bv, v);
  k_trans<<<dim3(16, Cn, Bn), 256, 0, stream>>>(v, vT, Cn);
  k_eh<<<dim3(Wn, Bn), 256, 0, stream>>>(qT, kT, e);   // e aliases xT_hi; all xT readers done
  k_ew<<<dim3(Hn, Bn), 256, 0, stream>>>(q, k, e);
  k_softmax<<<(Bn * Nn) / 4, 256, 0, stream>>>(e, attb); // attb aliases q/k/qT/kT (dead now)
  k_comb_h_mfma<<<dim3(Cn / 128, Wn, Bn), 256, 0, stream>>>(attb, vT, ohT);
  k_comb_w_mfma<<<dim3(Cn / 128, Hn, Bn), 256, 0, stream>>>(attb, v, ow);
  k_fuse<<<dim3(16, Cn, Bn), 256, 0, stream>>>(in, ohT, ow, addend, gamma, out);
}

extern "C" void kernel_launch(void* const* d_in, const int* in_sizes, int n_in,
                              void* d_out, int out_size, void* d_ws, size_t ws_size,
                              hipStream_t stream){
  (void)in_sizes; (void)n_in; (void)out_size; (void)ws_size;
  const float* x         = (const float*)d_in[0];
  const float* w_q_right = (const float*)d_in[1];
  const float* w_v_right = (const float*)d_in[2];
  const float* w_up      = (const float*)d_in[3];
  const float* b_up      = (const float*)d_in[4];
  const float* w_q_left  = (const float*)d_in[5];
  const float* w_v_left  = (const float*)d_in[6];
  const float* wq        = (const float*)d_in[7];
  const float* bq        = (const float*)d_in[8];
  const float* wk        = (const float*)d_in[9];
  const float* bk        = (const float*)d_in[10];
  const float* wv        = (const float*)d_in[11];
  const float* bv        = (const float*)d_in[12];
  const float* gamma     = (const float*)d_in[13];

  const size_t SZ_MAP = (size_t)Bn * Cn * Nn;     // 33.5M elements
  char* p = (char*)d_ws;
  float* buf0   = (float*)p; p += SZ_MAP * 4;
  float* buf1   = (float*)p; p += SZ_MAP * 4;
  bf16*  vbuf   = (bf16*)p;  p += SZ_MAP * 2;
  bf16*  vT     = (bf16*)p;  p += SZ_MAP * 2;
  bf16*  qbuf   = (bf16*)p;  p += (size_t)Bn * CQn * Nn * 2;   // qbuf..kT contiguous:
  bf16*  kbuf   = (bf16*)p;  p += (size_t)Bn * CQn * Nn * 2;   //   also used as attb
  bf16*  qT     = (bf16*)p;  p += (size_t)Bn * CQn * Nn * 2;   //   (Bn*Nn*256 bf16 exactly)
  bf16*  kT     = (bf16*)p;  p += (size_t)Bn * CQn * Nn * 2;
  float* ebuf   = (float*)p; p += (size_t)Bn * Nn * 256 * 4;  // doubles as xT_hi (bf16)
  float* logits = (float*)p; p += (size_t)Bn * Nn * 4;
  float* ctxlog = (float*)p; p += (size_t)Bn * Nn * 4;
  float* msp    = (float*)p; p += (size_t)Bn * Nn * 4;
  float* xbar   = (float*)p; p += Bn * Cn * 4;
  float* wgt    = (float*)p; p += Bn * Cn * 4;
  float* u      = (float*)p; p += Bn * Cn * 4;
  float* mch    = (float*)p; p += Bn * Cn * 4;
  float* avg    = (float*)p; p += Bn * CIn * 4;
  float* ctx    = (float*)p; p += Bn * CIn * 4;
  float* stats_sp = (float*)p; p += 64;
  float* stats_ch = (float*)p; p += 64;
  bf16*  wvb    = (bf16*)p;  p += (size_t)Cn * Cn * 2;
  bf16*  wqk_hi = (bf16*)p;  p += (size_t)128 * Cn * 2;
  bf16*  wqk_lo = (bf16*)p;  p += (size_t)128 * Cn * 2;
  float* bqk    = (float*)p; p += 128 * 4;
  bf16*  xT_hi  = (bf16*)ebuf;    // alias: lifetime ends before e is written
  bf16*  xT_lo  = (bf16*)d_out;   // alias: lifetime ends before ohT/fuse writes d_out
  bf16*  attb   = qbuf;           // alias: q/k/qT/kT dead once softmax runs

  // ---- weight prep (once) ----
  k_cvt_w<<<(Cn * Cn + 255) / 256, 256, 0, stream>>>(wv, wvb, Cn * Cn);
  k_prep_wqk<<<(128 * Cn) / 256, 256, 0, stream>>>(wq, wk, bq, bk, wqk_hi, wqk_lo, bqk);

  // ---- stage 0: gating masks ----
  k_dotc<<<Bn * Nn / 256, 256, 0, stream>>>(x, w_q_right, 0, logits);
  k_rowmean<<<Bn * Cn, 256, 0, stream>>>(x, xbar, 1.f / Nn);
  k_rowdot<<<Bn, 256, 0, stream>>>(w_q_left, xbar, avg);
  k_coldot<<<dim3(Cn / 256, Bn), 256, 0, stream>>>(w_v_left, avg, u);
  k_stats<<<Bn, 1024, 0, stream>>>(logits, stats_sp);
  k_weighted<<<Bn * Cn, 256, 0, stream>>>(x, logits, stats_sp, wgt);
  k_rowdot<<<Bn, 256, 0, stream>>>(w_v_right, wgt, ctx);
  k_mch2<<<dim3(Cn / 256, Bn), 256, 0, stream>>>(w_up, b_up, ctx, mch);
  k_dotc<<<Bn * Nn / 256, 256, 0, stream>>>(x, u, Cn, ctxlog);
  k_stats<<<Bn, 1024, 0, stream>>>(ctxlog, stats_ch);
  k_msp<<<Bn * Nn / 256, 256, 0, stream>>>(ctxlog, stats_ch, msp);
  k_apply<<<(int)(SZ_MAP / 256), 256, 0, stream>>>(x, mch, msp, buf0, buf1);

  // ---- CA1: cc' = CA(cc), in-place buf0; tmp = d_out ----
  run_ca(buf0, wqk_hi, wqk_lo, bqk, wvb, bv, gamma, nullptr, buf0,
         qbuf, kbuf, qT, kT, vbuf, vT, ebuf, attb, xT_hi, xT_lo, (bf16*)d_out, stream);
  // ---- CA2: s = CA(cs) + cc' -> buf0 ----
  run_ca(buf1, wqk_hi, wqk_lo, bqk, wvb, bv, gamma, buf0, buf0,
         qbuf, kbuf, qT, kT, vbuf, vT, ebuf, attb, xT_hi, xT_lo, (bf16*)d_out, stream);
  // ---- CA3: out = CA(s) -> d_out; tmp = buf1 ----
  run_ca(buf0, wqk_hi, wqk_lo, bqk, wvb, bv, gamma, nullptr, (float*)d_out,
         qbuf, kbuf, qT, kT, vbuf, vT, ebuf, attb, xT_hi, xT_lo, (bf16*)buf1, stream);
}

// Round 7
// 1619.000 us; speedup vs baseline: 2.5115x; 1.0080x over previous
//
#include <hip/hip_runtime.h>
#include <hip/hip_bf16.h>
#include <math.h>

typedef __hip_bfloat16 bf16;
typedef __attribute__((ext_vector_type(8))) short s16x8;
typedef __attribute__((ext_vector_type(4))) float f32x4;

constexpr int Bn  = 4;
constexpr int Cn  = 512;
constexpr int Hn  = 128;
constexpr int Wn  = 128;
constexpr int Nn  = Hn * Wn;   // 16384
constexpr int CQn = 64;
constexpr int CIn = 256;

__device__ __forceinline__ float bf2f(bf16 v){ return __bfloat162float(v); }
__device__ __forceinline__ bf16  f2bf(float v){ return __float2bfloat16(v); }

// async global->LDS, 16B per lane; LDS dest must be wave-uniform base (HW adds lane*16)
__device__ __forceinline__ void gload_lds16(const void* g, void* l){
  __builtin_amdgcn_global_load_lds(
      (const __attribute__((address_space(1))) unsigned int*)g,
      (__attribute__((address_space(3))) unsigned int*)l,
      16, 0, 0);
}

// ============================ stage 0 ============================

// out[b*Nn+n] = sum_c w[b*wstride + c] * x[(b*Cn+c)*Nn + n]
__global__ __launch_bounds__(256) void k_dotc(const float* __restrict__ x,
                                              const float* __restrict__ w,
                                              int wstride,
                                              float* __restrict__ out){
  int t = blockIdx.x * 256 + threadIdx.x;      // over B*Nn
  int b = t >> 14;
  const float* wp = w + (size_t)b * wstride;
  const float* xp = x + (size_t)b * Cn * Nn + (t & (Nn - 1));
  float acc = 0.f;
  #pragma unroll 8
  for (int c = 0; c < Cn; ++c) acc += wp[c] * xp[(size_t)c * Nn];
  out[t] = acc;
}

// out[bc] = scale * sum_n x[bc*Nn+n]
__global__ __launch_bounds__(256) void k_rowmean(const float* __restrict__ x,
                                                 float* __restrict__ out,
                                                 float scale){
  int bc = blockIdx.x;
  const float* xp = x + (size_t)bc * Nn;
  float acc = 0.f;
  for (int n = threadIdx.x; n < Nn; n += 256) acc += xp[n];
  for (int o = 32; o > 0; o >>= 1) acc += __shfl_down(acc, o);
  __shared__ float red[4];
  if ((threadIdx.x & 63) == 0) red[threadIdx.x >> 6] = acc;
  __syncthreads();
  if (threadIdx.x == 0) out[bc] = (red[0] + red[1] + red[2] + red[3]) * scale;
}

// out[b][i] = sum_j W[i][j]*vec[b][j]; W: CIn x Cn row-major; grid Bn, 256 thr (one per i)
__global__ __launch_bounds__(256) void k_rowdot(const float* __restrict__ W,
                                                const float* __restrict__ vec,
                                                float* __restrict__ out){
  __shared__ float vs[Cn];
  int b = blockIdx.x, t = threadIdx.x;
  for (int j = t; j < Cn; j += 256) vs[j] = vec[b * Cn + j];
  __syncthreads();
  const float4* wp = (const float4*)(W + (size_t)t * Cn);
  float a = 0.f;
  #pragma unroll 4
  for (int j = 0; j < Cn / 4; ++j){
    float4 w4 = wp[j];
    a += w4.x * vs[4*j] + w4.y * vs[4*j+1] + w4.z * vs[4*j+2] + w4.w * vs[4*j+3];
  }
  out[b * CIn + t] = a;
}

// out[b][c] = sum_j W[j][c]*vec[b][j]; W: CIn x Cn; grid (Cn/256, Bn)
__global__ __launch_bounds__(256) void k_coldot(const float* __restrict__ W,
                                                const float* __restrict__ vec,
                                                float* __restrict__ out){
  __shared__ float vs[CIn];
  int b = blockIdx.y, t = threadIdx.x;
  int c = blockIdx.x * 256 + t;
  if (t < CIn) vs[t] = vec[b * CIn + t];
  __syncthreads();
  float a = 0.f;
  #pragma unroll 8
  for (int j = 0; j < CIn; ++j) a += W[(size_t)j * Cn + c] * vs[j];
  out[b * Cn + c] = a;
}

// mch[b][o] = sigmoid(sum_ci w_up[o][ci]*ctx[b][ci] + b_up[o]); grid (Cn/256, Bn)
__global__ __launch_bounds__(256) void k_mch2(const float* __restrict__ w_up,
                                              const float* __restrict__ b_up,
                                              const float* __restrict__ ctx,
                                              float* __restrict__ mch){
  __shared__ float cs[CIn];
  int b = blockIdx.y, t = threadIdx.x;
  int o = blockIdx.x * 256 + t;
  if (t < CIn) cs[t] = ctx[b * CIn + t];
  __syncthreads();
  const float4* wp = (const float4*)(w_up + (size_t)o * CIn);
  float a = b_up[o];
  #pragma unroll 4
  for (int j = 0; j < CIn / 4; ++j){
    float4 w4 = wp[j];
    a += w4.x * cs[4*j] + w4.y * cs[4*j+1] + w4.z * cs[4*j+2] + w4.w * cs[4*j+3];
  }
  mch[b * Cn + o] = 1.f / (1.f + expf(-a));
}

// per-b max & sumexp over Nn values
__global__ __launch_bounds__(1024) void k_stats(const float* __restrict__ vv,
                                                float* __restrict__ stats){
  int b = blockIdx.x;
  const float* pp = vv + (size_t)b * Nn;
  int t = threadIdx.x;
  float m = -3.4e38f;
  for (int n = t; n < Nn; n += 1024) m = fmaxf(m, pp[n]);
  for (int o = 32; o > 0; o >>= 1) m = fmaxf(m, __shfl_down(m, o));
  __shared__ float red[16];
  int wid = t >> 6, lid = t & 63;
  if (lid == 0) red[wid] = m;
  __syncthreads();
  if (t == 0){
    float q = red[0];
    for (int i = 1; i < 16; i++) q = fmaxf(q, red[i]);
    red[0] = q;
  }
  __syncthreads();
  m = red[0];
  __syncthreads();
  float s = 0.f;
  for (int n = t; n < Nn; n += 1024) s += expf(pp[n] - m);
  for (int o = 32; o > 0; o >>= 1) s += __shfl_down(s, o);
  if (lid == 0) red[wid] = s;
  __syncthreads();
  if (t == 0){
    float q = 0.f;
    for (int i = 0; i < 16; i++) q += red[i];
    stats[b * 2]     = m;
    stats[b * 2 + 1] = q;
  }
}

// weighted[b,c] = sum_n x[b,c,n]*exp(l[b,n]-m)/den
__global__ __launch_bounds__(256) void k_weighted(const float* __restrict__ x,
                                                  const float* __restrict__ logits,
                                                  const float* __restrict__ stats,
                                                  float* __restrict__ out){
  int bc = blockIdx.x;
  int b = bc >> 9;
  const float* xp = x + (size_t)bc * Nn;
  const float* lp = logits + (size_t)b * Nn;
  float m = stats[b * 2], den = stats[b * 2 + 1];
  float acc = 0.f;
  for (int n = threadIdx.x; n < Nn; n += 256) acc += xp[n] * expf(lp[n] - m);
  for (int o = 32; o > 0; o >>= 1) acc += __shfl_down(acc, o);
  __shared__ float red[4];
  if ((threadIdx.x & 63) == 0) red[threadIdx.x >> 6] = acc;
  __syncthreads();
  if (threadIdx.x == 0) out[bc] = (red[0] + red[1] + red[2] + red[3]) / den;
}

// msp[b,n] = sigmoid(exp(l-m)/den)
__global__ __launch_bounds__(256) void k_msp(const float* __restrict__ lg,
                                             const float* __restrict__ stats,
                                             float* __restrict__ msp){
  int t = blockIdx.x * 256 + threadIdx.x;
  int b = t >> 14;
  float v = expf(lg[t] - stats[b * 2]) / stats[b * 2 + 1];
  msp[t] = 1.f / (1.f + expf(-v));
}

// cc = x * mch[b,c] ; cs = x * msp[b,n]
__global__ __launch_bounds__(256) void k_apply(const float* __restrict__ x,
                                               const float* __restrict__ mch,
                                               const float* __restrict__ msp,
                                               float* __restrict__ cc,
                                               float* __restrict__ cs){
  size_t t = (size_t)blockIdx.x * 256 + threadIdx.x;
  int bc = (int)(t >> 14);
  int b  = bc >> 9;
  int n  = (int)(t & (Nn - 1));
  float xv = x[t];
  cc[t] = xv * mch[bc];
  cs[t] = xv * msp[b * Nn + n];
}

// ============================ conversions ============================

// wv fp32 [c][c'] -> bf16 (same layout)
__global__ __launch_bounds__(256) void k_cvt_w(const float* __restrict__ in,
                                               bf16* __restrict__ out, int n){
  int t = blockIdx.x * 256 + threadIdx.x;
  if (t < n) out[t] = f2bf(in[t]);
}

// wqk hi/lo: rows 0-63 = wq, 64-127 = wk (bf16 split); bqk fp32
__global__ __launch_bounds__(256) void k_prep_wqk(const float* __restrict__ wq,
                                                  const float* __restrict__ wk,
                                                  const float* __restrict__ bq,
                                                  const float* __restrict__ bk,
                                                  bf16* __restrict__ wqk_hi,
                                                  bf16* __restrict__ wqk_lo,
                                                  float* __restrict__ bqk){
  int t = blockIdx.x * 256 + threadIdx.x;   // over 128*512
  int o = t >> 9, c = t & 511;
  float v = (o < 64) ? wq[(size_t)o * Cn + c] : wk[(size_t)(o - 64) * Cn + c];
  bf16 h = f2bf(v);
  wqk_hi[t] = h;
  wqk_lo[t] = f2bf(v - bf2f(h));
  if (t < 128) bqk[t] = (t < 64) ? bq[t] : bk[t - 64];
}

// in[b][c][n] fp32 -> xT_hi/xT_lo [b][n][c] bf16 split (K-contiguous for MFMA)
__global__ __launch_bounds__(256) void k_cvt_T(const float* __restrict__ in,
                                               bf16* __restrict__ out_hi,
                                               bf16* __restrict__ out_lo){
  __shared__ bf16 th_[32][33];
  __shared__ bf16 tl_[32][33];
  int nt = blockIdx.x, ct = blockIdx.y, b = blockIdx.z;
  int n0 = nt * 32, c0 = ct * 32;
  int t = threadIdx.x;
  #pragma unroll
  for (int kk = 0; kk < 4; ++kk){
    int idx = t + kk * 256;
    int cl = idx >> 5, nl = idx & 31;
    float v = in[((size_t)(b * Cn + c0 + cl)) * Nn + n0 + nl];
    bf16 h = f2bf(v);
    th_[cl][nl] = h;
    tl_[cl][nl] = f2bf(v - bf2f(h));
  }
  __syncthreads();
  #pragma unroll
  for (int kk = 0; kk < 4; ++kk){
    int idx = t + kk * 256;
    int nl = idx >> 5, cl = idx & 31;
    size_t o = ((size_t)(b * Nn + n0 + nl)) * Cn + c0 + cl;
    out_hi[o] = th_[cl][nl];
    out_lo[o] = tl_[cl][nl];
  }
}

// ============================ MFMA GEMMs ============================

// V = Wv @ X. xT: [b][n][c'] bf16, wvb: [c][c'] bf16. 128x128 tile, BK=64.
// 1-D grid of 2048, XCD-chunked swizzle: 4 cb-blocks of one nb adjacent per XCD.
__global__ __launch_bounds__(256) void k_v_mfma(const bf16* __restrict__ xT,
                                                const bf16* __restrict__ wvb,
                                                const float* __restrict__ bv,
                                                bf16* __restrict__ v){
  __shared__ short As[128 * 64];
  __shared__ short Bs[128 * 64];
  __shared__ float bvs[128];
  int lin = blockIdx.x;
  int swz = (lin & 7) * 256 + (lin >> 3);   // 2048 = 8 XCD chunks of 256
  int cb = (swz & 3) * 128;
  int nb = ((swz >> 2) & 127) * 128;
  int b  = swz >> 9;
  int t = threadIdx.x, lane = t & 63, wid = t >> 6;
  int wm = wid >> 1, wn = wid & 1;
  int l15 = lane & 15, l4 = lane >> 4;
  if (t < 128) bvs[t] = bv[cb + t];
  f32x4 acc[4][4];
  #pragma unroll
  for (int i = 0; i < 4; i++)
    #pragma unroll
    for (int j = 0; j < 4; j++) acc[i][j] = (f32x4){0.f, 0.f, 0.f, 0.f};

  const bf16* wp = wvb + (size_t)cb * Cn;
  const bf16* xp = xT + ((size_t)b * Nn + nb) * Cn;
  int r8 = lane >> 3;
  int kc = (lane & 7) * 8;
  for (int kt = 0; kt < 8; ++kt){
    int k0 = kt * 64;
    #pragma unroll
    for (int j = 0; j < 4; ++j){
      int inst = wid * 4 + j;
      int row = inst * 8 + r8;
      gload_lds16(wp + (size_t)row * Cn + k0 + kc, (char*)As + inst * 1024);
      gload_lds16(xp + (size_t)row * Cn + k0 + kc, (char*)Bs + inst * 1024);
    }
    __syncthreads();
    #pragma unroll
    for (int kk = 0; kk < 64; kk += 32){
      s16x8 a[4], bb[4];
      #pragma unroll
      for (int mi = 0; mi < 4; mi++)
        a[mi] = *(const s16x8*)&As[(wm * 64 + mi * 16 + l15) * 64 + kk + l4 * 8];
      #pragma unroll
      for (int ni = 0; ni < 4; ni++)
        bb[ni] = *(const s16x8*)&Bs[(wn * 64 + ni * 16 + l15) * 64 + kk + l4 * 8];
      #pragma unroll
      for (int mi = 0; mi < 4; mi++)
        #pragma unroll
        for (int ni = 0; ni < 4; ni++)
          acc[mi][ni] = __builtin_amdgcn_mfma_f32_16x16x32_bf16(a[mi], bb[ni], acc[mi][ni], 0, 0, 0);
    }
    __syncthreads();
  }
  #pragma unroll
  for (int mi = 0; mi < 4; mi++){
    #pragma unroll
    for (int r = 0; r < 4; r++){
      int cl = wm * 64 + mi * 16 + l4 * 4 + r;
      int c  = cb + cl;
      float bias = bvs[cl];
      #pragma unroll
      for (int ni = 0; ni < 4; ni++){
        int n = nb + wn * 64 + ni * 16 + l15;
        v[((size_t)(b * Cn + c)) * Nn + n] = f2bf(acc[mi][ni][r] + bias);
      }
    }
  }
}

// Q,K = [Wq;Wk] @ X with split-precision bf16 (x=hi+lo, w=hi+lo; 3 MFMA terms).
__global__ __launch_bounds__(256) void k_qk_mfma(const bf16* __restrict__ xT_hi,
                                                 const bf16* __restrict__ xT_lo,
                                                 const bf16* __restrict__ wqk_hi,
                                                 const bf16* __restrict__ wqk_lo,
                                                 const float* __restrict__ bqk,
                                                 bf16* __restrict__ q,
                                                 bf16* __restrict__ k){
  __shared__ short Ah[128 * 64];
  __shared__ short Al[128 * 64];
  __shared__ short Bh[128 * 64];
  __shared__ short Bl[128 * 64];
  __shared__ float bs[128];
  int nb = blockIdx.x * 128, b = blockIdx.y;
  int t = threadIdx.x, lane = t & 63, wid = t >> 6;
  int wm = wid >> 1, wn = wid & 1;
  int l15 = lane & 15, l4 = lane >> 4;
  if (t < 128) bs[t] = bqk[t];
  f32x4 acc[4][4];
  #pragma unroll
  for (int i = 0; i < 4; i++)
    #pragma unroll
    for (int j = 0; j < 4; j++) acc[i][j] = (f32x4){0.f, 0.f, 0.f, 0.f};

  const bf16* xh = xT_hi + ((size_t)b * Nn + nb) * Cn;
  const bf16* xl = xT_lo + ((size_t)b * Nn + nb) * Cn;
  int r8 = lane >> 3;
  int kc = (lane & 7) * 8;
  for (int kt = 0; kt < 8; ++kt){
    int k0 = kt * 64;
    #pragma unroll
    for (int j = 0; j < 4; ++j){
      int inst = wid * 4 + j;
      int row = inst * 8 + r8;
      size_t off = (size_t)row * Cn + k0 + kc;
      gload_lds16(wqk_hi + off, (char*)Ah + inst * 1024);
      gload_lds16(wqk_lo + off, (char*)Al + inst * 1024);
      gload_lds16(xh + off,     (char*)Bh + inst * 1024);
      gload_lds16(xl + off,     (char*)Bl + inst * 1024);
    }
    __syncthreads();
    #pragma unroll
    for (int kk = 0; kk < 64; kk += 32){
      s16x8 ah[4], al[4], bh[4], bl[4];
      #pragma unroll
      for (int mi = 0; mi < 4; mi++){
        int idx = (wm * 64 + mi * 16 + l15) * 64 + kk + l4 * 8;
        ah[mi] = *(const s16x8*)&Ah[idx];
        al[mi] = *(const s16x8*)&Al[idx];
      }
      #pragma unroll
      for (int ni = 0; ni < 4; ni++){
        int idx = (wn * 64 + ni * 16 + l15) * 64 + kk + l4 * 8;
        bh[ni] = *(const s16x8*)&Bh[idx];
        bl[ni] = *(const s16x8*)&Bl[idx];
      }
      #pragma unroll
      for (int mi = 0; mi < 4; mi++)
        #pragma unroll
        for (int ni = 0; ni < 4; ni++){
          acc[mi][ni] = __builtin_amdgcn_mfma_f32_16x16x32_bf16(ah[mi], bh[ni], acc[mi][ni], 0, 0, 0);
          acc[mi][ni] = __builtin_amdgcn_mfma_f32_16x16x32_bf16(ah[mi], bl[ni], acc[mi][ni], 0, 0, 0);
          acc[mi][ni] = __builtin_amdgcn_mfma_f32_16x16x32_bf16(al[mi], bh[ni], acc[mi][ni], 0, 0, 0);
        }
    }
    __syncthreads();
  }
  #pragma unroll
  for (int mi = 0; mi < 4; mi++){
    #pragma unroll
    for (int r = 0; r < 4; r++){
      int o = wm * 64 + mi * 16 + l4 * 4 + r;
      float bias = bs[o];
      #pragma unroll
      for (int ni = 0; ni < 4; ni++){
        int n = nb + wn * 64 + ni * 16 + l15;
        float val = acc[mi][ni][r] + bias;
        if (o < 64) q[((size_t)(b * CQn + o)) * Nn + n]        = f2bf(val);
        else        k[((size_t)(b * CQn + o - 64)) * Nn + n]   = f2bf(val);
      }
    }
  }
}

// comb_h: per (b,w): ohT[b,w,c,h] = sum_g att[b,h,w,g]*vT[b,w,c,g]; swizzled grid
__global__ __launch_bounds__(256) void k_comb_h_mfma(const bf16* __restrict__ att,
                                                     const bf16* __restrict__ vT,
                                                     bf16* __restrict__ ohT){
  __shared__ short As[128 * 128];
  __shared__ short Bs[128 * 128];
  int lin = blockIdx.x;
  int swz = (lin & 7) * 256 + (lin >> 3);
  int cb = (swz & 3) * 128;
  int w  = (swz >> 2) & 127;
  int b  = swz >> 9;
  int t = threadIdx.x, lane = t & 63, wid = t >> 6;
  int wm = wid >> 1, wn = wid & 1;
  int l15 = lane & 15, l4 = lane >> 4;

  // stage V tile (rows c, K-contig), swizzled; 16B (s16x8) chunks
  const bf16* vp = vT + ((size_t)(b * Wn + w) * Cn + cb) * Hn;
  for (int s = t; s < 2048; s += 256){
    int row = s >> 4, seg = s & 15;
    s16x8 d = *(const s16x8*)(vp + (size_t)row * Hn + seg * 8);
    int byte = (row * 256 + seg * 16) ^ ((row & 7) << 4);
    *(s16x8*)((char*)As + byte) = d;
  }
  // stage att tile (rows h, first 128 cols), bf16 direct, swizzled
  const bf16* ap = att + ((size_t)(b * Hn) * Wn + w) * 256;
  for (int s = t; s < 2048; s += 256){
    int row = s >> 4, seg = s & 15;
    s16x8 d = *(const s16x8*)(ap + (size_t)row * (Wn * 256) + seg * 8);
    int byte = (row * 256 + seg * 16) ^ ((row & 7) << 4);
    *(s16x8*)((char*)Bs + byte) = d;
  }
  __syncthreads();

  f32x4 acc[4][4];
  #pragma unroll
  for (int i = 0; i < 4; i++)
    #pragma unroll
    for (int j = 0; j < 4; j++) acc[i][j] = (f32x4){0.f, 0.f, 0.f, 0.f};
  #pragma unroll
  for (int kk = 0; kk < 128; kk += 32){
    s16x8 a[4], bb[4];
    #pragma unroll
    for (int mi = 0; mi < 4; mi++){
      int row = wm * 64 + mi * 16 + l15;
      int byte = (row * 256 + (kk + l4 * 8) * 2) ^ ((row & 7) << 4);
      a[mi] = *(const s16x8*)((char*)As + byte);
    }
    #pragma unroll
    for (int ni = 0; ni < 4; ni++){
      int row = wn * 64 + ni * 16 + l15;
      int byte = (row * 256 + (kk + l4 * 8) * 2) ^ ((row & 7) << 4);
      bb[ni] = *(const s16x8*)((char*)Bs + byte);
    }
    #pragma unroll
    for (int mi = 0; mi < 4; mi++)
      #pragma unroll
      for (int ni = 0; ni < 4; ni++)
        acc[mi][ni] = __builtin_amdgcn_mfma_f32_16x16x32_bf16(a[mi], bb[ni], acc[mi][ni], 0, 0, 0);
  }
  bf16* op = ohT + ((size_t)(b * Wn + w) * Cn + cb) * Hn;
  #pragma unroll
  for (int mi = 0; mi < 4; mi++)
    #pragma unroll
    for (int r = 0; r < 4; r++){
      int cl = wm * 64 + mi * 16 + l4 * 4 + r;
      #pragma unroll
      for (int ni = 0; ni < 4; ni++){
        int h = wn * 64 + ni * 16 + l15;
        op[(size_t)cl * Hn + h] = f2bf(acc[mi][ni][r]);
      }
    }
}

// comb_w: per (b,h): ow[b,c,h,w_] = sum_g att[b,h,w_,128+g]*v[b,c,h,g]; swizzled grid
__global__ __launch_bounds__(256) void k_comb_w_mfma(const bf16* __restrict__ att,
                                                     const bf16* __restrict__ v,
                                                     bf16* __restrict__ ow){
  __shared__ short As[128 * 128];
  __shared__ short Bs[128 * 128];
  int lin = blockIdx.x;
  int swz = (lin & 7) * 256 + (lin >> 3);
  int cb = (swz & 3) * 128;
  int h  = (swz >> 2) & 127;
  int b  = swz >> 9;
  int t = threadIdx.x, lane = t & 63, wid = t >> 6;
  int wm = wid >> 1, wn = wid & 1;
  int l15 = lane & 15, l4 = lane >> 4;

  const bf16* vp = v + (size_t)(b * Cn + cb) * Nn + (size_t)h * Wn;
  for (int s = t; s < 2048; s += 256){
    int row = s >> 4, seg = s & 15;
    s16x8 d = *(const s16x8*)(vp + (size_t)row * Nn + seg * 8);
    int byte = (row * 256 + seg * 16) ^ ((row & 7) << 4);
    *(s16x8*)((char*)As + byte) = d;
  }
  const bf16* ap = att + ((size_t)(b * Hn + h) * Wn) * 256 + 128;
  for (int s = t; s < 2048; s += 256){
    int row = s >> 4, seg = s & 15;
    s16x8 d = *(const s16x8*)(ap + (size_t)row * 256 + seg * 8);
    int byte = (row * 256 + seg * 16) ^ ((row & 7) << 4);
    *(s16x8*)((char*)Bs + byte) = d;
  }
  __syncthreads();

  f32x4 acc[4][4];
  #pragma unroll
  for (int i = 0; i < 4; i++)
    #pragma unroll
    for (int j = 0; j < 4; j++) acc[i][j] = (f32x4){0.f, 0.f, 0.f, 0.f};
  #pragma unroll
  for (int kk = 0; kk < 128; kk += 32){
    s16x8 a[4], bb[4];
    #pragma unroll
    for (int mi = 0; mi < 4; mi++){
      int row = wm * 64 + mi * 16 + l15;
      int byte = (row * 256 + (kk + l4 * 8) * 2) ^ ((row & 7) << 4);
      a[mi] = *(const s16x8*)((char*)As + byte);
    }
    #pragma unroll
    for (int ni = 0; ni < 4; ni++){
      int row = wn * 64 + ni * 16 + l15;
      int byte = (row * 256 + (kk + l4 * 8) * 2) ^ ((row & 7) << 4);
      bb[ni] = *(const s16x8*)((char*)Bs + byte);
    }
    #pragma unroll
    for (int mi = 0; mi < 4; mi++)
      #pragma unroll
      for (int ni = 0; ni < 4; ni++)
        acc[mi][ni] = __builtin_amdgcn_mfma_f32_16x16x32_bf16(a[mi], bb[ni], acc[mi][ni], 0, 0, 0);
  }
  bf16* op = ow + (size_t)(b * Cn + cb) * Nn + (size_t)h * Wn;
  #pragma unroll
  for (int mi = 0; mi < 4; mi++)
    #pragma unroll
    for (int r = 0; r < 4; r++){
      int cl = wm * 64 + mi * 16 + l4 * 4 + r;
      #pragma unroll
      for (int ni = 0; ni < 4; ni++){
        int wr = wn * 64 + ni * 16 + l15;
        op[(size_t)cl * Nn + wr] = f2bf(acc[mi][ni][r]);
      }
    }
}

// ============================ remaining CA kernels ============================

// [b,c,h,w] -> [b,w,c,h] (bf16), 32x32 tiles
__global__ __launch_bounds__(256) void k_trans(const bf16* __restrict__ in,
                                               bf16* __restrict__ out,
                                               int CH){
  __shared__ bf16 tile[32][33];
  int tl = blockIdx.x, c = blockIdx.y, b = blockIdx.z;
  int th = tl >> 2, tw = tl & 3;
  int h0 = th * 32, w0 = tw * 32;
  int t = threadIdx.x;
  const bf16* ip = in + ((size_t)(b * CH + c)) * Nn;
  #pragma unroll
  for (int kk = 0; kk < 4; ++kk){
    int idx = t + kk * 256;
    int hl = idx >> 5, wl = idx & 31;
    tile[hl][wl] = ip[(h0 + hl) * Wn + w0 + wl];
  }
  __syncthreads();
  #pragma unroll
  for (int kk = 0; kk < 4; ++kk){
    int idx = t + kk * 256;
    int wl = idx >> 5, hl = idx & 31;
    out[((size_t)(b * Wn + w0 + wl) * CH + c) * Hn + h0 + hl] = tile[hl][wl];
  }
}

// e_h[h,g] = sum_c qT[b,w,c,h]*kT[b,w,c,g], diag -> -1e30
__global__ __launch_bounds__(256) void k_eh(const bf16* __restrict__ qT,
                                            const bf16* __restrict__ kT,
                                            float* __restrict__ e){
  __shared__ float smem[16384];
  float* qs = smem;
  float* ks = smem + 8192;
  int w = blockIdx.x, b = blockIdx.y;
  int t = threadIdx.x;
  const bf16* qp = qT + (size_t)(b * Wn + w) * CQn * Hn;
  const bf16* kp = kT + (size_t)(b * Wn + w) * CQn * Hn;
  for (int i = t; i < 8192; i += 256){ qs[i] = bf2f(qp[i]); ks[i] = bf2f(kp[i]); }
  __syncthreads();
  int hg = t >> 3, gg = t & 7;
  float acc[4][16];
  #pragma unroll
  for (int i = 0; i < 4; i++)
    #pragma unroll
    for (int j = 0; j < 16; j++) acc[i][j] = 0.f;
  for (int c = 0; c < CQn; ++c){
    float qv[4], kv[16];
    #pragma unroll
    for (int i = 0; i < 4; i++) qv[i] = qs[c * 128 + hg * 4 + i];
    #pragma unroll
    for (int j = 0; j < 16; j++) kv[j] = ks[c * 128 + gg + 8 * j];
    #pragma unroll
    for (int i = 0; i < 4; i++)
      #pragma unroll
      for (int j = 0; j < 16; j++) acc[i][j] += qv[i] * kv[j];
  }
  __syncthreads();
  #pragma unroll
  for (int i = 0; i < 4; i++)
    #pragma unroll
    for (int j = 0; j < 16; j++)
      smem[(hg * 4 + i) * 128 + gg + 8 * j] = acc[i][j];
  __syncthreads();
  for (int kk = 0; kk < 64; ++kk){
    int idx = t + kk * 256;
    int h = idx >> 7, g = idx & 127;
    float val = (h == g) ? -1e30f : smem[idx];
    e[((size_t)(b * Hn + h) * Wn + w) * 256 + g] = val;
  }
}

// e_w[w,v] = sum_c q[b,c,h,w]*k[b,c,h,v]
__global__ __launch_bounds__(256) void k_ew(const bf16* __restrict__ q,
                                            const bf16* __restrict__ k,
                                            float* __restrict__ e){
  __shared__ float smem[16384];
  float* qs = smem;
  float* ks = smem + 8192;
  int h = blockIdx.x, b = blockIdx.y;
  int t = threadIdx.x;
  for (int i = t; i < 8192; i += 256){
    int c = i >> 7, wl = i & 127;
    size_t base = ((size_t)(b * CQn + c) * Hn + h) * Wn + wl;
    qs[i] = bf2f(q[base]);
    ks[i] = bf2f(k[base]);
  }
  __syncthreads();
  int wg = t >> 3, vg = t & 7;
  float acc[4][16];
  #pragma unroll
  for (int i = 0; i < 4; i++)
    #pragma unroll
    for (int j = 0; j < 16; j++) acc[i][j] = 0.f;
  for (int c = 0; c < CQn; ++c){
    float qv[4], kv[16];
    #pragma unroll
    for (int i = 0; i < 4; i++) qv[i] = qs[c * 128 + wg * 4 + i];
    #pragma unroll
    for (int j = 0; j < 16; j++) kv[j] = ks[c * 128 + vg + 8 * j];
    #pragma unroll
    for (int i = 0; i < 4; i++)
      #pragma unroll
      for (int j = 0; j < 16; j++) acc[i][j] += qv[i] * kv[j];
  }
  __syncthreads();
  #pragma unroll
  for (int i = 0; i < 4; i++)
    #pragma unroll
    for (int j = 0; j < 16; j++)
      smem[(wg * 4 + i) * 128 + vg + 8 * j] = acc[i][j];
  __syncthreads();
  for (int kk = 0; kk < 64; ++kk){
    int idx = t + kk * 256;
    int wr = idx >> 7, vc = idx & 127;
    e[((size_t)(b * Hn + h) * Wn + wr) * 256 + 128 + vc] = smem[idx];
  }
}

// softmax over 256 per row: read fp32 e, write bf16 att; one wave per row
__global__ __launch_bounds__(256) void k_softmax(const float* __restrict__ e,
                                                 bf16* __restrict__ att){
  int wid = threadIdx.x >> 6, lid = threadIdx.x & 63;
  size_t row = (size_t)blockIdx.x * 4 + wid;
  const float* p = e + row * 256;
  float4 v = *(const float4*)(p + lid * 4);
  float m = fmaxf(fmaxf(v.x, v.y), fmaxf(v.z, v.w));
  for (int o = 32; o > 0; o >>= 1) m = fmaxf(m, __shfl_xor(m, o));
  v.x = expf(v.x - m); v.y = expf(v.y - m); v.z = expf(v.z - m); v.w = expf(v.w - m);
  float s = v.x + v.y + v.z + v.w;
  for (int o = 32; o > 0; o >>= 1) s += __shfl_xor(s, o);
  float inv = 1.f / s;
  bf16 b0 = f2bf(v.x * inv), b1 = f2bf(v.y * inv), b2 = f2bf(v.z * inv), b3 = f2bf(v.w * inv);
  ushort4 o4 = { *(unsigned short*)&b0, *(unsigned short*)&b1,
                 *(unsigned short*)&b2, *(unsigned short*)&b3 };
  *(ushort4*)((unsigned short*)att + row * 256 + lid * 4) = o4;
}

// out = gamma*(ohT^T + ow) + in (+ addend); one block per (c,b), full 128x128 tile.
// ohT staged with 256B-coalesced loads + transposed LDS scatter; rows out coalesced.
__global__ __launch_bounds__(256) void k_fuse2(const float* __restrict__ in,
                                               const bf16* __restrict__ ohT,
                                               const bf16* __restrict__ ow,
                                               const float* __restrict__ addend,
                                               const float* __restrict__ gamma,
                                               float* __restrict__ out){
  __shared__ unsigned short tileT[128][138];   // [h][w], pad 138 -> 4-way write conflict max
  int c = blockIdx.x, b = blockIdx.y;
  int t = threadIdx.x;
  float g = gamma[0];
  const bf16* ohp = ohT + ((size_t)(b * Wn) * Cn + c) * Hn;
  #pragma unroll
  for (int i = 0; i < 8; ++i){
    int s = t + i * 256;            // 0..2047
    int w = s >> 4, seg = s & 15;   // 16 lanes -> 256B of one ohT row
    s16x8 d = *(const s16x8*)(ohp + (size_t)w * (Cn * Hn) + seg * 8);
    #pragma unroll
    for (int j = 0; j < 8; ++j)
      tileT[seg * 8 + j][w] = (unsigned short)d[j];
  }
  __syncthreads();
  size_t base = ((size_t)(b * Cn + c)) * Nn;
  #pragma unroll
  for (int i = 0; i < 16; ++i){
    int o = t + i * 256;            // 0..4095
    int h = o >> 5, w4 = (o & 31) * 4;
    size_t idx = base + (size_t)h * Wn + w4;
    float4 inv = *(const float4*)(in + idx);
    ushort4 owv = *(const ushort4*)((const unsigned short*)ow + idx);
    float r[4];
    #pragma unroll
    for (int j = 0; j < 4; ++j){
      unsigned short uh = tileT[h][w4 + j];
      unsigned short uo = ((const unsigned short*)&owv)[j];
      float ohv = bf2f(*(bf16*)&uh);
      float owf = bf2f(*(bf16*)&uo);
      float iv  = ((const float*)&inv)[j];
      r[j] = g * (ohv + owf) + iv;
    }
    if (addend){
      float4 av = *(const float4*)(addend + idx);
      r[0] += av.x; r[1] += av.y; r[2] += av.z; r[3] += av.w;
    }
    float4 o4 = { r[0], r[1], r[2], r[3] };
    *(float4*)(out + idx) = o4;
  }
}

// ============================ host ============================

static void run_ca(const float* in, const bf16* wqk_hi, const bf16* wqk_lo,
                   const float* bqk, const bf16* wvb, const float* bv,
                   const float* gamma, const float* addend, float* out,
                   bf16* q, bf16* k, bf16* qT, bf16* kT, bf16* v, bf16* vT,
                   float* e, bf16* attb, bf16* xT_hi, bf16* xT_lo, bf16* tmp,
                   hipStream_t stream){
  bf16* ohT = tmp;
  bf16* ow  = tmp + (size_t)Bn * Cn * Nn;
  k_cvt_T<<<dim3(Nn / 32, Cn / 32, Bn), 256, 0, stream>>>(in, xT_hi, xT_lo);
  k_qk_mfma<<<dim3(Nn / 128, Bn), 256, 0, stream>>>(xT_hi, xT_lo, wqk_hi, wqk_lo, bqk, q, k);
  k_trans<<<dim3(16, CQn, Bn), 256, 0, stream>>>(q, qT, CQn);
  k_trans<<<dim3(16, CQn, Bn), 256, 0, stream>>>(k, kT, CQn);
  k_v_mfma<<<2048, 256, 0, stream>>>(xT_hi, wvb, bv, v);
  k_trans<<<dim3(16, Cn, Bn), 256, 0, stream>>>(v, vT, Cn);
  k_eh<<<dim3(Wn, Bn), 256, 0, stream>>>(qT, kT, e);   // e aliases xT_hi; all xT readers done
  k_ew<<<dim3(Hn, Bn), 256, 0, stream>>>(q, k, e);
  k_softmax<<<(Bn * Nn) / 4, 256, 0, stream>>>(e, attb); // attb aliases q/k/qT/kT (dead now)
  k_comb_h_mfma<<<2048, 256, 0, stream>>>(attb, vT, ohT);
  k_comb_w_mfma<<<2048, 256, 0, stream>>>(attb, v, ow);
  k_fuse2<<<dim3(Cn, Bn), 256, 0, stream>>>(in, ohT, ow, addend, gamma, out);
}

extern "C" void kernel_launch(void* const* d_in, const int* in_sizes, int n_in,
                              void* d_out, int out_size, void* d_ws, size_t ws_size,
                              hipStream_t stream){
  (void)in_sizes; (void)n_in; (void)out_size; (void)ws_size;
  const float* x         = (const float*)d_in[0];
  const float* w_q_right = (const float*)d_in[1];
  const float* w_v_right = (const float*)d_in[2];
  const float* w_up      = (const float*)d_in[3];
  const float* b_up      = (const float*)d_in[4];
  const float* w_q_left  = (const float*)d_in[5];
  const float* w_v_left  = (const float*)d_in[6];
  const float* wq        = (const float*)d_in[7];
  const float* bq        = (const float*)d_in[8];
  const float* wk        = (const float*)d_in[9];
  const float* bk        = (const float*)d_in[10];
  const float* wv        = (const float*)d_in[11];
  const float* bv        = (const float*)d_in[12];
  const float* gamma     = (const float*)d_in[13];

  const size_t SZ_MAP = (size_t)Bn * Cn * Nn;     // 33.5M elements
  char* p = (char*)d_ws;
  float* buf0   = (float*)p; p += SZ_MAP * 4;
  float* buf1   = (float*)p; p += SZ_MAP * 4;
  bf16*  vbuf   = (bf16*)p;  p += SZ_MAP * 2;
  bf16*  vT     = (bf16*)p;  p += SZ_MAP * 2;
  bf16*  qbuf   = (bf16*)p;  p += (size_t)Bn * CQn * Nn * 2;   // qbuf..kT contiguous:
  bf16*  kbuf   = (bf16*)p;  p += (size_t)Bn * CQn * Nn * 2;   //   also used as attb
  bf16*  qT     = (bf16*)p;  p += (size_t)Bn * CQn * Nn * 2;   //   (Bn*Nn*256 bf16 exactly)
  bf16*  kT     = (bf16*)p;  p += (size_t)Bn * CQn * Nn * 2;
  float* ebuf   = (float*)p; p += (size_t)Bn * Nn * 256 * 4;  // doubles as xT_hi (bf16)
  float* logits = (float*)p; p += (size_t)Bn * Nn * 4;
  float* ctxlog = (float*)p; p += (size_t)Bn * Nn * 4;
  float* msp    = (float*)p; p += (size_t)Bn * Nn * 4;
  float* xbar   = (float*)p; p += Bn * Cn * 4;
  float* wgt    = (float*)p; p += Bn * Cn * 4;
  float* u      = (float*)p; p += Bn * Cn * 4;
  float* mch    = (float*)p; p += Bn * Cn * 4;
  float* avg    = (float*)p; p += Bn * CIn * 4;
  float* ctx    = (float*)p; p += Bn * CIn * 4;
  float* stats_sp = (float*)p; p += 64;
  float* stats_ch = (float*)p; p += 64;
  bf16*  wvb    = (bf16*)p;  p += (size_t)Cn * Cn * 2;
  bf16*  wqk_hi = (bf16*)p;  p += (size_t)128 * Cn * 2;
  bf16*  wqk_lo = (bf16*)p;  p += (size_t)128 * Cn * 2;
  float* bqk    = (float*)p; p += 128 * 4;
  bf16*  xT_hi  = (bf16*)ebuf;    // alias: lifetime ends before e is written
  bf16*  xT_lo  = (bf16*)d_out;   // alias: lifetime ends before ohT/fuse writes d_out
  bf16*  attb   = qbuf;           // alias: q/k/qT/kT dead once softmax runs

  // ---- weight prep (once) ----
  k_cvt_w<<<(Cn * Cn + 255) / 256, 256, 0, stream>>>(wv, wvb, Cn * Cn);
  k_prep_wqk<<<(128 * Cn) / 256, 256, 0, stream>>>(wq, wk, bq, bk, wqk_hi, wqk_lo, bqk);

  // ---- stage 0: gating masks ----
  k_dotc<<<Bn * Nn / 256, 256, 0, stream>>>(x, w_q_right, 0, logits);
  k_rowmean<<<Bn * Cn, 256, 0, stream>>>(x, xbar, 1.f / Nn);
  k_rowdot<<<Bn, 256, 0, stream>>>(w_q_left, xbar, avg);
  k_coldot<<<dim3(Cn / 256, Bn), 256, 0, stream>>>(w_v_left, avg, u);
  k_stats<<<Bn, 1024, 0, stream>>>(logits, stats_sp);
  k_weighted<<<Bn * Cn, 256, 0, stream>>>(x, logits, stats_sp, wgt);
  k_rowdot<<<Bn, 256, 0, stream>>>(w_v_right, wgt, ctx);
  k_mch2<<<dim3(Cn / 256, Bn), 256, 0, stream>>>(w_up, b_up, ctx, mch);
  k_dotc<<<Bn * Nn / 256, 256, 0, stream>>>(x, u, Cn, ctxlog);
  k_stats<<<Bn, 1024, 0, stream>>>(ctxlog, stats_ch);
  k_msp<<<Bn * Nn / 256, 256, 0, stream>>>(ctxlog, stats_ch, msp);
  k_apply<<<(int)(SZ_MAP / 256), 256, 0, stream>>>(x, mch, msp, buf0, buf1);

  // ---- CA1: cc' = CA(cc), in-place buf0; tmp = d_out ----
  run_ca(buf0, wqk_hi, wqk_lo, bqk, wvb, bv, gamma, nullptr, buf0,
         qbuf, kbuf, qT, kT, vbuf, vT, ebuf, attb, xT_hi, xT_lo, (bf16*)d_out, stream);
  // ---- CA2: s = CA(cs) + cc' -> buf0 ----
  run_ca(buf1, wqk_hi, wqk_lo, bqk, wvb, bv, gamma, buf0, buf0,
         qbuf, kbuf, qT, kT, vbuf, vT, ebuf, attb, xT_hi, xT_lo, (bf16*)d_out, stream);
  // ---- CA3: out = CA(s) -> d_out; tmp = buf1 ----
  run_ca(buf0, wqk_hi, wqk_lo, bqk, wvb, bv, gamma, nullptr, (float*)d_out,
         qbuf, kbuf, qT, kT, vbuf, vT, ebuf, attb, xT_hi, xT_lo, (bf16*)buf1, stream);
}

// Round 8
// 1617.531 us; speedup vs baseline: 2.5137x; 1.0009x over previous
//
#include <hip/hip_runtime.h>
#include <hip/hip_bf16.h>
#include <math.h>

typedef __hip_bfloat16 bf16;
typedef __attribute__((ext_vector_type(8))) short s16x8;
typedef __attribute__((ext_vector_type(4))) float f32x4;

constexpr int Bn  = 4;
constexpr int Cn  = 512;
constexpr int Hn  = 128;
constexpr int Wn  = 128;
constexpr int Nn  = Hn * Wn;   // 16384
constexpr int CQn = 64;
constexpr int CIn = 256;

__device__ __forceinline__ float bf2f(bf16 v){ return __bfloat162float(v); }
__device__ __forceinline__ bf16  f2bf(float v){ return __float2bfloat16(v); }

// async global->LDS, 16B per lane; LDS dest must be wave-uniform base (HW adds lane*16)
__device__ __forceinline__ void gload_lds16(const void* g, void* l){
  __builtin_amdgcn_global_load_lds(
      (const __attribute__((address_space(1))) unsigned int*)g,
      (__attribute__((address_space(3))) unsigned int*)l,
      16, 0, 0);
}

// ============================ stage 0 ============================

// out[b*Nn+n] = sum_c w[b*wstride + c] * x[(b*Cn+c)*Nn + n]
__global__ __launch_bounds__(256) void k_dotc(const float* __restrict__ x,
                                              const float* __restrict__ w,
                                              int wstride,
                                              float* __restrict__ out){
  int t = blockIdx.x * 256 + threadIdx.x;      // over B*Nn
  int b = t >> 14;
  const float* wp = w + (size_t)b * wstride;
  const float* xp = x + (size_t)b * Cn * Nn + (t & (Nn - 1));
  float acc = 0.f;
  #pragma unroll 8
  for (int c = 0; c < Cn; ++c) acc += wp[c] * xp[(size_t)c * Nn];
  out[t] = acc;
}

// out[bc] = scale * sum_n x[bc*Nn+n]
__global__ __launch_bounds__(256) void k_rowmean(const float* __restrict__ x,
                                                 float* __restrict__ out,
                                                 float scale){
  int bc = blockIdx.x;
  const float* xp = x + (size_t)bc * Nn;
  float acc = 0.f;
  for (int n = threadIdx.x; n < Nn; n += 256) acc += xp[n];
  for (int o = 32; o > 0; o >>= 1) acc += __shfl_down(acc, o);
  __shared__ float red[4];
  if ((threadIdx.x & 63) == 0) red[threadIdx.x >> 6] = acc;
  __syncthreads();
  if (threadIdx.x == 0) out[bc] = (red[0] + red[1] + red[2] + red[3]) * scale;
}

// out[b][i] = sum_j W[i][j]*vec[b][j]; W: CIn x Cn row-major; grid Bn, 256 thr (one per i)
__global__ __launch_bounds__(256) void k_rowdot(const float* __restrict__ W,
                                                const float* __restrict__ vec,
                                                float* __restrict__ out){
  __shared__ float vs[Cn];
  int b = blockIdx.x, t = threadIdx.x;
  for (int j = t; j < Cn; j += 256) vs[j] = vec[b * Cn + j];
  __syncthreads();
  const float4* wp = (const float4*)(W + (size_t)t * Cn);
  float a = 0.f;
  #pragma unroll 4
  for (int j = 0; j < Cn / 4; ++j){
    float4 w4 = wp[j];
    a += w4.x * vs[4*j] + w4.y * vs[4*j+1] + w4.z * vs[4*j+2] + w4.w * vs[4*j+3];
  }
  out[b * CIn + t] = a;
}

// out[b][c] = sum_j W[j][c]*vec[b][j]; W: CIn x Cn; grid (Cn/256, Bn)
__global__ __launch_bounds__(256) void k_coldot(const float* __restrict__ W,
                                                const float* __restrict__ vec,
                                                float* __restrict__ out){
  __shared__ float vs[CIn];
  int b = blockIdx.y, t = threadIdx.x;
  int c = blockIdx.x * 256 + t;
  if (t < CIn) vs[t] = vec[b * CIn + t];
  __syncthreads();
  float a = 0.f;
  #pragma unroll 8
  for (int j = 0; j < CIn; ++j) a += W[(size_t)j * Cn + c] * vs[j];
  out[b * Cn + c] = a;
}

// mch[b][o] = sigmoid(sum_ci w_up[o][ci]*ctx[b][ci] + b_up[o]); grid (Cn/256, Bn)
__global__ __launch_bounds__(256) void k_mch2(const float* __restrict__ w_up,
                                              const float* __restrict__ b_up,
                                              const float* __restrict__ ctx,
                                              float* __restrict__ mch){
  __shared__ float cs[CIn];
  int b = blockIdx.y, t = threadIdx.x;
  int o = blockIdx.x * 256 + t;
  if (t < CIn) cs[t] = ctx[b * CIn + t];
  __syncthreads();
  const float4* wp = (const float4*)(w_up + (size_t)o * CIn);
  float a = b_up[o];
  #pragma unroll 4
  for (int j = 0; j < CIn / 4; ++j){
    float4 w4 = wp[j];
    a += w4.x * cs[4*j] + w4.y * cs[4*j+1] + w4.z * cs[4*j+2] + w4.w * cs[4*j+3];
  }
  mch[b * Cn + o] = 1.f / (1.f + expf(-a));
}

// per-b max & sumexp over Nn values
__global__ __launch_bounds__(1024) void k_stats(const float* __restrict__ vv,
                                                float* __restrict__ stats){
  int b = blockIdx.x;
  const float* pp = vv + (size_t)b * Nn;
  int t = threadIdx.x;
  float m = -3.4e38f;
  for (int n = t; n < Nn; n += 1024) m = fmaxf(m, pp[n]);
  for (int o = 32; o > 0; o >>= 1) m = fmaxf(m, __shfl_down(m, o));
  __shared__ float red[16];
  int wid = t >> 6, lid = t & 63;
  if (lid == 0) red[wid] = m;
  __syncthreads();
  if (t == 0){
    float q = red[0];
    for (int i = 1; i < 16; i++) q = fmaxf(q, red[i]);
    red[0] = q;
  }
  __syncthreads();
  m = red[0];
  __syncthreads();
  float s = 0.f;
  for (int n = t; n < Nn; n += 1024) s += expf(pp[n] - m);
  for (int o = 32; o > 0; o >>= 1) s += __shfl_down(s, o);
  if (lid == 0) red[wid] = s;
  __syncthreads();
  if (t == 0){
    float q = 0.f;
    for (int i = 0; i < 16; i++) q += red[i];
    stats[b * 2]     = m;
    stats[b * 2 + 1] = q;
  }
}

// weighted[b,c] = sum_n x[b,c,n]*exp(l[b,n]-m)/den
__global__ __launch_bounds__(256) void k_weighted(const float* __restrict__ x,
                                                  const float* __restrict__ logits,
                                                  const float* __restrict__ stats,
                                                  float* __restrict__ out){
  int bc = blockIdx.x;
  int b = bc >> 9;
  const float* xp = x + (size_t)bc * Nn;
  const float* lp = logits + (size_t)b * Nn;
  float m = stats[b * 2], den = stats[b * 2 + 1];
  float acc = 0.f;
  for (int n = threadIdx.x; n < Nn; n += 256) acc += xp[n] * expf(lp[n] - m);
  for (int o = 32; o > 0; o >>= 1) acc += __shfl_down(acc, o);
  __shared__ float red[4];
  if ((threadIdx.x & 63) == 0) red[threadIdx.x >> 6] = acc;
  __syncthreads();
  if (threadIdx.x == 0) out[bc] = (red[0] + red[1] + red[2] + red[3]) / den;
}

// msp[b,n] = sigmoid(exp(l-m)/den)
__global__ __launch_bounds__(256) void k_msp(const float* __restrict__ lg,
                                             const float* __restrict__ stats,
                                             float* __restrict__ msp){
  int t = blockIdx.x * 256 + threadIdx.x;
  int b = t >> 14;
  float v = expf(lg[t] - stats[b * 2]) / stats[b * 2 + 1];
  msp[t] = 1.f / (1.f + expf(-v));
}

// Fused: cc = x*mch, cs = x*msp, plus ccT hi/lo bf16 (transposed) for CA1's MFMA inputs.
// grid (Nn/32, Cn/32, Bn)
__global__ __launch_bounds__(256) void k_applyT(const float* __restrict__ x,
                                                const float* __restrict__ mch,
                                                const float* __restrict__ msp,
                                                float* __restrict__ cc,
                                                float* __restrict__ cs,
                                                bf16* __restrict__ out_hi,
                                                bf16* __restrict__ out_lo){
  __shared__ bf16 th_[32][33];
  __shared__ bf16 tl_[32][33];
  int nt = blockIdx.x, ct = blockIdx.y, b = blockIdx.z;
  int n0 = nt * 32, c0 = ct * 32;
  int t = threadIdx.x;
  #pragma unroll
  for (int kk = 0; kk < 4; ++kk){
    int idx = t + kk * 256;
    int cl = idx >> 5, nl = idx & 31;
    size_t off = ((size_t)(b * Cn + c0 + cl)) * Nn + n0 + nl;
    float xv = x[off];
    float ccv = xv * mch[b * Cn + c0 + cl];
    float csv = xv * msp[b * Nn + n0 + nl];
    cc[off] = ccv;
    cs[off] = csv;
    bf16 h = f2bf(ccv);
    th_[cl][nl] = h;
    tl_[cl][nl] = f2bf(ccv - bf2f(h));
  }
  __syncthreads();
  #pragma unroll
  for (int kk = 0; kk < 4; ++kk){
    int idx = t + kk * 256;
    int nl = idx >> 5, cl = idx & 31;
    size_t o = ((size_t)(b * Nn + n0 + nl)) * Cn + c0 + cl;
    out_hi[o] = th_[cl][nl];
    out_lo[o] = tl_[cl][nl];
  }
}

// ============================ conversions ============================

// wv fp32 [c][c'] -> bf16 (same layout)
__global__ __launch_bounds__(256) void k_cvt_w(const float* __restrict__ in,
                                               bf16* __restrict__ out, int n){
  int t = blockIdx.x * 256 + threadIdx.x;
  if (t < n) out[t] = f2bf(in[t]);
}

// wqk hi/lo: rows 0-63 = wq, 64-127 = wk (bf16 split); bqk fp32
__global__ __launch_bounds__(256) void k_prep_wqk(const float* __restrict__ wq,
                                                  const float* __restrict__ wk,
                                                  const float* __restrict__ bq,
                                                  const float* __restrict__ bk,
                                                  bf16* __restrict__ wqk_hi,
                                                  bf16* __restrict__ wqk_lo,
                                                  float* __restrict__ bqk){
  int t = blockIdx.x * 256 + threadIdx.x;   // over 128*512
  int o = t >> 9, c = t & 511;
  float v = (o < 64) ? wq[(size_t)o * Cn + c] : wk[(size_t)(o - 64) * Cn + c];
  bf16 h = f2bf(v);
  wqk_hi[t] = h;
  wqk_lo[t] = f2bf(v - bf2f(h));
  if (t < 128) bqk[t] = (t < 64) ? bq[t] : bk[t - 64];
}

// in[b][c][n] fp32 -> xT_hi/xT_lo [b][n][c] bf16 split (K-contiguous for MFMA)
__global__ __launch_bounds__(256) void k_cvt_T(const float* __restrict__ in,
                                               bf16* __restrict__ out_hi,
                                               bf16* __restrict__ out_lo){
  __shared__ bf16 th_[32][33];
  __shared__ bf16 tl_[32][33];
  int nt = blockIdx.x, ct = blockIdx.y, b = blockIdx.z;
  int n0 = nt * 32, c0 = ct * 32;
  int t = threadIdx.x;
  #pragma unroll
  for (int kk = 0; kk < 4; ++kk){
    int idx = t + kk * 256;
    int cl = idx >> 5, nl = idx & 31;
    float v = in[((size_t)(b * Cn + c0 + cl)) * Nn + n0 + nl];
    bf16 h = f2bf(v);
    th_[cl][nl] = h;
    tl_[cl][nl] = f2bf(v - bf2f(h));
  }
  __syncthreads();
  #pragma unroll
  for (int kk = 0; kk < 4; ++kk){
    int idx = t + kk * 256;
    int nl = idx >> 5, cl = idx & 31;
    size_t o = ((size_t)(b * Nn + n0 + nl)) * Cn + c0 + cl;
    out_hi[o] = th_[cl][nl];
    out_lo[o] = tl_[cl][nl];
  }
}

// ============================ MFMA GEMMs ============================

// V = Wv @ X. xT: [b][n][c'] bf16, wvb: [c][c'] bf16. 128x128 tile, BK=64.
// 1-D grid of 2048, XCD-chunked swizzle: 4 cb-blocks of one nb adjacent per XCD.
__global__ __launch_bounds__(256) void k_v_mfma(const bf16* __restrict__ xT,
                                                const bf16* __restrict__ wvb,
                                                const float* __restrict__ bv,
                                                bf16* __restrict__ v){
  __shared__ short As[128 * 64];
  __shared__ short Bs[128 * 64];
  __shared__ float bvs[128];
  int lin = blockIdx.x;
  int swz = (lin & 7) * 256 + (lin >> 3);   // 2048 = 8 XCD chunks of 256
  int cb = (swz & 3) * 128;
  int nb = ((swz >> 2) & 127) * 128;
  int b  = swz >> 9;
  int t = threadIdx.x, lane = t & 63, wid = t >> 6;
  int wm = wid >> 1, wn = wid & 1;
  int l15 = lane & 15, l4 = lane >> 4;
  if (t < 128) bvs[t] = bv[cb + t];
  f32x4 acc[4][4];
  #pragma unroll
  for (int i = 0; i < 4; i++)
    #pragma unroll
    for (int j = 0; j < 4; j++) acc[i][j] = (f32x4){0.f, 0.f, 0.f, 0.f};

  const bf16* wp = wvb + (size_t)cb * Cn;
  const bf16* xp = xT + ((size_t)b * Nn + nb) * Cn;
  int r8 = lane >> 3;
  int kc = (lane & 7) * 8;
  for (int kt = 0; kt < 8; ++kt){
    int k0 = kt * 64;
    #pragma unroll
    for (int j = 0; j < 4; ++j){
      int inst = wid * 4 + j;
      int row = inst * 8 + r8;
      gload_lds16(wp + (size_t)row * Cn + k0 + kc, (char*)As + inst * 1024);
      gload_lds16(xp + (size_t)row * Cn + k0 + kc, (char*)Bs + inst * 1024);
    }
    __syncthreads();
    #pragma unroll
    for (int kk = 0; kk < 64; kk += 32){
      s16x8 a[4], bb[4];
      #pragma unroll
      for (int mi = 0; mi < 4; mi++)
        a[mi] = *(const s16x8*)&As[(wm * 64 + mi * 16 + l15) * 64 + kk + l4 * 8];
      #pragma unroll
      for (int ni = 0; ni < 4; ni++)
        bb[ni] = *(const s16x8*)&Bs[(wn * 64 + ni * 16 + l15) * 64 + kk + l4 * 8];
      #pragma unroll
      for (int mi = 0; mi < 4; mi++)
        #pragma unroll
        for (int ni = 0; ni < 4; ni++)
          acc[mi][ni] = __builtin_amdgcn_mfma_f32_16x16x32_bf16(a[mi], bb[ni], acc[mi][ni], 0, 0, 0);
    }
    __syncthreads();
  }
  #pragma unroll
  for (int mi = 0; mi < 4; mi++){
    #pragma unroll
    for (int r = 0; r < 4; r++){
      int cl = wm * 64 + mi * 16 + l4 * 4 + r;
      int c  = cb + cl;
      float bias = bvs[cl];
      #pragma unroll
      for (int ni = 0; ni < 4; ni++){
        int n = nb + wn * 64 + ni * 16 + l15;
        v[((size_t)(b * Cn + c)) * Nn + n] = f2bf(acc[mi][ni][r] + bias);
      }
    }
  }
}

// Q,K = [Wq;Wk] @ X with split-precision bf16 (x=hi+lo, w=hi+lo; 3 MFMA terms).
__global__ __launch_bounds__(256) void k_qk_mfma(const bf16* __restrict__ xT_hi,
                                                 const bf16* __restrict__ xT_lo,
                                                 const bf16* __restrict__ wqk_hi,
                                                 const bf16* __restrict__ wqk_lo,
                                                 const float* __restrict__ bqk,
                                                 bf16* __restrict__ q,
                                                 bf16* __restrict__ k){
  __shared__ short Ah[128 * 64];
  __shared__ short Al[128 * 64];
  __shared__ short Bh[128 * 64];
  __shared__ short Bl[128 * 64];
  __shared__ float bs[128];
  int nb = blockIdx.x * 128, b = blockIdx.y;
  int t = threadIdx.x, lane = t & 63, wid = t >> 6;
  int wm = wid >> 1, wn = wid & 1;
  int l15 = lane & 15, l4 = lane >> 4;
  if (t < 128) bs[t] = bqk[t];
  f32x4 acc[4][4];
  #pragma unroll
  for (int i = 0; i < 4; i++)
    #pragma unroll
    for (int j = 0; j < 4; j++) acc[i][j] = (f32x4){0.f, 0.f, 0.f, 0.f};

  const bf16* xh = xT_hi + ((size_t)b * Nn + nb) * Cn;
  const bf16* xl = xT_lo + ((size_t)b * Nn + nb) * Cn;
  int r8 = lane >> 3;
  int kc = (lane & 7) * 8;
  for (int kt = 0; kt < 8; ++kt){
    int k0 = kt * 64;
    #pragma unroll
    for (int j = 0; j < 4; ++j){
      int inst = wid * 4 + j;
      int row = inst * 8 + r8;
      size_t off = (size_t)row * Cn + k0 + kc;
      gload_lds16(wqk_hi + off, (char*)Ah + inst * 1024);
      gload_lds16(wqk_lo + off, (char*)Al + inst * 1024);
      gload_lds16(xh + off,     (char*)Bh + inst * 1024);
      gload_lds16(xl + off,     (char*)Bl + inst * 1024);
    }
    __syncthreads();
    #pragma unroll
    for (int kk = 0; kk < 64; kk += 32){
      s16x8 ah[4], al[4], bh[4], bl[4];
      #pragma unroll
      for (int mi = 0; mi < 4; mi++){
        int idx = (wm * 64 + mi * 16 + l15) * 64 + kk + l4 * 8;
        ah[mi] = *(const s16x8*)&Ah[idx];
        al[mi] = *(const s16x8*)&Al[idx];
      }
      #pragma unroll
      for (int ni = 0; ni < 4; ni++){
        int idx = (wn * 64 + ni * 16 + l15) * 64 + kk + l4 * 8;
        bh[ni] = *(const s16x8*)&Bh[idx];
        bl[ni] = *(const s16x8*)&Bl[idx];
      }
      #pragma unroll
      for (int mi = 0; mi < 4; mi++)
        #pragma unroll
        for (int ni = 0; ni < 4; ni++){
          acc[mi][ni] = __builtin_amdgcn_mfma_f32_16x16x32_bf16(ah[mi], bh[ni], acc[mi][ni], 0, 0, 0);
          acc[mi][ni] = __builtin_amdgcn_mfma_f32_16x16x32_bf16(ah[mi], bl[ni], acc[mi][ni], 0, 0, 0);
          acc[mi][ni] = __builtin_amdgcn_mfma_f32_16x16x32_bf16(al[mi], bh[ni], acc[mi][ni], 0, 0, 0);
        }
    }
    __syncthreads();
  }
  #pragma unroll
  for (int mi = 0; mi < 4; mi++){
    #pragma unroll
    for (int r = 0; r < 4; r++){
      int o = wm * 64 + mi * 16 + l4 * 4 + r;
      float bias = bs[o];
      #pragma unroll
      for (int ni = 0; ni < 4; ni++){
        int n = nb + wn * 64 + ni * 16 + l15;
        float val = acc[mi][ni][r] + bias;
        if (o < 64) q[((size_t)(b * CQn + o)) * Nn + n]        = f2bf(val);
        else        k[((size_t)(b * CQn + o - 64)) * Nn + n]   = f2bf(val);
      }
    }
  }
}

// comb_h: per (b,w): ohT[b,w,c,h] = sum_g att[b,h,w,g]*vT[b,w,c,g]; swizzled grid
__global__ __launch_bounds__(256) void k_comb_h_mfma(const bf16* __restrict__ att,
                                                     const bf16* __restrict__ vT,
                                                     bf16* __restrict__ ohT){
  __shared__ short As[128 * 128];
  __shared__ short Bs[128 * 128];
  int lin = blockIdx.x;
  int swz = (lin & 7) * 256 + (lin >> 3);
  int cb = (swz & 3) * 128;
  int w  = (swz >> 2) & 127;
  int b  = swz >> 9;
  int t = threadIdx.x, lane = t & 63, wid = t >> 6;
  int wm = wid >> 1, wn = wid & 1;
  int l15 = lane & 15, l4 = lane >> 4;

  // stage V tile (rows c, K-contig), swizzled; 16B (s16x8) chunks
  const bf16* vp = vT + ((size_t)(b * Wn + w) * Cn + cb) * Hn;
  for (int s = t; s < 2048; s += 256){
    int row = s >> 4, seg = s & 15;
    s16x8 d = *(const s16x8*)(vp + (size_t)row * Hn + seg * 8);
    int byte = (row * 256 + seg * 16) ^ ((row & 7) << 4);
    *(s16x8*)((char*)As + byte) = d;
  }
  // stage att tile (rows h, first 128 cols), bf16 direct, swizzled
  const bf16* ap = att + ((size_t)(b * Hn) * Wn + w) * 256;
  for (int s = t; s < 2048; s += 256){
    int row = s >> 4, seg = s & 15;
    s16x8 d = *(const s16x8*)(ap + (size_t)row * (Wn * 256) + seg * 8);
    int byte = (row * 256 + seg * 16) ^ ((row & 7) << 4);
    *(s16x8*)((char*)Bs + byte) = d;
  }
  __syncthreads();

  f32x4 acc[4][4];
  #pragma unroll
  for (int i = 0; i < 4; i++)
    #pragma unroll
    for (int j = 0; j < 4; j++) acc[i][j] = (f32x4){0.f, 0.f, 0.f, 0.f};
  #pragma unroll
  for (int kk = 0; kk < 128; kk += 32){
    s16x8 a[4], bb[4];
    #pragma unroll
    for (int mi = 0; mi < 4; mi++){
      int row = wm * 64 + mi * 16 + l15;
      int byte = (row * 256 + (kk + l4 * 8) * 2) ^ ((row & 7) << 4);
      a[mi] = *(const s16x8*)((char*)As + byte);
    }
    #pragma unroll
    for (int ni = 0; ni < 4; ni++){
      int row = wn * 64 + ni * 16 + l15;
      int byte = (row * 256 + (kk + l4 * 8) * 2) ^ ((row & 7) << 4);
      bb[ni] = *(const s16x8*)((char*)Bs + byte);
    }
    #pragma unroll
    for (int mi = 0; mi < 4; mi++)
      #pragma unroll
      for (int ni = 0; ni < 4; ni++)
        acc[mi][ni] = __builtin_amdgcn_mfma_f32_16x16x32_bf16(a[mi], bb[ni], acc[mi][ni], 0, 0, 0);
  }
  bf16* op = ohT + ((size_t)(b * Wn + w) * Cn + cb) * Hn;
  #pragma unroll
  for (int mi = 0; mi < 4; mi++)
    #pragma unroll
    for (int r = 0; r < 4; r++){
      int cl = wm * 64 + mi * 16 + l4 * 4 + r;
      #pragma unroll
      for (int ni = 0; ni < 4; ni++){
        int h = wn * 64 + ni * 16 + l15;
        op[(size_t)cl * Hn + h] = f2bf(acc[mi][ni][r]);
      }
    }
}

// comb_w: per (b,h): ow[b,c,h,w_] = sum_g att[b,h,w_,128+g]*v[b,c,h,g]; swizzled grid
__global__ __launch_bounds__(256) void k_comb_w_mfma(const bf16* __restrict__ att,
                                                     const bf16* __restrict__ v,
                                                     bf16* __restrict__ ow){
  __shared__ short As[128 * 128];
  __shared__ short Bs[128 * 128];
  int lin = blockIdx.x;
  int swz = (lin & 7) * 256 + (lin >> 3);
  int cb = (swz & 3) * 128;
  int h  = (swz >> 2) & 127;
  int b  = swz >> 9;
  int t = threadIdx.x, lane = t & 63, wid = t >> 6;
  int wm = wid >> 1, wn = wid & 1;
  int l15 = lane & 15, l4 = lane >> 4;

  const bf16* vp = v + (size_t)(b * Cn + cb) * Nn + (size_t)h * Wn;
  for (int s = t; s < 2048; s += 256){
    int row = s >> 4, seg = s & 15;
    s16x8 d = *(const s16x8*)(vp + (size_t)row * Nn + seg * 8);
    int byte = (row * 256 + seg * 16) ^ ((row & 7) << 4);
    *(s16x8*)((char*)As + byte) = d;
  }
  const bf16* ap = att + ((size_t)(b * Hn + h) * Wn) * 256 + 128;
  for (int s = t; s < 2048; s += 256){
    int row = s >> 4, seg = s & 15;
    s16x8 d = *(const s16x8*)(ap + (size_t)row * 256 + seg * 8);
    int byte = (row * 256 + seg * 16) ^ ((row & 7) << 4);
    *(s16x8*)((char*)Bs + byte) = d;
  }
  __syncthreads();

  f32x4 acc[4][4];
  #pragma unroll
  for (int i = 0; i < 4; i++)
    #pragma unroll
    for (int j = 0; j < 4; j++) acc[i][j] = (f32x4){0.f, 0.f, 0.f, 0.f};
  #pragma unroll
  for (int kk = 0; kk < 128; kk += 32){
    s16x8 a[4], bb[4];
    #pragma unroll
    for (int mi = 0; mi < 4; mi++){
      int row = wm * 64 + mi * 16 + l15;
      int byte = (row * 256 + (kk + l4 * 8) * 2) ^ ((row & 7) << 4);
      a[mi] = *(const s16x8*)((char*)As + byte);
    }
    #pragma unroll
    for (int ni = 0; ni < 4; ni++){
      int row = wn * 64 + ni * 16 + l15;
      int byte = (row * 256 + (kk + l4 * 8) * 2) ^ ((row & 7) << 4);
      bb[ni] = *(const s16x8*)((char*)Bs + byte);
    }
    #pragma unroll
    for (int mi = 0; mi < 4; mi++)
      #pragma unroll
      for (int ni = 0; ni < 4; ni++)
        acc[mi][ni] = __builtin_amdgcn_mfma_f32_16x16x32_bf16(a[mi], bb[ni], acc[mi][ni], 0, 0, 0);
  }
  bf16* op = ow + (size_t)(b * Cn + cb) * Nn + (size_t)h * Wn;
  #pragma unroll
  for (int mi = 0; mi < 4; mi++)
    #pragma unroll
    for (int r = 0; r < 4; r++){
      int cl = wm * 64 + mi * 16 + l4 * 4 + r;
      #pragma unroll
      for (int ni = 0; ni < 4; ni++){
        int wr = wn * 64 + ni * 16 + l15;
        op[(size_t)cl * Nn + wr] = f2bf(acc[mi][ni][r]);
      }
    }
}

// ============================ remaining CA kernels ============================

// [b,c,h,w] -> [b,w,c,h] (bf16), 32x32 tiles
__global__ __launch_bounds__(256) void k_trans(const bf16* __restrict__ in,
                                               bf16* __restrict__ out,
                                               int CH){
  __shared__ bf16 tile[32][33];
  int tl = blockIdx.x, c = blockIdx.y, b = blockIdx.z;
  int th = tl >> 2, tw = tl & 3;
  int h0 = th * 32, w0 = tw * 32;
  int t = threadIdx.x;
  const bf16* ip = in + ((size_t)(b * CH + c)) * Nn;
  #pragma unroll
  for (int kk = 0; kk < 4; ++kk){
    int idx = t + kk * 256;
    int hl = idx >> 5, wl = idx & 31;
    tile[hl][wl] = ip[(h0 + hl) * Wn + w0 + wl];
  }
  __syncthreads();
  #pragma unroll
  for (int kk = 0; kk < 4; ++kk){
    int idx = t + kk * 256;
    int wl = idx >> 5, hl = idx & 31;
    out[((size_t)(b * Wn + w0 + wl) * CH + c) * Hn + h0 + hl] = tile[hl][wl];
  }
}

// e_h[h,g] = sum_c qT[b,w,c,h]*kT[b,w,c,g], diag -> -1e30
__global__ __launch_bounds__(256) void k_eh(const bf16* __restrict__ qT,
                                            const bf16* __restrict__ kT,
                                            float* __restrict__ e){
  __shared__ float smem[16384];
  float* qs = smem;
  float* ks = smem + 8192;
  int w = blockIdx.x, b = blockIdx.y;
  int t = threadIdx.x;
  const bf16* qp = qT + (size_t)(b * Wn + w) * CQn * Hn;
  const bf16* kp = kT + (size_t)(b * Wn + w) * CQn * Hn;
  for (int i = t; i < 8192; i += 256){ qs[i] = bf2f(qp[i]); ks[i] = bf2f(kp[i]); }
  __syncthreads();
  int hg = t >> 3, gg = t & 7;
  float acc[4][16];
  #pragma unroll
  for (int i = 0; i < 4; i++)
    #pragma unroll
    for (int j = 0; j < 16; j++) acc[i][j] = 0.f;
  for (int c = 0; c < CQn; ++c){
    float qv[4], kv[16];
    #pragma unroll
    for (int i = 0; i < 4; i++) qv[i] = qs[c * 128 + hg * 4 + i];
    #pragma unroll
    for (int j = 0; j < 16; j++) kv[j] = ks[c * 128 + gg + 8 * j];
    #pragma unroll
    for (int i = 0; i < 4; i++)
      #pragma unroll
      for (int j = 0; j < 16; j++) acc[i][j] += qv[i] * kv[j];
  }
  __syncthreads();
  #pragma unroll
  for (int i = 0; i < 4; i++)
    #pragma unroll
    for (int j = 0; j < 16; j++)
      smem[(hg * 4 + i) * 128 + gg + 8 * j] = acc[i][j];
  __syncthreads();
  for (int kk = 0; kk < 64; ++kk){
    int idx = t + kk * 256;
    int h = idx >> 7, g = idx & 127;
    float val = (h == g) ? -1e30f : smem[idx];
    e[((size_t)(b * Hn + h) * Wn + w) * 256 + g] = val;
  }
}

// e_w[w,v] = sum_c q[b,c,h,w]*k[b,c,h,v]
__global__ __launch_bounds__(256) void k_ew(const bf16* __restrict__ q,
                                            const bf16* __restrict__ k,
                                            float* __restrict__ e){
  __shared__ float smem[16384];
  float* qs = smem;
  float* ks = smem + 8192;
  int h = blockIdx.x, b = blockIdx.y;
  int t = threadIdx.x;
  for (int i = t; i < 8192; i += 256){
    int c = i >> 7, wl = i & 127;
    size_t base = ((size_t)(b * CQn + c) * Hn + h) * Wn + wl;
    qs[i] = bf2f(q[base]);
    ks[i] = bf2f(k[base]);
  }
  __syncthreads();
  int wg = t >> 3, vg = t & 7;
  float acc[4][16];
  #pragma unroll
  for (int i = 0; i < 4; i++)
    #pragma unroll
    for (int j = 0; j < 16; j++) acc[i][j] = 0.f;
  for (int c = 0; c < CQn; ++c){
    float qv[4], kv[16];
    #pragma unroll
    for (int i = 0; i < 4; i++) qv[i] = qs[c * 128 + wg * 4 + i];
    #pragma unroll
    for (int j = 0; j < 16; j++) kv[j] = ks[c * 128 + vg + 8 * j];
    #pragma unroll
    for (int i = 0; i < 4; i++)
      #pragma unroll
      for (int j = 0; j < 16; j++) acc[i][j] += qv[i] * kv[j];
  }
  __syncthreads();
  #pragma unroll
  for (int i = 0; i < 4; i++)
    #pragma unroll
    for (int j = 0; j < 16; j++)
      smem[(wg * 4 + i) * 128 + vg + 8 * j] = acc[i][j];
  __syncthreads();
  for (int kk = 0; kk < 64; ++kk){
    int idx = t + kk * 256;
    int wr = idx >> 7, vc = idx & 127;
    e[((size_t)(b * Hn + h) * Wn + wr) * 256 + 128 + vc] = smem[idx];
  }
}

// softmax over 256 per row: read fp32 e, write bf16 att; one wave per row
__global__ __launch_bounds__(256) void k_softmax(const float* __restrict__ e,
                                                 bf16* __restrict__ att){
  int wid = threadIdx.x >> 6, lid = threadIdx.x & 63;
  size_t row = (size_t)blockIdx.x * 4 + wid;
  const float* p = e + row * 256;
  float4 v = *(const float4*)(p + lid * 4);
  float m = fmaxf(fmaxf(v.x, v.y), fmaxf(v.z, v.w));
  for (int o = 32; o > 0; o >>= 1) m = fmaxf(m, __shfl_xor(m, o));
  v.x = expf(v.x - m); v.y = expf(v.y - m); v.z = expf(v.z - m); v.w = expf(v.w - m);
  float s = v.x + v.y + v.z + v.w;
  for (int o = 32; o > 0; o >>= 1) s += __shfl_xor(s, o);
  float inv = 1.f / s;
  bf16 b0 = f2bf(v.x * inv), b1 = f2bf(v.y * inv), b2 = f2bf(v.z * inv), b3 = f2bf(v.w * inv);
  ushort4 o4 = { *(unsigned short*)&b0, *(unsigned short*)&b1,
                 *(unsigned short*)&b2, *(unsigned short*)&b3 };
  *(ushort4*)((unsigned short*)att + row * 256 + lid * 4) = o4;
}

// out = gamma*(ohT^T + ow) + in (+ addend); one block per (c,b), two w-half phases.
// LDS 128x70 u16 (17.9 KB) -> 8 blocks/CU full residency.
__global__ __launch_bounds__(256) void k_fuse2(const float* __restrict__ in,
                                               const bf16* __restrict__ ohT,
                                               const bf16* __restrict__ ow,
                                               const float* __restrict__ addend,
                                               const float* __restrict__ gamma,
                                               float* __restrict__ out){
  __shared__ unsigned short tileT[128][70];   // [h][w-half], pad 70 -> 4-way write conflict max
  int c = blockIdx.x, b = blockIdx.y;
  int t = threadIdx.x;
  float g = gamma[0];
  const bf16* ohp = ohT + ((size_t)(b * Wn) * Cn + c) * Hn;
  size_t base = ((size_t)(b * Cn + c)) * Nn;
  #pragma unroll
  for (int phase = 0; phase < 2; ++phase){
    int w0 = phase * 64;
    #pragma unroll
    for (int i = 0; i < 4; ++i){
      int s = t + i * 256;            // 0..1023
      int w = s >> 4, seg = s & 15;   // 16 lanes -> 256B of one ohT row
      s16x8 d = *(const s16x8*)(ohp + (size_t)(w0 + w) * (Cn * Hn) + seg * 8);
      #pragma unroll
      for (int j = 0; j < 8; ++j)
        tileT[seg * 8 + j][w] = (unsigned short)d[j];
    }
    __syncthreads();
    #pragma unroll
    for (int i = 0; i < 8; ++i){
      int o = t + i * 256;            // 0..2047
      int h = o >> 4, w4 = (o & 15) * 4;
      size_t idx = base + (size_t)h * Wn + w0 + w4;
      float4 inv = *(const float4*)(in + idx);
      ushort4 owv = *(const ushort4*)((const unsigned short*)ow + idx);
      float r[4];
      #pragma unroll
      for (int j = 0; j < 4; ++j){
        unsigned short uh = tileT[h][w4 + j];
        unsigned short uo = ((const unsigned short*)&owv)[j];
        float ohv = bf2f(*(bf16*)&uh);
        float owf = bf2f(*(bf16*)&uo);
        float iv  = ((const float*)&inv)[j];
        r[j] = g * (ohv + owf) + iv;
      }
      if (addend){
        float4 av = *(const float4*)(addend + idx);
        r[0] += av.x; r[1] += av.y; r[2] += av.z; r[3] += av.w;
      }
      float4 o4 = { r[0], r[1], r[2], r[3] };
      *(float4*)(out + idx) = o4;
    }
    __syncthreads();
  }
}

// ============================ host ============================

static void run_ca(const float* in, const bf16* wqk_hi, const bf16* wqk_lo,
                   const float* bqk, const bf16* wvb, const float* bv,
                   const float* gamma, const float* addend, float* out,
                   bf16* q, bf16* k, bf16* qT, bf16* kT, bf16* v, bf16* vT,
                   float* e, bf16* attb, bf16* xT_hi, bf16* xT_lo, bf16* tmp,
                   bool do_cvt, hipStream_t stream){
  bf16* ohT = tmp;
  bf16* ow  = tmp + (size_t)Bn * Cn * Nn;
  if (do_cvt)
    k_cvt_T<<<dim3(Nn / 32, Cn / 32, Bn), 256, 0, stream>>>(in, xT_hi, xT_lo);
  k_qk_mfma<<<dim3(Nn / 128, Bn), 256, 0, stream>>>(xT_hi, xT_lo, wqk_hi, wqk_lo, bqk, q, k);
  k_trans<<<dim3(16, CQn, Bn), 256, 0, stream>>>(q, qT, CQn);
  k_trans<<<dim3(16, CQn, Bn), 256, 0, stream>>>(k, kT, CQn);
  k_v_mfma<<<2048, 256, 0, stream>>>(xT_hi, wvb, bv, v);
  k_trans<<<dim3(16, Cn, Bn), 256, 0, stream>>>(v, vT, Cn);
  k_eh<<<dim3(Wn, Bn), 256, 0, stream>>>(qT, kT, e);   // e aliases xT_hi; all xT readers done
  k_ew<<<dim3(Hn, Bn), 256, 0, stream>>>(q, k, e);
  k_softmax<<<(Bn * Nn) / 4, 256, 0, stream>>>(e, attb); // attb aliases q/k/qT/kT (dead now)
  k_comb_h_mfma<<<2048, 256, 0, stream>>>(attb, vT, ohT);
  k_comb_w_mfma<<<2048, 256, 0, stream>>>(attb, v, ow);
  k_fuse2<<<dim3(Cn, Bn), 256, 0, stream>>>(in, ohT, ow, addend, gamma, out);
}

extern "C" void kernel_launch(void* const* d_in, const int* in_sizes, int n_in,
                              void* d_out, int out_size, void* d_ws, size_t ws_size,
                              hipStream_t stream){
  (void)in_sizes; (void)n_in; (void)out_size; (void)ws_size;
  const float* x         = (const float*)d_in[0];
  const float* w_q_right = (const float*)d_in[1];
  const float* w_v_right = (const float*)d_in[2];
  const float* w_up      = (const float*)d_in[3];
  const float* b_up      = (const float*)d_in[4];
  const float* w_q_left  = (const float*)d_in[5];
  const float* w_v_left  = (const float*)d_in[6];
  const float* wq        = (const float*)d_in[7];
  const float* bq        = (const float*)d_in[8];
  const float* wk        = (const float*)d_in[9];
  const float* bk        = (const float*)d_in[10];
  const float* wv        = (const float*)d_in[11];
  const float* bv        = (const float*)d_in[12];
  const float* gamma     = (const float*)d_in[13];

  const size_t SZ_MAP = (size_t)Bn * Cn * Nn;     // 33.5M elements
  char* p = (char*)d_ws;
  float* buf0   = (float*)p; p += SZ_MAP * 4;
  float* buf1   = (float*)p; p += SZ_MAP * 4;
  bf16*  vbuf   = (bf16*)p;  p += SZ_MAP * 2;
  bf16*  vT     = (bf16*)p;  p += SZ_MAP * 2;
  bf16*  qbuf   = (bf16*)p;  p += (size_t)Bn * CQn * Nn * 2;   // qbuf..kT contiguous:
  bf16*  kbuf   = (bf16*)p;  p += (size_t)Bn * CQn * Nn * 2;   //   also used as attb
  bf16*  qT     = (bf16*)p;  p += (size_t)Bn * CQn * Nn * 2;   //   (Bn*Nn*256 bf16 exactly)
  bf16*  kT     = (bf16*)p;  p += (size_t)Bn * CQn * Nn * 2;
  float* ebuf   = (float*)p; p += (size_t)Bn * Nn * 256 * 4;  // doubles as xT_hi (bf16)
  float* logits = (float*)p; p += (size_t)Bn * Nn * 4;
  float* ctxlog = (float*)p; p += (size_t)Bn * Nn * 4;
  float* msp    = (float*)p; p += (size_t)Bn * Nn * 4;
  float* xbar   = (float*)p; p += Bn * Cn * 4;
  float* wgt    = (float*)p; p += Bn * Cn * 4;
  float* u      = (float*)p; p += Bn * Cn * 4;
  float* mch    = (float*)p; p += Bn * Cn * 4;
  float* avg    = (float*)p; p += Bn * CIn * 4;
  float* ctx    = (float*)p; p += Bn * CIn * 4;
  float* stats_sp = (float*)p; p += 64;
  float* stats_ch = (float*)p; p += 64;
  bf16*  wvb    = (bf16*)p;  p += (size_t)Cn * Cn * 2;
  bf16*  wqk_hi = (bf16*)p;  p += (size_t)128 * Cn * 2;
  bf16*  wqk_lo = (bf16*)p;  p += (size_t)128 * Cn * 2;
  float* bqk    = (float*)p; p += 128 * 4;
  bf16*  xT_hi  = (bf16*)ebuf;    // alias: lifetime ends before e is written
  bf16*  xT_lo  = (bf16*)d_out;   // alias: lifetime ends before ohT/fuse writes d_out
  bf16*  attb   = qbuf;           // alias: q/k/qT/kT dead once softmax runs

  // ---- weight prep (once) ----
  k_cvt_w<<<(Cn * Cn + 255) / 256, 256, 0, stream>>>(wv, wvb, Cn * Cn);
  k_prep_wqk<<<(128 * Cn) / 256, 256, 0, stream>>>(wq, wk, bq, bk, wqk_hi, wqk_lo, bqk);

  // ---- stage 0: gating masks ----
  k_dotc<<<Bn * Nn / 256, 256, 0, stream>>>(x, w_q_right, 0, logits);
  k_rowmean<<<Bn * Cn, 256, 0, stream>>>(x, xbar, 1.f / Nn);
  k_rowdot<<<Bn, 256, 0, stream>>>(w_q_left, xbar, avg);
  k_coldot<<<dim3(Cn / 256, Bn), 256, 0, stream>>>(w_v_left, avg, u);
  k_stats<<<Bn, 1024, 0, stream>>>(logits, stats_sp);
  k_weighted<<<Bn * Cn, 256, 0, stream>>>(x, logits, stats_sp, wgt);
  k_rowdot<<<Bn, 256, 0, stream>>>(w_v_right, wgt, ctx);
  k_mch2<<<dim3(Cn / 256, Bn), 256, 0, stream>>>(w_up, b_up, ctx, mch);
  k_dotc<<<Bn * Nn / 256, 256, 0, stream>>>(x, u, Cn, ctxlog);
  k_stats<<<Bn, 1024, 0, stream>>>(ctxlog, stats_ch);
  k_msp<<<Bn * Nn / 256, 256, 0, stream>>>(ctxlog, stats_ch, msp);
  // fused apply + transpose-convert of cc (CA1's MFMA input)
  k_applyT<<<dim3(Nn / 32, Cn / 32, Bn), 256, 0, stream>>>(x, mch, msp, buf0, buf1,
                                                           xT_hi, xT_lo);

  // ---- CA1: cc' = CA(cc), in-place buf0; tmp = d_out (xT already built) ----
  run_ca(buf0, wqk_hi, wqk_lo, bqk, wvb, bv, gamma, nullptr, buf0,
         qbuf, kbuf, qT, kT, vbuf, vT, ebuf, attb, xT_hi, xT_lo, (bf16*)d_out,
         false, stream);
  // ---- CA2: s = CA(cs) + cc' -> buf0 ----
  run_ca(buf1, wqk_hi, wqk_lo, bqk, wvb, bv, gamma, buf0, buf0,
         qbuf, kbuf, qT, kT, vbuf, vT, ebuf, attb, xT_hi, xT_lo, (bf16*)d_out,
         true, stream);
  // ---- CA3: out = CA(s) -> d_out; tmp = buf1 ----
  run_ca(buf0, wqk_hi, wqk_lo, bqk, wvb, bv, gamma, nullptr, (float*)d_out,
         qbuf, kbuf, qT, kT, vbuf, vT, ebuf, attb, xT_hi, xT_lo, (bf16*)buf1,
         true, stream);
}

// Round 9
// 1605.150 us; speedup vs baseline: 2.5331x; 1.0077x over previous
//
#include <hip/hip_runtime.h>
#include <hip/hip_bf16.h>
#include <math.h>

typedef __hip_bfloat16 bf16;
typedef __attribute__((ext_vector_type(8))) short s16x8;
typedef __attribute__((ext_vector_type(4))) float f32x4;

constexpr int Bn  = 4;
constexpr int Cn  = 512;
constexpr int Hn  = 128;
constexpr int Wn  = 128;
constexpr int Nn  = Hn * Wn;   // 16384
constexpr int CQn = 64;
constexpr int CIn = 256;

__device__ __forceinline__ float bf2f(bf16 v){ return __bfloat162float(v); }
__device__ __forceinline__ bf16  f2bf(float v){ return __float2bfloat16(v); }

// async global->LDS, 16B per lane; LDS dest must be wave-uniform base (HW adds lane*16)
__device__ __forceinline__ void gload_lds16(const void* g, void* l){
  __builtin_amdgcn_global_load_lds(
      (const __attribute__((address_space(1))) unsigned int*)g,
      (__attribute__((address_space(3))) unsigned int*)l,
      16, 0, 0);
}

// ============================ stage 0 ============================

__global__ __launch_bounds__(256) void k_dotc(const float* __restrict__ x,
                                              const float* __restrict__ w,
                                              int wstride,
                                              float* __restrict__ out){
  int t = blockIdx.x * 256 + threadIdx.x;      // over B*Nn
  int b = t >> 14;
  const float* wp = w + (size_t)b * wstride;
  const float* xp = x + (size_t)b * Cn * Nn + (t & (Nn - 1));
  float acc = 0.f;
  #pragma unroll 8
  for (int c = 0; c < Cn; ++c) acc += wp[c] * xp[(size_t)c * Nn];
  out[t] = acc;
}

__global__ __launch_bounds__(256) void k_rowmean(const float* __restrict__ x,
                                                 float* __restrict__ out,
                                                 float scale){
  int bc = blockIdx.x;
  const float* xp = x + (size_t)bc * Nn;
  float acc = 0.f;
  for (int n = threadIdx.x; n < Nn; n += 256) acc += xp[n];
  for (int o = 32; o > 0; o >>= 1) acc += __shfl_down(acc, o);
  __shared__ float red[4];
  if ((threadIdx.x & 63) == 0) red[threadIdx.x >> 6] = acc;
  __syncthreads();
  if (threadIdx.x == 0) out[bc] = (red[0] + red[1] + red[2] + red[3]) * scale;
}

__global__ __launch_bounds__(256) void k_rowdot(const float* __restrict__ W,
                                                const float* __restrict__ vec,
                                                float* __restrict__ out){
  __shared__ float vs[Cn];
  int b = blockIdx.x, t = threadIdx.x;
  for (int j = t; j < Cn; j += 256) vs[j] = vec[b * Cn + j];
  __syncthreads();
  const float4* wp = (const float4*)(W + (size_t)t * Cn);
  float a = 0.f;
  #pragma unroll 4
  for (int j = 0; j < Cn / 4; ++j){
    float4 w4 = wp[j];
    a += w4.x * vs[4*j] + w4.y * vs[4*j+1] + w4.z * vs[4*j+2] + w4.w * vs[4*j+3];
  }
  out[b * CIn + t] = a;
}

__global__ __launch_bounds__(256) void k_coldot(const float* __restrict__ W,
                                                const float* __restrict__ vec,
                                                float* __restrict__ out){
  __shared__ float vs[CIn];
  int b = blockIdx.y, t = threadIdx.x;
  int c = blockIdx.x * 256 + t;
  if (t < CIn) vs[t] = vec[b * CIn + t];
  __syncthreads();
  float a = 0.f;
  #pragma unroll 8
  for (int j = 0; j < CIn; ++j) a += W[(size_t)j * Cn + c] * vs[j];
  out[b * Cn + c] = a;
}

__global__ __launch_bounds__(256) void k_mch2(const float* __restrict__ w_up,
                                              const float* __restrict__ b_up,
                                              const float* __restrict__ ctx,
                                              float* __restrict__ mch){
  __shared__ float cs[CIn];
  int b = blockIdx.y, t = threadIdx.x;
  int o = blockIdx.x * 256 + t;
  if (t < CIn) cs[t] = ctx[b * CIn + t];
  __syncthreads();
  const float4* wp = (const float4*)(w_up + (size_t)o * CIn);
  float a = b_up[o];
  #pragma unroll 4
  for (int j = 0; j < CIn / 4; ++j){
    float4 w4 = wp[j];
    a += w4.x * cs[4*j] + w4.y * cs[4*j+1] + w4.z * cs[4*j+2] + w4.w * cs[4*j+3];
  }
  mch[b * Cn + o] = 1.f / (1.f + expf(-a));
}

__global__ __launch_bounds__(1024) void k_stats(const float* __restrict__ vv,
                                                float* __restrict__ stats){
  int b = blockIdx.x;
  const float* pp = vv + (size_t)b * Nn;
  int t = threadIdx.x;
  float m = -3.4e38f;
  for (int n = t; n < Nn; n += 1024) m = fmaxf(m, pp[n]);
  for (int o = 32; o > 0; o >>= 1) m = fmaxf(m, __shfl_down(m, o));
  __shared__ float red[16];
  int wid = t >> 6, lid = t & 63;
  if (lid == 0) red[wid] = m;
  __syncthreads();
  if (t == 0){
    float q = red[0];
    for (int i = 1; i < 16; i++) q = fmaxf(q, red[i]);
    red[0] = q;
  }
  __syncthreads();
  m = red[0];
  __syncthreads();
  float s = 0.f;
  for (int n = t; n < Nn; n += 1024) s += expf(pp[n] - m);
  for (int o = 32; o > 0; o >>= 1) s += __shfl_down(s, o);
  if (lid == 0) red[wid] = s;
  __syncthreads();
  if (t == 0){
    float q = 0.f;
    for (int i = 0; i < 16; i++) q += red[i];
    stats[b * 2]     = m;
    stats[b * 2 + 1] = q;
  }
}

__global__ __launch_bounds__(256) void k_weighted(const float* __restrict__ x,
                                                  const float* __restrict__ logits,
                                                  const float* __restrict__ stats,
                                                  float* __restrict__ out){
  int bc = blockIdx.x;
  int b = bc >> 9;
  const float* xp = x + (size_t)bc * Nn;
  const float* lp = logits + (size_t)b * Nn;
  float m = stats[b * 2], den = stats[b * 2 + 1];
  float acc = 0.f;
  for (int n = threadIdx.x; n < Nn; n += 256) acc += xp[n] * expf(lp[n] - m);
  for (int o = 32; o > 0; o >>= 1) acc += __shfl_down(acc, o);
  __shared__ float red[4];
  if ((threadIdx.x & 63) == 0) red[threadIdx.x >> 6] = acc;
  __syncthreads();
  if (threadIdx.x == 0) out[bc] = (red[0] + red[1] + red[2] + red[3]) / den;
}

__global__ __launch_bounds__(256) void k_msp(const float* __restrict__ lg,
                                             const float* __restrict__ stats,
                                             float* __restrict__ msp){
  int t = blockIdx.x * 256 + threadIdx.x;
  int b = t >> 14;
  float v = expf(lg[t] - stats[b * 2]) / stats[b * 2 + 1];
  msp[t] = 1.f / (1.f + expf(-v));
}

// Fused: cc = x*mch, cs = x*msp, plus ccT hi/lo bf16 (transposed) for CA1's MFMA inputs.
__global__ __launch_bounds__(256) void k_applyT(const float* __restrict__ x,
                                                const float* __restrict__ mch,
                                                const float* __restrict__ msp,
                                                float* __restrict__ cc,
                                                float* __restrict__ cs,
                                                bf16* __restrict__ out_hi,
                                                bf16* __restrict__ out_lo){
  __shared__ bf16 th_[32][33];
  __shared__ bf16 tl_[32][33];
  int nt = blockIdx.x, ct = blockIdx.y, b = blockIdx.z;
  int n0 = nt * 32, c0 = ct * 32;
  int t = threadIdx.x;
  #pragma unroll
  for (int kk = 0; kk < 4; ++kk){
    int idx = t + kk * 256;
    int cl = idx >> 5, nl = idx & 31;
    size_t off = ((size_t)(b * Cn + c0 + cl)) * Nn + n0 + nl;
    float xv = x[off];
    float ccv = xv * mch[b * Cn + c0 + cl];
    float csv = xv * msp[b * Nn + n0 + nl];
    cc[off] = ccv;
    cs[off] = csv;
    bf16 h = f2bf(ccv);
    th_[cl][nl] = h;
    tl_[cl][nl] = f2bf(ccv - bf2f(h));
  }
  __syncthreads();
  #pragma unroll
  for (int kk = 0; kk < 4; ++kk){
    int idx = t + kk * 256;
    int nl = idx >> 5, cl = idx & 31;
    size_t o = ((size_t)(b * Nn + n0 + nl)) * Cn + c0 + cl;
    out_hi[o] = th_[cl][nl];
    out_lo[o] = tl_[cl][nl];
  }
}

// ============================ conversions ============================

__global__ __launch_bounds__(256) void k_cvt_w(const float* __restrict__ in,
                                               bf16* __restrict__ out, int n){
  int t = blockIdx.x * 256 + threadIdx.x;
  if (t < n) out[t] = f2bf(in[t]);
}

__global__ __launch_bounds__(256) void k_prep_wqk(const float* __restrict__ wq,
                                                  const float* __restrict__ wk,
                                                  const float* __restrict__ bq,
                                                  const float* __restrict__ bk,
                                                  bf16* __restrict__ wqk_hi,
                                                  bf16* __restrict__ wqk_lo,
                                                  float* __restrict__ bqk){
  int t = blockIdx.x * 256 + threadIdx.x;   // over 128*512
  int o = t >> 9, c = t & 511;
  float v = (o < 64) ? wq[(size_t)o * Cn + c] : wk[(size_t)(o - 64) * Cn + c];
  bf16 h = f2bf(v);
  wqk_hi[t] = h;
  wqk_lo[t] = f2bf(v - bf2f(h));
  if (t < 128) bqk[t] = (t < 64) ? bq[t] : bk[t - 64];
}

__global__ __launch_bounds__(256) void k_cvt_T(const float* __restrict__ in,
                                               bf16* __restrict__ out_hi,
                                               bf16* __restrict__ out_lo){
  __shared__ bf16 th_[32][33];
  __shared__ bf16 tl_[32][33];
  int nt = blockIdx.x, ct = blockIdx.y, b = blockIdx.z;
  int n0 = nt * 32, c0 = ct * 32;
  int t = threadIdx.x;
  #pragma unroll
  for (int kk = 0; kk < 4; ++kk){
    int idx = t + kk * 256;
    int cl = idx >> 5, nl = idx & 31;
    float v = in[((size_t)(b * Cn + c0 + cl)) * Nn + n0 + nl];
    bf16 h = f2bf(v);
    th_[cl][nl] = h;
    tl_[cl][nl] = f2bf(v - bf2f(h));
  }
  __syncthreads();
  #pragma unroll
  for (int kk = 0; kk < 4; ++kk){
    int idx = t + kk * 256;
    int nl = idx >> 5, cl = idx & 31;
    size_t o = ((size_t)(b * Nn + n0 + nl)) * Cn + c0 + cl;
    out_hi[o] = th_[cl][nl];
    out_lo[o] = tl_[cl][nl];
  }
}

// ============================ MFMA GEMMs ============================

// V = Wv @ X. 128x128 tile, BK=64. XCD-chunked 1D grid of 2048.
__global__ __launch_bounds__(256) void k_v_mfma(const bf16* __restrict__ xT,
                                                const bf16* __restrict__ wvb,
                                                const float* __restrict__ bv,
                                                bf16* __restrict__ v){
  __shared__ short As[128 * 64];
  __shared__ short Bs[128 * 64];
  __shared__ float bvs[128];
  int lin = blockIdx.x;
  int swz = (lin & 7) * 256 + (lin >> 3);
  int cb = (swz & 3) * 128;
  int nb = ((swz >> 2) & 127) * 128;
  int b  = swz >> 9;
  int t = threadIdx.x, lane = t & 63, wid = t >> 6;
  int wm = wid >> 1, wn = wid & 1;
  int l15 = lane & 15, l4 = lane >> 4;
  if (t < 128) bvs[t] = bv[cb + t];
  f32x4 acc[4][4];
  #pragma unroll
  for (int i = 0; i < 4; i++)
    #pragma unroll
    for (int j = 0; j < 4; j++) acc[i][j] = (f32x4){0.f, 0.f, 0.f, 0.f};

  const bf16* wp = wvb + (size_t)cb * Cn;
  const bf16* xp = xT + ((size_t)b * Nn + nb) * Cn;
  int r8 = lane >> 3;
  int kc = (lane & 7) * 8;
  for (int kt = 0; kt < 8; ++kt){
    int k0 = kt * 64;
    #pragma unroll
    for (int j = 0; j < 4; ++j){
      int inst = wid * 4 + j;
      int row = inst * 8 + r8;
      gload_lds16(wp + (size_t)row * Cn + k0 + kc, (char*)As + inst * 1024);
      gload_lds16(xp + (size_t)row * Cn + k0 + kc, (char*)Bs + inst * 1024);
    }
    __syncthreads();
    #pragma unroll
    for (int kk = 0; kk < 64; kk += 32){
      s16x8 a[4], bb[4];
      #pragma unroll
      for (int mi = 0; mi < 4; mi++)
        a[mi] = *(const s16x8*)&As[(wm * 64 + mi * 16 + l15) * 64 + kk + l4 * 8];
      #pragma unroll
      for (int ni = 0; ni < 4; ni++)
        bb[ni] = *(const s16x8*)&Bs[(wn * 64 + ni * 16 + l15) * 64 + kk + l4 * 8];
      #pragma unroll
      for (int mi = 0; mi < 4; mi++)
        #pragma unroll
        for (int ni = 0; ni < 4; ni++)
          acc[mi][ni] = __builtin_amdgcn_mfma_f32_16x16x32_bf16(a[mi], bb[ni], acc[mi][ni], 0, 0, 0);
    }
    __syncthreads();
  }
  #pragma unroll
  for (int mi = 0; mi < 4; mi++){
    #pragma unroll
    for (int r = 0; r < 4; r++){
      int cl = wm * 64 + mi * 16 + l4 * 4 + r;
      int c  = cb + cl;
      float bias = bvs[cl];
      #pragma unroll
      for (int ni = 0; ni < 4; ni++){
        int n = nb + wn * 64 + ni * 16 + l15;
        v[((size_t)(b * Cn + c)) * Nn + n] = f2bf(acc[mi][ni][r] + bias);
      }
    }
  }
}

// Q,K = [Wq;Wk] @ X with split-precision bf16 (3 MFMA terms).
__global__ __launch_bounds__(256) void k_qk_mfma(const bf16* __restrict__ xT_hi,
                                                 const bf16* __restrict__ xT_lo,
                                                 const bf16* __restrict__ wqk_hi,
                                                 const bf16* __restrict__ wqk_lo,
                                                 const float* __restrict__ bqk,
                                                 bf16* __restrict__ q,
                                                 bf16* __restrict__ k){
  __shared__ short Ah[128 * 64];
  __shared__ short Al[128 * 64];
  __shared__ short Bh[128 * 64];
  __shared__ short Bl[128 * 64];
  __shared__ float bs[128];
  int nb = blockIdx.x * 128, b = blockIdx.y;
  int t = threadIdx.x, lane = t & 63, wid = t >> 6;
  int wm = wid >> 1, wn = wid & 1;
  int l15 = lane & 15, l4 = lane >> 4;
  if (t < 128) bs[t] = bqk[t];
  f32x4 acc[4][4];
  #pragma unroll
  for (int i = 0; i < 4; i++)
    #pragma unroll
    for (int j = 0; j < 4; j++) acc[i][j] = (f32x4){0.f, 0.f, 0.f, 0.f};

  const bf16* xh = xT_hi + ((size_t)b * Nn + nb) * Cn;
  const bf16* xl = xT_lo + ((size_t)b * Nn + nb) * Cn;
  int r8 = lane >> 3;
  int kc = (lane & 7) * 8;
  for (int kt = 0; kt < 8; ++kt){
    int k0 = kt * 64;
    #pragma unroll
    for (int j = 0; j < 4; ++j){
      int inst = wid * 4 + j;
      int row = inst * 8 + r8;
      size_t off = (size_t)row * Cn + k0 + kc;
      gload_lds16(wqk_hi + off, (char*)Ah + inst * 1024);
      gload_lds16(wqk_lo + off, (char*)Al + inst * 1024);
      gload_lds16(xh + off,     (char*)Bh + inst * 1024);
      gload_lds16(xl + off,     (char*)Bl + inst * 1024);
    }
    __syncthreads();
    #pragma unroll
    for (int kk = 0; kk < 64; kk += 32){
      s16x8 ah[4], al[4], bh[4], bl[4];
      #pragma unroll
      for (int mi = 0; mi < 4; mi++){
        int idx = (wm * 64 + mi * 16 + l15) * 64 + kk + l4 * 8;
        ah[mi] = *(const s16x8*)&Ah[idx];
        al[mi] = *(const s16x8*)&Al[idx];
      }
      #pragma unroll
      for (int ni = 0; ni < 4; ni++){
        int idx = (wn * 64 + ni * 16 + l15) * 64 + kk + l4 * 8;
        bh[ni] = *(const s16x8*)&Bh[idx];
        bl[ni] = *(const s16x8*)&Bl[idx];
      }
      #pragma unroll
      for (int mi = 0; mi < 4; mi++)
        #pragma unroll
        for (int ni = 0; ni < 4; ni++){
          acc[mi][ni] = __builtin_amdgcn_mfma_f32_16x16x32_bf16(ah[mi], bh[ni], acc[mi][ni], 0, 0, 0);
          acc[mi][ni] = __builtin_amdgcn_mfma_f32_16x16x32_bf16(ah[mi], bl[ni], acc[mi][ni], 0, 0, 0);
          acc[mi][ni] = __builtin_amdgcn_mfma_f32_16x16x32_bf16(al[mi], bh[ni], acc[mi][ni], 0, 0, 0);
        }
    }
    __syncthreads();
  }
  #pragma unroll
  for (int mi = 0; mi < 4; mi++){
    #pragma unroll
    for (int r = 0; r < 4; r++){
      int o = wm * 64 + mi * 16 + l4 * 4 + r;
      float bias = bs[o];
      #pragma unroll
      for (int ni = 0; ni < 4; ni++){
        int n = nb + wn * 64 + ni * 16 + l15;
        float val = acc[mi][ni][r] + bias;
        if (o < 64) q[((size_t)(b * CQn + o)) * Nn + n]        = f2bf(val);
        else        k[((size_t)(b * CQn + o - 64)) * Nn + n]   = f2bf(val);
      }
    }
  }
}

// comb_h: per (b,w): ohT[b,w,c,h] = alpha_h(h) * sum_g att_h[b,w,h,g]*vT[b,w,c,g]
__global__ __launch_bounds__(256) void k_comb_h_mfma(const bf16* __restrict__ att_h,
                                                     const float* __restrict__ ah,
                                                     const bf16* __restrict__ vT,
                                                     bf16* __restrict__ ohT){
  __shared__ short As[128 * 128];
  __shared__ short Bs[128 * 128];
  __shared__ float alph[128];
  int lin = blockIdx.x;
  int swz = (lin & 7) * 256 + (lin >> 3);
  int cb = (swz & 3) * 128;
  int w  = (swz >> 2) & 127;
  int b  = swz >> 9;
  int t = threadIdx.x, lane = t & 63, wid = t >> 6;
  int wm = wid >> 1, wn = wid & 1;
  int l15 = lane & 15, l4 = lane >> 4;

  if (t < 128) alph[t] = ah[(size_t)(b * Wn + w) * Hn + t];
  // stage V tile (rows c, K-contig), swizzled; 16B chunks
  const bf16* vp = vT + ((size_t)(b * Wn + w) * Cn + cb) * Hn;
  for (int s = t; s < 2048; s += 256){
    int row = s >> 4, seg = s & 15;
    s16x8 d = *(const s16x8*)(vp + (size_t)row * Hn + seg * 8);
    int byte = (row * 256 + seg * 16) ^ ((row & 7) << 4);
    *(s16x8*)((char*)As + byte) = d;
  }
  // stage att_h tile (contiguous [h][g] block), swizzled
  const bf16* ap = att_h + (size_t)(b * Wn + w) * (Hn * 128);
  for (int s = t; s < 2048; s += 256){
    int row = s >> 4, seg = s & 15;
    s16x8 d = *(const s16x8*)(ap + (size_t)s * 8);
    int byte = (row * 256 + seg * 16) ^ ((row & 7) << 4);
    *(s16x8*)((char*)Bs + byte) = d;
  }
  __syncthreads();

  f32x4 acc[4][4];
  #pragma unroll
  for (int i = 0; i < 4; i++)
    #pragma unroll
    for (int j = 0; j < 4; j++) acc[i][j] = (f32x4){0.f, 0.f, 0.f, 0.f};
  #pragma unroll
  for (int kk = 0; kk < 128; kk += 32){
    s16x8 a[4], bb[4];
    #pragma unroll
    for (int mi = 0; mi < 4; mi++){
      int row = wm * 64 + mi * 16 + l15;
      int byte = (row * 256 + (kk + l4 * 8) * 2) ^ ((row & 7) << 4);
      a[mi] = *(const s16x8*)((char*)As + byte);
    }
    #pragma unroll
    for (int ni = 0; ni < 4; ni++){
      int row = wn * 64 + ni * 16 + l15;
      int byte = (row * 256 + (kk + l4 * 8) * 2) ^ ((row & 7) << 4);
      bb[ni] = *(const s16x8*)((char*)Bs + byte);
    }
    #pragma unroll
    for (int mi = 0; mi < 4; mi++)
      #pragma unroll
      for (int ni = 0; ni < 4; ni++)
        acc[mi][ni] = __builtin_amdgcn_mfma_f32_16x16x32_bf16(a[mi], bb[ni], acc[mi][ni], 0, 0, 0);
  }
  bf16* op = ohT + ((size_t)(b * Wn + w) * Cn + cb) * Hn;
  #pragma unroll
  for (int ni = 0; ni < 4; ni++){
    int h = wn * 64 + ni * 16 + l15;
    float a_ = alph[h];
    #pragma unroll
    for (int mi = 0; mi < 4; mi++)
      #pragma unroll
      for (int r = 0; r < 4; r++){
        int cl = wm * 64 + mi * 16 + l4 * 4 + r;
        op[(size_t)cl * Hn + h] = f2bf(acc[mi][ni][r] * a_);
      }
  }
}

// comb_w: per (b,h): ow[b,c,h,w_] = alpha_w(w_) * sum_v att_w[b,h,w_,v]*v[b,c,h,v]
__global__ __launch_bounds__(256) void k_comb_w_mfma(const bf16* __restrict__ att_w,
                                                     const float* __restrict__ aw,
                                                     const bf16* __restrict__ v,
                                                     bf16* __restrict__ ow){
  __shared__ short As[128 * 128];
  __shared__ short Bs[128 * 128];
  __shared__ float alph[128];
  int lin = blockIdx.x;
  int swz = (lin & 7) * 256 + (lin >> 3);
  int cb = (swz & 3) * 128;
  int h  = (swz >> 2) & 127;
  int b  = swz >> 9;
  int t = threadIdx.x, lane = t & 63, wid = t >> 6;
  int wm = wid >> 1, wn = wid & 1;
  int l15 = lane & 15, l4 = lane >> 4;

  if (t < 128) alph[t] = aw[(size_t)(b * Hn + h) * Wn + t];
  const bf16* vp = v + (size_t)(b * Cn + cb) * Nn + (size_t)h * Wn;
  for (int s = t; s < 2048; s += 256){
    int row = s >> 4, seg = s & 15;
    s16x8 d = *(const s16x8*)(vp + (size_t)row * Nn + seg * 8);
    int byte = (row * 256 + seg * 16) ^ ((row & 7) << 4);
    *(s16x8*)((char*)As + byte) = d;
  }
  const bf16* ap = att_w + (size_t)(b * Hn + h) * (Wn * 128);
  for (int s = t; s < 2048; s += 256){
    int row = s >> 4, seg = s & 15;
    s16x8 d = *(const s16x8*)(ap + (size_t)s * 8);
    int byte = (row * 256 + seg * 16) ^ ((row & 7) << 4);
    *(s16x8*)((char*)Bs + byte) = d;
  }
  __syncthreads();

  f32x4 acc[4][4];
  #pragma unroll
  for (int i = 0; i < 4; i++)
    #pragma unroll
    for (int j = 0; j < 4; j++) acc[i][j] = (f32x4){0.f, 0.f, 0.f, 0.f};
  #pragma unroll
  for (int kk = 0; kk < 128; kk += 32){
    s16x8 a[4], bb[4];
    #pragma unroll
    for (int mi = 0; mi < 4; mi++){
      int row = wm * 64 + mi * 16 + l15;
      int byte = (row * 256 + (kk + l4 * 8) * 2) ^ ((row & 7) << 4);
      a[mi] = *(const s16x8*)((char*)As + byte);
    }
    #pragma unroll
    for (int ni = 0; ni < 4; ni++){
      int row = wn * 64 + ni * 16 + l15;
      int byte = (row * 256 + (kk + l4 * 8) * 2) ^ ((row & 7) << 4);
      bb[ni] = *(const s16x8*)((char*)Bs + byte);
    }
    #pragma unroll
    for (int mi = 0; mi < 4; mi++)
      #pragma unroll
      for (int ni = 0; ni < 4; ni++)
        acc[mi][ni] = __builtin_amdgcn_mfma_f32_16x16x32_bf16(a[mi], bb[ni], acc[mi][ni], 0, 0, 0);
  }
  bf16* op = ow + (size_t)(b * Cn + cb) * Nn + (size_t)h * Wn;
  #pragma unroll
  for (int ni = 0; ni < 4; ni++){
    int wr = wn * 64 + ni * 16 + l15;
    float a_ = alph[wr];
    #pragma unroll
    for (int mi = 0; mi < 4; mi++)
      #pragma unroll
      for (int r = 0; r < 4; r++){
        int cl = wm * 64 + mi * 16 + l4 * 4 + r;
        op[(size_t)cl * Nn + wr] = f2bf(acc[mi][ni][r] * a_);
      }
  }
}

// ============================ remaining CA kernels ============================

__global__ __launch_bounds__(256) void k_trans(const bf16* __restrict__ in,
                                               bf16* __restrict__ out,
                                               int CH){
  __shared__ bf16 tile[32][33];
  int tl = blockIdx.x, c = blockIdx.y, b = blockIdx.z;
  int th = tl >> 2, tw = tl & 3;
  int h0 = th * 32, w0 = tw * 32;
  int t = threadIdx.x;
  const bf16* ip = in + ((size_t)(b * CH + c)) * Nn;
  #pragma unroll
  for (int kk = 0; kk < 4; ++kk){
    int idx = t + kk * 256;
    int hl = idx >> 5, wl = idx & 31;
    tile[hl][wl] = ip[(h0 + hl) * Wn + w0 + wl];
  }
  __syncthreads();
  #pragma unroll
  for (int kk = 0; kk < 4; ++kk){
    int idx = t + kk * 256;
    int wl = idx >> 5, hl = idx & 31;
    out[((size_t)(b * Wn + w0 + wl) * CH + c) * Hn + h0 + hl] = tile[hl][wl];
  }
}

// e_h + partial softmax: att_h[b,w,h,g] = bf16(exp(e_h - m_h(h))), stats mh/sh[b,w,h]
__global__ __launch_bounds__(256) void k_eh_sm(const bf16* __restrict__ qT,
                                               const bf16* __restrict__ kT,
                                               bf16* __restrict__ att_h,
                                               float* __restrict__ mh,
                                               float* __restrict__ sh){
  __shared__ float smem[16384];
  float* qs = smem;
  float* ks = smem + 8192;
  int w = blockIdx.x, b = blockIdx.y;
  int t = threadIdx.x;
  const bf16* qp = qT + (size_t)(b * Wn + w) * CQn * Hn;
  const bf16* kp = kT + (size_t)(b * Wn + w) * CQn * Hn;
  for (int i = t; i < 8192; i += 256){ qs[i] = bf2f(qp[i]); ks[i] = bf2f(kp[i]); }
  __syncthreads();
  int hg = t >> 3, gg = t & 7;
  float acc[4][16];
  #pragma unroll
  for (int i = 0; i < 4; i++)
    #pragma unroll
    for (int j = 0; j < 16; j++) acc[i][j] = 0.f;
  for (int c = 0; c < CQn; ++c){
    float qv[4], kv[16];
    #pragma unroll
    for (int i = 0; i < 4; i++) qv[i] = qs[c * 128 + hg * 4 + i];
    #pragma unroll
    for (int j = 0; j < 16; j++) kv[j] = ks[c * 128 + gg + 8 * j];
    #pragma unroll
    for (int i = 0; i < 4; i++)
      #pragma unroll
      for (int j = 0; j < 16; j++) acc[i][j] += qv[i] * kv[j];
  }
  // diag mask, row stats, exp
  float mrow[4], srow[4];
  #pragma unroll
  for (int i = 0; i < 4; i++){
    int hrow = hg * 4 + i;
    #pragma unroll
    for (int j = 0; j < 16; j++)
      if (hrow == gg + 8 * j) acc[i][j] = -1e30f;
    float m = acc[i][0];
    #pragma unroll
    for (int j = 1; j < 16; j++) m = fmaxf(m, acc[i][j]);
    m = fmaxf(m, __shfl_xor(m, 1));
    m = fmaxf(m, __shfl_xor(m, 2));
    m = fmaxf(m, __shfl_xor(m, 4));
    mrow[i] = m;
    float s = 0.f;
    #pragma unroll
    for (int j = 0; j < 16; j++){ acc[i][j] = expf(acc[i][j] - m); s += acc[i][j]; }
    s += __shfl_xor(s, 1);
    s += __shfl_xor(s, 2);
    s += __shfl_xor(s, 4);
    srow[i] = s;
  }
  __syncthreads();
  unsigned short* sm16 = (unsigned short*)smem;
  #pragma unroll
  for (int i = 0; i < 4; i++)
    #pragma unroll
    for (int j = 0; j < 16; j++){
      bf16 bv = f2bf(acc[i][j]);
      sm16[(hg * 4 + i) * 128 + gg + 8 * j] = *(unsigned short*)&bv;
    }
  if (gg == 0){
    #pragma unroll
    for (int i = 0; i < 4; i++){
      mh[(size_t)(b * Wn + w) * Hn + hg * 4 + i] = mrow[i];
      sh[(size_t)(b * Wn + w) * Hn + hg * 4 + i] = srow[i];
    }
  }
  __syncthreads();
  s16x8* op = (s16x8*)(att_h + (size_t)(b * Wn + w) * (Hn * 128));
  const s16x8* sp = (const s16x8*)sm16;
  for (int s_ = t; s_ < 2048; s_ += 256) op[s_] = sp[s_];
}

// e_w + partial softmax: att_w[b,h,w,v] = bf16(exp(e_w - m_w(w))), stats mw/sw[b,h,w]
__global__ __launch_bounds__(256) void k_ew_sm(const bf16* __restrict__ q,
                                               const bf16* __restrict__ k,
                                               bf16* __restrict__ att_w,
                                               float* __restrict__ mw,
                                               float* __restrict__ sw){
  __shared__ float smem[16384];
  float* qs = smem;
  float* ks = smem + 8192;
  int h = blockIdx.x, b = blockIdx.y;
  int t = threadIdx.x;
  for (int i = t; i < 8192; i += 256){
    int c = i >> 7, wl = i & 127;
    size_t base = ((size_t)(b * CQn + c) * Hn + h) * Wn + wl;
    qs[i] = bf2f(q[base]);
    ks[i] = bf2f(k[base]);
  }
  __syncthreads();
  int wg = t >> 3, vg = t & 7;
  float acc[4][16];
  #pragma unroll
  for (int i = 0; i < 4; i++)
    #pragma unroll
    for (int j = 0; j < 16; j++) acc[i][j] = 0.f;
  for (int c = 0; c < CQn; ++c){
    float qv[4], kv[16];
    #pragma unroll
    for (int i = 0; i < 4; i++) qv[i] = qs[c * 128 + wg * 4 + i];
    #pragma unroll
    for (int j = 0; j < 16; j++) kv[j] = ks[c * 128 + vg + 8 * j];
    #pragma unroll
    for (int i = 0; i < 4; i++)
      #pragma unroll
      for (int j = 0; j < 16; j++) acc[i][j] += qv[i] * kv[j];
  }
  float mrow[4], srow[4];
  #pragma unroll
  for (int i = 0; i < 4; i++){
    float m = acc[i][0];
    #pragma unroll
    for (int j = 1; j < 16; j++) m = fmaxf(m, acc[i][j]);
    m = fmaxf(m, __shfl_xor(m, 1));
    m = fmaxf(m, __shfl_xor(m, 2));
    m = fmaxf(m, __shfl_xor(m, 4));
    mrow[i] = m;
    float s = 0.f;
    #pragma unroll
    for (int j = 0; j < 16; j++){ acc[i][j] = expf(acc[i][j] - m); s += acc[i][j]; }
    s += __shfl_xor(s, 1);
    s += __shfl_xor(s, 2);
    s += __shfl_xor(s, 4);
    srow[i] = s;
  }
  __syncthreads();
  unsigned short* sm16 = (unsigned short*)smem;
  #pragma unroll
  for (int i = 0; i < 4; i++)
    #pragma unroll
    for (int j = 0; j < 16; j++){
      bf16 bv = f2bf(acc[i][j]);
      sm16[(wg * 4 + i) * 128 + vg + 8 * j] = *(unsigned short*)&bv;
    }
  if (vg == 0){
    #pragma unroll
    for (int i = 0; i < 4; i++){
      mw[(size_t)(b * Hn + h) * Wn + wg * 4 + i] = mrow[i];
      sw[(size_t)(b * Hn + h) * Wn + wg * 4 + i] = srow[i];
    }
  }
  __syncthreads();
  s16x8* op = (s16x8*)(att_w + (size_t)(b * Hn + h) * (Wn * 128));
  const s16x8* sp = (const s16x8*)sm16;
  for (int s_ = t; s_ < 2048; s_ += 256) op[s_] = sp[s_];
}

// merge stats: alpha_h[b,w,h], alpha_w[b,h,w]
__global__ __launch_bounds__(256) void k_alpha(const float* __restrict__ mh,
                                               const float* __restrict__ sh,
                                               const float* __restrict__ mw,
                                               const float* __restrict__ sw,
                                               float* __restrict__ ah,
                                               float* __restrict__ aw){
  int t = blockIdx.x * 256 + threadIdx.x;   // (b*Hn+h)*Wn + w
  int b = t >> 14;
  int hw = t & (Nn - 1);
  int h = hw >> 7, w = hw & 127;
  size_t ih = (size_t)(b * Wn + w) * Hn + h;
  size_t iw = t;
  float mhv = mh[ih], mwv = mw[iw];
  float M = fmaxf(mhv, mwv);
  float eh_ = expf(mhv - M), ew_ = expf(mwv - M);
  float inv = 1.f / (sh[ih] * eh_ + sw[iw] * ew_);
  ah[ih] = eh_ * inv;
  aw[iw] = ew_ * inv;
}

// out = gamma*(ohT^T + ow) + in (+ addend); single-phase tile, XCD-chunked grid.
__global__ __launch_bounds__(256) void k_fuse2(const float* __restrict__ in,
                                               const bf16* __restrict__ ohT,
                                               const bf16* __restrict__ ow,
                                               const float* __restrict__ addend,
                                               const float* __restrict__ gamma,
                                               float* __restrict__ out){
  __shared__ unsigned short tileT[128][138];
  int lin = blockIdx.x;
  int swz = (lin & 7) * 256 + (lin >> 3);   // each XCD: contiguous 256 c's of one b
  int c = swz & 511;
  int b = swz >> 9;
  int t = threadIdx.x;
  float g = gamma[0];
  const bf16* ohp = ohT + ((size_t)(b * Wn) * Cn + c) * Hn;
  #pragma unroll
  for (int i = 0; i < 8; ++i){
    int s = t + i * 256;            // 0..2047
    int w = s >> 4, seg = s & 15;
    s16x8 d = *(const s16x8*)(ohp + (size_t)w * (Cn * Hn) + seg * 8);
    #pragma unroll
    for (int j = 0; j < 8; ++j)
      tileT[seg * 8 + j][w] = (unsigned short)d[j];
  }
  __syncthreads();
  size_t base = ((size_t)(b * Cn + c)) * Nn;
  #pragma unroll
  for (int i = 0; i < 16; ++i){
    int o = t + i * 256;            // 0..4095
    int h = o >> 5, w4 = (o & 31) * 4;
    size_t idx = base + (size_t)h * Wn + w4;
    float4 inv = *(const float4*)(in + idx);
    ushort4 owv = *(const ushort4*)((const unsigned short*)ow + idx);
    float r[4];
    #pragma unroll
    for (int j = 0; j < 4; ++j){
      unsigned short uh = tileT[h][w4 + j];
      unsigned short uo = ((const unsigned short*)&owv)[j];
      float ohv = bf2f(*(bf16*)&uh);
      float owf = bf2f(*(bf16*)&uo);
      float iv  = ((const float*)&inv)[j];
      r[j] = g * (ohv + owf) + iv;
    }
    if (addend){
      float4 av = *(const float4*)(addend + idx);
      r[0] += av.x; r[1] += av.y; r[2] += av.z; r[3] += av.w;
    }
    float4 o4 = { r[0], r[1], r[2], r[3] };
    *(float4*)(out + idx) = o4;
  }
}

// ============================ host ============================

static void run_ca(const float* in, const bf16* wqk_hi, const bf16* wqk_lo,
                   const float* bqk, const bf16* wvb, const float* bv,
                   const float* gamma, const float* addend, float* out,
                   bf16* q, bf16* k, bf16* qT, bf16* kT, bf16* v, bf16* vT,
                   bf16* att_h, bf16* att_w,
                   float* mh, float* sh, float* mw, float* sw, float* ah, float* aw,
                   bf16* xT_hi, bf16* xT_lo, bf16* tmp,
                   bool do_cvt, hipStream_t stream){
  bf16* ohT = tmp;
  bf16* ow  = tmp + (size_t)Bn * Cn * Nn;
  if (do_cvt)
    k_cvt_T<<<dim3(Nn / 32, Cn / 32, Bn), 256, 0, stream>>>(in, xT_hi, xT_lo);
  k_qk_mfma<<<dim3(Nn / 128, Bn), 256, 0, stream>>>(xT_hi, xT_lo, wqk_hi, wqk_lo, bqk, q, k);
  k_trans<<<dim3(16, CQn, Bn), 256, 0, stream>>>(q, qT, CQn);
  k_trans<<<dim3(16, CQn, Bn), 256, 0, stream>>>(k, kT, CQn);
  k_v_mfma<<<2048, 256, 0, stream>>>(xT_hi, wvb, bv, v);
  k_trans<<<dim3(16, Cn, Bn), 256, 0, stream>>>(v, vT, Cn);
  // att buffers alias xT_hi region; all xT readers are done by here
  k_eh_sm<<<dim3(Wn, Bn), 256, 0, stream>>>(qT, kT, att_h, mh, sh);
  k_ew_sm<<<dim3(Hn, Bn), 256, 0, stream>>>(q, k, att_w, mw, sw);
  k_alpha<<<Bn * Nn / 256, 256, 0, stream>>>(mh, sh, mw, sw, ah, aw);
  k_comb_h_mfma<<<2048, 256, 0, stream>>>(att_h, ah, vT, ohT);
  k_comb_w_mfma<<<2048, 256, 0, stream>>>(att_w, aw, v, ow);
  k_fuse2<<<2048, 256, 0, stream>>>(in, ohT, ow, addend, gamma, out);
}

extern "C" void kernel_launch(void* const* d_in, const int* in_sizes, int n_in,
                              void* d_out, int out_size, void* d_ws, size_t ws_size,
                              hipStream_t stream){
  (void)in_sizes; (void)n_in; (void)out_size; (void)ws_size;
  const float* x         = (const float*)d_in[0];
  const float* w_q_right = (const float*)d_in[1];
  const float* w_v_right = (const float*)d_in[2];
  const float* w_up      = (const float*)d_in[3];
  const float* b_up      = (const float*)d_in[4];
  const float* w_q_left  = (const float*)d_in[5];
  const float* w_v_left  = (const float*)d_in[6];
  const float* wq        = (const float*)d_in[7];
  const float* bq        = (const float*)d_in[8];
  const float* wk        = (const float*)d_in[9];
  const float* bk        = (const float*)d_in[10];
  const float* wv        = (const float*)d_in[11];
  const float* bv        = (const float*)d_in[12];
  const float* gamma     = (const float*)d_in[13];

  const size_t SZ_MAP = (size_t)Bn * Cn * Nn;     // 33.5M elements
  char* p = (char*)d_ws;
  float* buf0   = (float*)p; p += SZ_MAP * 4;
  float* buf1   = (float*)p; p += SZ_MAP * 4;
  bf16*  vbuf   = (bf16*)p;  p += SZ_MAP * 2;
  bf16*  vT     = (bf16*)p;  p += SZ_MAP * 2;
  bf16*  qbuf   = (bf16*)p;  p += (size_t)Bn * CQn * Nn * 2;
  bf16*  kbuf   = (bf16*)p;  p += (size_t)Bn * CQn * Nn * 2;
  bf16*  qT     = (bf16*)p;  p += (size_t)Bn * CQn * Nn * 2;
  bf16*  kT     = (bf16*)p;  p += (size_t)Bn * CQn * Nn * 2;
  float* ebuf   = (float*)p; p += (size_t)Bn * Nn * 256 * 4;  // xT_hi / att / stats arena
  float* logits = (float*)p; p += (size_t)Bn * Nn * 4;
  float* ctxlog = (float*)p; p += (size_t)Bn * Nn * 4;
  float* msp    = (float*)p; p += (size_t)Bn * Nn * 4;
  float* xbar   = (float*)p; p += Bn * Cn * 4;
  float* wgt    = (float*)p; p += Bn * Cn * 4;
  float* u      = (float*)p; p += Bn * Cn * 4;
  float* mch    = (float*)p; p += Bn * Cn * 4;
  float* avg    = (float*)p; p += Bn * CIn * 4;
  float* ctx    = (float*)p; p += Bn * CIn * 4;
  float* stats_sp = (float*)p; p += 64;
  float* stats_ch = (float*)p; p += 64;
  bf16*  wvb    = (bf16*)p;  p += (size_t)Cn * Cn * 2;
  bf16*  wqk_hi = (bf16*)p;  p += (size_t)128 * Cn * 2;
  bf16*  wqk_lo = (bf16*)p;  p += (size_t)128 * Cn * 2;
  float* bqk    = (float*)p; p += 128 * 4;

  bf16*  xT_hi  = (bf16*)ebuf;    // dead before att written
  bf16*  xT_lo  = (bf16*)d_out;   // dead before ohT/fuse writes d_out
  // att + stats arena inside ebuf (xT_hi dead after v_mfma)
  bf16*  att_h  = (bf16*)ebuf;
  bf16*  att_w  = att_h + (size_t)Bn * Nn * 128;
  float* mh     = (float*)(att_w + (size_t)Bn * Nn * 128);
  float* sh     = mh + Bn * Nn;
  float* mw     = sh + Bn * Nn;
  float* sw     = mw + Bn * Nn;
  float* ah     = sw + Bn * Nn;
  float* aw     = ah + Bn * Nn;

  // ---- weight prep (once) ----
  k_cvt_w<<<(Cn * Cn + 255) / 256, 256, 0, stream>>>(wv, wvb, Cn * Cn);
  k_prep_wqk<<<(128 * Cn) / 256, 256, 0, stream>>>(wq, wk, bq, bk, wqk_hi, wqk_lo, bqk);

  // ---- stage 0: gating masks ----
  k_dotc<<<Bn * Nn / 256, 256, 0, stream>>>(x, w_q_right, 0, logits);
  k_rowmean<<<Bn * Cn, 256, 0, stream>>>(x, xbar, 1.f / Nn);
  k_rowdot<<<Bn, 256, 0, stream>>>(w_q_left, xbar, avg);
  k_coldot<<<dim3(Cn / 256, Bn), 256, 0, stream>>>(w_v_left, avg, u);
  k_stats<<<Bn, 1024, 0, stream>>>(logits, stats_sp);
  k_weighted<<<Bn * Cn, 256, 0, stream>>>(x, logits, stats_sp, wgt);
  k_rowdot<<<Bn, 256, 0, stream>>>(w_v_right, wgt, ctx);
  k_mch2<<<dim3(Cn / 256, Bn), 256, 0, stream>>>(w_up, b_up, ctx, mch);
  k_dotc<<<Bn * Nn / 256, 256, 0, stream>>>(x, u, Cn, ctxlog);
  k_stats<<<Bn, 1024, 0, stream>>>(ctxlog, stats_ch);
  k_msp<<<Bn * Nn / 256, 256, 0, stream>>>(ctxlog, stats_ch, msp);
  k_applyT<<<dim3(Nn / 32, Cn / 32, Bn), 256, 0, stream>>>(x, mch, msp, buf0, buf1,
                                                           xT_hi, xT_lo);

  // ---- CA1: cc' = CA(cc), in-place buf0; tmp = d_out (xT already built) ----
  run_ca(buf0, wqk_hi, wqk_lo, bqk, wvb, bv, gamma, nullptr, buf0,
         qbuf, kbuf, qT, kT, vbuf, vT, att_h, att_w, mh, sh, mw, sw, ah, aw,
         xT_hi, xT_lo, (bf16*)d_out, false, stream);
  // ---- CA2: s = CA(cs) + cc' -> buf0 ----
  run_ca(buf1, wqk_hi, wqk_lo, bqk, wvb, bv, gamma, buf0, buf0,
         qbuf, kbuf, qT, kT, vbuf, vT, att_h, att_w, mh, sh, mw, sw, ah, aw,
         xT_hi, xT_lo, (bf16*)d_out, true, stream);
  // ---- CA3: out = CA(s) -> d_out; tmp = buf1 ----
  run_ca(buf0, wqk_hi, wqk_lo, bqk, wvb, bv, gamma, nullptr, (float*)d_out,
         qbuf, kbuf, qT, kT, vbuf, vT, att_h, att_w, mh, sh, mw, sw, ah, aw,
         xT_hi, xT_lo, (bf16*)buf1, true, stream);
}

// Round 10
// 1515.545 us; speedup vs baseline: 2.6829x; 1.0591x over previous
//
#include <hip/hip_runtime.h>
#include <hip/hip_bf16.h>
#include <math.h>

typedef __hip_bfloat16 bf16;
typedef __attribute__((ext_vector_type(8))) short s16x8;
typedef __attribute__((ext_vector_type(4))) float f32x4;

constexpr int Bn  = 4;
constexpr int Cn  = 512;
constexpr int Hn  = 128;
constexpr int Wn  = 128;
constexpr int Nn  = Hn * Wn;   // 16384
constexpr int CQn = 64;
constexpr int CIn = 256;

__device__ __forceinline__ float bf2f(bf16 v){ return __bfloat162float(v); }
__device__ __forceinline__ bf16  f2bf(float v){ return __float2bfloat16(v); }

// async global->LDS, 16B per lane; LDS dest must be wave-uniform base (HW adds lane*16)
__device__ __forceinline__ void gload_lds16(const void* g, void* l){
  __builtin_amdgcn_global_load_lds(
      (const __attribute__((address_space(1))) unsigned int*)g,
      (__attribute__((address_space(3))) unsigned int*)l,
      16, 0, 0);
}

// ============================ stage 0 ============================

__global__ __launch_bounds__(256) void k_dotc(const float* __restrict__ x,
                                              const float* __restrict__ w,
                                              int wstride,
                                              float* __restrict__ out){
  int t = blockIdx.x * 256 + threadIdx.x;      // over B*Nn
  int b = t >> 14;
  const float* wp = w + (size_t)b * wstride;
  const float* xp = x + (size_t)b * Cn * Nn + (t & (Nn - 1));
  float acc = 0.f;
  #pragma unroll 8
  for (int c = 0; c < Cn; ++c) acc += wp[c] * xp[(size_t)c * Nn];
  out[t] = acc;
}

__global__ __launch_bounds__(256) void k_rowmean(const float* __restrict__ x,
                                                 float* __restrict__ out,
                                                 float scale){
  int bc = blockIdx.x;
  const float* xp = x + (size_t)bc * Nn;
  float acc = 0.f;
  for (int n = threadIdx.x; n < Nn; n += 256) acc += xp[n];
  for (int o = 32; o > 0; o >>= 1) acc += __shfl_down(acc, o);
  __shared__ float red[4];
  if ((threadIdx.x & 63) == 0) red[threadIdx.x >> 6] = acc;
  __syncthreads();
  if (threadIdx.x == 0) out[bc] = (red[0] + red[1] + red[2] + red[3]) * scale;
}

__global__ __launch_bounds__(256) void k_rowdot(const float* __restrict__ W,
                                                const float* __restrict__ vec,
                                                float* __restrict__ out){
  __shared__ float vs[Cn];
  int b = blockIdx.x, t = threadIdx.x;
  for (int j = t; j < Cn; j += 256) vs[j] = vec[b * Cn + j];
  __syncthreads();
  const float4* wp = (const float4*)(W + (size_t)t * Cn);
  float a = 0.f;
  #pragma unroll 4
  for (int j = 0; j < Cn / 4; ++j){
    float4 w4 = wp[j];
    a += w4.x * vs[4*j] + w4.y * vs[4*j+1] + w4.z * vs[4*j+2] + w4.w * vs[4*j+3];
  }
  out[b * CIn + t] = a;
}

__global__ __launch_bounds__(256) void k_coldot(const float* __restrict__ W,
                                                const float* __restrict__ vec,
                                                float* __restrict__ out){
  __shared__ float vs[CIn];
  int b = blockIdx.y, t = threadIdx.x;
  int c = blockIdx.x * 256 + t;
  if (t < CIn) vs[t] = vec[b * CIn + t];
  __syncthreads();
  float a = 0.f;
  #pragma unroll 8
  for (int j = 0; j < CIn; ++j) a += W[(size_t)j * Cn + c] * vs[j];
  out[b * Cn + c] = a;
}

__global__ __launch_bounds__(256) void k_mch2(const float* __restrict__ w_up,
                                              const float* __restrict__ b_up,
                                              const float* __restrict__ ctx,
                                              float* __restrict__ mch){
  __shared__ float cs[CIn];
  int b = blockIdx.y, t = threadIdx.x;
  int o = blockIdx.x * 256 + t;
  if (t < CIn) cs[t] = ctx[b * CIn + t];
  __syncthreads();
  const float4* wp = (const float4*)(w_up + (size_t)o * CIn);
  float a = b_up[o];
  #pragma unroll 4
  for (int j = 0; j < CIn / 4; ++j){
    float4 w4 = wp[j];
    a += w4.x * cs[4*j] + w4.y * cs[4*j+1] + w4.z * cs[4*j+2] + w4.w * cs[4*j+3];
  }
  mch[b * Cn + o] = 1.f / (1.f + expf(-a));
}

__global__ __launch_bounds__(1024) void k_stats(const float* __restrict__ vv,
                                                float* __restrict__ stats){
  int b = blockIdx.x;
  const float* pp = vv + (size_t)b * Nn;
  int t = threadIdx.x;
  float m = -3.4e38f;
  for (int n = t; n < Nn; n += 1024) m = fmaxf(m, pp[n]);
  for (int o = 32; o > 0; o >>= 1) m = fmaxf(m, __shfl_down(m, o));
  __shared__ float red[16];
  int wid = t >> 6, lid = t & 63;
  if (lid == 0) red[wid] = m;
  __syncthreads();
  if (t == 0){
    float q = red[0];
    for (int i = 1; i < 16; i++) q = fmaxf(q, red[i]);
    red[0] = q;
  }
  __syncthreads();
  m = red[0];
  __syncthreads();
  float s = 0.f;
  for (int n = t; n < Nn; n += 1024) s += expf(pp[n] - m);
  for (int o = 32; o > 0; o >>= 1) s += __shfl_down(s, o);
  if (lid == 0) red[wid] = s;
  __syncthreads();
  if (t == 0){
    float q = 0.f;
    for (int i = 0; i < 16; i++) q += red[i];
    stats[b * 2]     = m;
    stats[b * 2 + 1] = q;
  }
}

__global__ __launch_bounds__(256) void k_weighted(const float* __restrict__ x,
                                                  const float* __restrict__ logits,
                                                  const float* __restrict__ stats,
                                                  float* __restrict__ out){
  int bc = blockIdx.x;
  int b = bc >> 9;
  const float* xp = x + (size_t)bc * Nn;
  const float* lp = logits + (size_t)b * Nn;
  float m = stats[b * 2], den = stats[b * 2 + 1];
  float acc = 0.f;
  for (int n = threadIdx.x; n < Nn; n += 256) acc += xp[n] * expf(lp[n] - m);
  for (int o = 32; o > 0; o >>= 1) acc += __shfl_down(acc, o);
  __shared__ float red[4];
  if ((threadIdx.x & 63) == 0) red[threadIdx.x >> 6] = acc;
  __syncthreads();
  if (threadIdx.x == 0) out[bc] = (red[0] + red[1] + red[2] + red[3]) / den;
}

__global__ __launch_bounds__(256) void k_msp(const float* __restrict__ lg,
                                             const float* __restrict__ stats,
                                             float* __restrict__ msp){
  int t = blockIdx.x * 256 + threadIdx.x;
  int b = t >> 14;
  float v = expf(lg[t] - stats[b * 2]) / stats[b * 2 + 1];
  msp[t] = 1.f / (1.f + expf(-v));
}

// Fused: cc = x*mch, cs = x*msp, plus ccT hi/lo bf16 (transposed) for CA1's MFMA inputs.
__global__ __launch_bounds__(256) void k_applyT(const float* __restrict__ x,
                                                const float* __restrict__ mch,
                                                const float* __restrict__ msp,
                                                float* __restrict__ cc,
                                                float* __restrict__ cs,
                                                bf16* __restrict__ out_hi,
                                                bf16* __restrict__ out_lo){
  __shared__ bf16 th_[32][33];
  __shared__ bf16 tl_[32][33];
  int nt = blockIdx.x, ct = blockIdx.y, b = blockIdx.z;
  int n0 = nt * 32, c0 = ct * 32;
  int t = threadIdx.x;
  #pragma unroll
  for (int kk = 0; kk < 4; ++kk){
    int idx = t + kk * 256;
    int cl = idx >> 5, nl = idx & 31;
    size_t off = ((size_t)(b * Cn + c0 + cl)) * Nn + n0 + nl;
    float xv = x[off];
    float ccv = xv * mch[b * Cn + c0 + cl];
    float csv = xv * msp[b * Nn + n0 + nl];
    cc[off] = ccv;
    cs[off] = csv;
    bf16 h = f2bf(ccv);
    th_[cl][nl] = h;
    tl_[cl][nl] = f2bf(ccv - bf2f(h));
  }
  __syncthreads();
  #pragma unroll
  for (int kk = 0; kk < 4; ++kk){
    int idx = t + kk * 256;
    int nl = idx >> 5, cl = idx & 31;
    size_t o = ((size_t)(b * Nn + n0 + nl)) * Cn + c0 + cl;
    out_hi[o] = th_[cl][nl];
    out_lo[o] = tl_[cl][nl];
  }
}

// ============================ conversions ============================

__global__ __launch_bounds__(256) void k_cvt_w(const float* __restrict__ in,
                                               bf16* __restrict__ out, int n){
  int t = blockIdx.x * 256 + threadIdx.x;
  if (t < n) out[t] = f2bf(in[t]);
}

__global__ __launch_bounds__(256) void k_prep_wqk(const float* __restrict__ wq,
                                                  const float* __restrict__ wk,
                                                  const float* __restrict__ bq,
                                                  const float* __restrict__ bk,
                                                  bf16* __restrict__ wqk_hi,
                                                  bf16* __restrict__ wqk_lo,
                                                  float* __restrict__ bqk){
  int t = blockIdx.x * 256 + threadIdx.x;   // over 128*512
  int o = t >> 9, c = t & 511;
  float v = (o < 64) ? wq[(size_t)o * Cn + c] : wk[(size_t)(o - 64) * Cn + c];
  bf16 h = f2bf(v);
  wqk_hi[t] = h;
  wqk_lo[t] = f2bf(v - bf2f(h));
  if (t < 128) bqk[t] = (t < 64) ? bq[t] : bk[t - 64];
}

__global__ __launch_bounds__(256) void k_cvt_T(const float* __restrict__ in,
                                               bf16* __restrict__ out_hi,
                                               bf16* __restrict__ out_lo){
  __shared__ bf16 th_[32][33];
  __shared__ bf16 tl_[32][33];
  int nt = blockIdx.x, ct = blockIdx.y, b = blockIdx.z;
  int n0 = nt * 32, c0 = ct * 32;
  int t = threadIdx.x;
  #pragma unroll
  for (int kk = 0; kk < 4; ++kk){
    int idx = t + kk * 256;
    int cl = idx >> 5, nl = idx & 31;
    float v = in[((size_t)(b * Cn + c0 + cl)) * Nn + n0 + nl];
    bf16 h = f2bf(v);
    th_[cl][nl] = h;
    tl_[cl][nl] = f2bf(v - bf2f(h));
  }
  __syncthreads();
  #pragma unroll
  for (int kk = 0; kk < 4; ++kk){
    int idx = t + kk * 256;
    int nl = idx >> 5, cl = idx & 31;
    size_t o = ((size_t)(b * Nn + n0 + nl)) * Cn + c0 + cl;
    out_hi[o] = th_[cl][nl];
    out_lo[o] = tl_[cl][nl];
  }
}

// ============================ MFMA GEMMs ============================

// V = Wv @ X. 128x128 tile, BK=64. XCD-chunked 1D grid of 2048.
__global__ __launch_bounds__(256) void k_v_mfma(const bf16* __restrict__ xT,
                                                const bf16* __restrict__ wvb,
                                                const float* __restrict__ bv,
                                                bf16* __restrict__ v){
  __shared__ short As[128 * 64];
  __shared__ short Bs[128 * 64];
  __shared__ float bvs[128];
  int lin = blockIdx.x;
  int swz = (lin & 7) * 256 + (lin >> 3);
  int cb = (swz & 3) * 128;
  int nb = ((swz >> 2) & 127) * 128;
  int b  = swz >> 9;
  int t = threadIdx.x, lane = t & 63, wid = t >> 6;
  int wm = wid >> 1, wn = wid & 1;
  int l15 = lane & 15, l4 = lane >> 4;
  if (t < 128) bvs[t] = bv[cb + t];
  f32x4 acc[4][4];
  #pragma unroll
  for (int i = 0; i < 4; i++)
    #pragma unroll
    for (int j = 0; j < 4; j++) acc[i][j] = (f32x4){0.f, 0.f, 0.f, 0.f};

  const bf16* wp = wvb + (size_t)cb * Cn;
  const bf16* xp = xT + ((size_t)b * Nn + nb) * Cn;
  int r8 = lane >> 3;
  int kc = (lane & 7) * 8;
  for (int kt = 0; kt < 8; ++kt){
    int k0 = kt * 64;
    #pragma unroll
    for (int j = 0; j < 4; ++j){
      int inst = wid * 4 + j;
      int row = inst * 8 + r8;
      gload_lds16(wp + (size_t)row * Cn + k0 + kc, (char*)As + inst * 1024);
      gload_lds16(xp + (size_t)row * Cn + k0 + kc, (char*)Bs + inst * 1024);
    }
    __syncthreads();
    #pragma unroll
    for (int kk = 0; kk < 64; kk += 32){
      s16x8 a[4], bb[4];
      #pragma unroll
      for (int mi = 0; mi < 4; mi++)
        a[mi] = *(const s16x8*)&As[(wm * 64 + mi * 16 + l15) * 64 + kk + l4 * 8];
      #pragma unroll
      for (int ni = 0; ni < 4; ni++)
        bb[ni] = *(const s16x8*)&Bs[(wn * 64 + ni * 16 + l15) * 64 + kk + l4 * 8];
      #pragma unroll
      for (int mi = 0; mi < 4; mi++)
        #pragma unroll
        for (int ni = 0; ni < 4; ni++)
          acc[mi][ni] = __builtin_amdgcn_mfma_f32_16x16x32_bf16(a[mi], bb[ni], acc[mi][ni], 0, 0, 0);
    }
    __syncthreads();
  }
  #pragma unroll
  for (int mi = 0; mi < 4; mi++){
    #pragma unroll
    for (int r = 0; r < 4; r++){
      int cl = wm * 64 + mi * 16 + l4 * 4 + r;
      int c  = cb + cl;
      float bias = bvs[cl];
      #pragma unroll
      for (int ni = 0; ni < 4; ni++){
        int n = nb + wn * 64 + ni * 16 + l15;
        v[((size_t)(b * Cn + c)) * Nn + n] = f2bf(acc[mi][ni][r] + bias);
      }
    }
  }
}

// Q,K = [Wq;Wk] @ X with split-precision bf16 (3 MFMA terms).
__global__ __launch_bounds__(256) void k_qk_mfma(const bf16* __restrict__ xT_hi,
                                                 const bf16* __restrict__ xT_lo,
                                                 const bf16* __restrict__ wqk_hi,
                                                 const bf16* __restrict__ wqk_lo,
                                                 const float* __restrict__ bqk,
                                                 bf16* __restrict__ q,
                                                 bf16* __restrict__ k){
  __shared__ short Ah[128 * 64];
  __shared__ short Al[128 * 64];
  __shared__ short Bh[128 * 64];
  __shared__ short Bl[128 * 64];
  __shared__ float bs[128];
  int nb = blockIdx.x * 128, b = blockIdx.y;
  int t = threadIdx.x, lane = t & 63, wid = t >> 6;
  int wm = wid >> 1, wn = wid & 1;
  int l15 = lane & 15, l4 = lane >> 4;
  if (t < 128) bs[t] = bqk[t];
  f32x4 acc[4][4];
  #pragma unroll
  for (int i = 0; i < 4; i++)
    #pragma unroll
    for (int j = 0; j < 4; j++) acc[i][j] = (f32x4){0.f, 0.f, 0.f, 0.f};

  const bf16* xh = xT_hi + ((size_t)b * Nn + nb) * Cn;
  const bf16* xl = xT_lo + ((size_t)b * Nn + nb) * Cn;
  int r8 = lane >> 3;
  int kc = (lane & 7) * 8;
  for (int kt = 0; kt < 8; ++kt){
    int k0 = kt * 64;
    #pragma unroll
    for (int j = 0; j < 4; ++j){
      int inst = wid * 4 + j;
      int row = inst * 8 + r8;
      size_t off = (size_t)row * Cn + k0 + kc;
      gload_lds16(wqk_hi + off, (char*)Ah + inst * 1024);
      gload_lds16(wqk_lo + off, (char*)Al + inst * 1024);
      gload_lds16(xh + off,     (char*)Bh + inst * 1024);
      gload_lds16(xl + off,     (char*)Bl + inst * 1024);
    }
    __syncthreads();
    #pragma unroll
    for (int kk = 0; kk < 64; kk += 32){
      s16x8 ah[4], al[4], bh[4], bl[4];
      #pragma unroll
      for (int mi = 0; mi < 4; mi++){
        int idx = (wm * 64 + mi * 16 + l15) * 64 + kk + l4 * 8;
        ah[mi] = *(const s16x8*)&Ah[idx];
        al[mi] = *(const s16x8*)&Al[idx];
      }
      #pragma unroll
      for (int ni = 0; ni < 4; ni++){
        int idx = (wn * 64 + ni * 16 + l15) * 64 + kk + l4 * 8;
        bh[ni] = *(const s16x8*)&Bh[idx];
        bl[ni] = *(const s16x8*)&Bl[idx];
      }
      #pragma unroll
      for (int mi = 0; mi < 4; mi++)
        #pragma unroll
        for (int ni = 0; ni < 4; ni++){
          acc[mi][ni] = __builtin_amdgcn_mfma_f32_16x16x32_bf16(ah[mi], bh[ni], acc[mi][ni], 0, 0, 0);
          acc[mi][ni] = __builtin_amdgcn_mfma_f32_16x16x32_bf16(ah[mi], bl[ni], acc[mi][ni], 0, 0, 0);
          acc[mi][ni] = __builtin_amdgcn_mfma_f32_16x16x32_bf16(al[mi], bh[ni], acc[mi][ni], 0, 0, 0);
        }
    }
    __syncthreads();
  }
  #pragma unroll
  for (int mi = 0; mi < 4; mi++){
    #pragma unroll
    for (int r = 0; r < 4; r++){
      int o = wm * 64 + mi * 16 + l4 * 4 + r;
      float bias = bs[o];
      #pragma unroll
      for (int ni = 0; ni < 4; ni++){
        int n = nb + wn * 64 + ni * 16 + l15;
        float val = acc[mi][ni][r] + bias;
        if (o < 64) q[((size_t)(b * CQn + o)) * Nn + n]        = f2bf(val);
        else        k[((size_t)(b * CQn + o - 64)) * Nn + n]   = f2bf(val);
      }
    }
  }
}

// ============================ fused attention ============================

// per (b,w): e_h (VALU) + diag + row stats + exp->bf16 p in LDS, then
// ohT_raw[b,w,c,h] = sum_g p[h,g]*vT[b,w,c,g]  (unnormalized; alpha applied in fuse)
__global__ __launch_bounds__(256) void k_att_h(const bf16* __restrict__ qT,
                                               const bf16* __restrict__ kT,
                                               const bf16* __restrict__ vT,
                                               float* __restrict__ mh,
                                               float* __restrict__ sh,
                                               bf16* __restrict__ ohT){
  __shared__ float smem[16384];                 // 64KB
  float* qs = smem;
  float* ks = smem + 8192;
  char* attb = (char*)smem;                     // phase 2: p tile, lower 32KB
  char* vbb  = (char*)smem + 32768;             // phase 2: V tile, upper 32KB
  int w = blockIdx.x, b = blockIdx.y;
  int t = threadIdx.x, lane = t & 63, wid = t >> 6;
  const bf16* qp = qT + (size_t)(b * Wn + w) * CQn * Hn;
  const bf16* kp = kT + (size_t)(b * Wn + w) * CQn * Hn;
  for (int i = t; i < 8192; i += 256){ qs[i] = bf2f(qp[i]); ks[i] = bf2f(kp[i]); }
  __syncthreads();
  int hg = t >> 3, gg = t & 7;
  float acc[4][16];
  #pragma unroll
  for (int i = 0; i < 4; i++)
    #pragma unroll
    for (int j = 0; j < 16; j++) acc[i][j] = 0.f;
  for (int c = 0; c < CQn; ++c){
    float qv[4], kv[16];
    #pragma unroll
    for (int i = 0; i < 4; i++) qv[i] = qs[c * 128 + hg * 4 + i];
    #pragma unroll
    for (int j = 0; j < 16; j++) kv[j] = ks[c * 128 + gg + 8 * j];
    #pragma unroll
    for (int i = 0; i < 4; i++)
      #pragma unroll
      for (int j = 0; j < 16; j++) acc[i][j] += qv[i] * kv[j];
  }
  float mrow[4], srow[4];
  #pragma unroll
  for (int i = 0; i < 4; i++){
    int hrow = hg * 4 + i;
    #pragma unroll
    for (int j = 0; j < 16; j++)
      if (hrow == gg + 8 * j) acc[i][j] = -1e30f;
    float m = acc[i][0];
    #pragma unroll
    for (int j = 1; j < 16; j++) m = fmaxf(m, acc[i][j]);
    m = fmaxf(m, __shfl_xor(m, 1));
    m = fmaxf(m, __shfl_xor(m, 2));
    m = fmaxf(m, __shfl_xor(m, 4));
    mrow[i] = m;
    float s = 0.f;
    #pragma unroll
    for (int j = 0; j < 16; j++){ acc[i][j] = expf(acc[i][j] - m); s += acc[i][j]; }
    s += __shfl_xor(s, 1);
    s += __shfl_xor(s, 2);
    s += __shfl_xor(s, 4);
    srow[i] = s;
  }
  __syncthreads();   // all qs/ks reads done before overwrite
  // write p (bf16) swizzled: logical [h][g], byte = (h*256+g*2)^((h&7)<<4)
  #pragma unroll
  for (int i = 0; i < 4; i++)
    #pragma unroll
    for (int j = 0; j < 16; j++){
      int h = hg * 4 + i, g = gg + 8 * j;
      bf16 bv = f2bf(acc[i][j]);
      int byte = (h * 256 + g * 2) ^ ((h & 7) << 4);
      *(unsigned short*)(attb + byte) = *(unsigned short*)&bv;
    }
  if (gg == 0){
    #pragma unroll
    for (int i = 0; i < 4; i++){
      mh[(size_t)(b * Wn + w) * Hn + hg * 4 + i] = mrow[i];
      sh[(size_t)(b * Wn + w) * Hn + hg * 4 + i] = srow[i];
    }
  }
  __syncthreads();
  // phase 2: MFMA over 4 c-tiles
  int wm = wid >> 1, wn = wid & 1;
  int l15 = lane & 15, l4 = lane >> 4;
  for (int cb = 0; cb < Cn; cb += 128){
    const bf16* vp = vT + ((size_t)(b * Wn + w) * Cn + cb) * Hn;
    for (int s = t; s < 2048; s += 256){
      int row = s >> 4, seg = s & 15;
      s16x8 d = *(const s16x8*)(vp + (size_t)row * Hn + seg * 8);
      int byte = (row * 256 + seg * 16) ^ ((row & 7) << 4);
      *(s16x8*)(vbb + byte) = d;
    }
    __syncthreads();
    f32x4 acc2[4][4];
    #pragma unroll
    for (int i = 0; i < 4; i++)
      #pragma unroll
      for (int j = 0; j < 4; j++) acc2[i][j] = (f32x4){0.f, 0.f, 0.f, 0.f};
    #pragma unroll
    for (int kk = 0; kk < 128; kk += 32){
      s16x8 a[4], bb[4];
      #pragma unroll
      for (int mi = 0; mi < 4; mi++){
        int row = wm * 64 + mi * 16 + l15;
        int byte = (row * 256 + (kk + l4 * 8) * 2) ^ ((row & 7) << 4);
        a[mi] = *(const s16x8*)(vbb + byte);
      }
      #pragma unroll
      for (int ni = 0; ni < 4; ni++){
        int row = wn * 64 + ni * 16 + l15;
        int byte = (row * 256 + (kk + l4 * 8) * 2) ^ ((row & 7) << 4);
        bb[ni] = *(const s16x8*)(attb + byte);
      }
      #pragma unroll
      for (int mi = 0; mi < 4; mi++)
        #pragma unroll
        for (int ni = 0; ni < 4; ni++)
          acc2[mi][ni] = __builtin_amdgcn_mfma_f32_16x16x32_bf16(a[mi], bb[ni], acc2[mi][ni], 0, 0, 0);
    }
    bf16* op = ohT + ((size_t)(b * Wn + w) * Cn + cb) * Hn;
    #pragma unroll
    for (int mi = 0; mi < 4; mi++)
      #pragma unroll
      for (int r = 0; r < 4; r++){
        int cl = wm * 64 + mi * 16 + l4 * 4 + r;
        #pragma unroll
        for (int ni = 0; ni < 4; ni++){
          int h = wn * 64 + ni * 16 + l15;
          op[(size_t)cl * Hn + h] = f2bf(acc2[mi][ni][r]);
        }
      }
    __syncthreads();
  }
}

// per (b,h): e_w + stats + exp->p, then ow_raw[b,c,h,w_] = sum_v p[w_,v]*v[b,c,h,v]
__global__ __launch_bounds__(256) void k_att_w(const bf16* __restrict__ q,
                                               const bf16* __restrict__ k,
                                               const bf16* __restrict__ v,
                                               float* __restrict__ mw,
                                               float* __restrict__ sw,
                                               bf16* __restrict__ ow){
  __shared__ float smem[16384];
  float* qs = smem;
  float* ks = smem + 8192;
  char* attb = (char*)smem;
  char* vbb  = (char*)smem + 32768;
  int h = blockIdx.x, b = blockIdx.y;
  int t = threadIdx.x, lane = t & 63, wid = t >> 6;
  for (int i = t; i < 8192; i += 256){
    int c = i >> 7, wl = i & 127;
    size_t base = ((size_t)(b * CQn + c) * Hn + h) * Wn + wl;
    qs[i] = bf2f(q[base]);
    ks[i] = bf2f(k[base]);
  }
  __syncthreads();
  int wg = t >> 3, vg = t & 7;
  float acc[4][16];
  #pragma unroll
  for (int i = 0; i < 4; i++)
    #pragma unroll
    for (int j = 0; j < 16; j++) acc[i][j] = 0.f;
  for (int c = 0; c < CQn; ++c){
    float qv[4], kv[16];
    #pragma unroll
    for (int i = 0; i < 4; i++) qv[i] = qs[c * 128 + wg * 4 + i];
    #pragma unroll
    for (int j = 0; j < 16; j++) kv[j] = ks[c * 128 + vg + 8 * j];
    #pragma unroll
    for (int i = 0; i < 4; i++)
      #pragma unroll
      for (int j = 0; j < 16; j++) acc[i][j] += qv[i] * kv[j];
  }
  float mrow[4], srow[4];
  #pragma unroll
  for (int i = 0; i < 4; i++){
    float m = acc[i][0];
    #pragma unroll
    for (int j = 1; j < 16; j++) m = fmaxf(m, acc[i][j]);
    m = fmaxf(m, __shfl_xor(m, 1));
    m = fmaxf(m, __shfl_xor(m, 2));
    m = fmaxf(m, __shfl_xor(m, 4));
    mrow[i] = m;
    float s = 0.f;
    #pragma unroll
    for (int j = 0; j < 16; j++){ acc[i][j] = expf(acc[i][j] - m); s += acc[i][j]; }
    s += __shfl_xor(s, 1);
    s += __shfl_xor(s, 2);
    s += __shfl_xor(s, 4);
    srow[i] = s;
  }
  __syncthreads();
  #pragma unroll
  for (int i = 0; i < 4; i++)
    #pragma unroll
    for (int j = 0; j < 16; j++){
      int wr = wg * 4 + i, g = vg + 8 * j;
      bf16 bv = f2bf(acc[i][j]);
      int byte = (wr * 256 + g * 2) ^ ((wr & 7) << 4);
      *(unsigned short*)(attb + byte) = *(unsigned short*)&bv;
    }
  if (vg == 0){
    #pragma unroll
    for (int i = 0; i < 4; i++){
      mw[(size_t)(b * Hn + h) * Wn + wg * 4 + i] = mrow[i];
      sw[(size_t)(b * Hn + h) * Wn + wg * 4 + i] = srow[i];
    }
  }
  __syncthreads();
  int wm = wid >> 1, wn = wid & 1;
  int l15 = lane & 15, l4 = lane >> 4;
  for (int cb = 0; cb < Cn; cb += 128){
    const bf16* vp = v + (size_t)(b * Cn + cb) * Nn + (size_t)h * Wn;
    for (int s = t; s < 2048; s += 256){
      int row = s >> 4, seg = s & 15;
      s16x8 d = *(const s16x8*)(vp + (size_t)row * Nn + seg * 8);
      int byte = (row * 256 + seg * 16) ^ ((row & 7) << 4);
      *(s16x8*)(vbb + byte) = d;
    }
    __syncthreads();
    f32x4 acc2[4][4];
    #pragma unroll
    for (int i = 0; i < 4; i++)
      #pragma unroll
      for (int j = 0; j < 4; j++) acc2[i][j] = (f32x4){0.f, 0.f, 0.f, 0.f};
    #pragma unroll
    for (int kk = 0; kk < 128; kk += 32){
      s16x8 a[4], bb[4];
      #pragma unroll
      for (int mi = 0; mi < 4; mi++){
        int row = wm * 64 + mi * 16 + l15;
        int byte = (row * 256 + (kk + l4 * 8) * 2) ^ ((row & 7) << 4);
        a[mi] = *(const s16x8*)(vbb + byte);
      }
      #pragma unroll
      for (int ni = 0; ni < 4; ni++){
        int row = wn * 64 + ni * 16 + l15;
        int byte = (row * 256 + (kk + l4 * 8) * 2) ^ ((row & 7) << 4);
        bb[ni] = *(const s16x8*)(attb + byte);
      }
      #pragma unroll
      for (int mi = 0; mi < 4; mi++)
        #pragma unroll
        for (int ni = 0; ni < 4; ni++)
          acc2[mi][ni] = __builtin_amdgcn_mfma_f32_16x16x32_bf16(a[mi], bb[ni], acc2[mi][ni], 0, 0, 0);
    }
    bf16* op = ow + (size_t)(b * Cn + cb) * Nn + (size_t)h * Wn;
    #pragma unroll
    for (int mi = 0; mi < 4; mi++)
      #pragma unroll
      for (int r = 0; r < 4; r++){
        int cl = wm * 64 + mi * 16 + l4 * 4 + r;
        #pragma unroll
        for (int ni = 0; ni < 4; ni++){
          int wr = wn * 64 + ni * 16 + l15;
          op[(size_t)cl * Nn + wr] = f2bf(acc2[mi][ni][r]);
        }
      }
    __syncthreads();
  }
}

// merge stats -> alphas, both in [b,h,w] layout for fuse
__global__ __launch_bounds__(256) void k_alpha(const float* __restrict__ mh,
                                               const float* __restrict__ sh,
                                               const float* __restrict__ mw,
                                               const float* __restrict__ sw,
                                               float* __restrict__ ahT,
                                               float* __restrict__ aw){
  int t = blockIdx.x * 256 + threadIdx.x;   // (b*Hn+h)*Wn + w
  int b = t >> 14;
  int hw = t & (Nn - 1);
  int h = hw >> 7, w = hw & 127;
  size_t ih = (size_t)(b * Wn + w) * Hn + h;
  size_t iw = t;
  float mhv = mh[ih], mwv = mw[iw];
  float M = fmaxf(mhv, mwv);
  float eh_ = expf(mhv - M), ew_ = expf(mwv - M);
  float inv = 1.f / (sh[ih] * eh_ + sw[iw] * ew_);
  ahT[t] = eh_ * inv;
  aw[t]  = ew_ * inv;
}

// ============================ remaining CA kernels ============================

__global__ __launch_bounds__(256) void k_trans(const bf16* __restrict__ in,
                                               bf16* __restrict__ out,
                                               int CH){
  __shared__ bf16 tile[32][33];
  int tl = blockIdx.x, c = blockIdx.y, b = blockIdx.z;
  int th = tl >> 2, tw = tl & 3;
  int h0 = th * 32, w0 = tw * 32;
  int t = threadIdx.x;
  const bf16* ip = in + ((size_t)(b * CH + c)) * Nn;
  #pragma unroll
  for (int kk = 0; kk < 4; ++kk){
    int idx = t + kk * 256;
    int hl = idx >> 5, wl = idx & 31;
    tile[hl][wl] = ip[(h0 + hl) * Wn + w0 + wl];
  }
  __syncthreads();
  #pragma unroll
  for (int kk = 0; kk < 4; ++kk){
    int idx = t + kk * 256;
    int wl = idx >> 5, hl = idx & 31;
    out[((size_t)(b * Wn + w0 + wl) * CH + c) * Hn + h0 + hl] = tile[hl][wl];
  }
}

// out = gamma*(ah*ohT^T + aw*ow) + in (+ addend); XCD-chunked grid.
__global__ __launch_bounds__(256) void k_fuse2(const float* __restrict__ in,
                                               const bf16* __restrict__ ohT,
                                               const bf16* __restrict__ ow,
                                               const float* __restrict__ ahT,
                                               const float* __restrict__ aw,
                                               const float* __restrict__ addend,
                                               const float* __restrict__ gamma,
                                               float* __restrict__ out){
  __shared__ unsigned short tileT[128][138];
  int lin = blockIdx.x;
  int swz = (lin & 7) * 256 + (lin >> 3);   // each XCD: contiguous 256 c's of one b
  int c = swz & 511;
  int b = swz >> 9;
  int t = threadIdx.x;
  float g = gamma[0];
  const bf16* ohp = ohT + ((size_t)(b * Wn) * Cn + c) * Hn;
  #pragma unroll
  for (int i = 0; i < 8; ++i){
    int s = t + i * 256;            // 0..2047
    int w = s >> 4, seg = s & 15;
    s16x8 d = *(const s16x8*)(ohp + (size_t)w * (Cn * Hn) + seg * 8);
    #pragma unroll
    for (int j = 0; j < 8; ++j)
      tileT[seg * 8 + j][w] = (unsigned short)d[j];
  }
  __syncthreads();
  size_t base = ((size_t)(b * Cn + c)) * Nn;
  #pragma unroll
  for (int i = 0; i < 16; ++i){
    int o = t + i * 256;            // 0..4095
    int h = o >> 5, w4 = (o & 31) * 4;
    size_t idx = base + (size_t)h * Wn + w4;
    size_t aidx = (size_t)b * Nn + (size_t)h * Wn + w4;
    float4 inv = *(const float4*)(in + idx);
    ushort4 owv = *(const ushort4*)((const unsigned short*)ow + idx);
    float4 ah4 = *(const float4*)(ahT + aidx);
    float4 aw4 = *(const float4*)(aw + aidx);
    float r[4];
    #pragma unroll
    for (int j = 0; j < 4; ++j){
      unsigned short uh = tileT[h][w4 + j];
      unsigned short uo = ((const unsigned short*)&owv)[j];
      float ohv = bf2f(*(bf16*)&uh);
      float owf = bf2f(*(bf16*)&uo);
      float iv  = ((const float*)&inv)[j];
      float ahv = ((const float*)&ah4)[j];
      float awv = ((const float*)&aw4)[j];
      r[j] = g * (ahv * ohv + awv * owf) + iv;
    }
    if (addend){
      float4 av = *(const float4*)(addend + idx);
      r[0] += av.x; r[1] += av.y; r[2] += av.z; r[3] += av.w;
    }
    float4 o4 = { r[0], r[1], r[2], r[3] };
    *(float4*)(out + idx) = o4;
  }
}

// ============================ host ============================

static void run_ca(const float* in, const bf16* wqk_hi, const bf16* wqk_lo,
                   const float* bqk, const bf16* wvb, const float* bv,
                   const float* gamma, const float* addend, float* out,
                   bf16* q, bf16* k, bf16* qT, bf16* kT, bf16* v, bf16* vT,
                   float* mh, float* sh, float* mw, float* sw, float* ahT, float* aw,
                   bf16* xT_hi, bf16* xT_lo, bf16* tmp,
                   bool do_cvt, hipStream_t stream){
  bf16* ohT = tmp;
  bf16* ow  = tmp + (size_t)Bn * Cn * Nn;
  if (do_cvt)
    k_cvt_T<<<dim3(Nn / 32, Cn / 32, Bn), 256, 0, stream>>>(in, xT_hi, xT_lo);
  k_qk_mfma<<<dim3(Nn / 128, Bn), 256, 0, stream>>>(xT_hi, xT_lo, wqk_hi, wqk_lo, bqk, q, k);
  k_trans<<<dim3(16, CQn, Bn), 256, 0, stream>>>(q, qT, CQn);
  k_trans<<<dim3(16, CQn, Bn), 256, 0, stream>>>(k, kT, CQn);
  k_v_mfma<<<2048, 256, 0, stream>>>(xT_hi, wvb, bv, v);
  k_trans<<<dim3(16, Cn, Bn), 256, 0, stream>>>(v, vT, Cn);
  k_att_h<<<dim3(Wn, Bn), 256, 0, stream>>>(qT, kT, vT, mh, sh, ohT);
  k_att_w<<<dim3(Hn, Bn), 256, 0, stream>>>(q, k, v, mw, sw, ow);
  k_alpha<<<Bn * Nn / 256, 256, 0, stream>>>(mh, sh, mw, sw, ahT, aw);
  k_fuse2<<<2048, 256, 0, stream>>>(in, ohT, ow, ahT, aw, addend, gamma, out);
}

extern "C" void kernel_launch(void* const* d_in, const int* in_sizes, int n_in,
                              void* d_out, int out_size, void* d_ws, size_t ws_size,
                              hipStream_t stream){
  (void)in_sizes; (void)n_in; (void)out_size; (void)ws_size;
  const float* x         = (const float*)d_in[0];
  const float* w_q_right = (const float*)d_in[1];
  const float* w_v_right = (const float*)d_in[2];
  const float* w_up      = (const float*)d_in[3];
  const float* b_up      = (const float*)d_in[4];
  const float* w_q_left  = (const float*)d_in[5];
  const float* w_v_left  = (const float*)d_in[6];
  const float* wq        = (const float*)d_in[7];
  const float* bq        = (const float*)d_in[8];
  const float* wk        = (const float*)d_in[9];
  const float* bk        = (const float*)d_in[10];
  const float* wv        = (const float*)d_in[11];
  const float* bv        = (const float*)d_in[12];
  const float* gamma     = (const float*)d_in[13];

  const size_t SZ_MAP = (size_t)Bn * Cn * Nn;     // 33.5M elements
  char* p = (char*)d_ws;
  float* buf0   = (float*)p; p += SZ_MAP * 4;
  float* buf1   = (float*)p; p += SZ_MAP * 4;
  bf16*  vbuf   = (bf16*)p;  p += SZ_MAP * 2;
  bf16*  vT     = (bf16*)p;  p += SZ_MAP * 2;
  bf16*  qbuf   = (bf16*)p;  p += (size_t)Bn * CQn * Nn * 2;
  bf16*  kbuf   = (bf16*)p;  p += (size_t)Bn * CQn * Nn * 2;
  bf16*  qT     = (bf16*)p;  p += (size_t)Bn * CQn * Nn * 2;
  bf16*  kT     = (bf16*)p;  p += (size_t)Bn * CQn * Nn * 2;
  float* ebuf   = (float*)p; p += (size_t)SZ_MAP * 2;         // xT_hi arena (67MB)
  float* logits = (float*)p; p += (size_t)Bn * Nn * 4;
  float* ctxlog = (float*)p; p += (size_t)Bn * Nn * 4;
  float* msp    = (float*)p; p += (size_t)Bn * Nn * 4;
  float* xbar   = (float*)p; p += Bn * Cn * 4;
  float* wgt    = (float*)p; p += Bn * Cn * 4;
  float* u      = (float*)p; p += Bn * Cn * 4;
  float* mch    = (float*)p; p += Bn * Cn * 4;
  float* avg    = (float*)p; p += Bn * CIn * 4;
  float* ctx    = (float*)p; p += Bn * CIn * 4;
  float* stats_sp = (float*)p; p += 64;
  float* stats_ch = (float*)p; p += 64;
  bf16*  wvb    = (bf16*)p;  p += (size_t)Cn * Cn * 2;
  bf16*  wqk_hi = (bf16*)p;  p += (size_t)128 * Cn * 2;
  bf16*  wqk_lo = (bf16*)p;  p += (size_t)128 * Cn * 2;
  float* bqk    = (float*)p; p += 128 * 4;
  float* mh     = (float*)p; p += (size_t)Bn * Nn * 4;
  float* sh     = (float*)p; p += (size_t)Bn * Nn * 4;
  float* mw     = (float*)p; p += (size_t)Bn * Nn * 4;
  float* sw     = (float*)p; p += (size_t)Bn * Nn * 4;
  float* ahT    = (float*)p; p += (size_t)Bn * Nn * 4;
  float* aw     = (float*)p; p += (size_t)Bn * Nn * 4;

  bf16*  xT_hi  = (bf16*)ebuf;    // dead after v_mfma of each CA
  bf16*  xT_lo  = (bf16*)d_out;   // dead before ohT/fuse writes d_out

  // ---- weight prep (once) ----
  k_cvt_w<<<(Cn * Cn + 255) / 256, 256, 0, stream>>>(wv, wvb, Cn * Cn);
  k_prep_wqk<<<(128 * Cn) / 256, 256, 0, stream>>>(wq, wk, bq, bk, wqk_hi, wqk_lo, bqk);

  // ---- stage 0: gating masks ----
  k_dotc<<<Bn * Nn / 256, 256, 0, stream>>>(x, w_q_right, 0, logits);
  k_rowmean<<<Bn * Cn, 256, 0, stream>>>(x, xbar, 1.f / Nn);
  k_rowdot<<<Bn, 256, 0, stream>>>(w_q_left, xbar, avg);
  k_coldot<<<dim3(Cn / 256, Bn), 256, 0, stream>>>(w_v_left, avg, u);
  k_stats<<<Bn, 1024, 0, stream>>>(logits, stats_sp);
  k_weighted<<<Bn * Cn, 256, 0, stream>>>(x, logits, stats_sp, wgt);
  k_rowdot<<<Bn, 256, 0, stream>>>(w_v_right, wgt, ctx);
  k_mch2<<<dim3(Cn / 256, Bn), 256, 0, stream>>>(w_up, b_up, ctx, mch);
  k_dotc<<<Bn * Nn / 256, 256, 0, stream>>>(x, u, Cn, ctxlog);
  k_stats<<<Bn, 1024, 0, stream>>>(ctxlog, stats_ch);
  k_msp<<<Bn * Nn / 256, 256, 0, stream>>>(ctxlog, stats_ch, msp);
  k_applyT<<<dim3(Nn / 32, Cn / 32, Bn), 256, 0, stream>>>(x, mch, msp, buf0, buf1,
                                                           xT_hi, xT_lo);

  // ---- CA1: cc' = CA(cc), in-place buf0; tmp = d_out (xT already built) ----
  run_ca(buf0, wqk_hi, wqk_lo, bqk, wvb, bv, gamma, nullptr, buf0,
         qbuf, kbuf, qT, kT, vbuf, vT, mh, sh, mw, sw, ahT, aw,
         xT_hi, xT_lo, (bf16*)d_out, false, stream);
  // ---- CA2: s = CA(cs) + cc' -> buf0 ----
  run_ca(buf1, wqk_hi, wqk_lo, bqk, wvb, bv, gamma, buf0, buf0,
         qbuf, kbuf, qT, kT, vbuf, vT, mh, sh, mw, sw, ahT, aw,
         xT_hi, xT_lo, (bf16*)d_out, true, stream);
  // ---- CA3: out = CA(s) -> d_out; tmp = buf1 ----
  run_ca(buf0, wqk_hi, wqk_lo, bqk, wvb, bv, gamma, nullptr, (float*)d_out,
         qbuf, kbuf, qT, kT, vbuf, vT, mh, sh, mw, sw, ahT, aw,
         xT_hi, xT_lo, (bf16*)buf1, true, stream);
}

// Round 11
// 1400.210 us; speedup vs baseline: 2.9039x; 1.0824x over previous
//
#include <hip/hip_runtime.h>
#include <hip/hip_bf16.h>
#include <math.h>

typedef __hip_bfloat16 bf16;
typedef __attribute__((ext_vector_type(8))) short s16x8;
typedef __attribute__((ext_vector_type(4))) float f32x4;

constexpr int Bn  = 4;
constexpr int Cn  = 512;
constexpr int Hn  = 128;
constexpr int Wn  = 128;
constexpr int Nn  = Hn * Wn;   // 16384
constexpr int CQn = 64;
constexpr int CIn = 256;

__device__ __forceinline__ float bf2f(bf16 v){ return __bfloat162float(v); }
__device__ __forceinline__ bf16  f2bf(float v){ return __float2bfloat16(v); }

// async global->LDS, 16B per lane; LDS dest must be wave-uniform base (HW adds lane*16)
__device__ __forceinline__ void gload_lds16(const void* g, void* l){
  __builtin_amdgcn_global_load_lds(
      (const __attribute__((address_space(1))) unsigned int*)g,
      (__attribute__((address_space(3))) unsigned int*)l,
      16, 0, 0);
}

// ============================ stage 0 ============================

__global__ __launch_bounds__(256) void k_dotc(const float* __restrict__ x,
                                              const float* __restrict__ w,
                                              int wstride,
                                              float* __restrict__ out){
  int t = blockIdx.x * 256 + threadIdx.x;      // over B*Nn
  int b = t >> 14;
  const float* wp = w + (size_t)b * wstride;
  const float* xp = x + (size_t)b * Cn * Nn + (t & (Nn - 1));
  float acc = 0.f;
  #pragma unroll 8
  for (int c = 0; c < Cn; ++c) acc += wp[c] * xp[(size_t)c * Nn];
  out[t] = acc;
}

__global__ __launch_bounds__(256) void k_rowmean(const float* __restrict__ x,
                                                 float* __restrict__ out,
                                                 float scale){
  int bc = blockIdx.x;
  const float* xp = x + (size_t)bc * Nn;
  float acc = 0.f;
  for (int n = threadIdx.x; n < Nn; n += 256) acc += xp[n];
  for (int o = 32; o > 0; o >>= 1) acc += __shfl_down(acc, o);
  __shared__ float red[4];
  if ((threadIdx.x & 63) == 0) red[threadIdx.x >> 6] = acc;
  __syncthreads();
  if (threadIdx.x == 0) out[bc] = (red[0] + red[1] + red[2] + red[3]) * scale;
}

__global__ __launch_bounds__(256) void k_rowdot(const float* __restrict__ W,
                                                const float* __restrict__ vec,
                                                float* __restrict__ out){
  __shared__ float vs[Cn];
  int b = blockIdx.x, t = threadIdx.x;
  for (int j = t; j < Cn; j += 256) vs[j] = vec[b * Cn + j];
  __syncthreads();
  const float4* wp = (const float4*)(W + (size_t)t * Cn);
  float a = 0.f;
  #pragma unroll 4
  for (int j = 0; j < Cn / 4; ++j){
    float4 w4 = wp[j];
    a += w4.x * vs[4*j] + w4.y * vs[4*j+1] + w4.z * vs[4*j+2] + w4.w * vs[4*j+3];
  }
  out[b * CIn + t] = a;
}

__global__ __launch_bounds__(256) void k_coldot(const float* __restrict__ W,
                                                const float* __restrict__ vec,
                                                float* __restrict__ out){
  __shared__ float vs[CIn];
  int b = blockIdx.y, t = threadIdx.x;
  int c = blockIdx.x * 256 + t;
  if (t < CIn) vs[t] = vec[b * CIn + t];
  __syncthreads();
  float a = 0.f;
  #pragma unroll 8
  for (int j = 0; j < CIn; ++j) a += W[(size_t)j * Cn + c] * vs[j];
  out[b * Cn + c] = a;
}

__global__ __launch_bounds__(256) void k_mch2(const float* __restrict__ w_up,
                                              const float* __restrict__ b_up,
                                              const float* __restrict__ ctx,
                                              float* __restrict__ mch){
  __shared__ float cs[CIn];
  int b = blockIdx.y, t = threadIdx.x;
  int o = blockIdx.x * 256 + t;
  if (t < CIn) cs[t] = ctx[b * CIn + t];
  __syncthreads();
  const float4* wp = (const float4*)(w_up + (size_t)o * CIn);
  float a = b_up[o];
  #pragma unroll 4
  for (int j = 0; j < CIn / 4; ++j){
    float4 w4 = wp[j];
    a += w4.x * cs[4*j] + w4.y * cs[4*j+1] + w4.z * cs[4*j+2] + w4.w * cs[4*j+3];
  }
  mch[b * Cn + o] = 1.f / (1.f + expf(-a));
}

__global__ __launch_bounds__(1024) void k_stats(const float* __restrict__ vv,
                                                float* __restrict__ stats){
  int b = blockIdx.x;
  const float* pp = vv + (size_t)b * Nn;
  int t = threadIdx.x;
  float m = -3.4e38f;
  for (int n = t; n < Nn; n += 1024) m = fmaxf(m, pp[n]);
  for (int o = 32; o > 0; o >>= 1) m = fmaxf(m, __shfl_down(m, o));
  __shared__ float red[16];
  int wid = t >> 6, lid = t & 63;
  if (lid == 0) red[wid] = m;
  __syncthreads();
  if (t == 0){
    float q = red[0];
    for (int i = 1; i < 16; i++) q = fmaxf(q, red[i]);
    red[0] = q;
  }
  __syncthreads();
  m = red[0];
  __syncthreads();
  float s = 0.f;
  for (int n = t; n < Nn; n += 1024) s += expf(pp[n] - m);
  for (int o = 32; o > 0; o >>= 1) s += __shfl_down(s, o);
  if (lid == 0) red[wid] = s;
  __syncthreads();
  if (t == 0){
    float q = 0.f;
    for (int i = 0; i < 16; i++) q += red[i];
    stats[b * 2]     = m;
    stats[b * 2 + 1] = q;
  }
}

__global__ __launch_bounds__(256) void k_weighted(const float* __restrict__ x,
                                                  const float* __restrict__ logits,
                                                  const float* __restrict__ stats,
                                                  float* __restrict__ out){
  int bc = blockIdx.x;
  int b = bc >> 9;
  const float* xp = x + (size_t)bc * Nn;
  const float* lp = logits + (size_t)b * Nn;
  float m = stats[b * 2], den = stats[b * 2 + 1];
  float acc = 0.f;
  for (int n = threadIdx.x; n < Nn; n += 256) acc += xp[n] * expf(lp[n] - m);
  for (int o = 32; o > 0; o >>= 1) acc += __shfl_down(acc, o);
  __shared__ float red[4];
  if ((threadIdx.x & 63) == 0) red[threadIdx.x >> 6] = acc;
  __syncthreads();
  if (threadIdx.x == 0) out[bc] = (red[0] + red[1] + red[2] + red[3]) / den;
}

__global__ __launch_bounds__(256) void k_msp(const float* __restrict__ lg,
                                             const float* __restrict__ stats,
                                             float* __restrict__ msp){
  int t = blockIdx.x * 256 + threadIdx.x;
  int b = t >> 14;
  float v = expf(lg[t] - stats[b * 2]) / stats[b * 2 + 1];
  msp[t] = 1.f / (1.f + expf(-v));
}

// ccT hi/lo only (cc = x*mch recomputed in fuse): reads x, writes transposed split
__global__ __launch_bounds__(256) void k_applyT2(const float* __restrict__ x,
                                                 const float* __restrict__ mch,
                                                 bf16* __restrict__ out_hi,
                                                 bf16* __restrict__ out_lo){
  __shared__ bf16 th_[32][33];
  __shared__ bf16 tl_[32][33];
  int nt = blockIdx.x, ct = blockIdx.y, b = blockIdx.z;
  int n0 = nt * 32, c0 = ct * 32;
  int t = threadIdx.x;
  #pragma unroll
  for (int kk = 0; kk < 4; ++kk){
    int idx = t + kk * 256;
    int cl = idx >> 5, nl = idx & 31;
    float v = x[((size_t)(b * Cn + c0 + cl)) * Nn + n0 + nl] * mch[b * Cn + c0 + cl];
    bf16 h = f2bf(v);
    th_[cl][nl] = h;
    tl_[cl][nl] = f2bf(v - bf2f(h));
  }
  __syncthreads();
  #pragma unroll
  for (int kk = 0; kk < 4; ++kk){
    int idx = t + kk * 256;
    int nl = idx >> 5, cl = idx & 31;
    size_t o = ((size_t)(b * Nn + n0 + nl)) * Cn + c0 + cl;
    out_hi[o] = th_[cl][nl];
    out_lo[o] = tl_[cl][nl];
  }
}

// csT hi/lo (cs = x*msp recomputed in fuse): reads x + msp
__global__ __launch_bounds__(256) void k_cvt_T2(const float* __restrict__ x,
                                                const float* __restrict__ msp,
                                                bf16* __restrict__ out_hi,
                                                bf16* __restrict__ out_lo){
  __shared__ bf16 th_[32][33];
  __shared__ bf16 tl_[32][33];
  int nt = blockIdx.x, ct = blockIdx.y, b = blockIdx.z;
  int n0 = nt * 32, c0 = ct * 32;
  int t = threadIdx.x;
  #pragma unroll
  for (int kk = 0; kk < 4; ++kk){
    int idx = t + kk * 256;
    int cl = idx >> 5, nl = idx & 31;
    float v = x[((size_t)(b * Cn + c0 + cl)) * Nn + n0 + nl] * msp[b * Nn + n0 + nl];
    bf16 h = f2bf(v);
    th_[cl][nl] = h;
    tl_[cl][nl] = f2bf(v - bf2f(h));
  }
  __syncthreads();
  #pragma unroll
  for (int kk = 0; kk < 4; ++kk){
    int idx = t + kk * 256;
    int nl = idx >> 5, cl = idx & 31;
    size_t o = ((size_t)(b * Nn + n0 + nl)) * Cn + c0 + cl;
    out_hi[o] = th_[cl][nl];
    out_lo[o] = tl_[cl][nl];
  }
}

// ============================ conversions ============================

__global__ __launch_bounds__(256) void k_cvt_w(const float* __restrict__ in,
                                               bf16* __restrict__ out, int n){
  int t = blockIdx.x * 256 + threadIdx.x;
  if (t < n) out[t] = f2bf(in[t]);
}

__global__ __launch_bounds__(256) void k_prep_wqk(const float* __restrict__ wq,
                                                  const float* __restrict__ wk,
                                                  const float* __restrict__ bq,
                                                  const float* __restrict__ bk,
                                                  bf16* __restrict__ wqk_hi,
                                                  bf16* __restrict__ wqk_lo,
                                                  float* __restrict__ bqk){
  int t = blockIdx.x * 256 + threadIdx.x;   // over 128*512
  int o = t >> 9, c = t & 511;
  float v = (o < 64) ? wq[(size_t)o * Cn + c] : wk[(size_t)(o - 64) * Cn + c];
  bf16 h = f2bf(v);
  wqk_hi[t] = h;
  wqk_lo[t] = f2bf(v - bf2f(h));
  if (t < 128) bqk[t] = (t < 64) ? bq[t] : bk[t - 64];
}

__global__ __launch_bounds__(256) void k_cvt_T(const float* __restrict__ in,
                                               bf16* __restrict__ out_hi,
                                               bf16* __restrict__ out_lo){
  __shared__ bf16 th_[32][33];
  __shared__ bf16 tl_[32][33];
  int nt = blockIdx.x, ct = blockIdx.y, b = blockIdx.z;
  int n0 = nt * 32, c0 = ct * 32;
  int t = threadIdx.x;
  #pragma unroll
  for (int kk = 0; kk < 4; ++kk){
    int idx = t + kk * 256;
    int cl = idx >> 5, nl = idx & 31;
    float v = in[((size_t)(b * Cn + c0 + cl)) * Nn + n0 + nl];
    bf16 h = f2bf(v);
    th_[cl][nl] = h;
    tl_[cl][nl] = f2bf(v - bf2f(h));
  }
  __syncthreads();
  #pragma unroll
  for (int kk = 0; kk < 4; ++kk){
    int idx = t + kk * 256;
    int nl = idx >> 5, cl = idx & 31;
    size_t o = ((size_t)(b * Nn + n0 + nl)) * Cn + c0 + cl;
    out_hi[o] = th_[cl][nl];
    out_lo[o] = tl_[cl][nl];
  }
}

// ============================ MFMA GEMMs ============================

// V = Wv @ X. 128x128 tile, BK=64. XCD-chunked 1D grid of 2048.
__global__ __launch_bounds__(256) void k_v_mfma(const bf16* __restrict__ xT,
                                                const bf16* __restrict__ wvb,
                                                const float* __restrict__ bv,
                                                bf16* __restrict__ v){
  __shared__ short As[128 * 64];
  __shared__ short Bs[128 * 64];
  __shared__ float bvs[128];
  int lin = blockIdx.x;
  int swz = (lin & 7) * 256 + (lin >> 3);
  int cb = (swz & 3) * 128;
  int nb = ((swz >> 2) & 127) * 128;
  int b  = swz >> 9;
  int t = threadIdx.x, lane = t & 63, wid = t >> 6;
  int wm = wid >> 1, wn = wid & 1;
  int l15 = lane & 15, l4 = lane >> 4;
  if (t < 128) bvs[t] = bv[cb + t];
  f32x4 acc[4][4];
  #pragma unroll
  for (int i = 0; i < 4; i++)
    #pragma unroll
    for (int j = 0; j < 4; j++) acc[i][j] = (f32x4){0.f, 0.f, 0.f, 0.f};

  const bf16* wp = wvb + (size_t)cb * Cn;
  const bf16* xp = xT + ((size_t)b * Nn + nb) * Cn;
  int r8 = lane >> 3;
  int kc = (lane & 7) * 8;
  for (int kt = 0; kt < 8; ++kt){
    int k0 = kt * 64;
    #pragma unroll
    for (int j = 0; j < 4; ++j){
      int inst = wid * 4 + j;
      int row = inst * 8 + r8;
      gload_lds16(wp + (size_t)row * Cn + k0 + kc, (char*)As + inst * 1024);
      gload_lds16(xp + (size_t)row * Cn + k0 + kc, (char*)Bs + inst * 1024);
    }
    __syncthreads();
    #pragma unroll
    for (int kk = 0; kk < 64; kk += 32){
      s16x8 a[4], bb[4];
      #pragma unroll
      for (int mi = 0; mi < 4; mi++)
        a[mi] = *(const s16x8*)&As[(wm * 64 + mi * 16 + l15) * 64 + kk + l4 * 8];
      #pragma unroll
      for (int ni = 0; ni < 4; ni++)
        bb[ni] = *(const s16x8*)&Bs[(wn * 64 + ni * 16 + l15) * 64 + kk + l4 * 8];
      #pragma unroll
      for (int mi = 0; mi < 4; mi++)
        #pragma unroll
        for (int ni = 0; ni < 4; ni++)
          acc[mi][ni] = __builtin_amdgcn_mfma_f32_16x16x32_bf16(a[mi], bb[ni], acc[mi][ni], 0, 0, 0);
    }
    __syncthreads();
  }
  #pragma unroll
  for (int mi = 0; mi < 4; mi++){
    #pragma unroll
    for (int r = 0; r < 4; r++){
      int cl = wm * 64 + mi * 16 + l4 * 4 + r;
      int c  = cb + cl;
      float bias = bvs[cl];
      #pragma unroll
      for (int ni = 0; ni < 4; ni++){
        int n = nb + wn * 64 + ni * 16 + l15;
        v[((size_t)(b * Cn + c)) * Nn + n] = f2bf(acc[mi][ni][r] + bias);
      }
    }
  }
}

// Q,K = [Wq;Wk] @ X with split-precision bf16 (3 MFMA terms).
__global__ __launch_bounds__(256) void k_qk_mfma(const bf16* __restrict__ xT_hi,
                                                 const bf16* __restrict__ xT_lo,
                                                 const bf16* __restrict__ wqk_hi,
                                                 const bf16* __restrict__ wqk_lo,
                                                 const float* __restrict__ bqk,
                                                 bf16* __restrict__ q,
                                                 bf16* __restrict__ k){
  __shared__ short Ah[128 * 64];
  __shared__ short Al[128 * 64];
  __shared__ short Bh[128 * 64];
  __shared__ short Bl[128 * 64];
  __shared__ float bs[128];
  int nb = blockIdx.x * 128, b = blockIdx.y;
  int t = threadIdx.x, lane = t & 63, wid = t >> 6;
  int wm = wid >> 1, wn = wid & 1;
  int l15 = lane & 15, l4 = lane >> 4;
  if (t < 128) bs[t] = bqk[t];
  f32x4 acc[4][4];
  #pragma unroll
  for (int i = 0; i < 4; i++)
    #pragma unroll
    for (int j = 0; j < 4; j++) acc[i][j] = (f32x4){0.f, 0.f, 0.f, 0.f};

  const bf16* xh = xT_hi + ((size_t)b * Nn + nb) * Cn;
  const bf16* xl = xT_lo + ((size_t)b * Nn + nb) * Cn;
  int r8 = lane >> 3;
  int kc = (lane & 7) * 8;
  for (int kt = 0; kt < 8; ++kt){
    int k0 = kt * 64;
    #pragma unroll
    for (int j = 0; j < 4; ++j){
      int inst = wid * 4 + j;
      int row = inst * 8 + r8;
      size_t off = (size_t)row * Cn + k0 + kc;
      gload_lds16(wqk_hi + off, (char*)Ah + inst * 1024);
      gload_lds16(wqk_lo + off, (char*)Al + inst * 1024);
      gload_lds16(xh + off,     (char*)Bh + inst * 1024);
      gload_lds16(xl + off,     (char*)Bl + inst * 1024);
    }
    __syncthreads();
    #pragma unroll
    for (int kk = 0; kk < 64; kk += 32){
      s16x8 ah[4], al[4], bh[4], bl[4];
      #pragma unroll
      for (int mi = 0; mi < 4; mi++){
        int idx = (wm * 64 + mi * 16 + l15) * 64 + kk + l4 * 8;
        ah[mi] = *(const s16x8*)&Ah[idx];
        al[mi] = *(const s16x8*)&Al[idx];
      }
      #pragma unroll
      for (int ni = 0; ni < 4; ni++){
        int idx = (wn * 64 + ni * 16 + l15) * 64 + kk + l4 * 8;
        bh[ni] = *(const s16x8*)&Bh[idx];
        bl[ni] = *(const s16x8*)&Bl[idx];
      }
      #pragma unroll
      for (int mi = 0; mi < 4; mi++)
        #pragma unroll
        for (int ni = 0; ni < 4; ni++){
          acc[mi][ni] = __builtin_amdgcn_mfma_f32_16x16x32_bf16(ah[mi], bh[ni], acc[mi][ni], 0, 0, 0);
          acc[mi][ni] = __builtin_amdgcn_mfma_f32_16x16x32_bf16(ah[mi], bl[ni], acc[mi][ni], 0, 0, 0);
          acc[mi][ni] = __builtin_amdgcn_mfma_f32_16x16x32_bf16(al[mi], bh[ni], acc[mi][ni], 0, 0, 0);
        }
    }
    __syncthreads();
  }
  #pragma unroll
  for (int mi = 0; mi < 4; mi++){
    #pragma unroll
    for (int r = 0; r < 4; r++){
      int o = wm * 64 + mi * 16 + l4 * 4 + r;
      float bias = bs[o];
      #pragma unroll
      for (int ni = 0; ni < 4; ni++){
        int n = nb + wn * 64 + ni * 16 + l15;
        float val = acc[mi][ni][r] + bias;
        if (o < 64) q[((size_t)(b * CQn + o)) * Nn + n]        = f2bf(val);
        else        k[((size_t)(b * CQn + o - 64)) * Nn + n]   = f2bf(val);
      }
    }
  }
}

// ============================ fused attention ============================

// per (b,w): e_h + stats + exp->p (LDS), then ohX[b,c,w,h] = sum_g p[h,g]*vT[b,w,c,g]
// (unnormalized; alpha applied in fuse). ohX layout [b][c][w][h] for streaming fuse reads.
__global__ __launch_bounds__(256) void k_att_h(const bf16* __restrict__ qT,
                                               const bf16* __restrict__ kT,
                                               const bf16* __restrict__ vT,
                                               float* __restrict__ mh,
                                               float* __restrict__ sh,
                                               bf16* __restrict__ ohX){
  __shared__ float smem[16384];                 // 64KB
  float* qs = smem;
  float* ks = smem + 8192;
  char* attb = (char*)smem;                     // phase 2: p tile, lower 32KB
  char* vbb  = (char*)smem + 32768;             // phase 2: V tile, upper 32KB
  int w = blockIdx.x, b = blockIdx.y;
  int t = threadIdx.x, lane = t & 63, wid = t >> 6;
  const bf16* qp = qT + (size_t)(b * Wn + w) * CQn * Hn;
  const bf16* kp = kT + (size_t)(b * Wn + w) * CQn * Hn;
  for (int i = t; i < 8192; i += 256){ qs[i] = bf2f(qp[i]); ks[i] = bf2f(kp[i]); }
  __syncthreads();
  int hg = t >> 3, gg = t & 7;
  float acc[4][16];
  #pragma unroll
  for (int i = 0; i < 4; i++)
    #pragma unroll
    for (int j = 0; j < 16; j++) acc[i][j] = 0.f;
  for (int c = 0; c < CQn; ++c){
    float qv[4], kv[16];
    #pragma unroll
    for (int i = 0; i < 4; i++) qv[i] = qs[c * 128 + hg * 4 + i];
    #pragma unroll
    for (int j = 0; j < 16; j++) kv[j] = ks[c * 128 + gg + 8 * j];
    #pragma unroll
    for (int i = 0; i < 4; i++)
      #pragma unroll
      for (int j = 0; j < 16; j++) acc[i][j] += qv[i] * kv[j];
  }
  float mrow[4], srow[4];
  #pragma unroll
  for (int i = 0; i < 4; i++){
    int hrow = hg * 4 + i;
    #pragma unroll
    for (int j = 0; j < 16; j++)
      if (hrow == gg + 8 * j) acc[i][j] = -1e30f;
    float m = acc[i][0];
    #pragma unroll
    for (int j = 1; j < 16; j++) m = fmaxf(m, acc[i][j]);
    m = fmaxf(m, __shfl_xor(m, 1));
    m = fmaxf(m, __shfl_xor(m, 2));
    m = fmaxf(m, __shfl_xor(m, 4));
    mrow[i] = m;
    float s = 0.f;
    #pragma unroll
    for (int j = 0; j < 16; j++){ acc[i][j] = expf(acc[i][j] - m); s += acc[i][j]; }
    s += __shfl_xor(s, 1);
    s += __shfl_xor(s, 2);
    s += __shfl_xor(s, 4);
    srow[i] = s;
  }
  __syncthreads();   // all qs/ks reads done before overwrite
  #pragma unroll
  for (int i = 0; i < 4; i++)
    #pragma unroll
    for (int j = 0; j < 16; j++){
      int h = hg * 4 + i, g = gg + 8 * j;
      bf16 bv = f2bf(acc[i][j]);
      int byte = (h * 256 + g * 2) ^ ((h & 7) << 4);
      *(unsigned short*)(attb + byte) = *(unsigned short*)&bv;
    }
  if (gg == 0){
    #pragma unroll
    for (int i = 0; i < 4; i++){
      mh[(size_t)(b * Wn + w) * Hn + hg * 4 + i] = mrow[i];
      sh[(size_t)(b * Wn + w) * Hn + hg * 4 + i] = srow[i];
    }
  }
  __syncthreads();
  // phase 2: MFMA over 4 c-tiles
  int wm = wid >> 1, wn = wid & 1;
  int l15 = lane & 15, l4 = lane >> 4;
  for (int cb = 0; cb < Cn; cb += 128){
    const bf16* vp = vT + ((size_t)(b * Wn + w) * Cn + cb) * Hn;
    for (int s = t; s < 2048; s += 256){
      int row = s >> 4, seg = s & 15;
      s16x8 d = *(const s16x8*)(vp + (size_t)row * Hn + seg * 8);
      int byte = (row * 256 + seg * 16) ^ ((row & 7) << 4);
      *(s16x8*)(vbb + byte) = d;
    }
    __syncthreads();
    f32x4 acc2[4][4];
    #pragma unroll
    for (int i = 0; i < 4; i++)
      #pragma unroll
      for (int j = 0; j < 4; j++) acc2[i][j] = (f32x4){0.f, 0.f, 0.f, 0.f};
    #pragma unroll
    for (int kk = 0; kk < 128; kk += 32){
      s16x8 a[4], bb[4];
      #pragma unroll
      for (int mi = 0; mi < 4; mi++){
        int row = wm * 64 + mi * 16 + l15;
        int byte = (row * 256 + (kk + l4 * 8) * 2) ^ ((row & 7) << 4);
        a[mi] = *(const s16x8*)(vbb + byte);
      }
      #pragma unroll
      for (int ni = 0; ni < 4; ni++){
        int row = wn * 64 + ni * 16 + l15;
        int byte = (row * 256 + (kk + l4 * 8) * 2) ^ ((row & 7) << 4);
        bb[ni] = *(const s16x8*)(attb + byte);
      }
      #pragma unroll
      for (int mi = 0; mi < 4; mi++)
        #pragma unroll
        for (int ni = 0; ni < 4; ni++)
          acc2[mi][ni] = __builtin_amdgcn_mfma_f32_16x16x32_bf16(a[mi], bb[ni], acc2[mi][ni], 0, 0, 0);
    }
    bf16* op = ohX + ((size_t)(b * Cn + cb)) * Nn + (size_t)w * Hn;
    #pragma unroll
    for (int mi = 0; mi < 4; mi++)
      #pragma unroll
      for (int r = 0; r < 4; r++){
        int cl = wm * 64 + mi * 16 + l4 * 4 + r;
        #pragma unroll
        for (int ni = 0; ni < 4; ni++){
          int h = wn * 64 + ni * 16 + l15;
          op[(size_t)cl * Nn + h] = f2bf(acc2[mi][ni][r]);
        }
      }
    __syncthreads();
  }
}

// per (b,h): e_w + stats + exp->p, then ow_raw[b,c,h,w_] = sum_v p[w_,v]*v[b,c,h,v]
__global__ __launch_bounds__(256) void k_att_w(const bf16* __restrict__ q,
                                               const bf16* __restrict__ k,
                                               const bf16* __restrict__ v,
                                               float* __restrict__ mw,
                                               float* __restrict__ sw,
                                               bf16* __restrict__ ow){
  __shared__ float smem[16384];
  float* qs = smem;
  float* ks = smem + 8192;
  char* attb = (char*)smem;
  char* vbb  = (char*)smem + 32768;
  int h = blockIdx.x, b = blockIdx.y;
  int t = threadIdx.x, lane = t & 63, wid = t >> 6;
  for (int i = t; i < 8192; i += 256){
    int c = i >> 7, wl = i & 127;
    size_t base = ((size_t)(b * CQn + c) * Hn + h) * Wn + wl;
    qs[i] = bf2f(q[base]);
    ks[i] = bf2f(k[base]);
  }
  __syncthreads();
  int wg = t >> 3, vg = t & 7;
  float acc[4][16];
  #pragma unroll
  for (int i = 0; i < 4; i++)
    #pragma unroll
    for (int j = 0; j < 16; j++) acc[i][j] = 0.f;
  for (int c = 0; c < CQn; ++c){
    float qv[4], kv[16];
    #pragma unroll
    for (int i = 0; i < 4; i++) qv[i] = qs[c * 128 + wg * 4 + i];
    #pragma unroll
    for (int j = 0; j < 16; j++) kv[j] = ks[c * 128 + vg + 8 * j];
    #pragma unroll
    for (int i = 0; i < 4; i++)
      #pragma unroll
      for (int j = 0; j < 16; j++) acc[i][j] += qv[i] * kv[j];
  }
  float mrow[4], srow[4];
  #pragma unroll
  for (int i = 0; i < 4; i++){
    float m = acc[i][0];
    #pragma unroll
    for (int j = 1; j < 16; j++) m = fmaxf(m, acc[i][j]);
    m = fmaxf(m, __shfl_xor(m, 1));
    m = fmaxf(m, __shfl_xor(m, 2));
    m = fmaxf(m, __shfl_xor(m, 4));
    mrow[i] = m;
    float s = 0.f;
    #pragma unroll
    for (int j = 0; j < 16; j++){ acc[i][j] = expf(acc[i][j] - m); s += acc[i][j]; }
    s += __shfl_xor(s, 1);
    s += __shfl_xor(s, 2);
    s += __shfl_xor(s, 4);
    srow[i] = s;
  }
  __syncthreads();
  #pragma unroll
  for (int i = 0; i < 4; i++)
    #pragma unroll
    for (int j = 0; j < 16; j++){
      int wr = wg * 4 + i, g = vg + 8 * j;
      bf16 bv = f2bf(acc[i][j]);
      int byte = (wr * 256 + g * 2) ^ ((wr & 7) << 4);
      *(unsigned short*)(attb + byte) = *(unsigned short*)&bv;
    }
  if (vg == 0){
    #pragma unroll
    for (int i = 0; i < 4; i++){
      mw[(size_t)(b * Hn + h) * Wn + wg * 4 + i] = mrow[i];
      sw[(size_t)(b * Hn + h) * Wn + wg * 4 + i] = srow[i];
    }
  }
  __syncthreads();
  int wm = wid >> 1, wn = wid & 1;
  int l15 = lane & 15, l4 = lane >> 4;
  for (int cb = 0; cb < Cn; cb += 128){
    const bf16* vp = v + (size_t)(b * Cn + cb) * Nn + (size_t)h * Wn;
    for (int s = t; s < 2048; s += 256){
      int row = s >> 4, seg = s & 15;
      s16x8 d = *(const s16x8*)(vp + (size_t)row * Nn + seg * 8);
      int byte = (row * 256 + seg * 16) ^ ((row & 7) << 4);
      *(s16x8*)(vbb + byte) = d;
    }
    __syncthreads();
    f32x4 acc2[4][4];
    #pragma unroll
    for (int i = 0; i < 4; i++)
      #pragma unroll
      for (int j = 0; j < 4; j++) acc2[i][j] = (f32x4){0.f, 0.f, 0.f, 0.f};
    #pragma unroll
    for (int kk = 0; kk < 128; kk += 32){
      s16x8 a[4], bb[4];
      #pragma unroll
      for (int mi = 0; mi < 4; mi++){
        int row = wm * 64 + mi * 16 + l15;
        int byte = (row * 256 + (kk + l4 * 8) * 2) ^ ((row & 7) << 4);
        a[mi] = *(const s16x8*)(vbb + byte);
      }
      #pragma unroll
      for (int ni = 0; ni < 4; ni++){
        int row = wn * 64 + ni * 16 + l15;
        int byte = (row * 256 + (kk + l4 * 8) * 2) ^ ((row & 7) << 4);
        bb[ni] = *(const s16x8*)(attb + byte);
      }
      #pragma unroll
      for (int mi = 0; mi < 4; mi++)
        #pragma unroll
        for (int ni = 0; ni < 4; ni++)
          acc2[mi][ni] = __builtin_amdgcn_mfma_f32_16x16x32_bf16(a[mi], bb[ni], acc2[mi][ni], 0, 0, 0);
    }
    bf16* op = ow + (size_t)(b * Cn + cb) * Nn + (size_t)h * Wn;
    #pragma unroll
    for (int mi = 0; mi < 4; mi++)
      #pragma unroll
      for (int r = 0; r < 4; r++){
        int cl = wm * 64 + mi * 16 + l4 * 4 + r;
        #pragma unroll
        for (int ni = 0; ni < 4; ni++){
          int wr = wn * 64 + ni * 16 + l15;
          op[(size_t)cl * Nn + wr] = f2bf(acc2[mi][ni][r]);
        }
      }
    __syncthreads();
  }
}

// merge stats -> alphas, both in [b,h,w] layout for fuse
__global__ __launch_bounds__(256) void k_alpha(const float* __restrict__ mh,
                                               const float* __restrict__ sh,
                                               const float* __restrict__ mw,
                                               const float* __restrict__ sw,
                                               float* __restrict__ ahT,
                                               float* __restrict__ aw){
  int t = blockIdx.x * 256 + threadIdx.x;   // (b*Hn+h)*Wn + w
  int b = t >> 14;
  int hw = t & (Nn - 1);
  int h = hw >> 7, w = hw & 127;
  size_t ih = (size_t)(b * Wn + w) * Hn + h;
  size_t iw = t;
  float mhv = mh[ih], mwv = mw[iw];
  float M = fmaxf(mhv, mwv);
  float eh_ = expf(mhv - M), ew_ = expf(mwv - M);
  float inv = 1.f / (sh[ih] * eh_ + sw[iw] * ew_);
  ahT[t] = eh_ * inv;
  aw[t]  = ew_ * inv;
}

// ============================ remaining CA kernels ============================

__global__ __launch_bounds__(256) void k_trans(const bf16* __restrict__ in,
                                               bf16* __restrict__ out,
                                               int CH){
  __shared__ bf16 tile[32][33];
  int tl = blockIdx.x, c = blockIdx.y, b = blockIdx.z;
  int th = tl >> 2, tw = tl & 3;
  int h0 = th * 32, w0 = tw * 32;
  int t = threadIdx.x;
  const bf16* ip = in + ((size_t)(b * CH + c)) * Nn;
  #pragma unroll
  for (int kk = 0; kk < 4; ++kk){
    int idx = t + kk * 256;
    int hl = idx >> 5, wl = idx & 31;
    tile[hl][wl] = ip[(h0 + hl) * Wn + w0 + wl];
  }
  __syncthreads();
  #pragma unroll
  for (int kk = 0; kk < 4; ++kk){
    int idx = t + kk * 256;
    int wl = idx >> 5, hl = idx & 31;
    out[((size_t)(b * Wn + w0 + wl) * CH + c) * Hn + h0 + hl] = tile[hl][wl];
  }
}

// out = gamma*(ah*ohX^T + aw*ow) + resid (+ addend)
// resid = in * (maskc?mch[c]:1) * (maskn?msp[n]:1)  — recomputes cc/cs exactly.
// ohX layout [b][c][w][h]: per-block read is one contiguous 32KB stream.
__global__ __launch_bounds__(256) void k_fuse2(const float* __restrict__ in,
                                               const float* __restrict__ maskc,
                                               const float* __restrict__ maskn,
                                               const bf16* __restrict__ ohX,
                                               const bf16* __restrict__ ow,
                                               const float* __restrict__ ahT,
                                               const float* __restrict__ aw,
                                               const float* __restrict__ addend,
                                               const float* __restrict__ gamma,
                                               float* __restrict__ out){
  __shared__ unsigned short tileT[128][138];
  int c = blockIdx.x, b = blockIdx.y;
  int t = threadIdx.x;
  float g = gamma[0];
  float mc = maskc ? maskc[b * Cn + c] : 1.f;
  const bf16* ohp = ohX + ((size_t)(b * Cn + c)) * Nn;   // contiguous [w][h]
  #pragma unroll
  for (int i = 0; i < 8; ++i){
    int s = t + i * 256;            // 0..2047
    int w = s >> 4, seg = s & 15;
    s16x8 d = *(const s16x8*)(ohp + (size_t)s * 8);
    #pragma unroll
    for (int j = 0; j < 8; ++j)
      tileT[seg * 8 + j][w] = (unsigned short)d[j];
  }
  __syncthreads();
  size_t base = ((size_t)(b * Cn + c)) * Nn;
  #pragma unroll
  for (int i = 0; i < 16; ++i){
    int o = t + i * 256;            // 0..4095
    int h = o >> 5, w4 = (o & 31) * 4;
    size_t idx = base + (size_t)h * Wn + w4;
    size_t aidx = (size_t)b * Nn + (size_t)h * Wn + w4;
    float4 inv = *(const float4*)(in + idx);
    ushort4 owv = *(const ushort4*)((const unsigned short*)ow + idx);
    float4 ah4 = *(const float4*)(ahT + aidx);
    float4 aw4 = *(const float4*)(aw + aidx);
    float4 mn4 = maskn ? *(const float4*)(maskn + aidx) : (float4){1.f,1.f,1.f,1.f};
    float r[4];
    #pragma unroll
    for (int j = 0; j < 4; ++j){
      unsigned short uh = tileT[h][w4 + j];
      unsigned short uo = ((const unsigned short*)&owv)[j];
      float ohv = bf2f(*(bf16*)&uh);
      float owf = bf2f(*(bf16*)&uo);
      float iv  = ((const float*)&inv)[j] * mc * ((const float*)&mn4)[j];
      float ahv = ((const float*)&ah4)[j];
      float awv = ((const float*)&aw4)[j];
      r[j] = g * (ahv * ohv + awv * owf) + iv;
    }
    if (addend){
      float4 av = *(const float4*)(addend + idx);
      r[0] += av.x; r[1] += av.y; r[2] += av.z; r[3] += av.w;
    }
    float4 o4 = { r[0], r[1], r[2], r[3] };
    *(float4*)(out + idx) = o4;
  }
}

// ============================ host ============================

static void run_ca(const float* resid, const float* maskc, const float* maskn,
                   const bf16* wqk_hi, const bf16* wqk_lo,
                   const float* bqk, const bf16* wvb, const float* bv,
                   const float* gamma, const float* addend, float* out,
                   bf16* q, bf16* k, bf16* qT, bf16* kT, bf16* v, bf16* vT,
                   float* mh, float* sh, float* mw, float* sw, float* ahT, float* aw,
                   bf16* xT_hi, bf16* xT_lo, bf16* tmp, hipStream_t stream){
  bf16* ohX = tmp;
  bf16* ow  = tmp + (size_t)Bn * Cn * Nn;
  k_qk_mfma<<<dim3(Nn / 128, Bn), 256, 0, stream>>>(xT_hi, xT_lo, wqk_hi, wqk_lo, bqk, q, k);
  k_trans<<<dim3(16, CQn, Bn), 256, 0, stream>>>(q, qT, CQn);
  k_trans<<<dim3(16, CQn, Bn), 256, 0, stream>>>(k, kT, CQn);
  k_v_mfma<<<2048, 256, 0, stream>>>(xT_hi, wvb, bv, v);
  k_trans<<<dim3(16, Cn, Bn), 256, 0, stream>>>(v, vT, Cn);
  k_att_h<<<dim3(Wn, Bn), 256, 0, stream>>>(qT, kT, vT, mh, sh, ohX);
  k_att_w<<<dim3(Hn, Bn), 256, 0, stream>>>(q, k, v, mw, sw, ow);
  k_alpha<<<Bn * Nn / 256, 256, 0, stream>>>(mh, sh, mw, sw, ahT, aw);
  k_fuse2<<<dim3(Cn, Bn), 256, 0, stream>>>(resid, maskc, maskn, ohX, ow, ahT, aw,
                                            addend, gamma, out);
}

extern "C" void kernel_launch(void* const* d_in, const int* in_sizes, int n_in,
                              void* d_out, int out_size, void* d_ws, size_t ws_size,
                              hipStream_t stream){
  (void)in_sizes; (void)n_in; (void)out_size; (void)ws_size;
  const float* x         = (const float*)d_in[0];
  const float* w_q_right = (const float*)d_in[1];
  const float* w_v_right = (const float*)d_in[2];
  const float* w_up      = (const float*)d_in[3];
  const float* b_up      = (const float*)d_in[4];
  const float* w_q_left  = (const float*)d_in[5];
  const float* w_v_left  = (const float*)d_in[6];
  const float* wq        = (const float*)d_in[7];
  const float* bq        = (const float*)d_in[8];
  const float* wk        = (const float*)d_in[9];
  const float* bk        = (const float*)d_in[10];
  const float* wv        = (const float*)d_in[11];
  const float* bv        = (const float*)d_in[12];
  const float* gamma     = (const float*)d_in[13];

  const size_t SZ_MAP = (size_t)Bn * Cn * Nn;     // 33.5M elements
  char* p = (char*)d_ws;
  float* buf0   = (float*)p; p += SZ_MAP * 4;
  float* buf1   = (float*)p; p += SZ_MAP * 4;     // CA3 tmp (ohX/ow)
  bf16*  vbuf   = (bf16*)p;  p += SZ_MAP * 2;
  bf16*  vT     = (bf16*)p;  p += SZ_MAP * 2;
  bf16*  qbuf   = (bf16*)p;  p += (size_t)Bn * CQn * Nn * 2;
  bf16*  kbuf   = (bf16*)p;  p += (size_t)Bn * CQn * Nn * 2;
  bf16*  qT     = (bf16*)p;  p += (size_t)Bn * CQn * Nn * 2;
  bf16*  kT     = (bf16*)p;  p += (size_t)Bn * CQn * Nn * 2;
  float* ebuf   = (float*)p; p += (size_t)SZ_MAP * 2;         // xT_hi arena (67MB)
  float* logits = (float*)p; p += (size_t)Bn * Nn * 4;
  float* ctxlog = (float*)p; p += (size_t)Bn * Nn * 4;
  float* msp    = (float*)p; p += (size_t)Bn * Nn * 4;
  float* xbar   = (float*)p; p += Bn * Cn * 4;
  float* wgt    = (float*)p; p += Bn * Cn * 4;
  float* u      = (float*)p; p += Bn * Cn * 4;
  float* mch    = (float*)p; p += Bn * Cn * 4;
  float* avg    = (float*)p; p += Bn * CIn * 4;
  float* ctx    = (float*)p; p += Bn * CIn * 4;
  float* stats_sp = (float*)p; p += 64;
  float* stats_ch = (float*)p; p += 64;
  bf16*  wvb    = (bf16*)p;  p += (size_t)Cn * Cn * 2;
  bf16*  wqk_hi = (bf16*)p;  p += (size_t)128 * Cn * 2;
  bf16*  wqk_lo = (bf16*)p;  p += (size_t)128 * Cn * 2;
  float* bqk    = (float*)p; p += 128 * 4;
  float* mh     = (float*)p; p += (size_t)Bn * Nn * 4;
  float* sh     = (float*)p; p += (size_t)Bn * Nn * 4;
  float* mw     = (float*)p; p += (size_t)Bn * Nn * 4;
  float* sw     = (float*)p; p += (size_t)Bn * Nn * 4;
  float* ahT    = (float*)p; p += (size_t)Bn * Nn * 4;
  float* aw     = (float*)p; p += (size_t)Bn * Nn * 4;

  bf16*  xT_hi  = (bf16*)ebuf;    // dead after v_mfma of each CA
  bf16*  xT_lo  = (bf16*)d_out;   // dead before attention writes d_out (CA1/CA2 tmp)

  // ---- weight prep (once) ----
  k_cvt_w<<<(Cn * Cn + 255) / 256, 256, 0, stream>>>(wv, wvb, Cn * Cn);
  k_prep_wqk<<<(128 * Cn) / 256, 256, 0, stream>>>(wq, wk, bq, bk, wqk_hi, wqk_lo, bqk);

  // ---- stage 0: gating masks ----
  k_dotc<<<Bn * Nn / 256, 256, 0, stream>>>(x, w_q_right, 0, logits);
  k_rowmean<<<Bn * Cn, 256, 0, stream>>>(x, xbar, 1.f / Nn);
  k_rowdot<<<Bn, 256, 0, stream>>>(w_q_left, xbar, avg);
  k_coldot<<<dim3(Cn / 256, Bn), 256, 0, stream>>>(w_v_left, avg, u);
  k_stats<<<Bn, 1024, 0, stream>>>(logits, stats_sp);
  k_weighted<<<Bn * Cn, 256, 0, stream>>>(x, logits, stats_sp, wgt);
  k_rowdot<<<Bn, 256, 0, stream>>>(w_v_right, wgt, ctx);
  k_mch2<<<dim3(Cn / 256, Bn), 256, 0, stream>>>(w_up, b_up, ctx, mch);
  k_dotc<<<Bn * Nn / 256, 256, 0, stream>>>(x, u, Cn, ctxlog);
  k_stats<<<Bn, 1024, 0, stream>>>(ctxlog, stats_ch);
  k_msp<<<Bn * Nn / 256, 256, 0, stream>>>(ctxlog, stats_ch, msp);

  // ---- CA1: in = cc = x*mch (recomputed in fuse); out = buf0; tmp = d_out ----
  k_applyT2<<<dim3(Nn / 32, Cn / 32, Bn), 256, 0, stream>>>(x, mch, xT_hi, xT_lo);
  run_ca(x, mch, nullptr, wqk_hi, wqk_lo, bqk, wvb, bv, gamma, nullptr, buf0,
         qbuf, kbuf, qT, kT, vbuf, vT, mh, sh, mw, sw, ahT, aw,
         xT_hi, xT_lo, (bf16*)d_out, stream);
  // ---- CA2: in = cs = x*msp; addend = buf0 (cc'); out = buf0; tmp = d_out ----
  k_cvt_T2<<<dim3(Nn / 32, Cn / 32, Bn), 256, 0, stream>>>(x, msp, xT_hi, xT_lo);
  run_ca(x, nullptr, msp, wqk_hi, wqk_lo, bqk, wvb, bv, gamma, buf0, buf0,
         qbuf, kbuf, qT, kT, vbuf, vT, mh, sh, mw, sw, ahT, aw,
         xT_hi, xT_lo, (bf16*)d_out, stream);
  // ---- CA3: in = s = buf0; out = d_out; tmp = buf1 ----
  k_cvt_T<<<dim3(Nn / 32, Cn / 32, Bn), 256, 0, stream>>>(buf0, xT_hi, xT_lo);
  run_ca(buf0, nullptr, nullptr, wqk_hi, wqk_lo, bqk, wvb, bv, gamma, nullptr,
         (float*)d_out,
         qbuf, kbuf, qT, kT, vbuf, vT, mh, sh, mw, sw, ahT, aw,
         xT_hi, xT_lo, (bf16*)buf1, stream);
}

// Round 12
// 1387.014 us; speedup vs baseline: 2.9315x; 1.0095x over previous
//
#include <hip/hip_runtime.h>
#include <hip/hip_bf16.h>
#include <math.h>

typedef __hip_bfloat16 bf16;
typedef __attribute__((ext_vector_type(8))) short s16x8;
typedef __attribute__((ext_vector_type(4))) float f32x4;

constexpr int Bn  = 4;
constexpr int Cn  = 512;
constexpr int Hn  = 128;
constexpr int Wn  = 128;
constexpr int Nn  = Hn * Wn;   // 16384
constexpr int CQn = 64;
constexpr int CIn = 256;

__device__ __forceinline__ float bf2f(bf16 v){ return __bfloat162float(v); }
__device__ __forceinline__ bf16  f2bf(float v){ return __float2bfloat16(v); }

// async global->LDS, 16B per lane; LDS dest must be wave-uniform base (HW adds lane*16)
__device__ __forceinline__ void gload_lds16(const void* g, void* l){
  __builtin_amdgcn_global_load_lds(
      (const __attribute__((address_space(1))) unsigned int*)g,
      (__attribute__((address_space(3))) unsigned int*)l,
      16, 0, 0);
}

// ============================ stage 0 ============================

__global__ __launch_bounds__(256) void k_dotc(const float* __restrict__ x,
                                              const float* __restrict__ w,
                                              int wstride,
                                              float* __restrict__ out){
  int t = blockIdx.x * 256 + threadIdx.x;      // over B*Nn
  int b = t >> 14;
  const float* wp = w + (size_t)b * wstride;
  const float* xp = x + (size_t)b * Cn * Nn + (t & (Nn - 1));
  float acc = 0.f;
  #pragma unroll 8
  for (int c = 0; c < Cn; ++c) acc += wp[c] * xp[(size_t)c * Nn];
  out[t] = acc;
}

__global__ __launch_bounds__(256) void k_rowmean(const float* __restrict__ x,
                                                 float* __restrict__ out,
                                                 float scale){
  int bc = blockIdx.x;
  const float* xp = x + (size_t)bc * Nn;
  float acc = 0.f;
  for (int n = threadIdx.x; n < Nn; n += 256) acc += xp[n];
  for (int o = 32; o > 0; o >>= 1) acc += __shfl_down(acc, o);
  __shared__ float red[4];
  if ((threadIdx.x & 63) == 0) red[threadIdx.x >> 6] = acc;
  __syncthreads();
  if (threadIdx.x == 0) out[bc] = (red[0] + red[1] + red[2] + red[3]) * scale;
}

__global__ __launch_bounds__(256) void k_rowdot(const float* __restrict__ W,
                                                const float* __restrict__ vec,
                                                float* __restrict__ out){
  __shared__ float vs[Cn];
  int b = blockIdx.x, t = threadIdx.x;
  for (int j = t; j < Cn; j += 256) vs[j] = vec[b * Cn + j];
  __syncthreads();
  const float4* wp = (const float4*)(W + (size_t)t * Cn);
  float a = 0.f;
  #pragma unroll 4
  for (int j = 0; j < Cn / 4; ++j){
    float4 w4 = wp[j];
    a += w4.x * vs[4*j] + w4.y * vs[4*j+1] + w4.z * vs[4*j+2] + w4.w * vs[4*j+3];
  }
  out[b * CIn + t] = a;
}

__global__ __launch_bounds__(256) void k_coldot(const float* __restrict__ W,
                                                const float* __restrict__ vec,
                                                float* __restrict__ out){
  __shared__ float vs[CIn];
  int b = blockIdx.y, t = threadIdx.x;
  int c = blockIdx.x * 256 + t;
  if (t < CIn) vs[t] = vec[b * CIn + t];
  __syncthreads();
  float a = 0.f;
  #pragma unroll 8
  for (int j = 0; j < CIn; ++j) a += W[(size_t)j * Cn + c] * vs[j];
  out[b * Cn + c] = a;
}

__global__ __launch_bounds__(256) void k_mch2(const float* __restrict__ w_up,
                                              const float* __restrict__ b_up,
                                              const float* __restrict__ ctx,
                                              float* __restrict__ mch){
  __shared__ float cs[CIn];
  int b = blockIdx.y, t = threadIdx.x;
  int o = blockIdx.x * 256 + t;
  if (t < CIn) cs[t] = ctx[b * CIn + t];
  __syncthreads();
  const float4* wp = (const float4*)(w_up + (size_t)o * CIn);
  float a = b_up[o];
  #pragma unroll 4
  for (int j = 0; j < CIn / 4; ++j){
    float4 w4 = wp[j];
    a += w4.x * cs[4*j] + w4.y * cs[4*j+1] + w4.z * cs[4*j+2] + w4.w * cs[4*j+3];
  }
  mch[b * Cn + o] = 1.f / (1.f + expf(-a));
}

__global__ __launch_bounds__(1024) void k_stats(const float* __restrict__ vv,
                                                float* __restrict__ stats){
  int b = blockIdx.x;
  const float* pp = vv + (size_t)b * Nn;
  int t = threadIdx.x;
  float m = -3.4e38f;
  for (int n = t; n < Nn; n += 1024) m = fmaxf(m, pp[n]);
  for (int o = 32; o > 0; o >>= 1) m = fmaxf(m, __shfl_down(m, o));
  __shared__ float red[16];
  int wid = t >> 6, lid = t & 63;
  if (lid == 0) red[wid] = m;
  __syncthreads();
  if (t == 0){
    float q = red[0];
    for (int i = 1; i < 16; i++) q = fmaxf(q, red[i]);
    red[0] = q;
  }
  __syncthreads();
  m = red[0];
  __syncthreads();
  float s = 0.f;
  for (int n = t; n < Nn; n += 1024) s += expf(pp[n] - m);
  for (int o = 32; o > 0; o >>= 1) s += __shfl_down(s, o);
  if (lid == 0) red[wid] = s;
  __syncthreads();
  if (t == 0){
    float q = 0.f;
    for (int i = 0; i < 16; i++) q += red[i];
    stats[b * 2]     = m;
    stats[b * 2 + 1] = q;
  }
}

__global__ __launch_bounds__(256) void k_weighted(const float* __restrict__ x,
                                                  const float* __restrict__ logits,
                                                  const float* __restrict__ stats,
                                                  float* __restrict__ out){
  int bc = blockIdx.x;
  int b = bc >> 9;
  const float* xp = x + (size_t)bc * Nn;
  const float* lp = logits + (size_t)b * Nn;
  float m = stats[b * 2], den = stats[b * 2 + 1];
  float acc = 0.f;
  for (int n = threadIdx.x; n < Nn; n += 256) acc += xp[n] * expf(lp[n] - m);
  for (int o = 32; o > 0; o >>= 1) acc += __shfl_down(acc, o);
  __shared__ float red[4];
  if ((threadIdx.x & 63) == 0) red[threadIdx.x >> 6] = acc;
  __syncthreads();
  if (threadIdx.x == 0) out[bc] = (red[0] + red[1] + red[2] + red[3]) / den;
}

__global__ __launch_bounds__(256) void k_msp(const float* __restrict__ lg,
                                             const float* __restrict__ stats,
                                             float* __restrict__ msp){
  int t = blockIdx.x * 256 + threadIdx.x;
  int b = t >> 14;
  float v = expf(lg[t] - stats[b * 2]) / stats[b * 2 + 1];
  msp[t] = 1.f / (1.f + expf(-v));
}

// ccT hi/lo only (cc = x*mch recomputed in fuse)
__global__ __launch_bounds__(256) void k_applyT2(const float* __restrict__ x,
                                                 const float* __restrict__ mch,
                                                 bf16* __restrict__ out_hi,
                                                 bf16* __restrict__ out_lo){
  __shared__ bf16 th_[32][33];
  __shared__ bf16 tl_[32][33];
  int nt = blockIdx.x, ct = blockIdx.y, b = blockIdx.z;
  int n0 = nt * 32, c0 = ct * 32;
  int t = threadIdx.x;
  #pragma unroll
  for (int kk = 0; kk < 4; ++kk){
    int idx = t + kk * 256;
    int cl = idx >> 5, nl = idx & 31;
    float v = x[((size_t)(b * Cn + c0 + cl)) * Nn + n0 + nl] * mch[b * Cn + c0 + cl];
    bf16 h = f2bf(v);
    th_[cl][nl] = h;
    tl_[cl][nl] = f2bf(v - bf2f(h));
  }
  __syncthreads();
  #pragma unroll
  for (int kk = 0; kk < 4; ++kk){
    int idx = t + kk * 256;
    int nl = idx >> 5, cl = idx & 31;
    size_t o = ((size_t)(b * Nn + n0 + nl)) * Cn + c0 + cl;
    out_hi[o] = th_[cl][nl];
    out_lo[o] = tl_[cl][nl];
  }
}

// csT hi/lo (cs = x*msp recomputed in fuse)
__global__ __launch_bounds__(256) void k_cvt_T2(const float* __restrict__ x,
                                                const float* __restrict__ msp,
                                                bf16* __restrict__ out_hi,
                                                bf16* __restrict__ out_lo){
  __shared__ bf16 th_[32][33];
  __shared__ bf16 tl_[32][33];
  int nt = blockIdx.x, ct = blockIdx.y, b = blockIdx.z;
  int n0 = nt * 32, c0 = ct * 32;
  int t = threadIdx.x;
  #pragma unroll
  for (int kk = 0; kk < 4; ++kk){
    int idx = t + kk * 256;
    int cl = idx >> 5, nl = idx & 31;
    float v = x[((size_t)(b * Cn + c0 + cl)) * Nn + n0 + nl] * msp[b * Nn + n0 + nl];
    bf16 h = f2bf(v);
    th_[cl][nl] = h;
    tl_[cl][nl] = f2bf(v - bf2f(h));
  }
  __syncthreads();
  #pragma unroll
  for (int kk = 0; kk < 4; ++kk){
    int idx = t + kk * 256;
    int nl = idx >> 5, cl = idx & 31;
    size_t o = ((size_t)(b * Nn + n0 + nl)) * Cn + c0 + cl;
    out_hi[o] = th_[cl][nl];
    out_lo[o] = tl_[cl][nl];
  }
}

// ============================ conversions ============================

__global__ __launch_bounds__(256) void k_cvt_w(const float* __restrict__ in,
                                               bf16* __restrict__ out, int n){
  int t = blockIdx.x * 256 + threadIdx.x;
  if (t < n) out[t] = f2bf(in[t]);
}

__global__ __launch_bounds__(256) void k_prep_wqk(const float* __restrict__ wq,
                                                  const float* __restrict__ wk,
                                                  const float* __restrict__ bq,
                                                  const float* __restrict__ bk,
                                                  bf16* __restrict__ wqk_hi,
                                                  bf16* __restrict__ wqk_lo,
                                                  float* __restrict__ bqk){
  int t = blockIdx.x * 256 + threadIdx.x;   // over 128*512
  int o = t >> 9, c = t & 511;
  float v = (o < 64) ? wq[(size_t)o * Cn + c] : wk[(size_t)(o - 64) * Cn + c];
  bf16 h = f2bf(v);
  wqk_hi[t] = h;
  wqk_lo[t] = f2bf(v - bf2f(h));
  if (t < 128) bqk[t] = (t < 64) ? bq[t] : bk[t - 64];
}

__global__ __launch_bounds__(256) void k_cvt_T(const float* __restrict__ in,
                                               bf16* __restrict__ out_hi,
                                               bf16* __restrict__ out_lo){
  __shared__ bf16 th_[32][33];
  __shared__ bf16 tl_[32][33];
  int nt = blockIdx.x, ct = blockIdx.y, b = blockIdx.z;
  int n0 = nt * 32, c0 = ct * 32;
  int t = threadIdx.x;
  #pragma unroll
  for (int kk = 0; kk < 4; ++kk){
    int idx = t + kk * 256;
    int cl = idx >> 5, nl = idx & 31;
    float v = in[((size_t)(b * Cn + c0 + cl)) * Nn + n0 + nl];
    bf16 h = f2bf(v);
    th_[cl][nl] = h;
    tl_[cl][nl] = f2bf(v - bf2f(h));
  }
  __syncthreads();
  #pragma unroll
  for (int kk = 0; kk < 4; ++kk){
    int idx = t + kk * 256;
    int nl = idx >> 5, cl = idx & 31;
    size_t o = ((size_t)(b * Nn + n0 + nl)) * Cn + c0 + cl;
    out_hi[o] = th_[cl][nl];
    out_lo[o] = tl_[cl][nl];
  }
}

// q/k [b][c(64)][h][w] -> [b][w][h][c]  (c-contiguous for MFMA frags)
__global__ __launch_bounds__(256) void k_trans4(const bf16* __restrict__ in,
                                                bf16* __restrict__ out){
  __shared__ bf16 tile[64][33];
  int wt = blockIdx.x, h = blockIdx.y, b = blockIdx.z;
  int w0 = wt * 32, t = threadIdx.x;
  #pragma unroll
  for (int i = 0; i < 8; ++i){
    int s = t + i * 256;
    int c = s >> 5, wl = s & 31;
    tile[c][wl] = in[((size_t)(b * CQn + c) * Hn + h) * Wn + w0 + wl];
  }
  __syncthreads();
  #pragma unroll
  for (int i = 0; i < 8; ++i){
    int s = t + i * 256;
    int wl = s >> 6, c = s & 63;
    out[(((size_t)b * Wn + w0 + wl) * Hn + h) * CQn + c] = tile[c][wl];
  }
}

// ============================ MFMA GEMMs ============================

// V = Wv @ X. 128x128 tile, BK=64. XCD-chunked 1D grid of 2048.
__global__ __launch_bounds__(256) void k_v_mfma(const bf16* __restrict__ xT,
                                                const bf16* __restrict__ wvb,
                                                const float* __restrict__ bv,
                                                bf16* __restrict__ v){
  __shared__ short As[128 * 64];
  __shared__ short Bs[128 * 64];
  __shared__ float bvs[128];
  int lin = blockIdx.x;
  int swz = (lin & 7) * 256 + (lin >> 3);
  int cb = (swz & 3) * 128;
  int nb = ((swz >> 2) & 127) * 128;
  int b  = swz >> 9;
  int t = threadIdx.x, lane = t & 63, wid = t >> 6;
  int wm = wid >> 1, wn = wid & 1;
  int l15 = lane & 15, l4 = lane >> 4;
  if (t < 128) bvs[t] = bv[cb + t];
  f32x4 acc[4][4];
  #pragma unroll
  for (int i = 0; i < 4; i++)
    #pragma unroll
    for (int j = 0; j < 4; j++) acc[i][j] = (f32x4){0.f, 0.f, 0.f, 0.f};

  const bf16* wp = wvb + (size_t)cb * Cn;
  const bf16* xp = xT + ((size_t)b * Nn + nb) * Cn;
  int r8 = lane >> 3;
  int kc = (lane & 7) * 8;
  for (int kt = 0; kt < 8; ++kt){
    int k0 = kt * 64;
    #pragma unroll
    for (int j = 0; j < 4; ++j){
      int inst = wid * 4 + j;
      int row = inst * 8 + r8;
      gload_lds16(wp + (size_t)row * Cn + k0 + kc, (char*)As + inst * 1024);
      gload_lds16(xp + (size_t)row * Cn + k0 + kc, (char*)Bs + inst * 1024);
    }
    __syncthreads();
    #pragma unroll
    for (int kk = 0; kk < 64; kk += 32){
      s16x8 a[4], bb[4];
      #pragma unroll
      for (int mi = 0; mi < 4; mi++)
        a[mi] = *(const s16x8*)&As[(wm * 64 + mi * 16 + l15) * 64 + kk + l4 * 8];
      #pragma unroll
      for (int ni = 0; ni < 4; ni++)
        bb[ni] = *(const s16x8*)&Bs[(wn * 64 + ni * 16 + l15) * 64 + kk + l4 * 8];
      #pragma unroll
      for (int mi = 0; mi < 4; mi++)
        #pragma unroll
        for (int ni = 0; ni < 4; ni++)
          acc[mi][ni] = __builtin_amdgcn_mfma_f32_16x16x32_bf16(a[mi], bb[ni], acc[mi][ni], 0, 0, 0);
    }
    __syncthreads();
  }
  #pragma unroll
  for (int mi = 0; mi < 4; mi++){
    #pragma unroll
    for (int r = 0; r < 4; r++){
      int cl = wm * 64 + mi * 16 + l4 * 4 + r;
      int c  = cb + cl;
      float bias = bvs[cl];
      #pragma unroll
      for (int ni = 0; ni < 4; ni++){
        int n = nb + wn * 64 + ni * 16 + l15;
        v[((size_t)(b * Cn + c)) * Nn + n] = f2bf(acc[mi][ni][r] + bias);
      }
    }
  }
}

// Q,K = [Wq;Wk] @ X with split-precision bf16 (3 MFMA terms).
__global__ __launch_bounds__(256) void k_qk_mfma(const bf16* __restrict__ xT_hi,
                                                 const bf16* __restrict__ xT_lo,
                                                 const bf16* __restrict__ wqk_hi,
                                                 const bf16* __restrict__ wqk_lo,
                                                 const float* __restrict__ bqk,
                                                 bf16* __restrict__ q,
                                                 bf16* __restrict__ k){
  __shared__ short Ah[128 * 64];
  __shared__ short Al[128 * 64];
  __shared__ short Bh[128 * 64];
  __shared__ short Bl[128 * 64];
  __shared__ float bs[128];
  int nb = blockIdx.x * 128, b = blockIdx.y;
  int t = threadIdx.x, lane = t & 63, wid = t >> 6;
  int wm = wid >> 1, wn = wid & 1;
  int l15 = lane & 15, l4 = lane >> 4;
  if (t < 128) bs[t] = bqk[t];
  f32x4 acc[4][4];
  #pragma unroll
  for (int i = 0; i < 4; i++)
    #pragma unroll
    for (int j = 0; j < 4; j++) acc[i][j] = (f32x4){0.f, 0.f, 0.f, 0.f};

  const bf16* xh = xT_hi + ((size_t)b * Nn + nb) * Cn;
  const bf16* xl = xT_lo + ((size_t)b * Nn + nb) * Cn;
  int r8 = lane >> 3;
  int kc = (lane & 7) * 8;
  for (int kt = 0; kt < 8; ++kt){
    int k0 = kt * 64;
    #pragma unroll
    for (int j = 0; j < 4; ++j){
      int inst = wid * 4 + j;
      int row = inst * 8 + r8;
      size_t off = (size_t)row * Cn + k0 + kc;
      gload_lds16(wqk_hi + off, (char*)Ah + inst * 1024);
      gload_lds16(wqk_lo + off, (char*)Al + inst * 1024);
      gload_lds16(xh + off,     (char*)Bh + inst * 1024);
      gload_lds16(xl + off,     (char*)Bl + inst * 1024);
    }
    __syncthreads();
    #pragma unroll
    for (int kk = 0; kk < 64; kk += 32){
      s16x8 ah[4], al[4], bh[4], bl[4];
      #pragma unroll
      for (int mi = 0; mi < 4; mi++){
        int idx = (wm * 64 + mi * 16 + l15) * 64 + kk + l4 * 8;
        ah[mi] = *(const s16x8*)&Ah[idx];
        al[mi] = *(const s16x8*)&Al[idx];
      }
      #pragma unroll
      for (int ni = 0; ni < 4; ni++){
        int idx = (wn * 64 + ni * 16 + l15) * 64 + kk + l4 * 8;
        bh[ni] = *(const s16x8*)&Bh[idx];
        bl[ni] = *(const s16x8*)&Bl[idx];
      }
      #pragma unroll
      for (int mi = 0; mi < 4; mi++)
        #pragma unroll
        for (int ni = 0; ni < 4; ni++){
          acc[mi][ni] = __builtin_amdgcn_mfma_f32_16x16x32_bf16(ah[mi], bh[ni], acc[mi][ni], 0, 0, 0);
          acc[mi][ni] = __builtin_amdgcn_mfma_f32_16x16x32_bf16(ah[mi], bl[ni], acc[mi][ni], 0, 0, 0);
          acc[mi][ni] = __builtin_amdgcn_mfma_f32_16x16x32_bf16(al[mi], bh[ni], acc[mi][ni], 0, 0, 0);
        }
    }
    __syncthreads();
  }
  #pragma unroll
  for (int mi = 0; mi < 4; mi++){
    #pragma unroll
    for (int r = 0; r < 4; r++){
      int o = wm * 64 + mi * 16 + l4 * 4 + r;
      float bias = bs[o];
      #pragma unroll
      for (int ni = 0; ni < 4; ni++){
        int n = nb + wn * 64 + ni * 16 + l15;
        float val = acc[mi][ni][r] + bias;
        if (o < 64) q[((size_t)(b * CQn + o)) * Nn + n]        = f2bf(val);
        else        k[((size_t)(b * CQn + o - 64)) * Nn + n]   = f2bf(val);
      }
    }
  }
}

// ============================ fused attention ============================

// per (b,w): MFMA e_h from qhw/khw ([b][w][h][c]), diag, stats, p->LDS, PV MFMA.
// ohX layout [b][c][w][h] (unnormalized; alpha in fuse).
__global__ __launch_bounds__(256) void k_att_h(const bf16* __restrict__ qhw,
                                               const bf16* __restrict__ khw,
                                               const bf16* __restrict__ vT,
                                               float* __restrict__ mh,
                                               float* __restrict__ sh,
                                               bf16* __restrict__ ohX){
  __shared__ char smem[65536];
  char* attb = smem;                 // p tile 32KB
  char* vbb  = smem + 32768;         // V tile 32KB (e-phase: first 2KB = stats)
  float* redm = (float*)(smem + 32768);        // [2][128]
  float* reds = redm + 256;                    // [2][128]
  int w = blockIdx.x, b = blockIdx.y;
  int t = threadIdx.x, lane = t & 63, wid = t >> 6;
  int wm = wid >> 1, wn = wid & 1;
  int l15 = lane & 15, l4 = lane >> 4;

  const bf16* qp = qhw + ((size_t)(b * Wn + w)) * (Hn * CQn);
  const bf16* kp = khw + ((size_t)(b * Wn + w)) * (Hn * CQn);
  f32x4 acc[4][4];
  #pragma unroll
  for (int i = 0; i < 4; i++)
    #pragma unroll
    for (int j = 0; j < 4; j++) acc[i][j] = (f32x4){0.f, 0.f, 0.f, 0.f};
  #pragma unroll
  for (int kk = 0; kk < 64; kk += 32){
    s16x8 a[4], bb[4];
    #pragma unroll
    for (int mi = 0; mi < 4; mi++)
      a[mi] = *(const s16x8*)(qp + (size_t)(wm * 64 + mi * 16 + l15) * CQn + kk + l4 * 8);
    #pragma unroll
    for (int ni = 0; ni < 4; ni++)
      bb[ni] = *(const s16x8*)(kp + (size_t)(wn * 64 + ni * 16 + l15) * CQn + kk + l4 * 8);
    #pragma unroll
    for (int mi = 0; mi < 4; mi++)
      #pragma unroll
      for (int ni = 0; ni < 4; ni++)
        acc[mi][ni] = __builtin_amdgcn_mfma_f32_16x16x32_bf16(a[mi], bb[ni], acc[mi][ni], 0, 0, 0);
  }
  // diag mask: h==g
  if (wm == wn){
    #pragma unroll
    for (int mi = 0; mi < 4; mi++)
      #pragma unroll
      for (int r = 0; r < 4; r++)
        if (l15 == l4 * 4 + r) acc[mi][mi][r] = -1e30f;
  }
  // row max (over g): reduce ni + shfl over l15, combine warps via LDS
  float rm[4][4];
  #pragma unroll
  for (int mi = 0; mi < 4; mi++)
    #pragma unroll
    for (int r = 0; r < 4; r++){
      float m = fmaxf(fmaxf(acc[mi][0][r], acc[mi][1][r]),
                      fmaxf(acc[mi][2][r], acc[mi][3][r]));
      m = fmaxf(m, __shfl_xor(m, 1));
      m = fmaxf(m, __shfl_xor(m, 2));
      m = fmaxf(m, __shfl_xor(m, 4));
      m = fmaxf(m, __shfl_xor(m, 8));
      rm[mi][r] = m;
    }
  if (l15 == 0){
    #pragma unroll
    for (int mi = 0; mi < 4; mi++)
      #pragma unroll
      for (int r = 0; r < 4; r++)
        redm[wn * 128 + wm * 64 + mi * 16 + l4 * 4 + r] = rm[mi][r];
  }
  __syncthreads();
  float rs[4][4];
  #pragma unroll
  for (int mi = 0; mi < 4; mi++)
    #pragma unroll
    for (int r = 0; r < 4; r++){
      int h = wm * 64 + mi * 16 + l4 * 4 + r;
      float m = fmaxf(redm[h], redm[128 + h]);
      rm[mi][r] = m;
      float s = 0.f;
      #pragma unroll
      for (int ni = 0; ni < 4; ni++){
        acc[mi][ni][r] = expf(acc[mi][ni][r] - m);
        s += acc[mi][ni][r];
      }
      s += __shfl_xor(s, 1);
      s += __shfl_xor(s, 2);
      s += __shfl_xor(s, 4);
      s += __shfl_xor(s, 8);
      rs[mi][r] = s;
    }
  if (l15 == 0){
    #pragma unroll
    for (int mi = 0; mi < 4; mi++)
      #pragma unroll
      for (int r = 0; r < 4; r++)
        reds[wn * 128 + wm * 64 + mi * 16 + l4 * 4 + r] = rs[mi][r];
  }
  __syncthreads();
  #pragma unroll
  for (int mi = 0; mi < 4; mi++)
    #pragma unroll
    for (int r = 0; r < 4; r++){
      int h = wm * 64 + mi * 16 + l4 * 4 + r;
      if (wn == 0 && l15 == 0){
        mh[(size_t)(b * Wn + w) * Hn + h] = rm[mi][r];
        sh[(size_t)(b * Wn + w) * Hn + h] = reds[h] + reds[128 + h];
      }
      #pragma unroll
      for (int ni = 0; ni < 4; ni++){
        int g = wn * 64 + ni * 16 + l15;
        bf16 bv = f2bf(acc[mi][ni][r]);
        int byte = (h * 256 + g * 2) ^ ((h & 7) << 4);
        *(unsigned short*)(attb + byte) = *(unsigned short*)&bv;
      }
    }
  __syncthreads();
  // PV MFMA over 4 c-tiles
  for (int cb = 0; cb < Cn; cb += 128){
    const bf16* vp = vT + ((size_t)(b * Wn + w) * Cn + cb) * Hn;
    for (int s = t; s < 2048; s += 256){
      int row = s >> 4, seg = s & 15;
      s16x8 d = *(const s16x8*)(vp + (size_t)row * Hn + seg * 8);
      int byte = (row * 256 + seg * 16) ^ ((row & 7) << 4);
      *(s16x8*)(vbb + byte) = d;
    }
    __syncthreads();
    f32x4 acc2[4][4];
    #pragma unroll
    for (int i = 0; i < 4; i++)
      #pragma unroll
      for (int j = 0; j < 4; j++) acc2[i][j] = (f32x4){0.f, 0.f, 0.f, 0.f};
    #pragma unroll
    for (int kk = 0; kk < 128; kk += 32){
      s16x8 a[4], bb[4];
      #pragma unroll
      for (int mi = 0; mi < 4; mi++){
        int row = wm * 64 + mi * 16 + l15;
        int byte = (row * 256 + (kk + l4 * 8) * 2) ^ ((row & 7) << 4);
        a[mi] = *(const s16x8*)(vbb + byte);
      }
      #pragma unroll
      for (int ni = 0; ni < 4; ni++){
        int row = wn * 64 + ni * 16 + l15;
        int byte = (row * 256 + (kk + l4 * 8) * 2) ^ ((row & 7) << 4);
        bb[ni] = *(const s16x8*)(attb + byte);
      }
      #pragma unroll
      for (int mi = 0; mi < 4; mi++)
        #pragma unroll
        for (int ni = 0; ni < 4; ni++)
          acc2[mi][ni] = __builtin_amdgcn_mfma_f32_16x16x32_bf16(a[mi], bb[ni], acc2[mi][ni], 0, 0, 0);
    }
    bf16* op = ohX + ((size_t)(b * Cn + cb)) * Nn + (size_t)w * Hn;
    #pragma unroll
    for (int mi = 0; mi < 4; mi++)
      #pragma unroll
      for (int r = 0; r < 4; r++){
        int cl = wm * 64 + mi * 16 + l4 * 4 + r;
        #pragma unroll
        for (int ni = 0; ni < 4; ni++){
          int h = wn * 64 + ni * 16 + l15;
          op[(size_t)cl * Nn + h] = f2bf(acc2[mi][ni][r]);
        }
      }
    __syncthreads();
  }
}

// per (b,h): MFMA e_w from qhw/khw (strided rows), stats, p->LDS, PV MFMA.
__global__ __launch_bounds__(256) void k_att_w(const bf16* __restrict__ qhw,
                                               const bf16* __restrict__ khw,
                                               const bf16* __restrict__ v,
                                               float* __restrict__ mw,
                                               float* __restrict__ sw,
                                               bf16* __restrict__ ow){
  __shared__ char smem[65536];
  char* attb = smem;
  char* vbb  = smem + 32768;
  float* redm = (float*)(smem + 32768);
  float* reds = redm + 256;
  int h = blockIdx.x, b = blockIdx.y;
  int t = threadIdx.x, lane = t & 63, wid = t >> 6;
  int wm = wid >> 1, wn = wid & 1;
  int l15 = lane & 15, l4 = lane >> 4;

  const bf16* qp = qhw + (size_t)b * Wn * Hn * CQn + (size_t)h * CQn;
  const bf16* kp = khw + (size_t)b * Wn * Hn * CQn + (size_t)h * CQn;
  f32x4 acc[4][4];
  #pragma unroll
  for (int i = 0; i < 4; i++)
    #pragma unroll
    for (int j = 0; j < 4; j++) acc[i][j] = (f32x4){0.f, 0.f, 0.f, 0.f};
  #pragma unroll
  for (int kk = 0; kk < 64; kk += 32){
    s16x8 a[4], bb[4];
    #pragma unroll
    for (int mi = 0; mi < 4; mi++)
      a[mi] = *(const s16x8*)(qp + (size_t)(wm * 64 + mi * 16 + l15) * (Hn * CQn) + kk + l4 * 8);
    #pragma unroll
    for (int ni = 0; ni < 4; ni++)
      bb[ni] = *(const s16x8*)(kp + (size_t)(wn * 64 + ni * 16 + l15) * (Hn * CQn) + kk + l4 * 8);
    #pragma unroll
    for (int mi = 0; mi < 4; mi++)
      #pragma unroll
      for (int ni = 0; ni < 4; ni++)
        acc[mi][ni] = __builtin_amdgcn_mfma_f32_16x16x32_bf16(a[mi], bb[ni], acc[mi][ni], 0, 0, 0);
  }
  float rm[4][4];
  #pragma unroll
  for (int mi = 0; mi < 4; mi++)
    #pragma unroll
    for (int r = 0; r < 4; r++){
      float m = fmaxf(fmaxf(acc[mi][0][r], acc[mi][1][r]),
                      fmaxf(acc[mi][2][r], acc[mi][3][r]));
      m = fmaxf(m, __shfl_xor(m, 1));
      m = fmaxf(m, __shfl_xor(m, 2));
      m = fmaxf(m, __shfl_xor(m, 4));
      m = fmaxf(m, __shfl_xor(m, 8));
      rm[mi][r] = m;
    }
  if (l15 == 0){
    #pragma unroll
    for (int mi = 0; mi < 4; mi++)
      #pragma unroll
      for (int r = 0; r < 4; r++)
        redm[wn * 128 + wm * 64 + mi * 16 + l4 * 4 + r] = rm[mi][r];
  }
  __syncthreads();
  float rs[4][4];
  #pragma unroll
  for (int mi = 0; mi < 4; mi++)
    #pragma unroll
    for (int r = 0; r < 4; r++){
      int wr = wm * 64 + mi * 16 + l4 * 4 + r;
      float m = fmaxf(redm[wr], redm[128 + wr]);
      rm[mi][r] = m;
      float s = 0.f;
      #pragma unroll
      for (int ni = 0; ni < 4; ni++){
        acc[mi][ni][r] = expf(acc[mi][ni][r] - m);
        s += acc[mi][ni][r];
      }
      s += __shfl_xor(s, 1);
      s += __shfl_xor(s, 2);
      s += __shfl_xor(s, 4);
      s += __shfl_xor(s, 8);
      rs[mi][r] = s;
    }
  if (l15 == 0){
    #pragma unroll
    for (int mi = 0; mi < 4; mi++)
      #pragma unroll
      for (int r = 0; r < 4; r++)
        reds[wn * 128 + wm * 64 + mi * 16 + l4 * 4 + r] = rs[mi][r];
  }
  __syncthreads();
  #pragma unroll
  for (int mi = 0; mi < 4; mi++)
    #pragma unroll
    for (int r = 0; r < 4; r++){
      int wr = wm * 64 + mi * 16 + l4 * 4 + r;
      if (wn == 0 && l15 == 0){
        mw[(size_t)(b * Hn + h) * Wn + wr] = rm[mi][r];
        sw[(size_t)(b * Hn + h) * Wn + wr] = reds[wr] + reds[128 + wr];
      }
      #pragma unroll
      for (int ni = 0; ni < 4; ni++){
        int g = wn * 64 + ni * 16 + l15;
        bf16 bv = f2bf(acc[mi][ni][r]);
        int byte = (wr * 256 + g * 2) ^ ((wr & 7) << 4);
        *(unsigned short*)(attb + byte) = *(unsigned short*)&bv;
      }
    }
  __syncthreads();
  for (int cb = 0; cb < Cn; cb += 128){
    const bf16* vp = v + (size_t)(b * Cn + cb) * Nn + (size_t)h * Wn;
    for (int s = t; s < 2048; s += 256){
      int row = s >> 4, seg = s & 15;
      s16x8 d = *(const s16x8*)(vp + (size_t)row * Nn + seg * 8);
      int byte = (row * 256 + seg * 16) ^ ((row & 7) << 4);
      *(s16x8*)(vbb + byte) = d;
    }
    __syncthreads();
    f32x4 acc2[4][4];
    #pragma unroll
    for (int i = 0; i < 4; i++)
      #pragma unroll
      for (int j = 0; j < 4; j++) acc2[i][j] = (f32x4){0.f, 0.f, 0.f, 0.f};
    #pragma unroll
    for (int kk = 0; kk < 128; kk += 32){
      s16x8 a[4], bb[4];
      #pragma unroll
      for (int mi = 0; mi < 4; mi++){
        int row = wm * 64 + mi * 16 + l15;
        int byte = (row * 256 + (kk + l4 * 8) * 2) ^ ((row & 7) << 4);
        a[mi] = *(const s16x8*)(vbb + byte);
      }
      #pragma unroll
      for (int ni = 0; ni < 4; ni++){
        int row = wn * 64 + ni * 16 + l15;
        int byte = (row * 256 + (kk + l4 * 8) * 2) ^ ((row & 7) << 4);
        bb[ni] = *(const s16x8*)(attb + byte);
      }
      #pragma unroll
      for (int mi = 0; mi < 4; mi++)
        #pragma unroll
        for (int ni = 0; ni < 4; ni++)
          acc2[mi][ni] = __builtin_amdgcn_mfma_f32_16x16x32_bf16(a[mi], bb[ni], acc2[mi][ni], 0, 0, 0);
    }
    bf16* op = ow + (size_t)(b * Cn + cb) * Nn + (size_t)h * Wn;
    #pragma unroll
    for (int mi = 0; mi < 4; mi++)
      #pragma unroll
      for (int r = 0; r < 4; r++){
        int cl = wm * 64 + mi * 16 + l4 * 4 + r;
        #pragma unroll
        for (int ni = 0; ni < 4; ni++){
          int wr = wn * 64 + ni * 16 + l15;
          op[(size_t)cl * Nn + wr] = f2bf(acc2[mi][ni][r]);
        }
      }
    __syncthreads();
  }
}

// merge stats -> alphas, both in [b,h,w] layout for fuse
__global__ __launch_bounds__(256) void k_alpha(const float* __restrict__ mh,
                                               const float* __restrict__ sh,
                                               const float* __restrict__ mw,
                                               const float* __restrict__ sw,
                                               float* __restrict__ ahT,
                                               float* __restrict__ aw){
  int t = blockIdx.x * 256 + threadIdx.x;   // (b*Hn+h)*Wn + w
  int b = t >> 14;
  int hw = t & (Nn - 1);
  int h = hw >> 7, w = hw & 127;
  size_t ih = (size_t)(b * Wn + w) * Hn + h;
  size_t iw = t;
  float mhv = mh[ih], mwv = mw[iw];
  float M = fmaxf(mhv, mwv);
  float eh_ = expf(mhv - M), ew_ = expf(mwv - M);
  float inv = 1.f / (sh[ih] * eh_ + sw[iw] * ew_);
  ahT[t] = eh_ * inv;
  aw[t]  = ew_ * inv;
}

// ============================ remaining CA kernels ============================

__global__ __launch_bounds__(256) void k_trans(const bf16* __restrict__ in,
                                               bf16* __restrict__ out,
                                               int CH){
  __shared__ bf16 tile[32][33];
  int tl = blockIdx.x, c = blockIdx.y, b = blockIdx.z;
  int th = tl >> 2, tw = tl & 3;
  int h0 = th * 32, w0 = tw * 32;
  int t = threadIdx.x;
  const bf16* ip = in + ((size_t)(b * CH + c)) * Nn;
  #pragma unroll
  for (int kk = 0; kk < 4; ++kk){
    int idx = t + kk * 256;
    int hl = idx >> 5, wl = idx & 31;
    tile[hl][wl] = ip[(h0 + hl) * Wn + w0 + wl];
  }
  __syncthreads();
  #pragma unroll
  for (int kk = 0; kk < 4; ++kk){
    int idx = t + kk * 256;
    int wl = idx >> 5, hl = idx & 31;
    out[((size_t)(b * Wn + w0 + wl) * CH + c) * Hn + h0 + hl] = tile[hl][wl];
  }
}

// out = gamma*(ah*ohX^T + aw*ow) + resid (+ addend)
__global__ __launch_bounds__(256) void k_fuse2(const float* __restrict__ in,
                                               const float* __restrict__ maskc,
                                               const float* __restrict__ maskn,
                                               const bf16* __restrict__ ohX,
                                               const bf16* __restrict__ ow,
                                               const float* __restrict__ ahT,
                                               const float* __restrict__ aw,
                                               const float* __restrict__ addend,
                                               const float* __restrict__ gamma,
                                               float* __restrict__ out){
  __shared__ unsigned short tileT[128][138];
  int c = blockIdx.x, b = blockIdx.y;
  int t = threadIdx.x;
  float g = gamma[0];
  float mc = maskc ? maskc[b * Cn + c] : 1.f;
  const bf16* ohp = ohX + ((size_t)(b * Cn + c)) * Nn;   // contiguous [w][h]
  #pragma unroll
  for (int i = 0; i < 8; ++i){
    int s = t + i * 256;            // 0..2047
    int w = s >> 4, seg = s & 15;
    s16x8 d = *(const s16x8*)(ohp + (size_t)s * 8);
    #pragma unroll
    for (int j = 0; j < 8; ++j)
      tileT[seg * 8 + j][w] = (unsigned short)d[j];
  }
  __syncthreads();
  size_t base = ((size_t)(b * Cn + c)) * Nn;
  #pragma unroll
  for (int i = 0; i < 16; ++i){
    int o = t + i * 256;            // 0..4095
    int h = o >> 5, w4 = (o & 31) * 4;
    size_t idx = base + (size_t)h * Wn + w4;
    size_t aidx = (size_t)b * Nn + (size_t)h * Wn + w4;
    float4 inv = *(const float4*)(in + idx);
    ushort4 owv = *(const ushort4*)((const unsigned short*)ow + idx);
    float4 ah4 = *(const float4*)(ahT + aidx);
    float4 aw4 = *(const float4*)(aw + aidx);
    float4 mn4 = maskn ? *(const float4*)(maskn + aidx) : (float4){1.f,1.f,1.f,1.f};
    float r[4];
    #pragma unroll
    for (int j = 0; j < 4; ++j){
      unsigned short uh = tileT[h][w4 + j];
      unsigned short uo = ((const unsigned short*)&owv)[j];
      float ohv = bf2f(*(bf16*)&uh);
      float owf = bf2f(*(bf16*)&uo);
      float iv  = ((const float*)&inv)[j] * mc * ((const float*)&mn4)[j];
      float ahv = ((const float*)&ah4)[j];
      float awv = ((const float*)&aw4)[j];
      r[j] = g * (ahv * ohv + awv * owf) + iv;
    }
    if (addend){
      float4 av = *(const float4*)(addend + idx);
      r[0] += av.x; r[1] += av.y; r[2] += av.z; r[3] += av.w;
    }
    float4 o4 = { r[0], r[1], r[2], r[3] };
    *(float4*)(out + idx) = o4;
  }
}

// ============================ host ============================

static void run_ca(const float* resid, const float* maskc, const float* maskn,
                   const bf16* wqk_hi, const bf16* wqk_lo,
                   const float* bqk, const bf16* wvb, const float* bv,
                   const float* gamma, const float* addend, float* out,
                   bf16* q, bf16* k, bf16* qhw, bf16* khw, bf16* v, bf16* vT,
                   float* mh, float* sh, float* mw, float* sw, float* ahT, float* aw,
                   bf16* xT_hi, bf16* xT_lo, bf16* tmp, hipStream_t stream){
  bf16* ohX = tmp;
  bf16* ow  = tmp + (size_t)Bn * Cn * Nn;
  k_qk_mfma<<<dim3(Nn / 128, Bn), 256, 0, stream>>>(xT_hi, xT_lo, wqk_hi, wqk_lo, bqk, q, k);
  k_trans4<<<dim3(Wn / 32, Hn, Bn), 256, 0, stream>>>(q, qhw);
  k_trans4<<<dim3(Wn / 32, Hn, Bn), 256, 0, stream>>>(k, khw);
  k_v_mfma<<<2048, 256, 0, stream>>>(xT_hi, wvb, bv, v);
  k_trans<<<dim3(16, Cn, Bn), 256, 0, stream>>>(v, vT, Cn);
  k_att_h<<<dim3(Wn, Bn), 256, 0, stream>>>(qhw, khw, vT, mh, sh, ohX);
  k_att_w<<<dim3(Hn, Bn), 256, 0, stream>>>(qhw, khw, v, mw, sw, ow);
  k_alpha<<<Bn * Nn / 256, 256, 0, stream>>>(mh, sh, mw, sw, ahT, aw);
  k_fuse2<<<dim3(Cn, Bn), 256, 0, stream>>>(resid, maskc, maskn, ohX, ow, ahT, aw,
                                            addend, gamma, out);
}

extern "C" void kernel_launch(void* const* d_in, const int* in_sizes, int n_in,
                              void* d_out, int out_size, void* d_ws, size_t ws_size,
                              hipStream_t stream){
  (void)in_sizes; (void)n_in; (void)out_size; (void)ws_size;
  const float* x         = (const float*)d_in[0];
  const float* w_q_right = (const float*)d_in[1];
  const float* w_v_right = (const float*)d_in[2];
  const float* w_up      = (const float*)d_in[3];
  const float* b_up      = (const float*)d_in[4];
  const float* w_q_left  = (const float*)d_in[5];
  const float* w_v_left  = (const float*)d_in[6];
  const float* wq        = (const float*)d_in[7];
  const float* bq        = (const float*)d_in[8];
  const float* wk        = (const float*)d_in[9];
  const float* bk        = (const float*)d_in[10];
  const float* wv        = (const float*)d_in[11];
  const float* bv        = (const float*)d_in[12];
  const float* gamma     = (const float*)d_in[13];

  const size_t SZ_MAP = (size_t)Bn * Cn * Nn;     // 33.5M elements
  char* p = (char*)d_ws;
  float* buf0   = (float*)p; p += SZ_MAP * 4;
  float* buf1   = (float*)p; p += SZ_MAP * 4;     // CA3 tmp (ohX/ow)
  bf16*  vbuf   = (bf16*)p;  p += SZ_MAP * 2;
  bf16*  vT     = (bf16*)p;  p += SZ_MAP * 2;
  bf16*  qbuf   = (bf16*)p;  p += (size_t)Bn * CQn * Nn * 2;
  bf16*  kbuf   = (bf16*)p;  p += (size_t)Bn * CQn * Nn * 2;
  bf16*  qhw    = (bf16*)p;  p += (size_t)Bn * CQn * Nn * 2;
  bf16*  khw    = (bf16*)p;  p += (size_t)Bn * CQn * Nn * 2;
  float* ebuf   = (float*)p; p += (size_t)SZ_MAP * 2;         // xT_hi arena (67MB)
  float* logits = (float*)p; p += (size_t)Bn * Nn * 4;
  float* ctxlog = (float*)p; p += (size_t)Bn * Nn * 4;
  float* msp    = (float*)p; p += (size_t)Bn * Nn * 4;
  float* xbar   = (float*)p; p += Bn * Cn * 4;
  float* wgt    = (float*)p; p += Bn * Cn * 4;
  float* u      = (float*)p; p += Bn * Cn * 4;
  float* mch    = (float*)p; p += Bn * Cn * 4;
  float* avg    = (float*)p; p += Bn * CIn * 4;
  float* ctx    = (float*)p; p += Bn * CIn * 4;
  float* stats_sp = (float*)p; p += 64;
  float* stats_ch = (float*)p; p += 64;
  bf16*  wvb    = (bf16*)p;  p += (size_t)Cn * Cn * 2;
  bf16*  wqk_hi = (bf16*)p;  p += (size_t)128 * Cn * 2;
  bf16*  wqk_lo = (bf16*)p;  p += (size_t)128 * Cn * 2;
  float* bqk    = (float*)p; p += 128 * 4;
  float* mh     = (float*)p; p += (size_t)Bn * Nn * 4;
  float* sh     = (float*)p; p += (size_t)Bn * Nn * 4;
  float* mw     = (float*)p; p += (size_t)Bn * Nn * 4;
  float* sw     = (float*)p; p += (size_t)Bn * Nn * 4;
  float* ahT    = (float*)p; p += (size_t)Bn * Nn * 4;
  float* aw     = (float*)p; p += (size_t)Bn * Nn * 4;

  bf16*  xT_hi  = (bf16*)ebuf;    // dead after v_mfma of each CA
  bf16*  xT_lo  = (bf16*)d_out;   // dead before attention writes d_out (CA1/CA2 tmp)

  // ---- weight prep (once) ----
  k_cvt_w<<<(Cn * Cn + 255) / 256, 256, 0, stream>>>(wv, wvb, Cn * Cn);
  k_prep_wqk<<<(128 * Cn) / 256, 256, 0, stream>>>(wq, wk, bq, bk, wqk_hi, wqk_lo, bqk);

  // ---- stage 0: gating masks ----
  k_dotc<<<Bn * Nn / 256, 256, 0, stream>>>(x, w_q_right, 0, logits);
  k_rowmean<<<Bn * Cn, 256, 0, stream>>>(x, xbar, 1.f / Nn);
  k_rowdot<<<Bn, 256, 0, stream>>>(w_q_left, xbar, avg);
  k_coldot<<<dim3(Cn / 256, Bn), 256, 0, stream>>>(w_v_left, avg, u);
  k_stats<<<Bn, 1024, 0, stream>>>(logits, stats_sp);
  k_weighted<<<Bn * Cn, 256, 0, stream>>>(x, logits, stats_sp, wgt);
  k_rowdot<<<Bn, 256, 0, stream>>>(w_v_right, wgt, ctx);
  k_mch2<<<dim3(Cn / 256, Bn), 256, 0, stream>>>(w_up, b_up, ctx, mch);
  k_dotc<<<Bn * Nn / 256, 256, 0, stream>>>(x, u, Cn, ctxlog);
  k_stats<<<Bn, 1024, 0, stream>>>(ctxlog, stats_ch);
  k_msp<<<Bn * Nn / 256, 256, 0, stream>>>(ctxlog, stats_ch, msp);

  // ---- CA1: in = cc = x*mch (recomputed in fuse); out = buf0; tmp = d_out ----
  k_applyT2<<<dim3(Nn / 32, Cn / 32, Bn), 256, 0, stream>>>(x, mch, xT_hi, xT_lo);
  run_ca(x, mch, nullptr, wqk_hi, wqk_lo, bqk, wvb, bv, gamma, nullptr, buf0,
         qbuf, kbuf, qhw, khw, vbuf, vT, mh, sh, mw, sw, ahT, aw,
         xT_hi, xT_lo, (bf16*)d_out, stream);
  // ---- CA2: in = cs = x*msp; addend = buf0 (cc'); out = buf0; tmp = d_out ----
  k_cvt_T2<<<dim3(Nn / 32, Cn / 32, Bn), 256, 0, stream>>>(x, msp, xT_hi, xT_lo);
  run_ca(x, nullptr, msp, wqk_hi, wqk_lo, bqk, wvb, bv, gamma, buf0, buf0,
         qbuf, kbuf, qhw, khw, vbuf, vT, mh, sh, mw, sw, ahT, aw,
         xT_hi, xT_lo, (bf16*)d_out, stream);
  // ---- CA3: in = s = buf0; out = d_out; tmp = buf1 ----
  k_cvt_T<<<dim3(Nn / 32, Cn / 32, Bn), 256, 0, stream>>>(buf0, xT_hi, xT_lo);
  run_ca(buf0, nullptr, nullptr, wqk_hi, wqk_lo, bqk, wvb, bv, gamma, nullptr,
         (float*)d_out,
         qbuf, kbuf, qhw, khw, vbuf, vT, mh, sh, mw, sw, ahT, aw,
         xT_hi, xT_lo, (bf16*)buf1, stream);
}